// Round 5
// baseline (4864.016 us; speedup 1.0000x reference)
//
#include <hip/hip_runtime.h>
#include <hip/hip_bf16.h>
#include <cfloat>
#include <math.h>

typedef __hip_bfloat16 bf16;

constexpr int B_ = 2, T_ = 24, N_ = 1500, E_ = 2000, M_ = 4000, G_ = 48;

__device__ __forceinline__ float b2f(bf16 v) { return __bfloat162float(v); }
__device__ __forceinline__ bf16 f2b(float v) { return __float2bfloat16(v); }
static inline int ceilDiv(int a, int b) { return (a + b - 1) / b; }

// ---------------- diagnostics ----------------
__global__ __launch_bounds__(256) void k_sentinel(float* __restrict__ out, int n, float val) {
  int i = blockIdx.x * 256 + threadIdx.x;
  if (i < n) out[i] = val;
}

__global__ __launch_bounds__(256) void k_chk_bf16(const bf16* __restrict__ b, size_t n, int stage,
                                                  int* __restrict__ flag) {
  size_t i = (size_t)blockIdx.x * 256 + threadIdx.x;
  size_t st = (size_t)gridDim.x * 256;
  int bad = 0;
  for (; i < n; i += st) {
    float f = b2f(b[i]);
    if (!isfinite(f) || fabsf(f) > 1e8f) { bad = 1; break; }
  }
  if (bad) atomicCAS(flag, 0, stage);
}

__global__ __launch_bounds__(256) void k_chk_f32(const float* __restrict__ b, size_t n, int stage,
                                                 int* __restrict__ flag) {
  size_t i = (size_t)blockIdx.x * 256 + threadIdx.x;
  size_t st = (size_t)gridDim.x * 256;
  int bad = 0;
  for (; i < n; i += st) {
    float f = b[i];
    if (!isfinite(f) || fabsf(f) > 1e8f) { bad = 1; break; }
  }
  if (bad) atomicCAS(flag, 0, stage);
}

__global__ __launch_bounds__(256) void k_chk_int(const int* __restrict__ b, size_t n, int lo, int hi,
                                                 int stage, int* __restrict__ flag) {
  size_t i = (size_t)blockIdx.x * 256 + threadIdx.x;
  size_t st = (size_t)gridDim.x * 256;
  int bad = 0;
  for (; i < n; i += st) {
    int v = b[i];
    if (v < lo || v >= hi) { bad = 1; break; }
  }
  if (bad) atomicCAS(flag, 0, stage);
}

__global__ __launch_bounds__(256) void k_flagout(const int* __restrict__ flag, float* __restrict__ out, int n) {
  int f = *flag;
  if (f == 0) return;
  int i = blockIdx.x * 256 + threadIdx.x;
  if (i < n) out[i] = 100.f + (float)f;
}

// ---------------- encoders: out = relu(in@W+b) bf16; optional pre-relu last-t save (f32) ----
template <int DIN, int DOUT, bool SAVE>
__global__ __launch_bounds__(256) void k_enc(const float* __restrict__ in, const float* __restrict__ W,
                                             const float* __restrict__ bias, bf16* __restrict__ out,
                                             float* __restrict__ last, int nodes) {
  int idx = blockIdx.x * 256 + threadIdx.x;
  if (idx >= G_ * nodes * DOUT) return;
  int d = idx % DOUT;
  int row = idx / DOUT;
  int node = row % nodes;
  int g = row / nodes;
  const float* ir = in + (size_t)row * DIN;
  float acc = bias[d];
#pragma unroll
  for (int i = 0; i < DIN; i++) acc += ir[i] * W[i * DOUT + d];
  if (SAVE) {
    if (g % T_ == T_ - 1) last[((size_t)(g / T_) * nodes + node) * DOUT + d] = acc;  // pre-relu
  }
  out[idx] = f2b(fmaxf(acc, 0.f));
}

// ---------------- NodeEdge linear: relu(act @ W(64x32) + b) -> outT[node][g*32+f] bf16 ----
__global__ __launch_bounds__(256) void k_lin_ne(const bf16* __restrict__ act, const float* __restrict__ W,
                                                const float* __restrict__ bias, bf16* __restrict__ outT,
                                                int nodes) {
  __shared__ float Ws[2048];
  __shared__ float bs[32];
  for (int i = threadIdx.x; i < 2048; i += 256) Ws[i] = W[i];
  if (threadIdx.x < 32) bs[threadIdx.x] = bias[threadIdx.x];
  __syncthreads();
  int idx = blockIdx.x * 256 + threadIdx.x;
  if (idx >= nodes * G_ * 32) return;
  int f = idx & 31;
  int rem = idx >> 5;
  int g = rem % G_;
  int node = rem / G_;
  const bf16* row = act + ((size_t)g * nodes + node) * 64;
  float acc = bs[f];
#pragma unroll
  for (int i = 0; i < 64; i++) acc += b2f(row[i]) * Ws[i * 32 + f];
  outT[idx] = f2b(fmaxf(acc, 0.f));
}

// ---------------- masked incidence: mat[n*E+e] = |inci|*w + p (bf16) ----------------
__global__ __launch_bounds__(256) void k_mat(const float* __restrict__ w, const float* __restrict__ p,
                                             const float* __restrict__ inci, bf16* __restrict__ mat,
                                             int total) {
  int i = blockIdx.x * 256 + threadIdx.x;
  if (i < total) mat[i] = f2b(w[i] * fabsf(inci[i]) + p[i]);
}

// transposed variant: mat[e*N+n] = |inci[n*E+e]|*w[e*N+n] + p[e*N+n]
__global__ void k_matT(const float* __restrict__ w, const float* __restrict__ p,
                       const float* __restrict__ inci, bf16* __restrict__ mat) {
  __shared__ float tl[32][33];
  int e0 = blockIdx.x * 32, n0 = blockIdx.y * 32;
  for (int r = threadIdx.y; r < 32; r += 8) {
    int n = n0 + r, e = e0 + threadIdx.x;
    tl[r][threadIdx.x] = (n < N_ && e < E_) ? fabsf(inci[(size_t)n * E_ + e]) : 0.f;
  }
  __syncthreads();
  for (int r = threadIdx.y; r < 32; r += 8) {
    int e = e0 + r, n = n0 + threadIdx.x;
    if (e < E_ && n < N_) {
      size_t o = (size_t)e * N_ + n;
      mat[o] = f2b(tl[threadIdx.x][r] * w[o] + p[o]);
    }
  }
}

// ---------------- unified tiled GEMM: C[M,N] = A(bf16) @ B [+bias][relu] ----------------
// AMODE 0: A = bf16 [Mm][Kk] at A0.
// AMODE 1: k<64 -> A0[row*64+k]; k>=64 -> A1[(node*G+g)*32+k-64], row=g*nodes+node. (GAT concat)
// AMODE 2: k<64 -> A0[row*64+k]; k>=64 -> A1[row*32+k-64].                         (conc concat)
// B dtype: BF16B ? bf16 : float. In-place C==A0 safe when gridDim.x==1.
template <int AMODE, bool BF16B, bool CF32>
__global__ __launch_bounds__(256) void k_gemm(const bf16* __restrict__ A0, const bf16* __restrict__ A1,
                                              const void* __restrict__ Bv, void* __restrict__ Cp,
                                              int Mm, int Kk, int Nn, int nodes,
                                              const float* __restrict__ bias, int relu) {
  __shared__ float As[64][17];
  __shared__ float Bs[16][64];
  int tx = threadIdx.x & 15;
  int ty = threadIdx.x >> 4;
  int bm = blockIdx.y * 64, bn = blockIdx.x * 64;
  float acc[4][4] = {};
  for (int k0 = 0; k0 < Kk; k0 += 16) {
    for (int i = threadIdx.x; i < 1024; i += 256) {
      int m = i >> 4, k = i & 15;
      int gm = bm + m, gk = k0 + k;
      float v = 0.f;
      if (gm < Mm && gk < Kk) {
        if (AMODE == 0) v = b2f(A0[(size_t)gm * Kk + gk]);
        else if (gk < 64) v = b2f(A0[(size_t)gm * 64 + gk]);
        else if (AMODE == 1) {
          int g = gm / nodes, nd = gm % nodes;
          v = b2f(A1[((size_t)nd * G_ + g) * 32 + (gk - 64)]);
        } else {
          v = b2f(A1[(size_t)gm * 32 + (gk - 64)]);
        }
      }
      As[m][k] = v;
    }
    for (int i = threadIdx.x; i < 1024; i += 256) {
      int k = i >> 6, n = i & 63;
      int gk = k0 + k, gn = bn + n;
      float v = 0.f;
      if (gk < Kk && gn < Nn) {
        if (BF16B) v = b2f(((const bf16*)Bv)[(size_t)gk * Nn + gn]);
        else v = ((const float*)Bv)[(size_t)gk * Nn + gn];
      }
      Bs[k][n] = v;
    }
    __syncthreads();
#pragma unroll
    for (int k = 0; k < 16; k++) {
      float4 b4 = *reinterpret_cast<const float4*>(&Bs[k][tx * 4]);
      float a0 = As[ty * 4 + 0][k], a1 = As[ty * 4 + 1][k], a2 = As[ty * 4 + 2][k], a3 = As[ty * 4 + 3][k];
      acc[0][0] += a0 * b4.x; acc[0][1] += a0 * b4.y; acc[0][2] += a0 * b4.z; acc[0][3] += a0 * b4.w;
      acc[1][0] += a1 * b4.x; acc[1][1] += a1 * b4.y; acc[1][2] += a1 * b4.z; acc[1][3] += a1 * b4.w;
      acc[2][0] += a2 * b4.x; acc[2][1] += a2 * b4.y; acc[2][2] += a2 * b4.z; acc[2][3] += a2 * b4.w;
      acc[3][0] += a3 * b4.x; acc[3][1] += a3 * b4.y; acc[3][2] += a3 * b4.z; acc[3][3] += a3 * b4.w;
    }
    __syncthreads();
  }
  for (int i = 0; i < 4; i++) {
    int gm = bm + ty * 4 + i;
    if (gm >= Mm) continue;
    for (int j = 0; j < 4; j++) {
      int gn = bn + tx * 4 + j;
      if (gn >= Nn) continue;
      float v = acc[i][j];
      if (bias) v += bias[gn];
      if (relu) v = fmaxf(v, 0.f);
      if (CF32) ((float*)Cp)[(size_t)gm * Nn + gn] = v;
      else ((bf16*)Cp)[(size_t)gm * Nn + gn] = f2b(v);
    }
  }
}

// ---------------- es/ed = z . a_s , z . a_d (wave per row) ----------------
__global__ __launch_bounds__(256) void k_esed(const bf16* __restrict__ z, const float* __restrict__ as_,
                                              const float* __restrict__ ad_, float* __restrict__ es,
                                              float* __restrict__ ed, int rows) {
  int wid = threadIdx.x >> 6, lane = threadIdx.x & 63;
  int row = blockIdx.x * 4 + wid;
  if (row >= rows) return;
  float zv = b2f(z[(size_t)row * 64 + lane]);
  float vs = zv * as_[lane];
  float vd = zv * ad_[lane];
#pragma unroll
  for (int off = 32; off; off >>= 1) { vs += __shfl_down(vs, off); vd += __shfl_down(vd, off); }
  if (lane == 0) { es[row] = vs; ed[row] = vd; }
}

// ---------------- GAT softmax-aggregation (CSR gather), writes relu(out+bias) bf16 ----------
__global__ __launch_bounds__(256) void k_gat_aggr(const bf16* __restrict__ z, const float* __restrict__ es,
                                                  const float* __restrict__ ed, const int* __restrict__ off,
                                                  const int* __restrict__ adj, const float* __restrict__ bias,
                                                  bf16* __restrict__ out, int nodes) {
  int wid = threadIdx.x >> 6, lane = threadIdx.x & 63;
  int idx = blockIdx.x * 4 + wid;
  if (idx >= G_ * nodes) return;
  int g = idx / nodes, node = idx % nodes;
  int s0 = off[node], s1 = off[node + 1];
  const float* esg = es + (size_t)g * nodes;
  float edval = ed[(size_t)g * nodes + node];
  float m = -FLT_MAX;
  for (int s = s0; s < s1; s++) {
    float a = esg[adj[s]] + edval;
    a = (a >= 0.f) ? a : 0.2f * a;
    m = fmaxf(m, a);
  }
  const bf16* zg = z + (size_t)g * nodes * 64;
  float den = 0.f, num = 0.f;
  for (int s = s0; s < s1; s++) {
    int src = adj[s];
    float a = esg[src] + edval;
    a = (a >= 0.f) ? a : 0.2f * a;
    float ex = expf(a - m);
    den += ex;
    num += ex * b2f(zg[(size_t)src * 64 + lane]);
  }
  float r = (s1 > s0) ? (num / den) : 0.f;
  out[(size_t)idx * 64 + lane] = f2b(fmaxf(r + bias[lane], 0.f));
}

// ---------------- CSR build ----------------
__global__ __launch_bounds__(256) void k_csr_count(const int* __restrict__ ind, int ner, int nn,
                                                   int* __restrict__ cnt, int* __restrict__ srcA,
                                                   int* __restrict__ dstA) {
  int i = blockIdx.x * 256 + threadIdx.x;
  int tot = ner + nn;
  if (i >= tot) return;
  int s_, d_;
  if (i < ner) { s_ = ind[i]; d_ = ind[ner + i]; }
  else { s_ = d_ = i - ner; }
  srcA[i] = s_; dstA[i] = d_;
  if (d_ >= 0 && d_ < nn) atomicAdd(&cnt[d_], 1);
}

__global__ __launch_bounds__(1024) void k_scan(const int* __restrict__ cnt, int* __restrict__ off, int n) {
  __shared__ int a[1024];
  int t = threadIdx.x;
  int c0 = (2 * t < n) ? cnt[2 * t] : 0;
  int c1 = (2 * t + 1 < n) ? cnt[2 * t + 1] : 0;
  a[t] = c0 + c1;
  __syncthreads();
  for (int d = 1; d < 1024; d <<= 1) {
    int u = (t >= d) ? a[t - d] : 0;
    __syncthreads();
    a[t] += u;
    __syncthreads();
  }
  int excl = (t > 0) ? a[t - 1] : 0;
  if (2 * t < n) off[2 * t] = excl;
  if (2 * t + 1 < n) off[2 * t + 1] = excl + c0;
  if (t == 0) off[n] = a[1023];
}

__global__ __launch_bounds__(256) void k_csr_fill(const int* __restrict__ srcA, const int* __restrict__ dstA,
                                                  const int* __restrict__ off, int* __restrict__ cur,
                                                  int* __restrict__ adj, int tot, int nn) {
  int i = blockIdx.x * 256 + threadIdx.x;
  if (i >= tot) return;
  int d_ = dstA[i];
  if (d_ < 0 || d_ >= nn) return;
  int pos = atomicAdd(&cur[d_], 1);
  adj[off[d_] + pos] = srcA[i];
}

// ---------------- (b,t,node,d) -> (row, d, t) and back (bf16) ----------------
__global__ __launch_bounds__(256) void k_to_time(const bf16* __restrict__ x, const bf16* __restrict__ e,
                                                 bf16* __restrict__ h) {
  __shared__ float tl[64 * 25];
  int r = blockIdx.x;
  const bf16* src; int nodes, b, node;
  if (r < B_ * N_) { b = r / N_; node = r % N_; src = x; nodes = N_; }
  else { int rr = r - B_ * N_; b = rr / E_; node = rr % E_; src = e; nodes = E_; }
  for (int i = threadIdx.x; i < 1536; i += 256) {
    int tt = i >> 6, d = i & 63;
    tl[d * 25 + tt] = b2f(src[((size_t)(b * T_ + tt) * nodes + node) * 64 + d]);
  }
  __syncthreads();
  bf16* dst = h + (size_t)r * 1536;
  for (int i = threadIdx.x; i < 1536; i += 256) {
    int d = i / 24, tt = i % 24;
    dst[i] = f2b(tl[d * 25 + tt]);
  }
}

__global__ __launch_bounds__(256) void k_from_time(const bf16* __restrict__ h, bf16* __restrict__ x,
                                                   bf16* __restrict__ e) {
  __shared__ float tl[64 * 25];
  int r = blockIdx.x;
  const bf16* src = h + (size_t)r * 1536;
  for (int i = threadIdx.x; i < 1536; i += 256) {
    int d = i / 24, tt = i % 24;
    tl[d * 25 + tt] = b2f(src[i]);
  }
  __syncthreads();
  bf16* dstp; int nodes, b, node;
  if (r < B_ * N_) { b = r / N_; node = r % N_; dstp = x; nodes = N_; }
  else { int rr = r - B_ * N_; b = rr / E_; node = rr % E_; dstp = e; nodes = E_; }
  for (int i = threadIdx.x; i < 1536; i += 256) {
    int tt = i >> 6, d = i & 63;
    dstp[((size_t)(b * T_ + tt) * nodes + node) * 64 + d] = f2b(tl[d * 25 + tt]);
  }
}

// ---------------- conv weight transpose: [o][i][k] f32 -> [(i*3+k)*64+o] f32 ----------------
__global__ __launch_bounds__(256) void k_wtrans(const float* __restrict__ W, float* __restrict__ out) {
  int i = blockIdx.x * 256 + threadIdx.x;
  if (i >= 12288) return;
  int o = i & 63;
  int rest = i >> 6;
  int k = rest % 3, ii = rest / 3;
  out[i] = W[(o * 64 + ii) * 3 + k];
}

// ---------------- causal dilated conv (in-place per row), relu, bf16 io ----------------
template <int DIL>
__global__ __launch_bounds__(128) void k_conv(bf16* __restrict__ h, const float* __restrict__ Wt,
                                              const float* __restrict__ bias, int Rtot) {
  __shared__ float Ws[12288];
  __shared__ float hin[2][1536];
  __shared__ float bs[64];
  for (int i = threadIdx.x; i < 12288; i += 128) Ws[i] = Wt[i];
  if (threadIdx.x < 64) bs[threadIdx.x] = bias[threadIdx.x];
  int r0 = blockIdx.x * 2;
  for (int i = threadIdx.x; i < 2 * 1536; i += 128) {
    int rr = i / 1536, j = i % 1536;
    int r = r0 + rr;
    hin[rr][j] = (r < Rtot) ? b2f(h[(size_t)r * 1536 + j]) : 0.f;
  }
  __syncthreads();
  int rr = threadIdx.x >> 6;
  int o = threadIdx.x & 63;
  int r = r0 + rr;
  if (r >= Rtot) return;
  float acc[24];
#pragma unroll
  for (int t = 0; t < 24; t++) acc[t] = bs[o];
  for (int ii = 0; ii < 64; ii++) {
    const float* hr = &hin[rr][ii * 24];
#pragma unroll
    for (int k = 0; k < 3; k++) {
      float w = Ws[(ii * 3 + k) * 64 + o];
      const int sh = (k - 2) * DIL;
#pragma unroll
      for (int t = 0; t < 24; t++) {
        int tap = t + sh;
        if (tap >= 0) acc[t] += w * hr[tap];
      }
    }
  }
  bf16* dst = h + (size_t)r * 1536 + o * 24;
#pragma unroll
  for (int t = 0; t < 24; t++) dst[t] = f2b(fmaxf(acc[t], 0.f));
}

// ---------------- per-batch: cumsum + residual + relu + head (wave per node) ----------------
template <bool XB>
__global__ __launch_bounds__(256) void k_out(const float* __restrict__ yx, const float* __restrict__ last,
                                             const float* __restrict__ oW, const float* __restrict__ ob_,
                                             float* __restrict__ dout, int nodes) {
  int wid = threadIdx.x >> 6, lane = threadIdx.x & 63;
  int node = blockIdx.x * 4 + wid;
  if (node >= nodes) return;
  float lw = oW[lane];
  float ob = ob_[0];
  float lv = last[(size_t)node * 64 + lane];
  float acc = 0.f;
  for (int tt = 0; tt < T_; tt++) {
    acc += yx[((size_t)tt * nodes + node) * 64 + lane];
    float v = fmaxf(acc + lv, 0.f);
    float p = v * lw;
#pragma unroll
    for (int o2 = 32; o2; o2 >>= 1) p += __shfl_down(p, o2);
    if (lane == 0) {
      float o = p + ob;
      if (XB) o = fminf(fmaxf(o / 6.f + 0.5f, 0.f), 1.f);
      else o = tanhf(o);
      dout[(size_t)tt * nodes + node] = o;
    }
  }
}

// ===================================================================================
extern "C" void kernel_launch(void* const* d_in, const int* in_sizes, int n_in,
                              void* d_out, int out_size, void* d_ws, size_t ws_size,
                              hipStream_t stream) {
  float* dout = (float*)d_out;

  // ---- host-side layout asserts ----
  if (n_in != 57) {
    k_sentinel<<<ceilDiv(out_size, 256), 256, 0, stream>>>(dout, out_size, 20000.f + 128.f * n_in);
    return;
  }
  static const int expSz[57] = {
      288000, 288000, 288000, 288000,
      256, 64, 192, 64, 128, 32, 96, 32,
      3000000,
      12288, 128, 128, 128, 12288, 128, 128, 128,
      4096, 64, 6000000, 6000000, 4096, 64, 6000000, 6000000,
      24576, 128,
      12288, 128, 128, 128, 12288, 128, 128, 128,
      4096, 64, 6000000, 6000000, 4096, 64, 6000000, 6000000,
      24576, 128,
      6144, 64, 4096, 64, 64, 1, 4000, 8000};
  for (int i = 0; i < 57; i++) {
    if (in_sizes[i] != expSz[i]) {
      k_sentinel<<<ceilDiv(out_size, 256), 256, 0, stream>>>(dout, out_size, 4096.f + 64.f * i);
      return;
    }
  }

  auto ff = [&](int i) { return (const float*)d_in[i]; };
  const float *x_in = ff(0), *e_in = ff(1), *b_in = ff(2), *a_in = ff(3);
  const float *enc0W = ff(4), *enc0b = ff(5), *enc1W = ff(6), *enc1b = ff(7);
  const float *enc2W = ff(8), *enc2b = ff(9), *enc3W = ff(10), *enc3b = ff(11);
  const float* inci = ff(12);
  const float *concW = ff(49), *concb = ff(50), *resW = ff(51), *resb = ff(52);
  const float *outW = ff(53), *outb = ff(54);
  const int* edge_ind = (const int*)d_in[55];
  const int* node_ind = (const int*)d_in[56];

  // ---- workspace layout, 256B-aligned blocks ----
  char* base = (char*)d_ws;
  size_t off = 0;
  auto A = [&](size_t bytes) { void* p = base + off; off = (off + bytes + 255) & ~(size_t)255; return p; };
  char* SCR = (char*)A(21504000);
  bf16* xbuf = (bf16*)A(9216000);
  bf16* ebuf = (bf16*)A(12288000);
  float* lastx = (float*)A(768000);
  float* laste = (float*)A(1024000);
  float* es = (float*)A(384000);
  float* edv = (float*)A(384000);
  float* wf32 = (float*)A(49152);
  int* flagp = (int*)A(256);
  int* cntN = (int*)A((size_t)(N_ + N_ + E_ + E_) * 4);
  int* curN = cntN + N_;
  int* cntE = curN + N_;
  int* curE = cntE + E_;
  int* offN = (int*)A((N_ + 1) * 4);
  int* offE = (int*)A((E_ + 1) * 4);
  int* srcN = (int*)A((E_ + N_) * 4);
  int* dstN = (int*)A((E_ + N_) * 4);
  int* adjN = (int*)A((E_ + N_) * 4);
  int* srcE = (int*)A((M_ + E_) * 4);
  int* dstE = (int*)A((M_ + E_) * 4);
  int* adjE = (int*)A((M_ + E_) * 4);
  size_t required = off;

  if (ws_size < required) {
    k_sentinel<<<ceilDiv(out_size, 256), 256, 0, stream>>>(dout, out_size, 1000.f + (float)(ws_size >> 20));
    return;
  }

  // SCR aliases (liveness-checked)
  bf16* matb = (bf16*)SCR;
  bf16* tlin = (bf16*)(SCR + 6144000);
  bf16* tmat = (bf16*)(SCR + 12288000);
  bf16* zbuf = (bf16*)SCR;
  bf16* bscr = (bf16*)SCR;
  bf16* hbuf = (bf16*)SCR;
  float* zres = (float*)SCR;

  // stage-check helpers
  auto CHKB = [&](const bf16* p, size_t n, int s) { k_chk_bf16<<<1024, 256, 0, stream>>>(p, n, s, flagp); };
  auto CHKF = [&](const float* p, size_t n, int s) { k_chk_f32<<<1024, 256, 0, stream>>>(p, n, s, flagp); };
  auto CHKI = [&](const int* p, size_t n, int lo, int hi, int s) { k_chk_int<<<1024, 256, 0, stream>>>(p, n, lo, hi, s, flagp); };

  const int totN = E_ + N_;   // 3500
  const int totE = M_ + E_;   // 6000

  // ---- CSR build ----
  hipMemsetAsync(flagp, 0, 256, stream);
  hipMemsetAsync(cntN, 0, (size_t)(N_ + N_ + E_ + E_) * sizeof(int), stream);
  k_csr_count<<<ceilDiv(totN, 256), 256, 0, stream>>>(edge_ind, E_, N_, cntN, srcN, dstN);
  k_scan<<<1, 1024, 0, stream>>>(cntN, offN, N_);
  k_csr_fill<<<ceilDiv(totN, 256), 256, 0, stream>>>(srcN, dstN, offN, curN, adjN, totN, N_);
  k_csr_count<<<ceilDiv(totE, 256), 256, 0, stream>>>(node_ind, M_, E_, cntE, srcE, dstE);
  k_scan<<<1, 1024, 0, stream>>>(cntE, offE, E_);
  k_csr_fill<<<ceilDiv(totE, 256), 256, 0, stream>>>(srcE, dstE, offE, curE, adjE, totE, E_);
  CHKI(adjN, totN, 0, N_, 1);
  CHKI(adjE, totE, 0, E_, 2);
  CHKI(offN, N_ + 1, 0, totN + 1, 1);
  CHKI(offE, E_ + 1, 0, totE + 1, 2);

  // ---- encoders ----
  k_enc<4, 64, true><<<ceilDiv(G_ * N_ * 64, 256), 256, 0, stream>>>(x_in, enc0W, enc0b, xbuf, lastx, N_);
  k_enc<3, 64, true><<<ceilDiv(G_ * E_ * 64, 256), 256, 0, stream>>>(e_in, enc1W, enc1b, ebuf, laste, E_);
  CHKB(xbuf, (size_t)G_ * N_ * 64, 3);
  CHKB(ebuf, (size_t)G_ * E_ * 64, 4);
  CHKF(lastx, (size_t)B_ * N_ * 64, 5);
  CHKF(laste, (size_t)B_ * E_ * 64, 6);

  auto stblock = [&](int sb, int s) {
    const float *gxW = ff(sb + 0), *gxas = ff(sb + 1), *gxad = ff(sb + 2), *gxb = ff(sb + 3);
    const float *geW = ff(sb + 4), *geas = ff(sb + 5), *gead = ff(sb + 6), *geb = ff(sb + 7);
    const float *neW = ff(sb + 8), *neb = ff(sb + 9), *nw = ff(sb + 10), *np_ = ff(sb + 11);
    const float *enW = ff(sb + 12), *enb = ff(sb + 13), *ew = ff(sb + 14), *ep = ff(sb + 15);
    const float *tpW = ff(sb + 16), *tpb = ff(sb + 17);
    int b0 = 7 + s * 21;
    for (int l = 0; l < 2; l++) {
      int lb = b0 + l * 8;
      // ---- node side: xe = NodeEdge(e); x = relu(GAT([x,xe])) ----
      k_lin_ne<<<ceilDiv(E_ * G_ * 32, 256), 256, 0, stream>>>(ebuf, neW + l * 2048, neb + l * 32, tlin, E_);
      CHKB(tlin, (size_t)E_ * G_ * 32, lb + 0);
      k_mat<<<ceilDiv(N_ * E_, 256), 256, 0, stream>>>(nw + (size_t)l * N_ * E_, np_ + (size_t)l * N_ * E_, inci, matb, N_ * E_);
      k_gemm<0, true, false><<<dim3(24, ceilDiv(N_, 64)), 256, 0, stream>>>(matb, nullptr, tlin, tmat, N_, E_, 1536, 0, nullptr, 0);
      CHKB(tmat, (size_t)N_ * G_ * 32, lb + 1);
      k_gemm<1, false, false><<<dim3(1, ceilDiv(G_ * N_, 64)), 256, 0, stream>>>(xbuf, tmat, gxW + l * 6144, zbuf, G_ * N_, 96, 64, N_, nullptr, 0);
      CHKB(zbuf, (size_t)G_ * N_ * 64, lb + 2);
      k_esed<<<ceilDiv(G_ * N_, 4), 256, 0, stream>>>(zbuf, gxas + l * 64, gxad + l * 64, es, edv, G_ * N_);
      k_gat_aggr<<<ceilDiv(G_ * N_, 4), 256, 0, stream>>>(zbuf, es, edv, offN, adjN, gxb + l * 64, xbuf, N_);
      CHKB(xbuf, (size_t)G_ * N_ * 64, lb + 3);
      // ---- edge side: ex = NodeEdge(x); e = relu(GAT([e,ex])) ----
      k_lin_ne<<<ceilDiv(N_ * G_ * 32, 256), 256, 0, stream>>>(xbuf, enW + l * 2048, enb + l * 32, tlin, N_);
      CHKB(tlin, (size_t)N_ * G_ * 32, lb + 4);
      k_matT<<<dim3(ceilDiv(E_, 32), ceilDiv(N_, 32)), dim3(32, 8), 0, stream>>>(ew + (size_t)l * E_ * N_, ep + (size_t)l * E_ * N_, inci, matb);
      k_gemm<0, true, false><<<dim3(24, ceilDiv(E_, 64)), 256, 0, stream>>>(matb, nullptr, tlin, tmat, E_, N_, 1536, 0, nullptr, 0);
      CHKB(tmat, (size_t)E_ * G_ * 32, lb + 5);
      k_gemm<1, false, false><<<dim3(1, ceilDiv(G_ * E_, 64)), 256, 0, stream>>>(ebuf, tmat, geW + l * 6144, zbuf, G_ * E_, 96, 64, E_, nullptr, 0);
      CHKB(zbuf, (size_t)G_ * E_ * 64, lb + 6);
      k_esed<<<ceilDiv(G_ * E_, 4), 256, 0, stream>>>(zbuf, geas + l * 64, gead + l * 64, es, edv, G_ * E_);
      k_gat_aggr<<<ceilDiv(G_ * E_, 4), 256, 0, stream>>>(zbuf, es, edv, offE, adjE, geb + l * 64, ebuf, E_);
      CHKB(ebuf, (size_t)G_ * E_ * 64, lb + 7);
    }
    // ---- temporal convs ----
    const int R = B_ * N_ + B_ * E_;  // 7000
    k_to_time<<<R, 256, 0, stream>>>(xbuf, ebuf, hbuf);
    CHKB(hbuf, (size_t)R * 1536, b0 + 16);
    k_wtrans<<<48, 256, 0, stream>>>(tpW, wf32);
    k_conv<1><<<ceilDiv(R, 2), 128, 0, stream>>>(hbuf, wf32, tpb, R);
    CHKB(hbuf, (size_t)R * 1536, b0 + 17);
    k_wtrans<<<48, 256, 0, stream>>>(tpW + 12288, wf32);
    k_conv<2><<<ceilDiv(R, 2), 128, 0, stream>>>(hbuf, wf32, tpb + 64, R);
    CHKB(hbuf, (size_t)R * 1536, b0 + 18);
    k_from_time<<<R, 256, 0, stream>>>(hbuf, xbuf, ebuf);
    CHKB(xbuf, (size_t)G_ * N_ * 64, b0 + 19);
    CHKB(ebuf, (size_t)G_ * E_ * 64, b0 + 20);
  };

  stblock(13, 0);

  // ---- conc (shared weights; in-place C==A0 safe: gridDim.x==1, per-block row ownership) ----
  k_enc<4, 32, false><<<ceilDiv(G_ * N_ * 32, 256), 256, 0, stream>>>(b_in, enc2W, enc2b, bscr, nullptr, N_);
  k_gemm<2, false, false><<<dim3(1, ceilDiv(G_ * N_, 64)), 256, 0, stream>>>(xbuf, bscr, concW, xbuf, G_ * N_, 96, 64, 0, concb, 1);
  CHKB(xbuf, (size_t)G_ * N_ * 64, 49);
  k_enc<3, 32, false><<<ceilDiv(G_ * E_ * 32, 256), 256, 0, stream>>>(a_in, enc3W, enc3b, bscr, nullptr, E_);
  k_gemm<2, false, false><<<dim3(1, ceilDiv(G_ * E_, 64)), 256, 0, stream>>>(ebuf, bscr, concW, ebuf, G_ * E_, 96, 64, 0, concb, 1);
  CHKB(ebuf, (size_t)G_ * E_ * 64, 50);

  stblock(31, 1);

  // ---- final per batch: y = x @ res_W + res_b (f32) ; cumsum_t ; +res ; relu ; head ----
  for (int b = 0; b < B_; b++) {
    k_gemm<0, false, true><<<dim3(1, ceilDiv(T_ * N_, 64)), 256, 0, stream>>>(
        xbuf + (size_t)b * T_ * N_ * 64, nullptr, resW, zres, T_ * N_, 64, 64, 0, resb, 0);
    CHKF(zres, (size_t)T_ * N_ * 64, 51);
    k_out<true><<<ceilDiv(N_, 4), 256, 0, stream>>>(
        zres, lastx + (size_t)b * N_ * 64, outW, outb, dout + (size_t)b * T_ * N_, N_);
  }
  for (int b = 0; b < B_; b++) {
    k_gemm<0, false, true><<<dim3(1, ceilDiv(T_ * E_, 64)), 256, 0, stream>>>(
        ebuf + (size_t)b * T_ * E_ * 64, nullptr, resW, zres, T_ * E_, 64, 64, 0, resb, 0);
    CHKF(zres, (size_t)T_ * E_ * 64, 52);
    k_out<false><<<ceilDiv(E_, 4), 256, 0, stream>>>(
        zres, laste + (size_t)b * E_ * 64, outW, outb, dout + (size_t)(B_ * T_ * N_) + (size_t)b * T_ * E_, E_);
  }

  // ---- if any stage tripped, overwrite output with 100+stage ----
  k_flagout<<<ceilDiv(out_size, 256), 256, 0, stream>>>(flagp, dout, out_size);
}

// Round 6
// 2264.420 us; speedup vs baseline: 2.1480x; 2.1480x over previous
//
#include <hip/hip_runtime.h>
#include <hip/hip_bf16.h>
#include <cfloat>
#include <math.h>

typedef __hip_bfloat16 bf16;
typedef __attribute__((ext_vector_type(8))) short short8v;
typedef __attribute__((ext_vector_type(4))) float f32x4;

constexpr int B_ = 2, T_ = 24, N_ = 1500, E_ = 2000, M_ = 4000, G_ = 48;
constexpr int KPN = 2016;  // padded K for node-side einsum (K=E_=2000)
constexpr int KPE = 1504;  // padded K for edge-side einsum (K=N_=1500)

__device__ __forceinline__ float b2f(bf16 v) { return __bfloat162float(v); }
__device__ __forceinline__ bf16 f2b(float v) { return __float2bfloat16(v); }
static inline int ceilDiv(int a, int b) { return (a + b - 1) / b; }

// ---------------- diagnostics (host-assert sentinel only) ----------------
__global__ __launch_bounds__(256) void k_sentinel(float* __restrict__ out, int n, float val) {
  int i = blockIdx.x * 256 + threadIdx.x;
  if (i < n) out[i] = val;
}

// ---------------- encoders ----------------
template <int DIN, int DOUT, bool SAVE>
__global__ __launch_bounds__(256) void k_enc(const float* __restrict__ in, const float* __restrict__ W,
                                             const float* __restrict__ bias, bf16* __restrict__ out,
                                             float* __restrict__ last, int nodes) {
  int idx = blockIdx.x * 256 + threadIdx.x;
  if (idx >= G_ * nodes * DOUT) return;
  int d = idx % DOUT;
  int row = idx / DOUT;
  int node = row % nodes;
  int g = row / nodes;
  const float* ir = in + (size_t)row * DIN;
  float acc = bias[d];
#pragma unroll
  for (int i = 0; i < DIN; i++) acc += ir[i] * W[i * DOUT + d];
  if (SAVE) {
    if (g % T_ == T_ - 1) last[((size_t)(g / T_) * nodes + node) * DOUT + d] = acc;  // pre-relu
  }
  out[idx] = f2b(fmaxf(acc, 0.f));
}

// ---------------- NodeEdge linear: relu(act @ W(64x32) + b) -> traw[node][g*32+f] bf16 ----
__global__ __launch_bounds__(256) void k_lin_ne(const bf16* __restrict__ act, const float* __restrict__ W,
                                                const float* __restrict__ bias, bf16* __restrict__ outT,
                                                int nodes) {
  __shared__ float Ws[2048];
  __shared__ float bs[32];
  for (int i = threadIdx.x; i < 2048; i += 256) Ws[i] = W[i];
  if (threadIdx.x < 32) bs[threadIdx.x] = bias[threadIdx.x];
  __syncthreads();
  int idx = blockIdx.x * 256 + threadIdx.x;
  if (idx >= nodes * G_ * 32) return;
  int f = idx & 31;
  int rem = idx >> 5;
  int g = rem % G_;
  int node = rem / G_;
  const bf16* row = act + ((size_t)g * nodes + node) * 64;
  float acc = bs[f];
#pragma unroll
  for (int i = 0; i < 64; i++) acc += b2f(row[i]) * Ws[i * 32 + f];
  outT[idx] = f2b(fmaxf(acc, 0.f));
}

// ---------------- bf16 transpose: in[K][1536] -> out[1536][Kp] (zero-padded) ----------------
__global__ void k_trans(const bf16* __restrict__ in, bf16* __restrict__ out, int K, int Kp) {
  __shared__ float tl[32][33];
  int c0 = blockIdx.x * 32, k0 = blockIdx.y * 32;
  for (int r = threadIdx.y; r < 32; r += 8) {
    int k = k0 + r, c = c0 + threadIdx.x;
    tl[r][threadIdx.x] = (k < K) ? b2f(in[(size_t)k * 1536 + c]) : 0.f;
  }
  __syncthreads();
  for (int r = threadIdx.y; r < 32; r += 8) {
    int c = c0 + r, k = k0 + threadIdx.x;
    if (k < Kp) out[(size_t)c * Kp + k] = f2b(tl[threadIdx.x][r]);
  }
}

// ---------------- masked incidence (padded): mat[n][k<E?val:0], [N_][Kp] ----------------
__global__ __launch_bounds__(256) void k_mat(const float* __restrict__ w, const float* __restrict__ p,
                                             const float* __restrict__ inci, bf16* __restrict__ mat,
                                             int rows, int K, int Kp) {
  int i = blockIdx.x * 256 + threadIdx.x;
  if (i >= rows * Kp) return;
  int row = i / Kp, k = i % Kp;
  float v = 0.f;
  if (k < K) {
    size_t o = (size_t)row * K + k;
    v = w[o] * fabsf(inci[o]) + p[o];
  }
  mat[i] = f2b(v);
}

// transposed variant: mat[e*KPE + n] = |inci[n][e]|*w[e*N+n] + p[e*N+n], zero-pad n>=N_
__global__ void k_matT(const float* __restrict__ w, const float* __restrict__ p,
                       const float* __restrict__ inci, bf16* __restrict__ mat) {
  __shared__ float tl[32][33];
  int e0 = blockIdx.x * 32, n0 = blockIdx.y * 32;
  for (int r = threadIdx.y; r < 32; r += 8) {
    int n = n0 + r, e = e0 + threadIdx.x;
    tl[r][threadIdx.x] = (n < N_ && e < E_) ? fabsf(inci[(size_t)n * E_ + e]) : 0.f;
  }
  __syncthreads();
  for (int r = threadIdx.y; r < 32; r += 8) {
    int e = e0 + r, n = n0 + threadIdx.x;
    if (e < E_ && n < KPE) {
      size_t o = (size_t)e * N_ + n;
      mat[(size_t)e * KPE + n] = (n < N_) ? f2b(tl[threadIdx.x][r] * w[o] + p[o]) : f2b(0.f);
    }
  }
}

// ---------------- weight transpose+cast: in f32 [K][N] -> out bf16 [N][Kp] ----------------
__global__ __launch_bounds__(256) void k_wT(const float* __restrict__ in, bf16* __restrict__ out,
                                            int K, int N, int Kp) {
  int i = blockIdx.x * 256 + threadIdx.x;
  if (i >= N * Kp) return;
  int n = i / Kp, k = i % Kp;
  out[i] = (k < K) ? f2b(in[(size_t)k * N + n]) : f2b(0.f);
}

// ---------------- MFMA GEMM: C[M][Nn] = A @ B, B given transposed Bt[Nn][Kp] ----------------
// AMODE 0: A = A0 bf16 [Mm][Kp].
// AMODE 1: k<64 -> A0[gm*64+k]; k>=64 -> A1[(nd*G_+g)*32+k-64], gm=g*nodes+nd. (GAT concat, Kp=96)
// AMODE 2: k<64 -> A0[gm*64+k]; k>=64 -> A1[gm*32+k-64].                      (conc concat, Kp=96)
// Block: 256 thr = 4 waves (2x2). BM=128, wave tile 64 x (BNt/2). In-place C==A0 safe iff gridDim.x==1.
template <int AMODE, int BNt, bool CF32b>
__global__ __launch_bounds__(256) void k_mgemm(const bf16* __restrict__ A0, const bf16* __restrict__ A1,
                                               const bf16* __restrict__ Bt, void* __restrict__ Cp,
                                               int Mm, int Kp, int Nn, int nodes,
                                               const float* __restrict__ bias, int relu) {
  constexpr int BM = 128;
  constexpr int WTN = BNt / 32;  // 16x16 frags per wave along N
  __shared__ __align__(16) short As[4][BM][8];
  __shared__ __align__(16) short Bs[4][BNt][8];
  int tid = threadIdx.x;
  int bm = blockIdx.y * BM;
  int bn = blockIdx.x * BNt;
  int lane = tid & 63;
  int wid = tid >> 6;
  int wr = wid >> 1, wc = wid & 1;
  f32x4 acc[4][WTN];
#pragma unroll
  for (int i = 0; i < 4; i++)
#pragma unroll
    for (int j = 0; j < WTN; j++) acc[i][j] = f32x4{0.f, 0.f, 0.f, 0.f};

  const int ar = tid >> 1;  // A stage row 0..127
  const int ah = tid & 1;   // which 16-k half
  const int kb = lane >> 4;
  const int lr = lane & 15;

  for (int k0 = 0; k0 < Kp; k0 += 32) {
    // ---- stage A (128 x 32, each thread 16 bf16 = 2 x uint4) ----
    uint4 va0 = {0, 0, 0, 0}, va1 = {0, 0, 0, 0};
    int gm = bm + ar;
    if (gm < Mm) {
      int ks = k0 + ah * 16;
      const bf16* src;
      if (AMODE == 0) src = A0 + (size_t)gm * Kp + ks;
      else if (ks < 64) src = A0 + (size_t)gm * 64 + ks;
      else if (AMODE == 1) {
        int g = gm / nodes, nd = gm % nodes;
        src = A1 + ((size_t)nd * G_ + g) * 32 + (ks - 64);
      } else {
        src = A1 + (size_t)gm * 32 + (ks - 64);
      }
      const uint4* p = reinterpret_cast<const uint4*>(src);
      va0 = p[0];
      va1 = p[1];
    }
    *reinterpret_cast<uint4*>(&As[ah * 2 + 0][ar][0]) = va0;
    *reinterpret_cast<uint4*>(&As[ah * 2 + 1][ar][0]) = va1;
    // ---- stage B (BNt x 32) ----
    if (BNt == 128) {
      int br = tid >> 1, bh = tid & 1;
      uint4 vb0 = {0, 0, 0, 0}, vb1 = {0, 0, 0, 0};
      int gn = bn + br;
      if (gn < Nn) {
        const uint4* p = reinterpret_cast<const uint4*>(Bt + (size_t)gn * Kp + k0 + bh * 16);
        vb0 = p[0];
        vb1 = p[1];
      }
      *reinterpret_cast<uint4*>(&Bs[bh * 2 + 0][br][0]) = vb0;
      *reinterpret_cast<uint4*>(&Bs[bh * 2 + 1][br][0]) = vb1;
    } else {
      int br = tid >> 2, bk = tid & 3;
      uint4 vb0 = {0, 0, 0, 0};
      int gn = bn + br;
      if (gn < Nn) vb0 = *reinterpret_cast<const uint4*>(Bt + (size_t)gn * Kp + k0 + bk * 8);
      *reinterpret_cast<uint4*>(&Bs[bk][br][0]) = vb0;
    }
    __syncthreads();
    // ---- fragments + MFMA ----
    short8v a[4], b[WTN];
#pragma unroll
    for (int mi = 0; mi < 4; mi++)
      a[mi] = *reinterpret_cast<const short8v*>(&As[kb][wr * 64 + mi * 16 + lr][0]);
#pragma unroll
    for (int ni = 0; ni < WTN; ni++)
      b[ni] = *reinterpret_cast<const short8v*>(&Bs[kb][wc * (BNt / 2) + ni * 16 + lr][0]);
#pragma unroll
    for (int mi = 0; mi < 4; mi++)
#pragma unroll
      for (int ni = 0; ni < WTN; ni++)
        acc[mi][ni] = __builtin_amdgcn_mfma_f32_16x16x32_bf16(a[mi], b[ni], acc[mi][ni], 0, 0, 0);
    __syncthreads();
  }
  // ---- epilogue: C/D layout col=lane&15, row=(lane>>4)*4+i ----
#pragma unroll
  for (int mi = 0; mi < 4; mi++) {
    int r0 = bm + wr * 64 + mi * 16 + (lane >> 4) * 4;
#pragma unroll
    for (int ni = 0; ni < WTN; ni++) {
      int col = bn + wc * (BNt / 2) + ni * 16 + lr;
      float bv = bias ? bias[col] : 0.f;
#pragma unroll
      for (int i = 0; i < 4; i++) {
        int r = r0 + i;
        if (r < Mm) {
          float v = acc[mi][ni][i] + bv;
          if (relu) v = fmaxf(v, 0.f);
          if (CF32b) ((float*)Cp)[(size_t)r * Nn + col] = v;
          else ((bf16*)Cp)[(size_t)r * Nn + col] = f2b(v);
        }
      }
    }
  }
}

// ---------------- es/ed = z . a_s , z . a_d (wave per row) ----------------
__global__ __launch_bounds__(256) void k_esed(const bf16* __restrict__ z, const float* __restrict__ as_,
                                              const float* __restrict__ ad_, float* __restrict__ es,
                                              float* __restrict__ ed, int rows) {
  int wid = threadIdx.x >> 6, lane = threadIdx.x & 63;
  int row = blockIdx.x * 4 + wid;
  if (row >= rows) return;
  float zv = b2f(z[(size_t)row * 64 + lane]);
  float vs = zv * as_[lane];
  float vd = zv * ad_[lane];
#pragma unroll
  for (int off = 32; off; off >>= 1) { vs += __shfl_down(vs, off); vd += __shfl_down(vd, off); }
  if (lane == 0) { es[row] = vs; ed[row] = vd; }
}

// ---------------- GAT softmax-aggregation (CSR gather) ----------------
__global__ __launch_bounds__(256) void k_gat_aggr(const bf16* __restrict__ z, const float* __restrict__ es,
                                                  const float* __restrict__ ed, const int* __restrict__ off,
                                                  const int* __restrict__ adj, const float* __restrict__ bias,
                                                  bf16* __restrict__ out, int nodes) {
  int wid = threadIdx.x >> 6, lane = threadIdx.x & 63;
  int idx = blockIdx.x * 4 + wid;
  if (idx >= G_ * nodes) return;
  int g = idx / nodes, node = idx % nodes;
  int s0 = off[node], s1 = off[node + 1];
  const float* esg = es + (size_t)g * nodes;
  float edval = ed[(size_t)g * nodes + node];
  float m = -FLT_MAX;
  for (int s = s0; s < s1; s++) {
    float a = esg[adj[s]] + edval;
    a = (a >= 0.f) ? a : 0.2f * a;
    m = fmaxf(m, a);
  }
  const bf16* zg = z + (size_t)g * nodes * 64;
  float den = 0.f, num = 0.f;
  for (int s = s0; s < s1; s++) {
    int src = adj[s];
    float a = esg[src] + edval;
    a = (a >= 0.f) ? a : 0.2f * a;
    float ex = expf(a - m);
    den += ex;
    num += ex * b2f(zg[(size_t)src * 64 + lane]);
  }
  float r = (s1 > s0) ? (num / den) : 0.f;
  out[(size_t)idx * 64 + lane] = f2b(fmaxf(r + bias[lane], 0.f));
}

// ---------------- CSR build ----------------
__global__ __launch_bounds__(256) void k_csr_count(const int* __restrict__ ind, int ner, int nn,
                                                   int* __restrict__ cnt, int* __restrict__ srcA,
                                                   int* __restrict__ dstA) {
  int i = blockIdx.x * 256 + threadIdx.x;
  int tot = ner + nn;
  if (i >= tot) return;
  int s_, d_;
  if (i < ner) { s_ = ind[i]; d_ = ind[ner + i]; }
  else { s_ = d_ = i - ner; }
  srcA[i] = s_; dstA[i] = d_;
  if (d_ >= 0 && d_ < nn) atomicAdd(&cnt[d_], 1);
}

__global__ __launch_bounds__(1024) void k_scan(const int* __restrict__ cnt, int* __restrict__ off, int n) {
  __shared__ int a[1024];
  int t = threadIdx.x;
  int c0 = (2 * t < n) ? cnt[2 * t] : 0;
  int c1 = (2 * t + 1 < n) ? cnt[2 * t + 1] : 0;
  a[t] = c0 + c1;
  __syncthreads();
  for (int d = 1; d < 1024; d <<= 1) {
    int u = (t >= d) ? a[t - d] : 0;
    __syncthreads();
    a[t] += u;
    __syncthreads();
  }
  int excl = (t > 0) ? a[t - 1] : 0;
  if (2 * t < n) off[2 * t] = excl;
  if (2 * t + 1 < n) off[2 * t + 1] = excl + c0;
  if (t == 0) off[n] = a[1023];
}

__global__ __launch_bounds__(256) void k_csr_fill(const int* __restrict__ srcA, const int* __restrict__ dstA,
                                                  const int* __restrict__ off, int* __restrict__ cur,
                                                  int* __restrict__ adj, int tot, int nn) {
  int i = blockIdx.x * 256 + threadIdx.x;
  if (i >= tot) return;
  int d_ = dstA[i];
  if (d_ < 0 || d_ >= nn) return;
  int pos = atomicAdd(&cur[d_], 1);
  adj[off[d_] + pos] = srcA[i];
}

// ---------------- (b,t,node,d) -> (row, d, t) and back (bf16) ----------------
__global__ __launch_bounds__(256) void k_to_time(const bf16* __restrict__ x, const bf16* __restrict__ e,
                                                 bf16* __restrict__ h) {
  __shared__ float tl[64 * 25];
  int r = blockIdx.x;
  const bf16* src; int nodes, b, node;
  if (r < B_ * N_) { b = r / N_; node = r % N_; src = x; nodes = N_; }
  else { int rr = r - B_ * N_; b = rr / E_; node = rr % E_; src = e; nodes = E_; }
  for (int i = threadIdx.x; i < 1536; i += 256) {
    int tt = i >> 6, d = i & 63;
    tl[d * 25 + tt] = b2f(src[((size_t)(b * T_ + tt) * nodes + node) * 64 + d]);
  }
  __syncthreads();
  bf16* dst = h + (size_t)r * 1536;
  for (int i = threadIdx.x; i < 1536; i += 256) {
    int d = i / 24, tt = i % 24;
    dst[i] = f2b(tl[d * 25 + tt]);
  }
}

__global__ __launch_bounds__(256) void k_from_time(const bf16* __restrict__ h, bf16* __restrict__ x,
                                                   bf16* __restrict__ e) {
  __shared__ float tl[64 * 25];
  int r = blockIdx.x;
  const bf16* src = h + (size_t)r * 1536;
  for (int i = threadIdx.x; i < 1536; i += 256) {
    int d = i / 24, tt = i % 24;
    tl[d * 25 + tt] = b2f(src[i]);
  }
  __syncthreads();
  bf16* dstp; int nodes, b, node;
  if (r < B_ * N_) { b = r / N_; node = r % N_; dstp = x; nodes = N_; }
  else { int rr = r - B_ * N_; b = rr / E_; node = rr % E_; dstp = e; nodes = E_; }
  for (int i = threadIdx.x; i < 1536; i += 256) {
    int tt = i >> 6, d = i & 63;
    dstp[((size_t)(b * T_ + tt) * nodes + node) * 64 + d] = f2b(tl[d * 25 + tt]);
  }
}

// ---------------- conv weight transpose: [o][i][k] f32 -> [(i*3+k)*64+o] f32 ----------------
__global__ __launch_bounds__(256) void k_wtrans(const float* __restrict__ W, float* __restrict__ out) {
  int i = blockIdx.x * 256 + threadIdx.x;
  if (i >= 12288) return;
  int o = i & 63;
  int rest = i >> 6;
  int k = rest % 3, ii = rest / 3;
  out[i] = W[(o * 64 + ii) * 3 + k];
}

// ---------------- causal dilated conv (in-place per row), relu, bf16 io ----------------
template <int DIL>
__global__ __launch_bounds__(128) void k_conv(bf16* __restrict__ h, const float* __restrict__ Wt,
                                              const float* __restrict__ bias, int Rtot) {
  __shared__ float Ws[12288];
  __shared__ float hin[2][1536];
  __shared__ float bs[64];
  for (int i = threadIdx.x; i < 12288; i += 128) Ws[i] = Wt[i];
  if (threadIdx.x < 64) bs[threadIdx.x] = bias[threadIdx.x];
  int r0 = blockIdx.x * 2;
  for (int i = threadIdx.x; i < 2 * 1536; i += 128) {
    int rr = i / 1536, j = i % 1536;
    int r = r0 + rr;
    hin[rr][j] = (r < Rtot) ? b2f(h[(size_t)r * 1536 + j]) : 0.f;
  }
  __syncthreads();
  int rr = threadIdx.x >> 6;
  int o = threadIdx.x & 63;
  int r = r0 + rr;
  if (r >= Rtot) return;
  float acc[24];
#pragma unroll
  for (int t = 0; t < 24; t++) acc[t] = bs[o];
  for (int ii = 0; ii < 64; ii++) {
    const float* hr = &hin[rr][ii * 24];
#pragma unroll
    for (int k = 0; k < 3; k++) {
      float w = Ws[(ii * 3 + k) * 64 + o];
      const int sh = (k - 2) * DIL;
#pragma unroll
      for (int t = 0; t < 24; t++) {
        int tap = t + sh;
        if (tap >= 0) acc[t] += w * hr[tap];
      }
    }
  }
  bf16* dst = h + (size_t)r * 1536 + o * 24;
#pragma unroll
  for (int t = 0; t < 24; t++) dst[t] = f2b(fmaxf(acc[t], 0.f));
}

// ---------------- per-batch: cumsum + residual + relu + head (wave per node) ----------------
template <bool XB>
__global__ __launch_bounds__(256) void k_out(const float* __restrict__ yx, const float* __restrict__ last,
                                             const float* __restrict__ oW, const float* __restrict__ ob_,
                                             float* __restrict__ dout, int nodes) {
  int wid = threadIdx.x >> 6, lane = threadIdx.x & 63;
  int node = blockIdx.x * 4 + wid;
  if (node >= nodes) return;
  float lw = oW[lane];
  float ob = ob_[0];
  float lv = last[(size_t)node * 64 + lane];
  float acc = 0.f;
  for (int tt = 0; tt < T_; tt++) {
    acc += yx[((size_t)tt * nodes + node) * 64 + lane];
    float v = fmaxf(acc + lv, 0.f);
    float p = v * lw;
#pragma unroll
    for (int o2 = 32; o2; o2 >>= 1) p += __shfl_down(p, o2);
    if (lane == 0) {
      float o = p + ob;
      if (XB) o = fminf(fmaxf(o / 6.f + 0.5f, 0.f), 1.f);
      else o = tanhf(o);
      dout[(size_t)tt * nodes + node] = o;
    }
  }
}

// ===================================================================================
extern "C" void kernel_launch(void* const* d_in, const int* in_sizes, int n_in,
                              void* d_out, int out_size, void* d_ws, size_t ws_size,
                              hipStream_t stream) {
  float* dout = (float*)d_out;

  // ---- host-side layout asserts (cheap, proven-green round 5) ----
  if (n_in != 57) {
    k_sentinel<<<ceilDiv(out_size, 256), 256, 0, stream>>>(dout, out_size, 20000.f + 128.f * n_in);
    return;
  }
  static const int expSz[57] = {
      288000, 288000, 288000, 288000,
      256, 64, 192, 64, 128, 32, 96, 32,
      3000000,
      12288, 128, 128, 128, 12288, 128, 128, 128,
      4096, 64, 6000000, 6000000, 4096, 64, 6000000, 6000000,
      24576, 128,
      12288, 128, 128, 128, 12288, 128, 128, 128,
      4096, 64, 6000000, 6000000, 4096, 64, 6000000, 6000000,
      24576, 128,
      6144, 64, 4096, 64, 64, 1, 4000, 8000};
  for (int i = 0; i < 57; i++) {
    if (in_sizes[i] != expSz[i]) {
      k_sentinel<<<ceilDiv(out_size, 256), 256, 0, stream>>>(dout, out_size, 4096.f + 64.f * i);
      return;
    }
  }

  auto ff = [&](int i) { return (const float*)d_in[i]; };
  const float *x_in = ff(0), *e_in = ff(1), *b_in = ff(2), *a_in = ff(3);
  const float *enc0W = ff(4), *enc0b = ff(5), *enc1W = ff(6), *enc1b = ff(7);
  const float *enc2W = ff(8), *enc2b = ff(9), *enc3W = ff(10), *enc3b = ff(11);
  const float* inci = ff(12);
  const float *concW = ff(49), *concb = ff(50), *resW = ff(51), *resb = ff(52);
  const float *outW = ff(53), *outb = ff(54);
  const int* edge_ind = (const int*)d_in[55];
  const int* node_ind = (const int*)d_in[56];

  // ---- workspace layout (~45.7 MB), 256B-aligned ----
  char* base = (char*)d_ws;
  size_t off = 0;
  auto A = [&](size_t bytes) { void* p = base + off; off = (off + bytes + 255) & ~(size_t)255; return p; };
  char* SCR = (char*)A(21504000);
  bf16* xbuf = (bf16*)A(9216000);
  bf16* ebuf = (bf16*)A(12288000);
  float* lastx = (float*)A(768000);
  float* laste = (float*)A(1024000);
  float* es = (float*)A(384000);
  float* edv = (float*)A(384000);
  float* wf32 = (float*)A(49152);
  bf16* wtb = (bf16*)A(16384);  // transposed bf16 weights (<= 64x96)
  int* cntN = (int*)A((size_t)(N_ + N_ + E_ + E_) * 4);
  int* curN = cntN + N_;
  int* cntE = curN + N_;
  int* curE = cntE + E_;
  int* offN = (int*)A((N_ + 1) * 4);
  int* offE = (int*)A((E_ + 1) * 4);
  int* srcN = (int*)A((E_ + N_) * 4);
  int* dstN = (int*)A((E_ + N_) * 4);
  int* adjN = (int*)A((E_ + N_) * 4);
  int* srcE = (int*)A((M_ + E_) * 4);
  int* dstE = (int*)A((M_ + E_) * 4);
  int* adjE = (int*)A((M_ + E_) * 4);
  size_t required = off;

  if (ws_size < required) {
    k_sentinel<<<ceilDiv(out_size, 256), 256, 0, stream>>>(dout, out_size, 1000.f + (float)(ws_size >> 20));
    return;
  }

  // SCR aliases (liveness-checked):
  //  phase einsum: matb@0 (<=6.05MB) | tlinT@6.55M (<=6.20MB) | traw/tmat@13.1M (<=6.15MB)
  //  phase z:      zbuf@0 (<=12.29MB) | tmat@13.1M live
  //  phase conc:   bscr@0 (<=6.15MB)
  //  phase conv:   hbuf@0 (21.5MB)
  //  phase res:    zres@0 (<=12.29MB)
  bf16* matb = (bf16*)SCR;
  bf16* tlinT = (bf16*)(SCR + 6553600);
  bf16* traw = (bf16*)(SCR + 13107200);
  bf16* tmat = (bf16*)(SCR + 13107200);
  bf16* zbuf = (bf16*)SCR;
  bf16* bscr = (bf16*)SCR;
  bf16* hbuf = (bf16*)SCR;
  float* zres = (float*)SCR;

  const int totN = E_ + N_;   // 3500
  const int totE = M_ + E_;   // 6000

  // ---- CSR build ----
  hipMemsetAsync(cntN, 0, (size_t)(N_ + N_ + E_ + E_) * sizeof(int), stream);
  k_csr_count<<<ceilDiv(totN, 256), 256, 0, stream>>>(edge_ind, E_, N_, cntN, srcN, dstN);
  k_scan<<<1, 1024, 0, stream>>>(cntN, offN, N_);
  k_csr_fill<<<ceilDiv(totN, 256), 256, 0, stream>>>(srcN, dstN, offN, curN, adjN, totN, N_);
  k_csr_count<<<ceilDiv(totE, 256), 256, 0, stream>>>(node_ind, M_, E_, cntE, srcE, dstE);
  k_scan<<<1, 1024, 0, stream>>>(cntE, offE, E_);
  k_csr_fill<<<ceilDiv(totE, 256), 256, 0, stream>>>(srcE, dstE, offE, curE, adjE, totE, E_);

  // ---- encoders ----
  k_enc<4, 64, true><<<ceilDiv(G_ * N_ * 64, 256), 256, 0, stream>>>(x_in, enc0W, enc0b, xbuf, lastx, N_);
  k_enc<3, 64, true><<<ceilDiv(G_ * E_ * 64, 256), 256, 0, stream>>>(e_in, enc1W, enc1b, ebuf, laste, E_);

  auto stblock = [&](int sb) {
    const float *gxW = ff(sb + 0), *gxas = ff(sb + 1), *gxad = ff(sb + 2), *gxb = ff(sb + 3);
    const float *geW = ff(sb + 4), *geas = ff(sb + 5), *gead = ff(sb + 6), *geb = ff(sb + 7);
    const float *neW = ff(sb + 8), *neb = ff(sb + 9), *nw = ff(sb + 10), *np_ = ff(sb + 11);
    const float *enW = ff(sb + 12), *enb = ff(sb + 13), *ew = ff(sb + 14), *ep = ff(sb + 15);
    const float *tpW = ff(sb + 16), *tpb = ff(sb + 17);
    for (int l = 0; l < 2; l++) {
      // ---- node side: xe = NodeEdge(e); x = relu(GAT([x,xe])) ----
      k_lin_ne<<<ceilDiv(E_ * G_ * 32, 256), 256, 0, stream>>>(ebuf, neW + l * 2048, neb + l * 32, traw, E_);
      k_trans<<<dim3(48, KPN / 32), dim3(32, 8), 0, stream>>>(traw, tlinT, E_, KPN);
      k_mat<<<ceilDiv(N_ * KPN, 256), 256, 0, stream>>>(nw + (size_t)l * N_ * E_, np_ + (size_t)l * N_ * E_, inci, matb, N_, E_, KPN);
      k_mgemm<0, 128, false><<<dim3(12, ceilDiv(N_, 128)), 256, 0, stream>>>(matb, nullptr, tlinT, tmat, N_, KPN, 1536, 0, nullptr, 0);
      k_wT<<<24, 256, 0, stream>>>(gxW + l * 6144, wtb, 96, 64, 96);
      k_mgemm<1, 64, false><<<dim3(1, ceilDiv(G_ * N_, 128)), 256, 0, stream>>>(xbuf, tmat, wtb, zbuf, G_ * N_, 96, 64, N_, nullptr, 0);
      k_esed<<<ceilDiv(G_ * N_, 4), 256, 0, stream>>>(zbuf, gxas + l * 64, gxad + l * 64, es, edv, G_ * N_);
      k_gat_aggr<<<ceilDiv(G_ * N_, 4), 256, 0, stream>>>(zbuf, es, edv, offN, adjN, gxb + l * 64, xbuf, N_);
      // ---- edge side: ex = NodeEdge(x); e = relu(GAT([e,ex])) ----
      k_lin_ne<<<ceilDiv(N_ * G_ * 32, 256), 256, 0, stream>>>(xbuf, enW + l * 2048, enb + l * 32, traw, N_);
      k_trans<<<dim3(48, KPE / 32), dim3(32, 8), 0, stream>>>(traw, tlinT, N_, KPE);
      k_matT<<<dim3(ceilDiv(E_, 32), KPE / 32), dim3(32, 8), 0, stream>>>(ew + (size_t)l * E_ * N_, ep + (size_t)l * E_ * N_, inci, matb);
      k_mgemm<0, 128, false><<<dim3(12, ceilDiv(E_, 128)), 256, 0, stream>>>(matb, nullptr, tlinT, tmat, E_, KPE, 1536, 0, nullptr, 0);
      k_wT<<<24, 256, 0, stream>>>(geW + l * 6144, wtb, 96, 64, 96);
      k_mgemm<1, 64, false><<<dim3(1, ceilDiv(G_ * E_, 128)), 256, 0, stream>>>(ebuf, tmat, wtb, zbuf, G_ * E_, 96, 64, E_, nullptr, 0);
      k_esed<<<ceilDiv(G_ * E_, 4), 256, 0, stream>>>(zbuf, geas + l * 64, gead + l * 64, es, edv, G_ * E_);
      k_gat_aggr<<<ceilDiv(G_ * E_, 4), 256, 0, stream>>>(zbuf, es, edv, offE, adjE, geb + l * 64, ebuf, E_);
    }
    // ---- temporal convs ----
    const int R = B_ * N_ + B_ * E_;  // 7000
    k_to_time<<<R, 256, 0, stream>>>(xbuf, ebuf, hbuf);
    k_wtrans<<<48, 256, 0, stream>>>(tpW, wf32);
    k_conv<1><<<ceilDiv(R, 2), 128, 0, stream>>>(hbuf, wf32, tpb, R);
    k_wtrans<<<48, 256, 0, stream>>>(tpW + 12288, wf32);
    k_conv<2><<<ceilDiv(R, 2), 128, 0, stream>>>(hbuf, wf32, tpb + 64, R);
    k_from_time<<<R, 256, 0, stream>>>(hbuf, xbuf, ebuf);
  };

  stblock(13);

  // ---- conc (shared weights; in-place: gridDim.x==1 row ownership) ----
  k_wT<<<24, 256, 0, stream>>>(concW, wtb, 96, 64, 96);
  k_enc<4, 32, false><<<ceilDiv(G_ * N_ * 32, 256), 256, 0, stream>>>(b_in, enc2W, enc2b, bscr, nullptr, N_);
  k_mgemm<2, 64, false><<<dim3(1, ceilDiv(G_ * N_, 128)), 256, 0, stream>>>(xbuf, bscr, wtb, xbuf, G_ * N_, 96, 64, 0, concb, 1);
  k_enc<3, 32, false><<<ceilDiv(G_ * E_ * 32, 256), 256, 0, stream>>>(a_in, enc3W, enc3b, bscr, nullptr, E_);
  k_mgemm<2, 64, false><<<dim3(1, ceilDiv(G_ * E_, 128)), 256, 0, stream>>>(ebuf, bscr, wtb, ebuf, G_ * E_, 96, 64, 0, concb, 1);

  stblock(31);

  // ---- final per batch: y = x @ res_W + res_b (f32) ; cumsum_t ; +res ; relu ; head ----
  k_wT<<<16, 256, 0, stream>>>(resW, wtb, 64, 64, 64);
  for (int b = 0; b < B_; b++) {
    k_mgemm<0, 64, true><<<dim3(1, ceilDiv(T_ * N_, 128)), 256, 0, stream>>>(
        xbuf + (size_t)b * T_ * N_ * 64, nullptr, wtb, zres, T_ * N_, 64, 64, 0, resb, 0);
    k_out<true><<<ceilDiv(N_, 4), 256, 0, stream>>>(
        zres, lastx + (size_t)b * N_ * 64, outW, outb, dout + (size_t)b * T_ * N_, N_);
  }
  for (int b = 0; b < B_; b++) {
    k_mgemm<0, 64, true><<<dim3(1, ceilDiv(T_ * E_, 128)), 256, 0, stream>>>(
        ebuf + (size_t)b * T_ * E_ * 64, nullptr, wtb, zres, T_ * E_, 64, 64, 0, resb, 0);
    k_out<false><<<ceilDiv(E_, 4), 256, 0, stream>>>(
        zres, laste + (size_t)b * E_ * 64, outW, outb, dout + (size_t)(B_ * T_ * N_) + (size_t)b * T_ * E_, E_);
  }
}

// Round 7
// 1717.699 us; speedup vs baseline: 2.8317x; 1.3183x over previous
//
#include <hip/hip_runtime.h>
#include <hip/hip_bf16.h>
#include <cfloat>
#include <math.h>

typedef __hip_bfloat16 bf16;
typedef __attribute__((ext_vector_type(8))) short short8v;
typedef __attribute__((ext_vector_type(4))) float f32x4;

constexpr int B_ = 2, T_ = 24, N_ = 1500, E_ = 2000, M_ = 4000, G_ = 48;
constexpr int KPN = 2016;  // padded K for node-side einsum (K=E_=2000)
constexpr int KPE = 1504;  // padded K for edge-side einsum (K=N_=1500)

__device__ __forceinline__ float b2f(bf16 v) { return __bfloat162float(v); }
__device__ __forceinline__ bf16 f2b(float v) { return __float2bfloat16(v); }
static inline int ceilDiv(int a, int b) { return (a + b - 1) / b; }

// ---------------- diagnostics (host-assert sentinel only) ----------------
__global__ __launch_bounds__(256) void k_sentinel(float* __restrict__ out, int n, float val) {
  int i = blockIdx.x * 256 + threadIdx.x;
  if (i < n) out[i] = val;
}

// ---------------- encoders ----------------
template <int DIN, int DOUT, bool SAVE>
__global__ __launch_bounds__(256) void k_enc(const float* __restrict__ in, const float* __restrict__ W,
                                             const float* __restrict__ bias, bf16* __restrict__ out,
                                             float* __restrict__ last, int nodes) {
  int idx = blockIdx.x * 256 + threadIdx.x;
  if (idx >= G_ * nodes * DOUT) return;
  int d = idx % DOUT;
  int row = idx / DOUT;
  int node = row % nodes;
  int g = row / nodes;
  const float* ir = in + (size_t)row * DIN;
  float acc = bias[d];
#pragma unroll
  for (int i = 0; i < DIN; i++) acc += ir[i] * W[i * DOUT + d];
  if (SAVE) {
    if (g % T_ == T_ - 1) last[((size_t)(g / T_) * nodes + node) * DOUT + d] = acc;  // pre-relu
  }
  out[idx] = f2b(fmaxf(acc, 0.f));
}

// ---------------- NodeEdge linear: relu(act @ W(64x32) + b) -> traw[node][g*32+f] bf16 ----
__global__ __launch_bounds__(256) void k_lin_ne(const bf16* __restrict__ act, const float* __restrict__ W,
                                                const float* __restrict__ bias, bf16* __restrict__ outT,
                                                int nodes) {
  __shared__ float Ws[2048];
  __shared__ float bs[32];
  for (int i = threadIdx.x; i < 2048; i += 256) Ws[i] = W[i];
  if (threadIdx.x < 32) bs[threadIdx.x] = bias[threadIdx.x];
  __syncthreads();
  int idx = blockIdx.x * 256 + threadIdx.x;
  if (idx >= nodes * G_ * 32) return;
  int f = idx & 31;
  int rem = idx >> 5;
  int g = rem % G_;
  int node = rem / G_;
  const bf16* row = act + ((size_t)g * nodes + node) * 64;
  float acc = bs[f];
#pragma unroll
  for (int i = 0; i < 64; i++) acc += b2f(row[i]) * Ws[i * 32 + f];
  outT[idx] = f2b(fmaxf(acc, 0.f));
}

// ---------------- bf16 transpose: in[K][1536] -> out[1536][Kp] (zero-padded) ----------------
__global__ void k_trans(const bf16* __restrict__ in, bf16* __restrict__ out, int K, int Kp) {
  __shared__ float tl[32][33];
  int c0 = blockIdx.x * 32, k0 = blockIdx.y * 32;
  for (int r = threadIdx.y; r < 32; r += 8) {
    int k = k0 + r, c = c0 + threadIdx.x;
    tl[r][threadIdx.x] = (k < K) ? b2f(in[(size_t)k * 1536 + c]) : 0.f;
  }
  __syncthreads();
  for (int r = threadIdx.y; r < 32; r += 8) {
    int c = c0 + r, k = k0 + threadIdx.x;
    if (k < Kp) out[(size_t)c * Kp + k] = f2b(tl[threadIdx.x][r]);
  }
}

// ---------------- masked incidence (padded): mat[n][k<E?val:0], [N_][Kp] ----------------
__global__ __launch_bounds__(256) void k_mat(const float* __restrict__ w, const float* __restrict__ p,
                                             const float* __restrict__ inci, bf16* __restrict__ mat,
                                             int rows, int K, int Kp) {
  int i = blockIdx.x * 256 + threadIdx.x;
  if (i >= rows * Kp) return;
  int row = i / Kp, k = i % Kp;
  float v = 0.f;
  if (k < K) {
    size_t o = (size_t)row * K + k;
    v = w[o] * fabsf(inci[o]) + p[o];
  }
  mat[i] = f2b(v);
}

// transposed variant: mat[e*KPE + n] = |inci[n][e]|*w[e*N+n] + p[e*N+n], zero-pad n>=N_
__global__ void k_matT(const float* __restrict__ w, const float* __restrict__ p,
                       const float* __restrict__ inci, bf16* __restrict__ mat) {
  __shared__ float tl[32][33];
  int e0 = blockIdx.x * 32, n0 = blockIdx.y * 32;
  for (int r = threadIdx.y; r < 32; r += 8) {
    int n = n0 + r, e = e0 + threadIdx.x;
    tl[r][threadIdx.x] = (n < N_ && e < E_) ? fabsf(inci[(size_t)n * E_ + e]) : 0.f;
  }
  __syncthreads();
  for (int r = threadIdx.y; r < 32; r += 8) {
    int e = e0 + r, n = n0 + threadIdx.x;
    if (e < E_ && n < KPE) {
      size_t o = (size_t)e * N_ + n;
      mat[(size_t)e * KPE + n] = (n < N_) ? f2b(tl[threadIdx.x][r] * w[o] + p[o]) : f2b(0.f);
    }
  }
}

// ---------------- weight transpose+cast: in f32 [K][N] -> out bf16 [N][Kp] ----------------
__global__ __launch_bounds__(256) void k_wT(const float* __restrict__ in, bf16* __restrict__ out,
                                            int K, int N, int Kp) {
  int i = blockIdx.x * 256 + threadIdx.x;
  if (i >= N * Kp) return;
  int n = i / Kp, k = i % Kp;
  out[i] = (k < K) ? f2b(in[(size_t)k * N + n]) : f2b(0.f);
}

// ---------------- conv weight pack: tpW f32 [o][i][k] -> wcb bf16 [k][o][i] ----------------
__global__ __launch_bounds__(256) void k_wc(const float* __restrict__ W, bf16* __restrict__ out) {
  int i = blockIdx.x * 256 + threadIdx.x;
  if (i >= 12288) return;
  int ii = i & 63;
  int rest = i >> 6;
  int o = rest & 63, k = rest >> 6;
  out[i] = f2b(W[(o * 64 + ii) * 3 + k]);
}

// ---------------- MFMA GEMM: C[M][Nn] = A @ B, B given transposed Bt[Nn][Kp] ----------------
// AMODE 0: A = A0 bf16 [Mm][Kp].
// AMODE 1: k<64 -> A0[gm*64+k]; k>=64 -> A1[(nd*G_+g)*32+k-64], gm=g*nodes+nd. (GAT concat, Kp=96)
// AMODE 2: k<64 -> A0[gm*64+k]; k>=64 -> A1[gm*32+k-64].                      (conc concat, Kp=96)
// Block: 256 thr = 4 waves (2x2). BM=128, wave tile 64 x (BNt/2). In-place C==A0 safe iff gridDim.x==1.
template <int AMODE, int BNt, bool CF32b>
__global__ __launch_bounds__(256) void k_mgemm(const bf16* __restrict__ A0, const bf16* __restrict__ A1,
                                               const bf16* __restrict__ Bt, void* __restrict__ Cp,
                                               int Mm, int Kp, int Nn, int nodes,
                                               const float* __restrict__ bias, int relu) {
  constexpr int BM = 128;
  constexpr int WTN = BNt / 32;  // 16x16 frags per wave along N
  __shared__ __align__(16) short As[4][BM][8];
  __shared__ __align__(16) short Bs[4][BNt][8];
  int tid = threadIdx.x;
  int bm = blockIdx.y * BM;
  int bn = blockIdx.x * BNt;
  int lane = tid & 63;
  int wid = tid >> 6;
  int wr = wid >> 1, wc = wid & 1;
  f32x4 acc[4][WTN];
#pragma unroll
  for (int i = 0; i < 4; i++)
#pragma unroll
    for (int j = 0; j < WTN; j++) acc[i][j] = f32x4{0.f, 0.f, 0.f, 0.f};

  const int ar = tid >> 1;  // A stage row 0..127
  const int ah = tid & 1;   // which 16-k half
  const int kb = lane >> 4;
  const int lr = lane & 15;

  for (int k0 = 0; k0 < Kp; k0 += 32) {
    // ---- stage A (128 x 32, each thread 16 bf16 = 2 x uint4) ----
    uint4 va0 = {0, 0, 0, 0}, va1 = {0, 0, 0, 0};
    int gm = bm + ar;
    if (gm < Mm) {
      int ks = k0 + ah * 16;
      const bf16* src;
      if (AMODE == 0) src = A0 + (size_t)gm * Kp + ks;
      else if (ks < 64) src = A0 + (size_t)gm * 64 + ks;
      else if (AMODE == 1) {
        int g = gm / nodes, nd = gm % nodes;
        src = A1 + ((size_t)nd * G_ + g) * 32 + (ks - 64);
      } else {
        src = A1 + (size_t)gm * 32 + (ks - 64);
      }
      const uint4* p = reinterpret_cast<const uint4*>(src);
      va0 = p[0];
      va1 = p[1];
    }
    *reinterpret_cast<uint4*>(&As[ah * 2 + 0][ar][0]) = va0;
    *reinterpret_cast<uint4*>(&As[ah * 2 + 1][ar][0]) = va1;
    // ---- stage B (BNt x 32) ----
    if (BNt == 128) {
      int br = tid >> 1, bh = tid & 1;
      uint4 vb0 = {0, 0, 0, 0}, vb1 = {0, 0, 0, 0};
      int gn = bn + br;
      if (gn < Nn) {
        const uint4* p = reinterpret_cast<const uint4*>(Bt + (size_t)gn * Kp + k0 + bh * 16);
        vb0 = p[0];
        vb1 = p[1];
      }
      *reinterpret_cast<uint4*>(&Bs[bh * 2 + 0][br][0]) = vb0;
      *reinterpret_cast<uint4*>(&Bs[bh * 2 + 1][br][0]) = vb1;
    } else {
      int br = tid >> 2, bk = tid & 3;
      uint4 vb0 = {0, 0, 0, 0};
      int gn = bn + br;
      if (gn < Nn) vb0 = *reinterpret_cast<const uint4*>(Bt + (size_t)gn * Kp + k0 + bk * 8);
      *reinterpret_cast<uint4*>(&Bs[bk][br][0]) = vb0;
    }
    __syncthreads();
    // ---- fragments + MFMA ----
    short8v a[4], b[WTN];
#pragma unroll
    for (int mi = 0; mi < 4; mi++)
      a[mi] = *reinterpret_cast<const short8v*>(&As[kb][wr * 64 + mi * 16 + lr][0]);
#pragma unroll
    for (int ni = 0; ni < WTN; ni++)
      b[ni] = *reinterpret_cast<const short8v*>(&Bs[kb][wc * (BNt / 2) + ni * 16 + lr][0]);
#pragma unroll
    for (int mi = 0; mi < 4; mi++)
#pragma unroll
      for (int ni = 0; ni < WTN; ni++)
        acc[mi][ni] = __builtin_amdgcn_mfma_f32_16x16x32_bf16(a[mi], b[ni], acc[mi][ni], 0, 0, 0);
    __syncthreads();
  }
  // ---- epilogue: C/D layout col=lane&15, row=(lane>>4)*4+i ----
#pragma unroll
  for (int mi = 0; mi < 4; mi++) {
    int r0 = bm + wr * 64 + mi * 16 + (lane >> 4) * 4;
#pragma unroll
    for (int ni = 0; ni < WTN; ni++) {
      int col = bn + wc * (BNt / 2) + ni * 16 + lr;
      float bv = bias ? bias[col] : 0.f;
#pragma unroll
      for (int i = 0; i < 4; i++) {
        int r = r0 + i;
        if (r < Mm) {
          float v = acc[mi][ni][i] + bv;
          if (relu) v = fmaxf(v, 0.f);
          if (CF32b) ((float*)Cp)[(size_t)r * Nn + col] = v;
          else ((bf16*)Cp)[(size_t)r * Nn + col] = f2b(v);
        }
      }
    }
  }
}

// ---------------- causal dilated conv as MFMA GEMM over row-shifted views ----------------
// C[row][o] = relu(bias[o] + sum_k A[row + (k-2)*DIL*nodes][:] @ Wc[k][o][:]) ; row t guard.
// A bf16 [Mm][64] in (b,t,node,d) row order; Wc bf16 [3][64 o][64 i]. C separate buffer (no alias).
template <int DIL>
__global__ __launch_bounds__(256) void k_cgemm(const bf16* __restrict__ A, const bf16* __restrict__ Wc,
                                               const float* __restrict__ bias, bf16* __restrict__ C,
                                               int Mm, int nodes) {
  __shared__ __align__(16) short As[4][128][8];
  __shared__ __align__(16) short Bs[4][64][8];
  int tid = threadIdx.x;
  int bm = blockIdx.x * 128;
  int lane = tid & 63;
  int wid = tid >> 6;
  int wr = wid >> 1, wc = wid & 1;
  f32x4 acc[4][2];
#pragma unroll
  for (int i = 0; i < 4; i++)
#pragma unroll
    for (int j = 0; j < 2; j++) acc[i][j] = f32x4{0.f, 0.f, 0.f, 0.f};

  const int ar = tid >> 1;
  const int ah = tid & 1;
  const int kb = lane >> 4;
  const int lr = lane & 15;
  const int gm = bm + ar;
  const int t = (gm / nodes) % T_;  // time index of this staged row

#pragma unroll
  for (int k = 0; k < 3; k++) {
    const int sh = (k - 2) * DIL;
    const bool valid = (gm < Mm) && (t + sh >= 0);
    const bf16* arow = A + ((size_t)gm + (size_t)sh * nodes) * 64;
    const bf16* Bt = Wc + k * 4096;
#pragma unroll
    for (int k0 = 0; k0 < 64; k0 += 32) {
      uint4 va0 = {0, 0, 0, 0}, va1 = {0, 0, 0, 0};
      if (valid) {
        const uint4* p = reinterpret_cast<const uint4*>(arow + k0 + ah * 16);
        va0 = p[0];
        va1 = p[1];
      }
      *reinterpret_cast<uint4*>(&As[ah * 2 + 0][ar][0]) = va0;
      *reinterpret_cast<uint4*>(&As[ah * 2 + 1][ar][0]) = va1;
      {
        int br = tid >> 2, bk = tid & 3;
        uint4 vb = *reinterpret_cast<const uint4*>(Bt + (size_t)br * 64 + k0 + bk * 8);
        *reinterpret_cast<uint4*>(&Bs[bk][br][0]) = vb;
      }
      __syncthreads();
      short8v a[4], b[2];
#pragma unroll
      for (int mi = 0; mi < 4; mi++)
        a[mi] = *reinterpret_cast<const short8v*>(&As[kb][wr * 64 + mi * 16 + lr][0]);
#pragma unroll
      for (int ni = 0; ni < 2; ni++)
        b[ni] = *reinterpret_cast<const short8v*>(&Bs[kb][wc * 32 + ni * 16 + lr][0]);
#pragma unroll
      for (int mi = 0; mi < 4; mi++)
#pragma unroll
        for (int ni = 0; ni < 2; ni++)
          acc[mi][ni] = __builtin_amdgcn_mfma_f32_16x16x32_bf16(a[mi], b[ni], acc[mi][ni], 0, 0, 0);
      __syncthreads();
    }
  }
#pragma unroll
  for (int mi = 0; mi < 4; mi++) {
    int r0 = bm + wr * 64 + mi * 16 + (lane >> 4) * 4;
#pragma unroll
    for (int ni = 0; ni < 2; ni++) {
      int col = wc * 32 + ni * 16 + lr;
      float bv = bias[col];
#pragma unroll
      for (int i = 0; i < 4; i++) {
        int r = r0 + i;
        if (r < Mm) C[(size_t)r * 64 + col] = f2b(fmaxf(acc[mi][ni][i] + bv, 0.f));
      }
    }
  }
}

// ---------------- es/ed = z . a_s , z . a_d (wave per row) ----------------
__global__ __launch_bounds__(256) void k_esed(const bf16* __restrict__ z, const float* __restrict__ as_,
                                              const float* __restrict__ ad_, float* __restrict__ es,
                                              float* __restrict__ ed, int rows) {
  int wid = threadIdx.x >> 6, lane = threadIdx.x & 63;
  int row = blockIdx.x * 4 + wid;
  if (row >= rows) return;
  float zv = b2f(z[(size_t)row * 64 + lane]);
  float vs = zv * as_[lane];
  float vd = zv * ad_[lane];
#pragma unroll
  for (int off = 32; off; off >>= 1) { vs += __shfl_down(vs, off); vd += __shfl_down(vd, off); }
  if (lane == 0) { es[row] = vs; ed[row] = vd; }
}

// ---------------- GAT softmax-aggregation (CSR gather) ----------------
__global__ __launch_bounds__(256) void k_gat_aggr(const bf16* __restrict__ z, const float* __restrict__ es,
                                                  const float* __restrict__ ed, const int* __restrict__ off,
                                                  const int* __restrict__ adj, const float* __restrict__ bias,
                                                  bf16* __restrict__ out, int nodes) {
  int wid = threadIdx.x >> 6, lane = threadIdx.x & 63;
  int idx = blockIdx.x * 4 + wid;
  if (idx >= G_ * nodes) return;
  int g = idx / nodes, node = idx % nodes;
  int s0 = off[node], s1 = off[node + 1];
  const float* esg = es + (size_t)g * nodes;
  float edval = ed[(size_t)g * nodes + node];
  float m = -FLT_MAX;
  for (int s = s0; s < s1; s++) {
    float a = esg[adj[s]] + edval;
    a = (a >= 0.f) ? a : 0.2f * a;
    m = fmaxf(m, a);
  }
  const bf16* zg = z + (size_t)g * nodes * 64;
  float den = 0.f, num = 0.f;
  for (int s = s0; s < s1; s++) {
    int src = adj[s];
    float a = esg[src] + edval;
    a = (a >= 0.f) ? a : 0.2f * a;
    float ex = expf(a - m);
    den += ex;
    num += ex * b2f(zg[(size_t)src * 64 + lane]);
  }
  float r = (s1 > s0) ? (num / den) : 0.f;
  out[(size_t)idx * 64 + lane] = f2b(fmaxf(r + bias[lane], 0.f));
}

// ---------------- CSR build ----------------
__global__ __launch_bounds__(256) void k_csr_count(const int* __restrict__ ind, int ner, int nn,
                                                   int* __restrict__ cnt, int* __restrict__ srcA,
                                                   int* __restrict__ dstA) {
  int i = blockIdx.x * 256 + threadIdx.x;
  int tot = ner + nn;
  if (i >= tot) return;
  int s_, d_;
  if (i < ner) { s_ = ind[i]; d_ = ind[ner + i]; }
  else { s_ = d_ = i - ner; }
  srcA[i] = s_; dstA[i] = d_;
  if (d_ >= 0 && d_ < nn) atomicAdd(&cnt[d_], 1);
}

__global__ __launch_bounds__(1024) void k_scan(const int* __restrict__ cnt, int* __restrict__ off, int n) {
  __shared__ int a[1024];
  int t = threadIdx.x;
  int c0 = (2 * t < n) ? cnt[2 * t] : 0;
  int c1 = (2 * t + 1 < n) ? cnt[2 * t + 1] : 0;
  a[t] = c0 + c1;
  __syncthreads();
  for (int d = 1; d < 1024; d <<= 1) {
    int u = (t >= d) ? a[t - d] : 0;
    __syncthreads();
    a[t] += u;
    __syncthreads();
  }
  int excl = (t > 0) ? a[t - 1] : 0;
  if (2 * t < n) off[2 * t] = excl;
  if (2 * t + 1 < n) off[2 * t + 1] = excl + c0;
  if (t == 0) off[n] = a[1023];
}

__global__ __launch_bounds__(256) void k_csr_fill(const int* __restrict__ srcA, const int* __restrict__ dstA,
                                                  const int* __restrict__ off, int* __restrict__ cur,
                                                  int* __restrict__ adj, int tot, int nn) {
  int i = blockIdx.x * 256 + threadIdx.x;
  if (i >= tot) return;
  int d_ = dstA[i];
  if (d_ < 0 || d_ >= nn) return;
  int pos = atomicAdd(&cur[d_], 1);
  adj[off[d_] + pos] = srcA[i];
}

// ---------------- per-batch: cumsum + residual + relu + head (wave per node) ----------------
template <bool XB>
__global__ __launch_bounds__(256) void k_out(const float* __restrict__ yx, const float* __restrict__ last,
                                             const float* __restrict__ oW, const float* __restrict__ ob_,
                                             float* __restrict__ dout, int nodes) {
  int wid = threadIdx.x >> 6, lane = threadIdx.x & 63;
  int node = blockIdx.x * 4 + wid;
  if (node >= nodes) return;
  float lw = oW[lane];
  float ob = ob_[0];
  float lv = last[(size_t)node * 64 + lane];
  float acc = 0.f;
  for (int tt = 0; tt < T_; tt++) {
    acc += yx[((size_t)tt * nodes + node) * 64 + lane];
    float v = fmaxf(acc + lv, 0.f);
    float p = v * lw;
#pragma unroll
    for (int o2 = 32; o2; o2 >>= 1) p += __shfl_down(p, o2);
    if (lane == 0) {
      float o = p + ob;
      if (XB) o = fminf(fmaxf(o / 6.f + 0.5f, 0.f), 1.f);
      else o = tanhf(o);
      dout[(size_t)tt * nodes + node] = o;
    }
  }
}

// ===================================================================================
extern "C" void kernel_launch(void* const* d_in, const int* in_sizes, int n_in,
                              void* d_out, int out_size, void* d_ws, size_t ws_size,
                              hipStream_t stream) {
  float* dout = (float*)d_out;

  // ---- host-side layout asserts (cheap, proven-green round 5) ----
  if (n_in != 57) {
    k_sentinel<<<ceilDiv(out_size, 256), 256, 0, stream>>>(dout, out_size, 20000.f + 128.f * n_in);
    return;
  }
  static const int expSz[57] = {
      288000, 288000, 288000, 288000,
      256, 64, 192, 64, 128, 32, 96, 32,
      3000000,
      12288, 128, 128, 128, 12288, 128, 128, 128,
      4096, 64, 6000000, 6000000, 4096, 64, 6000000, 6000000,
      24576, 128,
      12288, 128, 128, 128, 12288, 128, 128, 128,
      4096, 64, 6000000, 6000000, 4096, 64, 6000000, 6000000,
      24576, 128,
      6144, 64, 4096, 64, 64, 1, 4000, 8000};
  for (int i = 0; i < 57; i++) {
    if (in_sizes[i] != expSz[i]) {
      k_sentinel<<<ceilDiv(out_size, 256), 256, 0, stream>>>(dout, out_size, 4096.f + 64.f * i);
      return;
    }
  }

  auto ff = [&](int i) { return (const float*)d_in[i]; };
  const float *x_in = ff(0), *e_in = ff(1), *b_in = ff(2), *a_in = ff(3);
  const float *enc0W = ff(4), *enc0b = ff(5), *enc1W = ff(6), *enc1b = ff(7);
  const float *enc2W = ff(8), *enc2b = ff(9), *enc3W = ff(10), *enc3b = ff(11);
  const float* inci = ff(12);
  const float *concW = ff(49), *concb = ff(50), *resW = ff(51), *resb = ff(52);
  const float *outW = ff(53), *outb = ff(54);
  const int* edge_ind = (const int*)d_in[55];
  const int* node_ind = (const int*)d_in[56];

  // ---- workspace layout (~45.7 MB), 256B-aligned ----
  char* base = (char*)d_ws;
  size_t off = 0;
  auto A = [&](size_t bytes) { void* p = base + off; off = (off + bytes + 255) & ~(size_t)255; return p; };
  char* SCR = (char*)A(21504000);
  bf16* xbuf = (bf16*)A(9216000);
  bf16* ebuf = (bf16*)A(12288000);
  float* lastx = (float*)A(768000);
  float* laste = (float*)A(1024000);
  float* es = (float*)A(384000);
  float* edv = (float*)A(384000);
  bf16* wtb = (bf16*)A(16384);   // transposed bf16 weights (<= 64x96)
  bf16* wcb = (bf16*)A(24576);   // conv weights bf16 [3][64][64]
  int* cntN = (int*)A((size_t)(N_ + N_ + E_ + E_) * 4);
  int* curN = cntN + N_;
  int* cntE = curN + N_;
  int* curE = cntE + E_;
  int* offN = (int*)A((N_ + 1) * 4);
  int* offE = (int*)A((E_ + 1) * 4);
  int* srcN = (int*)A((E_ + N_) * 4);
  int* dstN = (int*)A((E_ + N_) * 4);
  int* adjN = (int*)A((E_ + N_) * 4);
  int* srcE = (int*)A((M_ + E_) * 4);
  int* dstE = (int*)A((M_ + E_) * 4);
  int* adjE = (int*)A((M_ + E_) * 4);
  size_t required = off;

  if (ws_size < required) {
    k_sentinel<<<ceilDiv(out_size, 256), 256, 0, stream>>>(dout, out_size, 1000.f + (float)(ws_size >> 20));
    return;
  }

  // SCR aliases (liveness-checked):
  //  phase einsum: matb@0 (<=6.05MB) | tlinT@6.55M (<=6.20MB) | traw/tmat@13.1M (<=6.15MB)
  //  phase z:      zbuf@0 (<=12.29MB) | tmat@13.1M live
  //  phase conc:   bscr@0 (<=6.15MB)
  //  phase conv:   cx1@0 (9.22MB) | ce1@9.22M (12.29MB)
  //  phase res:    zres@0 (<=12.29MB)
  bf16* matb = (bf16*)SCR;
  bf16* tlinT = (bf16*)(SCR + 6553600);
  bf16* traw = (bf16*)(SCR + 13107200);
  bf16* tmat = (bf16*)(SCR + 13107200);
  bf16* zbuf = (bf16*)SCR;
  bf16* bscr = (bf16*)SCR;
  bf16* cx1 = (bf16*)SCR;
  bf16* ce1 = (bf16*)(SCR + 9216000);
  float* zres = (float*)SCR;

  const int totN = E_ + N_;   // 3500
  const int totE = M_ + E_;   // 6000

  // ---- CSR build ----
  hipMemsetAsync(cntN, 0, (size_t)(N_ + N_ + E_ + E_) * sizeof(int), stream);
  k_csr_count<<<ceilDiv(totN, 256), 256, 0, stream>>>(edge_ind, E_, N_, cntN, srcN, dstN);
  k_scan<<<1, 1024, 0, stream>>>(cntN, offN, N_);
  k_csr_fill<<<ceilDiv(totN, 256), 256, 0, stream>>>(srcN, dstN, offN, curN, adjN, totN, N_);
  k_csr_count<<<ceilDiv(totE, 256), 256, 0, stream>>>(node_ind, M_, E_, cntE, srcE, dstE);
  k_scan<<<1, 1024, 0, stream>>>(cntE, offE, E_);
  k_csr_fill<<<ceilDiv(totE, 256), 256, 0, stream>>>(srcE, dstE, offE, curE, adjE, totE, E_);

  // ---- encoders ----
  k_enc<4, 64, true><<<ceilDiv(G_ * N_ * 64, 256), 256, 0, stream>>>(x_in, enc0W, enc0b, xbuf, lastx, N_);
  k_enc<3, 64, true><<<ceilDiv(G_ * E_ * 64, 256), 256, 0, stream>>>(e_in, enc1W, enc1b, ebuf, laste, E_);

  auto stblock = [&](int sb) {
    const float *gxW = ff(sb + 0), *gxas = ff(sb + 1), *gxad = ff(sb + 2), *gxb = ff(sb + 3);
    const float *geW = ff(sb + 4), *geas = ff(sb + 5), *gead = ff(sb + 6), *geb = ff(sb + 7);
    const float *neW = ff(sb + 8), *neb = ff(sb + 9), *nw = ff(sb + 10), *np_ = ff(sb + 11);
    const float *enW = ff(sb + 12), *enb = ff(sb + 13), *ew = ff(sb + 14), *ep = ff(sb + 15);
    const float *tpW = ff(sb + 16), *tpb = ff(sb + 17);
    for (int l = 0; l < 2; l++) {
      // ---- node side: xe = NodeEdge(e); x = relu(GAT([x,xe])) ----
      k_lin_ne<<<ceilDiv(E_ * G_ * 32, 256), 256, 0, stream>>>(ebuf, neW + l * 2048, neb + l * 32, traw, E_);
      k_trans<<<dim3(48, KPN / 32), dim3(32, 8), 0, stream>>>(traw, tlinT, E_, KPN);
      k_mat<<<ceilDiv(N_ * KPN, 256), 256, 0, stream>>>(nw + (size_t)l * N_ * E_, np_ + (size_t)l * N_ * E_, inci, matb, N_, E_, KPN);
      k_mgemm<0, 128, false><<<dim3(12, ceilDiv(N_, 128)), 256, 0, stream>>>(matb, nullptr, tlinT, tmat, N_, KPN, 1536, 0, nullptr, 0);
      k_wT<<<24, 256, 0, stream>>>(gxW + l * 6144, wtb, 96, 64, 96);
      k_mgemm<1, 64, false><<<dim3(1, ceilDiv(G_ * N_, 128)), 256, 0, stream>>>(xbuf, tmat, wtb, zbuf, G_ * N_, 96, 64, N_, nullptr, 0);
      k_esed<<<ceilDiv(G_ * N_, 4), 256, 0, stream>>>(zbuf, gxas + l * 64, gxad + l * 64, es, edv, G_ * N_);
      k_gat_aggr<<<ceilDiv(G_ * N_, 4), 256, 0, stream>>>(zbuf, es, edv, offN, adjN, gxb + l * 64, xbuf, N_);
      // ---- edge side: ex = NodeEdge(x); e = relu(GAT([e,ex])) ----
      k_lin_ne<<<ceilDiv(N_ * G_ * 32, 256), 256, 0, stream>>>(xbuf, enW + l * 2048, enb + l * 32, traw, N_);
      k_trans<<<dim3(48, KPE / 32), dim3(32, 8), 0, stream>>>(traw, tlinT, N_, KPE);
      k_matT<<<dim3(ceilDiv(E_, 32), KPE / 32), dim3(32, 8), 0, stream>>>(ew + (size_t)l * E_ * N_, ep + (size_t)l * E_ * N_, inci, matb);
      k_mgemm<0, 128, false><<<dim3(12, ceilDiv(E_, 128)), 256, 0, stream>>>(matb, nullptr, tlinT, tmat, E_, KPE, 1536, 0, nullptr, 0);
      k_wT<<<24, 256, 0, stream>>>(geW + l * 6144, wtb, 96, 64, 96);
      k_mgemm<1, 64, false><<<dim3(1, ceilDiv(G_ * E_, 128)), 256, 0, stream>>>(ebuf, tmat, wtb, zbuf, G_ * E_, 96, 64, E_, nullptr, 0);
      k_esed<<<ceilDiv(G_ * E_, 4), 256, 0, stream>>>(zbuf, geas + l * 64, gead + l * 64, es, edv, G_ * E_);
      k_gat_aggr<<<ceilDiv(G_ * E_, 4), 256, 0, stream>>>(zbuf, es, edv, offE, adjE, geb + l * 64, ebuf, E_);
    }
    // ---- temporal convs: shifted-view MFMA GEMMs (layout stays (b,t,node,d)) ----
    k_wc<<<48, 256, 0, stream>>>(tpW, wcb);
    k_cgemm<1><<<ceilDiv(G_ * N_, 128), 256, 0, stream>>>(xbuf, wcb, tpb, cx1, G_ * N_, N_);
    k_cgemm<1><<<ceilDiv(G_ * E_, 128), 256, 0, stream>>>(ebuf, wcb, tpb, ce1, G_ * E_, E_);
    k_wc<<<48, 256, 0, stream>>>(tpW + 12288, wcb);
    k_cgemm<2><<<ceilDiv(G_ * N_, 128), 256, 0, stream>>>(cx1, wcb, tpb + 64, xbuf, G_ * N_, N_);
    k_cgemm<2><<<ceilDiv(G_ * E_, 128), 256, 0, stream>>>(ce1, wcb, tpb + 64, ebuf, G_ * E_, E_);
  };

  stblock(13);

  // ---- conc (shared weights; in-place: gridDim.x==1 row ownership) ----
  k_wT<<<24, 256, 0, stream>>>(concW, wtb, 96, 64, 96);
  k_enc<4, 32, false><<<ceilDiv(G_ * N_ * 32, 256), 256, 0, stream>>>(b_in, enc2W, enc2b, bscr, nullptr, N_);
  k_mgemm<2, 64, false><<<dim3(1, ceilDiv(G_ * N_, 128)), 256, 0, stream>>>(xbuf, bscr, wtb, xbuf, G_ * N_, 96, 64, 0, concb, 1);
  k_enc<3, 32, false><<<ceilDiv(G_ * E_ * 32, 256), 256, 0, stream>>>(a_in, enc3W, enc3b, bscr, nullptr, E_);
  k_mgemm<2, 64, false><<<dim3(1, ceilDiv(G_ * E_, 128)), 256, 0, stream>>>(ebuf, bscr, wtb, ebuf, G_ * E_, 96, 64, 0, concb, 1);

  stblock(31);

  // ---- final per batch: y = x @ res_W + res_b (f32) ; cumsum_t ; +res ; relu ; head ----
  k_wT<<<16, 256, 0, stream>>>(resW, wtb, 64, 64, 64);
  for (int b = 0; b < B_; b++) {
    k_mgemm<0, 64, true><<<dim3(1, ceilDiv(T_ * N_, 128)), 256, 0, stream>>>(
        xbuf + (size_t)b * T_ * N_ * 64, nullptr, wtb, zres, T_ * N_, 64, 64, 0, resb, 0);
    k_out<true><<<ceilDiv(N_, 4), 256, 0, stream>>>(
        zres, lastx + (size_t)b * N_ * 64, outW, outb, dout + (size_t)b * T_ * N_, N_);
  }
  for (int b = 0; b < B_; b++) {
    k_mgemm<0, 64, true><<<dim3(1, ceilDiv(T_ * E_, 128)), 256, 0, stream>>>(
        ebuf + (size_t)b * T_ * E_ * 64, nullptr, wtb, zres, T_ * E_, 64, 64, 0, resb, 0);
    k_out<false><<<ceilDiv(E_, 4), 256, 0, stream>>>(
        zres, laste + (size_t)b * E_ * 64, outW, outb, dout + (size_t)(B_ * T_ * N_) + (size_t)b * T_ * E_, E_);
  }
}

// Round 8
// 1453.237 us; speedup vs baseline: 3.3470x; 1.1820x over previous
//
#include <hip/hip_runtime.h>
#include <hip/hip_bf16.h>
#include <cfloat>
#include <math.h>

typedef __hip_bfloat16 bf16;
typedef __attribute__((ext_vector_type(8))) short short8v;
typedef __attribute__((ext_vector_type(4))) float f32x4;

constexpr int B_ = 2, T_ = 24, N_ = 1500, E_ = 2000, M_ = 4000, G_ = 48;
constexpr int KPN = 2016;  // padded K for node-side einsum (K=E_=2000)
constexpr int KPE = 1504;  // padded K for edge-side einsum (K=N_=1500)

__device__ __forceinline__ float b2f(bf16 v) { return __bfloat162float(v); }
__device__ __forceinline__ bf16 f2b(float v) { return __float2bfloat16(v); }
static inline int ceilDiv(int a, int b) { return (a + b - 1) / b; }

// ---------------- diagnostics (host-assert sentinel only) ----------------
__global__ __launch_bounds__(256) void k_sentinel(float* __restrict__ out, int n, float val) {
  int i = blockIdx.x * 256 + threadIdx.x;
  if (i < n) out[i] = val;
}

// ---------------- fused weight prep: all transposed bf16 weights in one pass ----------------
// region layout (bf16 elems):
//  [0)      s1gx 2x6144   [12288) s1ge 2x6144   [24576) s2gx   [36864) s2ge
//  [49152)  conc 6144     [55296) res 4096
//  [59392)  conv: s1l0 12288, s1l1, s2l0, s2l1  (each [k][o][i])  end 108544
__global__ __launch_bounds__(256) void k_wprep(const float* __restrict__ g0, const float* __restrict__ e0,
                                               const float* __restrict__ g1, const float* __restrict__ e1,
                                               const float* __restrict__ cw, const float* __restrict__ rw,
                                               const float* __restrict__ t0, const float* __restrict__ t1,
                                               bf16* __restrict__ out) {
  int i = blockIdx.x * 256 + threadIdx.x;
  if (i >= 108544) return;
  float v;
  if (i < 49152) {
    int which = i / 12288, r = i % 12288;
    const float* W = which == 0 ? g0 : which == 1 ? e0 : which == 2 ? g1 : e1;
    int l = r / 6144, j = r % 6144;
    int n = j / 96, k = j % 96;
    v = W[l * 6144 + k * 64 + n];
  } else if (i < 55296) {
    int j = i - 49152, n = j / 96, k = j % 96;
    v = cw[k * 64 + n];
  } else if (i < 59392) {
    int j = i - 55296, n = j / 64, k = j % 64;
    v = rw[k * 64 + n];
  } else {
    int r = i - 59392;
    int which = r / 24576;
    const float* W = which ? t1 : t0;
    int rr = r % 24576;
    int l = rr / 12288, j = rr % 12288;
    int ii = j & 63, o = (j >> 6) & 63, k = j >> 12;
    v = W[l * 12288 + o * 192 + ii * 3 + k];
  }
  out[i] = f2b(v);
}

// ---------------- encoders ----------------
template <int DIN, int DOUT, bool SAVE>
__global__ __launch_bounds__(256) void k_enc(const float* __restrict__ in, const float* __restrict__ W,
                                             const float* __restrict__ bias, bf16* __restrict__ out,
                                             float* __restrict__ last, int nodes) {
  int idx = blockIdx.x * 256 + threadIdx.x;
  if (idx >= G_ * nodes * DOUT) return;
  int d = idx % DOUT;
  int row = idx / DOUT;
  int node = row % nodes;
  int g = row / nodes;
  const float* ir = in + (size_t)row * DIN;
  float acc = bias[d];
#pragma unroll
  for (int i = 0; i < DIN; i++) acc += ir[i] * W[i * DOUT + d];
  if (SAVE) {
    if (g % T_ == T_ - 1) last[((size_t)(g / T_) * nodes + node) * DOUT + d] = acc;  // pre-relu
  }
  out[idx] = f2b(fmaxf(acc, 0.f));
}

// ---------------- NodeEdge linear: relu(act @ W(64x32) + b) -> traw[node][g*32+f] bf16 ----
__global__ __launch_bounds__(256) void k_lin_ne(const bf16* __restrict__ act, const float* __restrict__ W,
                                                const float* __restrict__ bias, bf16* __restrict__ outT,
                                                int nodes) {
  __shared__ float Ws[2048];
  __shared__ float bs[32];
  for (int i = threadIdx.x; i < 2048; i += 256) Ws[i] = W[i];
  if (threadIdx.x < 32) bs[threadIdx.x] = bias[threadIdx.x];
  __syncthreads();
  int idx = blockIdx.x * 256 + threadIdx.x;
  if (idx >= nodes * G_ * 32) return;
  int f = idx & 31;
  int rem = idx >> 5;
  int g = rem % G_;
  int node = rem / G_;
  const bf16* row = act + ((size_t)g * nodes + node) * 64;
  float acc = bs[f];
#pragma unroll
  for (int i = 0; i < 64; i++) acc += b2f(row[i]) * Ws[i * 32 + f];
  outT[idx] = f2b(fmaxf(acc, 0.f));
}

// ---------------- bf16 transpose: in[K][1536] -> out[1536][Kp] (zero-padded) ----------------
__global__ void k_trans(const bf16* __restrict__ in, bf16* __restrict__ out, int K, int Kp) {
  __shared__ float tl[32][33];
  int c0 = blockIdx.x * 32, k0 = blockIdx.y * 32;
  for (int r = threadIdx.y; r < 32; r += 8) {
    int k = k0 + r, c = c0 + threadIdx.x;
    tl[r][threadIdx.x] = (k < K) ? b2f(in[(size_t)k * 1536 + c]) : 0.f;
  }
  __syncthreads();
  for (int r = threadIdx.y; r < 32; r += 8) {
    int c = c0 + r, k = k0 + threadIdx.x;
    if (k < Kp) out[(size_t)c * Kp + k] = f2b(tl[threadIdx.x][r]);
  }
}

// ---------------- masked incidence (padded): mat[n][k<E?val:0], [N_][Kp] ----------------
__global__ __launch_bounds__(256) void k_mat(const float* __restrict__ w, const float* __restrict__ p,
                                             const float* __restrict__ inci, bf16* __restrict__ mat,
                                             int rows, int K, int Kp) {
  int i = blockIdx.x * 256 + threadIdx.x;
  if (i >= rows * Kp) return;
  int row = i / Kp, k = i % Kp;
  float v = 0.f;
  if (k < K) {
    size_t o = (size_t)row * K + k;
    v = w[o] * fabsf(inci[o]) + p[o];
  }
  mat[i] = f2b(v);
}

// transposed variant: mat[e*KPE + n] = |inci[n][e]|*w[e*N+n] + p[e*N+n], zero-pad n>=N_
__global__ void k_matT(const float* __restrict__ w, const float* __restrict__ p,
                       const float* __restrict__ inci, bf16* __restrict__ mat) {
  __shared__ float tl[32][33];
  int e0 = blockIdx.x * 32, n0 = blockIdx.y * 32;
  for (int r = threadIdx.y; r < 32; r += 8) {
    int n = n0 + r, e = e0 + threadIdx.x;
    tl[r][threadIdx.x] = (n < N_ && e < E_) ? fabsf(inci[(size_t)n * E_ + e]) : 0.f;
  }
  __syncthreads();
  for (int r = threadIdx.y; r < 32; r += 8) {
    int e = e0 + r, n = n0 + threadIdx.x;
    if (e < E_ && n < KPE) {
      size_t o = (size_t)e * N_ + n;
      mat[(size_t)e * KPE + n] = (n < N_) ? f2b(tl[threadIdx.x][r] * w[o] + p[o]) : f2b(0.f);
    }
  }
}

// ---------------- 64x64-tile MFMA GEMM, double-buffered LDS, 1 barrier/K-step ----------------
// C[M][Nn] = A[M][Kp] @ B (Bt[Nn][Kp]); bf16 out, no bias/relu. For the 8 incidence einsums.
__global__ __launch_bounds__(256) void k_mgemm64(const bf16* __restrict__ A0, const bf16* __restrict__ Bt,
                                                 bf16* __restrict__ Cp, int Mm, int Kp, int Nn) {
  __shared__ __align__(16) short As[2][4][64][8];
  __shared__ __align__(16) short Bs[2][4][64][8];
  int tid = threadIdx.x;
  int bm = blockIdx.y * 64, bn = blockIdx.x * 64;
  int lane = tid & 63, wid = tid >> 6;
  int wr = wid >> 1, wc = wid & 1;
  f32x4 acc[2][2];
#pragma unroll
  for (int i = 0; i < 2; i++)
#pragma unroll
    for (int j = 0; j < 2; j++) acc[i][j] = f32x4{0.f, 0.f, 0.f, 0.f};

  const int sr = tid >> 2;  // staged row 0..63
  const int sc = tid & 3;   // 8-elem k chunk (=kb)
  const int kb = lane >> 4, lr = lane & 15;
  const int gmA = bm + sr, gnB = bn + sr;
  const bool va_ok = (gmA < Mm), vb_ok = (gnB < Nn);
  const bf16* ap = A0 + (size_t)gmA * Kp + sc * 8;
  const bf16* bp = Bt + (size_t)gnB * Kp + sc * 8;

  uint4 va = {0, 0, 0, 0}, vb = {0, 0, 0, 0};
  if (va_ok) va = *reinterpret_cast<const uint4*>(ap);
  if (vb_ok) vb = *reinterpret_cast<const uint4*>(bp);
  int cur = 0;
  for (int k0 = 0; k0 < Kp; k0 += 32) {
    *reinterpret_cast<uint4*>(&As[cur][sc][sr][0]) = va;
    *reinterpret_cast<uint4*>(&Bs[cur][sc][sr][0]) = vb;
    __syncthreads();
    int kn = k0 + 32;
    if (kn < Kp) {  // issue next tile's loads early; they drain under MFMA below
      va = va_ok ? *reinterpret_cast<const uint4*>(ap + kn) : uint4{0, 0, 0, 0};
      vb = vb_ok ? *reinterpret_cast<const uint4*>(bp + kn) : uint4{0, 0, 0, 0};
    }
    short8v a[2], b[2];
#pragma unroll
    for (int mi = 0; mi < 2; mi++)
      a[mi] = *reinterpret_cast<const short8v*>(&As[cur][kb][wr * 32 + mi * 16 + lr][0]);
#pragma unroll
    for (int ni = 0; ni < 2; ni++)
      b[ni] = *reinterpret_cast<const short8v*>(&Bs[cur][kb][wc * 32 + ni * 16 + lr][0]);
#pragma unroll
    for (int mi = 0; mi < 2; mi++)
#pragma unroll
      for (int ni = 0; ni < 2; ni++)
        acc[mi][ni] = __builtin_amdgcn_mfma_f32_16x16x32_bf16(a[mi], b[ni], acc[mi][ni], 0, 0, 0);
    cur ^= 1;
  }
#pragma unroll
  for (int mi = 0; mi < 2; mi++) {
    int r0 = bm + wr * 32 + mi * 16 + (lane >> 4) * 4;
#pragma unroll
    for (int ni = 0; ni < 2; ni++) {
      int col = bn + wc * 32 + ni * 16 + lr;
      if (col >= Nn) continue;
#pragma unroll
      for (int i = 0; i < 4; i++) {
        int r = r0 + i;
        if (r < Mm) Cp[(size_t)r * Nn + col] = f2b(acc[mi][ni][i]);
      }
    }
  }
}

// ---------------- MFMA GEMM (128-row tile): z / conc / res GEMMs ----------------
// AMODE 0: A = A0 bf16 [Mm][Kp].
// AMODE 1: k<64 -> A0[gm*64+k]; k>=64 -> A1[(nd*G_+g)*32+k-64], gm=g*nodes+nd. (GAT concat, Kp=96)
// AMODE 2: k<64 -> A0[gm*64+k]; k>=64 -> A1[gm*32+k-64].                      (conc concat, Kp=96)
// In-place C==A0 safe iff gridDim.x==1.
template <int AMODE, int BNt, bool CF32b>
__global__ __launch_bounds__(256) void k_mgemm(const bf16* __restrict__ A0, const bf16* __restrict__ A1,
                                               const bf16* __restrict__ Bt, void* __restrict__ Cp,
                                               int Mm, int Kp, int Nn, int nodes,
                                               const float* __restrict__ bias, int relu) {
  constexpr int BM = 128;
  constexpr int WTN = BNt / 32;
  __shared__ __align__(16) short As[4][BM][8];
  __shared__ __align__(16) short Bs[4][BNt][8];
  int tid = threadIdx.x;
  int bm = blockIdx.y * BM;
  int bn = blockIdx.x * BNt;
  int lane = tid & 63;
  int wid = tid >> 6;
  int wr = wid >> 1, wc = wid & 1;
  f32x4 acc[4][WTN];
#pragma unroll
  for (int i = 0; i < 4; i++)
#pragma unroll
    for (int j = 0; j < WTN; j++) acc[i][j] = f32x4{0.f, 0.f, 0.f, 0.f};

  const int ar = tid >> 1;
  const int ah = tid & 1;
  const int kb = lane >> 4;
  const int lr = lane & 15;

  for (int k0 = 0; k0 < Kp; k0 += 32) {
    uint4 va0 = {0, 0, 0, 0}, va1 = {0, 0, 0, 0};
    int gm = bm + ar;
    if (gm < Mm) {
      int ks = k0 + ah * 16;
      const bf16* src;
      if (AMODE == 0) src = A0 + (size_t)gm * Kp + ks;
      else if (ks < 64) src = A0 + (size_t)gm * 64 + ks;
      else if (AMODE == 1) {
        int g = gm / nodes, nd = gm % nodes;
        src = A1 + ((size_t)nd * G_ + g) * 32 + (ks - 64);
      } else {
        src = A1 + (size_t)gm * 32 + (ks - 64);
      }
      const uint4* p = reinterpret_cast<const uint4*>(src);
      va0 = p[0];
      va1 = p[1];
    }
    *reinterpret_cast<uint4*>(&As[ah * 2 + 0][ar][0]) = va0;
    *reinterpret_cast<uint4*>(&As[ah * 2 + 1][ar][0]) = va1;
    if (BNt == 128) {
      int br = tid >> 1, bh = tid & 1;
      uint4 vb0 = {0, 0, 0, 0}, vb1 = {0, 0, 0, 0};
      int gn = bn + br;
      if (gn < Nn) {
        const uint4* p = reinterpret_cast<const uint4*>(Bt + (size_t)gn * Kp + k0 + bh * 16);
        vb0 = p[0];
        vb1 = p[1];
      }
      *reinterpret_cast<uint4*>(&Bs[bh * 2 + 0][br][0]) = vb0;
      *reinterpret_cast<uint4*>(&Bs[bh * 2 + 1][br][0]) = vb1;
    } else {
      int br = tid >> 2, bk = tid & 3;
      uint4 vb0 = {0, 0, 0, 0};
      int gn = bn + br;
      if (gn < Nn) vb0 = *reinterpret_cast<const uint4*>(Bt + (size_t)gn * Kp + k0 + bk * 8);
      *reinterpret_cast<uint4*>(&Bs[bk][br][0]) = vb0;
    }
    __syncthreads();
    short8v a[4], b[WTN];
#pragma unroll
    for (int mi = 0; mi < 4; mi++)
      a[mi] = *reinterpret_cast<const short8v*>(&As[kb][wr * 64 + mi * 16 + lr][0]);
#pragma unroll
    for (int ni = 0; ni < WTN; ni++)
      b[ni] = *reinterpret_cast<const short8v*>(&Bs[kb][wc * (BNt / 2) + ni * 16 + lr][0]);
#pragma unroll
    for (int mi = 0; mi < 4; mi++)
#pragma unroll
      for (int ni = 0; ni < WTN; ni++)
        acc[mi][ni] = __builtin_amdgcn_mfma_f32_16x16x32_bf16(a[mi], b[ni], acc[mi][ni], 0, 0, 0);
    __syncthreads();
  }
#pragma unroll
  for (int mi = 0; mi < 4; mi++) {
    int r0 = bm + wr * 64 + mi * 16 + (lane >> 4) * 4;
#pragma unroll
    for (int ni = 0; ni < WTN; ni++) {
      int col = bn + wc * (BNt / 2) + ni * 16 + lr;
      float bv = bias ? bias[col] : 0.f;
#pragma unroll
      for (int i = 0; i < 4; i++) {
        int r = r0 + i;
        if (r < Mm) {
          float v = acc[mi][ni][i] + bv;
          if (relu) v = fmaxf(v, 0.f);
          if (CF32b) ((float*)Cp)[(size_t)r * Nn + col] = v;
          else ((bf16*)Cp)[(size_t)r * Nn + col] = f2b(v);
        }
      }
    }
  }
}

// ---------------- causal dilated conv as MFMA GEMM over row-shifted views ----------------
template <int DIL>
__global__ __launch_bounds__(256) void k_cgemm(const bf16* __restrict__ A, const bf16* __restrict__ Wc,
                                               const float* __restrict__ bias, bf16* __restrict__ C,
                                               int Mm, int nodes) {
  __shared__ __align__(16) short As[4][128][8];
  __shared__ __align__(16) short Bs[4][64][8];
  int tid = threadIdx.x;
  int bm = blockIdx.x * 128;
  int lane = tid & 63;
  int wid = tid >> 6;
  int wr = wid >> 1, wc = wid & 1;
  f32x4 acc[4][2];
#pragma unroll
  for (int i = 0; i < 4; i++)
#pragma unroll
    for (int j = 0; j < 2; j++) acc[i][j] = f32x4{0.f, 0.f, 0.f, 0.f};

  const int ar = tid >> 1;
  const int ah = tid & 1;
  const int kb = lane >> 4;
  const int lr = lane & 15;
  const int gm = bm + ar;
  const int t = (gm / nodes) % T_;

#pragma unroll
  for (int k = 0; k < 3; k++) {
    const int sh = (k - 2) * DIL;
    const bool valid = (gm < Mm) && (t + sh >= 0);
    const bf16* arow = A + ((size_t)gm + (size_t)sh * nodes) * 64;
    const bf16* Bt = Wc + k * 4096;
#pragma unroll
    for (int k0 = 0; k0 < 64; k0 += 32) {
      uint4 va0 = {0, 0, 0, 0}, va1 = {0, 0, 0, 0};
      if (valid) {
        const uint4* p = reinterpret_cast<const uint4*>(arow + k0 + ah * 16);
        va0 = p[0];
        va1 = p[1];
      }
      *reinterpret_cast<uint4*>(&As[ah * 2 + 0][ar][0]) = va0;
      *reinterpret_cast<uint4*>(&As[ah * 2 + 1][ar][0]) = va1;
      {
        int br = tid >> 2, bk = tid & 3;
        uint4 vb = *reinterpret_cast<const uint4*>(Bt + (size_t)br * 64 + k0 + bk * 8);
        *reinterpret_cast<uint4*>(&Bs[bk][br][0]) = vb;
      }
      __syncthreads();
      short8v a[4], b[2];
#pragma unroll
      for (int mi = 0; mi < 4; mi++)
        a[mi] = *reinterpret_cast<const short8v*>(&As[kb][wr * 64 + mi * 16 + lr][0]);
#pragma unroll
      for (int ni = 0; ni < 2; ni++)
        b[ni] = *reinterpret_cast<const short8v*>(&Bs[kb][wc * 32 + ni * 16 + lr][0]);
#pragma unroll
      for (int mi = 0; mi < 4; mi++)
#pragma unroll
        for (int ni = 0; ni < 2; ni++)
          acc[mi][ni] = __builtin_amdgcn_mfma_f32_16x16x32_bf16(a[mi], b[ni], acc[mi][ni], 0, 0, 0);
      __syncthreads();
    }
  }
#pragma unroll
  for (int mi = 0; mi < 4; mi++) {
    int r0 = bm + wr * 64 + mi * 16 + (lane >> 4) * 4;
#pragma unroll
    for (int ni = 0; ni < 2; ni++) {
      int col = wc * 32 + ni * 16 + lr;
      float bv = bias[col];
#pragma unroll
      for (int i = 0; i < 4; i++) {
        int r = r0 + i;
        if (r < Mm) C[(size_t)r * 64 + col] = f2b(fmaxf(acc[mi][ni][i] + bv, 0.f));
      }
    }
  }
}

// ---------------- es/ed = z . a_s , z . a_d (wave per row) ----------------
__global__ __launch_bounds__(256) void k_esed(const bf16* __restrict__ z, const float* __restrict__ as_,
                                              const float* __restrict__ ad_, float* __restrict__ es,
                                              float* __restrict__ ed, int rows) {
  int wid = threadIdx.x >> 6, lane = threadIdx.x & 63;
  int row = blockIdx.x * 4 + wid;
  if (row >= rows) return;
  float zv = b2f(z[(size_t)row * 64 + lane]);
  float vs = zv * as_[lane];
  float vd = zv * ad_[lane];
#pragma unroll
  for (int off = 32; off; off >>= 1) { vs += __shfl_down(vs, off); vd += __shfl_down(vd, off); }
  if (lane == 0) { es[row] = vs; ed[row] = vd; }
}

// ---------------- GAT softmax-aggregation (CSR gather) ----------------
__global__ __launch_bounds__(256) void k_gat_aggr(const bf16* __restrict__ z, const float* __restrict__ es,
                                                  const float* __restrict__ ed, const int* __restrict__ off,
                                                  const int* __restrict__ adj, const float* __restrict__ bias,
                                                  bf16* __restrict__ out, int nodes) {
  int wid = threadIdx.x >> 6, lane = threadIdx.x & 63;
  int idx = blockIdx.x * 4 + wid;
  if (idx >= G_ * nodes) return;
  int g = idx / nodes, node = idx % nodes;
  int s0 = off[node], s1 = off[node + 1];
  const float* esg = es + (size_t)g * nodes;
  float edval = ed[(size_t)g * nodes + node];
  float m = -FLT_MAX;
  for (int s = s0; s < s1; s++) {
    float a = esg[adj[s]] + edval;
    a = (a >= 0.f) ? a : 0.2f * a;
    m = fmaxf(m, a);
  }
  const bf16* zg = z + (size_t)g * nodes * 64;
  float den = 0.f, num = 0.f;
  for (int s = s0; s < s1; s++) {
    int src = adj[s];
    float a = esg[src] + edval;
    a = (a >= 0.f) ? a : 0.2f * a;
    float ex = expf(a - m);
    den += ex;
    num += ex * b2f(zg[(size_t)src * 64 + lane]);
  }
  float r = (s1 > s0) ? (num / den) : 0.f;
  out[(size_t)idx * 64 + lane] = f2b(fmaxf(r + bias[lane], 0.f));
}

// ---------------- CSR build ----------------
__global__ __launch_bounds__(256) void k_csr_count(const int* __restrict__ ind, int ner, int nn,
                                                   int* __restrict__ cnt, int* __restrict__ srcA,
                                                   int* __restrict__ dstA) {
  int i = blockIdx.x * 256 + threadIdx.x;
  int tot = ner + nn;
  if (i >= tot) return;
  int s_, d_;
  if (i < ner) { s_ = ind[i]; d_ = ind[ner + i]; }
  else { s_ = d_ = i - ner; }
  srcA[i] = s_; dstA[i] = d_;
  if (d_ >= 0 && d_ < nn) atomicAdd(&cnt[d_], 1);
}

__global__ __launch_bounds__(1024) void k_scan(const int* __restrict__ cnt, int* __restrict__ off, int n) {
  __shared__ int a[1024];
  int t = threadIdx.x;
  int c0 = (2 * t < n) ? cnt[2 * t] : 0;
  int c1 = (2 * t + 1 < n) ? cnt[2 * t + 1] : 0;
  a[t] = c0 + c1;
  __syncthreads();
  for (int d = 1; d < 1024; d <<= 1) {
    int u = (t >= d) ? a[t - d] : 0;
    __syncthreads();
    a[t] += u;
    __syncthreads();
  }
  int excl = (t > 0) ? a[t - 1] : 0;
  if (2 * t < n) off[2 * t] = excl;
  if (2 * t + 1 < n) off[2 * t + 1] = excl + c0;
  if (t == 0) off[n] = a[1023];
}

__global__ __launch_bounds__(256) void k_csr_fill(const int* __restrict__ srcA, const int* __restrict__ dstA,
                                                  const int* __restrict__ off, int* __restrict__ cur,
                                                  int* __restrict__ adj, int tot, int nn) {
  int i = blockIdx.x * 256 + threadIdx.x;
  if (i >= tot) return;
  int d_ = dstA[i];
  if (d_ < 0 || d_ >= nn) return;
  int pos = atomicAdd(&cur[d_], 1);
  adj[off[d_] + pos] = srcA[i];
}

// ---------------- per-batch: cumsum + residual + relu + head (wave per node) ----------------
template <bool XB>
__global__ __launch_bounds__(256) void k_out(const float* __restrict__ yx, const float* __restrict__ last,
                                             const float* __restrict__ oW, const float* __restrict__ ob_,
                                             float* __restrict__ dout, int nodes) {
  int wid = threadIdx.x >> 6, lane = threadIdx.x & 63;
  int node = blockIdx.x * 4 + wid;
  if (node >= nodes) return;
  float lw = oW[lane];
  float ob = ob_[0];
  float lv = last[(size_t)node * 64 + lane];
  float acc = 0.f;
  for (int tt = 0; tt < T_; tt++) {
    acc += yx[((size_t)tt * nodes + node) * 64 + lane];
    float v = fmaxf(acc + lv, 0.f);
    float p = v * lw;
#pragma unroll
    for (int o2 = 32; o2; o2 >>= 1) p += __shfl_down(p, o2);
    if (lane == 0) {
      float o = p + ob;
      if (XB) o = fminf(fmaxf(o / 6.f + 0.5f, 0.f), 1.f);
      else o = tanhf(o);
      dout[(size_t)tt * nodes + node] = o;
    }
  }
}

// ===================================================================================
extern "C" void kernel_launch(void* const* d_in, const int* in_sizes, int n_in,
                              void* d_out, int out_size, void* d_ws, size_t ws_size,
                              hipStream_t stream) {
  float* dout = (float*)d_out;

  if (n_in != 57) {
    k_sentinel<<<ceilDiv(out_size, 256), 256, 0, stream>>>(dout, out_size, 20000.f + 128.f * n_in);
    return;
  }
  static const int expSz[57] = {
      288000, 288000, 288000, 288000,
      256, 64, 192, 64, 128, 32, 96, 32,
      3000000,
      12288, 128, 128, 128, 12288, 128, 128, 128,
      4096, 64, 6000000, 6000000, 4096, 64, 6000000, 6000000,
      24576, 128,
      12288, 128, 128, 128, 12288, 128, 128, 128,
      4096, 64, 6000000, 6000000, 4096, 64, 6000000, 6000000,
      24576, 128,
      6144, 64, 4096, 64, 64, 1, 4000, 8000};
  for (int i = 0; i < 57; i++) {
    if (in_sizes[i] != expSz[i]) {
      k_sentinel<<<ceilDiv(out_size, 256), 256, 0, stream>>>(dout, out_size, 4096.f + 64.f * i);
      return;
    }
  }

  auto ff = [&](int i) { return (const float*)d_in[i]; };
  const float *x_in = ff(0), *e_in = ff(1), *b_in = ff(2), *a_in = ff(3);
  const float *enc0W = ff(4), *enc0b = ff(5), *enc1W = ff(6), *enc1b = ff(7);
  const float *enc2W = ff(8), *enc2b = ff(9), *enc3W = ff(10), *enc3b = ff(11);
  const float* inci = ff(12);
  const float *concW = ff(49), *concb = ff(50), *resW = ff(51), *resb = ff(52);
  const float *outW = ff(53), *outb = ff(54);
  const int* edge_ind = (const int*)d_in[55];
  const int* node_ind = (const int*)d_in[56];

  // ---- workspace layout, 256B-aligned ----
  char* base = (char*)d_ws;
  size_t off = 0;
  auto A = [&](size_t bytes) { void* p = base + off; off = (off + bytes + 255) & ~(size_t)255; return p; };
  char* SCR = (char*)A(21504000);
  bf16* xbuf = (bf16*)A(9216000);
  bf16* ebuf = (bf16*)A(12288000);
  float* lastx = (float*)A(768000);
  float* laste = (float*)A(1024000);
  float* es = (float*)A(384000);
  float* edv = (float*)A(384000);
  bf16* wAll = (bf16*)A(217088);  // fused weight region (see k_wprep)
  int* cntN = (int*)A((size_t)(N_ + N_ + E_ + E_) * 4);
  int* curN = cntN + N_;
  int* cntE = curN + N_;
  int* curE = cntE + E_;
  int* offN = (int*)A((N_ + 1) * 4);
  int* offE = (int*)A((E_ + 1) * 4);
  int* srcN = (int*)A((E_ + N_) * 4);
  int* dstN = (int*)A((E_ + N_) * 4);
  int* adjN = (int*)A((E_ + N_) * 4);
  int* srcE = (int*)A((M_ + E_) * 4);
  int* dstE = (int*)A((M_ + E_) * 4);
  int* adjE = (int*)A((M_ + E_) * 4);
  size_t required = off;

  if (ws_size < required) {
    k_sentinel<<<ceilDiv(out_size, 256), 256, 0, stream>>>(dout, out_size, 1000.f + (float)(ws_size >> 20));
    return;
  }

  // SCR aliases (liveness-checked)
  bf16* matb = (bf16*)SCR;
  bf16* tlinT = (bf16*)(SCR + 6553600);
  bf16* traw = (bf16*)(SCR + 13107200);
  bf16* tmat = (bf16*)(SCR + 13107200);
  bf16* zbuf = (bf16*)SCR;
  bf16* bscr = (bf16*)SCR;
  bf16* cx1 = (bf16*)SCR;
  bf16* ce1 = (bf16*)(SCR + 9216000);
  float* zres = (float*)SCR;

  const int totN = E_ + N_;   // 3500
  const int totE = M_ + E_;   // 6000

  // ---- fused weight prep (all static transposes in one dispatch) ----
  k_wprep<<<ceilDiv(108544, 256), 256, 0, stream>>>(ff(13), ff(17), ff(31), ff(35), concW, resW,
                                                    ff(29), ff(47), wAll);

  // ---- CSR build ----
  hipMemsetAsync(cntN, 0, (size_t)(N_ + N_ + E_ + E_) * sizeof(int), stream);
  k_csr_count<<<ceilDiv(totN, 256), 256, 0, stream>>>(edge_ind, E_, N_, cntN, srcN, dstN);
  k_scan<<<1, 1024, 0, stream>>>(cntN, offN, N_);
  k_csr_fill<<<ceilDiv(totN, 256), 256, 0, stream>>>(srcN, dstN, offN, curN, adjN, totN, N_);
  k_csr_count<<<ceilDiv(totE, 256), 256, 0, stream>>>(node_ind, M_, E_, cntE, srcE, dstE);
  k_scan<<<1, 1024, 0, stream>>>(cntE, offE, E_);
  k_csr_fill<<<ceilDiv(totE, 256), 256, 0, stream>>>(srcE, dstE, offE, curE, adjE, totE, E_);

  // ---- encoders ----
  k_enc<4, 64, true><<<ceilDiv(G_ * N_ * 64, 256), 256, 0, stream>>>(x_in, enc0W, enc0b, xbuf, lastx, N_);
  k_enc<3, 64, true><<<ceilDiv(G_ * E_ * 64, 256), 256, 0, stream>>>(e_in, enc1W, enc1b, ebuf, laste, E_);

  auto stblock = [&](int sb, int sbi) {
    const float *gxas = ff(sb + 1), *gxad = ff(sb + 2), *gxb = ff(sb + 3);
    const float *geas = ff(sb + 5), *gead = ff(sb + 6), *geb = ff(sb + 7);
    const float *neW = ff(sb + 8), *neb = ff(sb + 9), *nw = ff(sb + 10), *np_ = ff(sb + 11);
    const float *enW = ff(sb + 12), *enb = ff(sb + 13), *ew = ff(sb + 14), *ep = ff(sb + 15);
    const float* tpb = ff(sb + 17);
    for (int l = 0; l < 2; l++) {
      const bf16* gxw_t = wAll + sbi * 24576 + l * 6144;
      const bf16* gew_t = wAll + sbi * 24576 + 12288 + l * 6144;
      // ---- node side: xe = NodeEdge(e); x = relu(GAT([x,xe])) ----
      k_lin_ne<<<ceilDiv(E_ * G_ * 32, 256), 256, 0, stream>>>(ebuf, neW + l * 2048, neb + l * 32, traw, E_);
      k_trans<<<dim3(48, KPN / 32), dim3(32, 8), 0, stream>>>(traw, tlinT, E_, KPN);
      k_mat<<<ceilDiv(N_ * KPN, 256), 256, 0, stream>>>(nw + (size_t)l * N_ * E_, np_ + (size_t)l * N_ * E_, inci, matb, N_, E_, KPN);
      k_mgemm64<<<dim3(24, ceilDiv(N_, 64)), 256, 0, stream>>>(matb, tlinT, tmat, N_, KPN, 1536);
      k_mgemm<1, 64, false><<<dim3(1, ceilDiv(G_ * N_, 128)), 256, 0, stream>>>(xbuf, tmat, gxw_t, zbuf, G_ * N_, 96, 64, N_, nullptr, 0);
      k_esed<<<ceilDiv(G_ * N_, 4), 256, 0, stream>>>(zbuf, gxas + l * 64, gxad + l * 64, es, edv, G_ * N_);
      k_gat_aggr<<<ceilDiv(G_ * N_, 4), 256, 0, stream>>>(zbuf, es, edv, offN, adjN, gxb + l * 64, xbuf, N_);
      // ---- edge side: ex = NodeEdge(x); e = relu(GAT([e,ex])) ----
      k_lin_ne<<<ceilDiv(N_ * G_ * 32, 256), 256, 0, stream>>>(xbuf, enW + l * 2048, enb + l * 32, traw, N_);
      k_trans<<<dim3(48, KPE / 32), dim3(32, 8), 0, stream>>>(traw, tlinT, N_, KPE);
      k_matT<<<dim3(ceilDiv(E_, 32), KPE / 32), dim3(32, 8), 0, stream>>>(ew + (size_t)l * E_ * N_, ep + (size_t)l * E_ * N_, inci, matb);
      k_mgemm64<<<dim3(24, ceilDiv(E_, 64)), 256, 0, stream>>>(matb, tlinT, tmat, E_, KPE, 1536);
      k_mgemm<1, 64, false><<<dim3(1, ceilDiv(G_ * E_, 128)), 256, 0, stream>>>(ebuf, tmat, gew_t, zbuf, G_ * E_, 96, 64, E_, nullptr, 0);
      k_esed<<<ceilDiv(G_ * E_, 4), 256, 0, stream>>>(zbuf, geas + l * 64, gead + l * 64, es, edv, G_ * E_);
      k_gat_aggr<<<ceilDiv(G_ * E_, 4), 256, 0, stream>>>(zbuf, es, edv, offE, adjE, geb + l * 64, ebuf, E_);
    }
    // ---- temporal convs: shifted-view MFMA GEMMs ----
    const bf16* cw0 = wAll + 59392 + sbi * 24576;
    const bf16* cw1 = cw0 + 12288;
    k_cgemm<1><<<ceilDiv(G_ * N_, 128), 256, 0, stream>>>(xbuf, cw0, tpb, cx1, G_ * N_, N_);
    k_cgemm<1><<<ceilDiv(G_ * E_, 128), 256, 0, stream>>>(ebuf, cw0, tpb, ce1, G_ * E_, E_);
    k_cgemm<2><<<ceilDiv(G_ * N_, 128), 256, 0, stream>>>(cx1, cw1, tpb + 64, xbuf, G_ * N_, N_);
    k_cgemm<2><<<ceilDiv(G_ * E_, 128), 256, 0, stream>>>(ce1, cw1, tpb + 64, ebuf, G_ * E_, E_);
  };

  stblock(13, 0);

  // ---- conc (shared weights; in-place: gridDim.x==1 row ownership) ----
  const bf16* concT = wAll + 49152;
  k_enc<4, 32, false><<<ceilDiv(G_ * N_ * 32, 256), 256, 0, stream>>>(b_in, enc2W, enc2b, bscr, nullptr, N_);
  k_mgemm<2, 64, false><<<dim3(1, ceilDiv(G_ * N_, 128)), 256, 0, stream>>>(xbuf, bscr, concT, xbuf, G_ * N_, 96, 64, 0, concb, 1);
  k_enc<3, 32, false><<<ceilDiv(G_ * E_ * 32, 256), 256, 0, stream>>>(a_in, enc3W, enc3b, bscr, nullptr, E_);
  k_mgemm<2, 64, false><<<dim3(1, ceilDiv(G_ * E_, 128)), 256, 0, stream>>>(ebuf, bscr, concT, ebuf, G_ * E_, 96, 64, 0, concb, 1);

  stblock(31, 1);

  // ---- final per batch ----
  const bf16* resT = wAll + 55296;
  for (int b = 0; b < B_; b++) {
    k_mgemm<0, 64, true><<<dim3(1, ceilDiv(T_ * N_, 128)), 256, 0, stream>>>(
        xbuf + (size_t)b * T_ * N_ * 64, nullptr, resT, zres, T_ * N_, 64, 64, 0, resb, 0);
    k_out<true><<<ceilDiv(N_, 4), 256, 0, stream>>>(
        zres, lastx + (size_t)b * N_ * 64, outW, outb, dout + (size_t)b * T_ * N_, N_);
  }
  for (int b = 0; b < B_; b++) {
    k_mgemm<0, 64, true><<<dim3(1, ceilDiv(T_ * E_, 128)), 256, 0, stream>>>(
        ebuf + (size_t)b * T_ * E_ * 64, nullptr, resT, zres, T_ * E_, 64, 64, 0, resb, 0);
    k_out<false><<<ceilDiv(E_, 4), 256, 0, stream>>>(
        zres, laste + (size_t)b * E_ * 64, outW, outb, dout + (size_t)(B_ * T_ * N_) + (size_t)b * T_ * E_, E_);
  }
}

// Round 9
// 1341.551 us; speedup vs baseline: 3.6257x; 1.0833x over previous
//
#include <hip/hip_runtime.h>
#include <hip/hip_bf16.h>
#include <cfloat>
#include <math.h>

typedef __hip_bfloat16 bf16;
typedef __attribute__((ext_vector_type(8))) short short8v;
typedef __attribute__((ext_vector_type(4))) float f32x4;

constexpr int B_ = 2, T_ = 24, N_ = 1500, E_ = 2000, M_ = 4000, G_ = 48;
constexpr int KPN = 2016;  // padded K for node-side einsum (K=E_=2000)
constexpr int KPE = 1504;  // padded K for edge-side einsum (K=N_=1500)

__device__ __forceinline__ float b2f(bf16 v) { return __bfloat162float(v); }
__device__ __forceinline__ bf16 f2b(float v) { return __float2bfloat16(v); }
static inline int ceilDiv(int a, int b) { return (a + b - 1) / b; }

// ---------------- diagnostics (host-assert sentinel only) ----------------
__global__ __launch_bounds__(256) void k_sentinel(float* __restrict__ out, int n, float val) {
  int i = blockIdx.x * 256 + threadIdx.x;
  if (i < n) out[i] = val;
}

// ---------------- fused weight prep: all transposed bf16 weights in one pass ----------------
__global__ __launch_bounds__(256) void k_wprep(const float* __restrict__ g0, const float* __restrict__ e0,
                                               const float* __restrict__ g1, const float* __restrict__ e1,
                                               const float* __restrict__ cw, const float* __restrict__ rw,
                                               const float* __restrict__ t0, const float* __restrict__ t1,
                                               bf16* __restrict__ out) {
  int i = blockIdx.x * 256 + threadIdx.x;
  if (i >= 108544) return;
  float v;
  if (i < 49152) {
    int which = i / 12288, r = i % 12288;
    const float* W = which == 0 ? g0 : which == 1 ? e0 : which == 2 ? g1 : e1;
    int l = r / 6144, j = r % 6144;
    int n = j / 96, k = j % 96;
    v = W[l * 6144 + k * 64 + n];
  } else if (i < 55296) {
    int j = i - 49152, n = j / 96, k = j % 96;
    v = cw[k * 64 + n];
  } else if (i < 59392) {
    int j = i - 55296, n = j / 64, k = j % 64;
    v = rw[k * 64 + n];
  } else {
    int r = i - 59392;
    int which = r / 24576;
    const float* W = which ? t1 : t0;
    int rr = r % 24576;
    int l = rr / 12288, j = rr % 12288;
    int ii = j & 63, o = (j >> 6) & 63, k = j >> 12;
    v = W[l * 12288 + o * 192 + ii * 3 + k];
  }
  out[i] = f2b(v);
}

// ---------------- encoders ----------------
template <int DIN, int DOUT, bool SAVE>
__global__ __launch_bounds__(256) void k_enc(const float* __restrict__ in, const float* __restrict__ W,
                                             const float* __restrict__ bias, bf16* __restrict__ out,
                                             float* __restrict__ last, int nodes) {
  int idx = blockIdx.x * 256 + threadIdx.x;
  if (idx >= G_ * nodes * DOUT) return;
  int d = idx % DOUT;
  int row = idx / DOUT;
  int node = row % nodes;
  int g = row / nodes;
  const float* ir = in + (size_t)row * DIN;
  float acc = bias[d];
#pragma unroll
  for (int i = 0; i < DIN; i++) acc += ir[i] * W[i * DOUT + d];
  if (SAVE) {
    if (g % T_ == T_ - 1) last[((size_t)(g / T_) * nodes + node) * DOUT + d] = acc;  // pre-relu
  }
  out[idx] = f2b(fmaxf(acc, 0.f));
}

// ---------------- NodeEdge linear: relu(act @ W(64x32) + b) -> traw[node][g*32+f] bf16 ----
__global__ __launch_bounds__(256) void k_lin_ne(const bf16* __restrict__ act, const float* __restrict__ W,
                                                const float* __restrict__ bias, bf16* __restrict__ outT,
                                                int nodes) {
  __shared__ float Ws[2048];
  __shared__ float bs[32];
  for (int i = threadIdx.x; i < 2048; i += 256) Ws[i] = W[i];
  if (threadIdx.x < 32) bs[threadIdx.x] = bias[threadIdx.x];
  __syncthreads();
  int idx = blockIdx.x * 256 + threadIdx.x;
  if (idx >= nodes * G_ * 32) return;
  int f = idx & 31;
  int rem = idx >> 5;
  int g = rem % G_;
  int node = rem / G_;
  const bf16* row = act + ((size_t)g * nodes + node) * 64;
  float acc = bs[f];
#pragma unroll
  for (int i = 0; i < 64; i++) acc += b2f(row[i]) * Ws[i * 32 + f];
  outT[idx] = f2b(fmaxf(acc, 0.f));
}

// ---------------- bf16 transpose: in[K][1536] -> out[1536][Kp] (zero-padded) ----------------
__global__ void k_trans(const bf16* __restrict__ in, bf16* __restrict__ out, int K, int Kp) {
  __shared__ float tl[32][33];
  int c0 = blockIdx.x * 32, k0 = blockIdx.y * 32;
  for (int r = threadIdx.y; r < 32; r += 8) {
    int k = k0 + r, c = c0 + threadIdx.x;
    tl[r][threadIdx.x] = (k < K) ? b2f(in[(size_t)k * 1536 + c]) : 0.f;
  }
  __syncthreads();
  for (int r = threadIdx.y; r < 32; r += 8) {
    int c = c0 + r, k = k0 + threadIdx.x;
    if (k < Kp) out[(size_t)c * Kp + k] = f2b(tl[threadIdx.x][r]);
  }
}

// ---------------- masked incidence (padded): mat[n][k<E?val:0], [N_][Kp] ----------------
__global__ __launch_bounds__(256) void k_mat(const float* __restrict__ w, const float* __restrict__ p,
                                             const float* __restrict__ inci, bf16* __restrict__ mat,
                                             int rows, int K, int Kp) {
  int i = blockIdx.x * 256 + threadIdx.x;
  if (i >= rows * Kp) return;
  int row = i / Kp, k = i % Kp;
  float v = 0.f;
  if (k < K) {
    size_t o = (size_t)row * K + k;
    v = w[o] * fabsf(inci[o]) + p[o];
  }
  mat[i] = f2b(v);
}

// transposed variant: mat[e*KPE + n] = |inci[n][e]|*w[e*N+n] + p[e*N+n], zero-pad n>=N_
__global__ void k_matT(const float* __restrict__ w, const float* __restrict__ p,
                       const float* __restrict__ inci, bf16* __restrict__ mat) {
  __shared__ float tl[32][33];
  int e0 = blockIdx.x * 32, n0 = blockIdx.y * 32;
  for (int r = threadIdx.y; r < 32; r += 8) {
    int n = n0 + r, e = e0 + threadIdx.x;
    tl[r][threadIdx.x] = (n < N_ && e < E_) ? fabsf(inci[(size_t)n * E_ + e]) : 0.f;
  }
  __syncthreads();
  for (int r = threadIdx.y; r < 32; r += 8) {
    int e = e0 + r, n = n0 + threadIdx.x;
    if (e < E_ && n < KPE) {
      size_t o = (size_t)e * N_ + n;
      mat[(size_t)e * KPE + n] = (n < N_) ? f2b(tl[threadIdx.x][r] * w[o] + p[o]) : f2b(0.f);
    }
  }
}

// ---------------- 64x64-tile MFMA GEMM, double-buffered LDS, 1 barrier/K-step ----------------
__global__ __launch_bounds__(256) void k_mgemm64(const bf16* __restrict__ A0, const bf16* __restrict__ Bt,
                                                 bf16* __restrict__ Cp, int Mm, int Kp, int Nn) {
  __shared__ __align__(16) short As[2][4][64][8];
  __shared__ __align__(16) short Bs[2][4][64][8];
  int tid = threadIdx.x;
  int bm = blockIdx.y * 64, bn = blockIdx.x * 64;
  int lane = tid & 63, wid = tid >> 6;
  int wr = wid >> 1, wc = wid & 1;
  f32x4 acc[2][2];
#pragma unroll
  for (int i = 0; i < 2; i++)
#pragma unroll
    for (int j = 0; j < 2; j++) acc[i][j] = f32x4{0.f, 0.f, 0.f, 0.f};

  const int sr = tid >> 2;
  const int sc = tid & 3;
  const int kb = lane >> 4, lr = lane & 15;
  const int gmA = bm + sr, gnB = bn + sr;
  const bool va_ok = (gmA < Mm), vb_ok = (gnB < Nn);
  const bf16* ap = A0 + (size_t)gmA * Kp + sc * 8;
  const bf16* bp = Bt + (size_t)gnB * Kp + sc * 8;

  uint4 va = {0, 0, 0, 0}, vb = {0, 0, 0, 0};
  if (va_ok) va = *reinterpret_cast<const uint4*>(ap);
  if (vb_ok) vb = *reinterpret_cast<const uint4*>(bp);
  int cur = 0;
  for (int k0 = 0; k0 < Kp; k0 += 32) {
    *reinterpret_cast<uint4*>(&As[cur][sc][sr][0]) = va;
    *reinterpret_cast<uint4*>(&Bs[cur][sc][sr][0]) = vb;
    __syncthreads();
    int kn = k0 + 32;
    if (kn < Kp) {
      va = va_ok ? *reinterpret_cast<const uint4*>(ap + kn) : uint4{0, 0, 0, 0};
      vb = vb_ok ? *reinterpret_cast<const uint4*>(bp + kn) : uint4{0, 0, 0, 0};
    }
    short8v a[2], b[2];
#pragma unroll
    for (int mi = 0; mi < 2; mi++)
      a[mi] = *reinterpret_cast<const short8v*>(&As[cur][kb][wr * 32 + mi * 16 + lr][0]);
#pragma unroll
    for (int ni = 0; ni < 2; ni++)
      b[ni] = *reinterpret_cast<const short8v*>(&Bs[cur][kb][wc * 32 + ni * 16 + lr][0]);
#pragma unroll
    for (int mi = 0; mi < 2; mi++)
#pragma unroll
      for (int ni = 0; ni < 2; ni++)
        acc[mi][ni] = __builtin_amdgcn_mfma_f32_16x16x32_bf16(a[mi], b[ni], acc[mi][ni], 0, 0, 0);
    cur ^= 1;
  }
#pragma unroll
  for (int mi = 0; mi < 2; mi++) {
    int r0 = bm + wr * 32 + mi * 16 + (lane >> 4) * 4;
#pragma unroll
    for (int ni = 0; ni < 2; ni++) {
      int col = bn + wc * 32 + ni * 16 + lr;
      if (col >= Nn) continue;
#pragma unroll
      for (int i = 0; i < 4; i++) {
        int r = r0 + i;
        if (r < Mm) Cp[(size_t)r * Nn + col] = f2b(acc[mi][ni][i]);
      }
    }
  }
}

// ---------------- MFMA GEMM (128-row tile): z / conc / res GEMMs ----------------
template <int AMODE, int BNt, bool CF32b>
__global__ __launch_bounds__(256) void k_mgemm(const bf16* __restrict__ A0, const bf16* __restrict__ A1,
                                               const bf16* __restrict__ Bt, void* __restrict__ Cp,
                                               int Mm, int Kp, int Nn, int nodes,
                                               const float* __restrict__ bias, int relu) {
  constexpr int BM = 128;
  constexpr int WTN = BNt / 32;
  __shared__ __align__(16) short As[4][BM][8];
  __shared__ __align__(16) short Bs[4][BNt][8];
  int tid = threadIdx.x;
  int bm = blockIdx.y * BM;
  int bn = blockIdx.x * BNt;
  int lane = tid & 63;
  int wid = tid >> 6;
  int wr = wid >> 1, wc = wid & 1;
  f32x4 acc[4][WTN];
#pragma unroll
  for (int i = 0; i < 4; i++)
#pragma unroll
    for (int j = 0; j < WTN; j++) acc[i][j] = f32x4{0.f, 0.f, 0.f, 0.f};

  const int ar = tid >> 1;
  const int ah = tid & 1;
  const int kb = lane >> 4;
  const int lr = lane & 15;

  for (int k0 = 0; k0 < Kp; k0 += 32) {
    uint4 va0 = {0, 0, 0, 0}, va1 = {0, 0, 0, 0};
    int gm = bm + ar;
    if (gm < Mm) {
      int ks = k0 + ah * 16;
      const bf16* src;
      if (AMODE == 0) src = A0 + (size_t)gm * Kp + ks;
      else if (ks < 64) src = A0 + (size_t)gm * 64 + ks;
      else if (AMODE == 1) {
        int g = gm / nodes, nd = gm % nodes;
        src = A1 + ((size_t)nd * G_ + g) * 32 + (ks - 64);
      } else {
        src = A1 + (size_t)gm * 32 + (ks - 64);
      }
      const uint4* p = reinterpret_cast<const uint4*>(src);
      va0 = p[0];
      va1 = p[1];
    }
    *reinterpret_cast<uint4*>(&As[ah * 2 + 0][ar][0]) = va0;
    *reinterpret_cast<uint4*>(&As[ah * 2 + 1][ar][0]) = va1;
    if (BNt == 128) {
      int br = tid >> 1, bh = tid & 1;
      uint4 vb0 = {0, 0, 0, 0}, vb1 = {0, 0, 0, 0};
      int gn = bn + br;
      if (gn < Nn) {
        const uint4* p = reinterpret_cast<const uint4*>(Bt + (size_t)gn * Kp + k0 + bh * 16);
        vb0 = p[0];
        vb1 = p[1];
      }
      *reinterpret_cast<uint4*>(&Bs[bh * 2 + 0][br][0]) = vb0;
      *reinterpret_cast<uint4*>(&Bs[bh * 2 + 1][br][0]) = vb1;
    } else {
      int br = tid >> 2, bk = tid & 3;
      uint4 vb0 = {0, 0, 0, 0};
      int gn = bn + br;
      if (gn < Nn) vb0 = *reinterpret_cast<const uint4*>(Bt + (size_t)gn * Kp + k0 + bk * 8);
      *reinterpret_cast<uint4*>(&Bs[bk][br][0]) = vb0;
    }
    __syncthreads();
    short8v a[4], b[WTN];
#pragma unroll
    for (int mi = 0; mi < 4; mi++)
      a[mi] = *reinterpret_cast<const short8v*>(&As[kb][wr * 64 + mi * 16 + lr][0]);
#pragma unroll
    for (int ni = 0; ni < WTN; ni++)
      b[ni] = *reinterpret_cast<const short8v*>(&Bs[kb][wc * (BNt / 2) + ni * 16 + lr][0]);
#pragma unroll
    for (int mi = 0; mi < 4; mi++)
#pragma unroll
      for (int ni = 0; ni < WTN; ni++)
        acc[mi][ni] = __builtin_amdgcn_mfma_f32_16x16x32_bf16(a[mi], b[ni], acc[mi][ni], 0, 0, 0);
    __syncthreads();
  }
#pragma unroll
  for (int mi = 0; mi < 4; mi++) {
    int r0 = bm + wr * 64 + mi * 16 + (lane >> 4) * 4;
#pragma unroll
    for (int ni = 0; ni < WTN; ni++) {
      int col = bn + wc * (BNt / 2) + ni * 16 + lr;
      float bv = bias ? bias[col] : 0.f;
#pragma unroll
      for (int i = 0; i < 4; i++) {
        int r = r0 + i;
        if (r < Mm) {
          float v = acc[mi][ni][i] + bv;
          if (relu) v = fmaxf(v, 0.f);
          if (CF32b) ((float*)Cp)[(size_t)r * Nn + col] = v;
          else ((bf16*)Cp)[(size_t)r * Nn + col] = f2b(v);
        }
      }
    }
  }
}

// ---------------- causal dilated conv as MFMA GEMM over row-shifted views ----------------
template <int DIL>
__global__ __launch_bounds__(256) void k_cgemm(const bf16* __restrict__ A, const bf16* __restrict__ Wc,
                                               const float* __restrict__ bias, bf16* __restrict__ C,
                                               int Mm, int nodes) {
  __shared__ __align__(16) short As[4][128][8];
  __shared__ __align__(16) short Bs[4][64][8];
  int tid = threadIdx.x;
  int bm = blockIdx.x * 128;
  int lane = tid & 63;
  int wid = tid >> 6;
  int wr = wid >> 1, wc = wid & 1;
  f32x4 acc[4][2];
#pragma unroll
  for (int i = 0; i < 4; i++)
#pragma unroll
    for (int j = 0; j < 2; j++) acc[i][j] = f32x4{0.f, 0.f, 0.f, 0.f};

  const int ar = tid >> 1;
  const int ah = tid & 1;
  const int kb = lane >> 4;
  const int lr = lane & 15;
  const int gm = bm + ar;
  const int t = (gm / nodes) % T_;

#pragma unroll
  for (int k = 0; k < 3; k++) {
    const int sh = (k - 2) * DIL;
    const bool valid = (gm < Mm) && (t + sh >= 0);
    const bf16* arow = A + ((size_t)gm + (size_t)sh * nodes) * 64;
    const bf16* Bt = Wc + k * 4096;
#pragma unroll
    for (int k0 = 0; k0 < 64; k0 += 32) {
      uint4 va0 = {0, 0, 0, 0}, va1 = {0, 0, 0, 0};
      if (valid) {
        const uint4* p = reinterpret_cast<const uint4*>(arow + k0 + ah * 16);
        va0 = p[0];
        va1 = p[1];
      }
      *reinterpret_cast<uint4*>(&As[ah * 2 + 0][ar][0]) = va0;
      *reinterpret_cast<uint4*>(&As[ah * 2 + 1][ar][0]) = va1;
      {
        int br = tid >> 2, bk = tid & 3;
        uint4 vb = *reinterpret_cast<const uint4*>(Bt + (size_t)br * 64 + k0 + bk * 8);
        *reinterpret_cast<uint4*>(&Bs[bk][br][0]) = vb;
      }
      __syncthreads();
      short8v a[4], b[2];
#pragma unroll
      for (int mi = 0; mi < 4; mi++)
        a[mi] = *reinterpret_cast<const short8v*>(&As[kb][wr * 64 + mi * 16 + lr][0]);
#pragma unroll
      for (int ni = 0; ni < 2; ni++)
        b[ni] = *reinterpret_cast<const short8v*>(&Bs[kb][wc * 32 + ni * 16 + lr][0]);
#pragma unroll
      for (int mi = 0; mi < 4; mi++)
#pragma unroll
        for (int ni = 0; ni < 2; ni++)
          acc[mi][ni] = __builtin_amdgcn_mfma_f32_16x16x32_bf16(a[mi], b[ni], acc[mi][ni], 0, 0, 0);
      __syncthreads();
    }
  }
#pragma unroll
  for (int mi = 0; mi < 4; mi++) {
    int r0 = bm + wr * 64 + mi * 16 + (lane >> 4) * 4;
#pragma unroll
    for (int ni = 0; ni < 2; ni++) {
      int col = wc * 32 + ni * 16 + lr;
      float bv = bias[col];
#pragma unroll
      for (int i = 0; i < 4; i++) {
        int r = r0 + i;
        if (r < Mm) C[(size_t)r * 64 + col] = f2b(fmaxf(acc[mi][ni][i] + bv, 0.f));
      }
    }
  }
}

// ---------------- es/ed = z . a_s , z . a_d (wave per row) ----------------
__global__ __launch_bounds__(256) void k_esed(const bf16* __restrict__ z, const float* __restrict__ as_,
                                              const float* __restrict__ ad_, float* __restrict__ es,
                                              float* __restrict__ ed, int rows) {
  int wid = threadIdx.x >> 6, lane = threadIdx.x & 63;
  int row = blockIdx.x * 4 + wid;
  if (row >= rows) return;
  float zv = b2f(z[(size_t)row * 64 + lane]);
  float vs = zv * as_[lane];
  float vd = zv * ad_[lane];
#pragma unroll
  for (int off = 32; off; off >>= 1) { vs += __shfl_down(vs, off); vd += __shfl_down(vd, off); }
  if (lane == 0) { es[row] = vs; ed[row] = vd; }
}

// ---------------- GAT softmax weights: thread per (g,node), normalized exp weights ----------
__global__ __launch_bounds__(256) void k_gat_w(const float* __restrict__ es, const float* __restrict__ edv,
                                               const int* __restrict__ off, const int* __restrict__ adj,
                                               float* __restrict__ wgt, int nodes, int tot) {
  int idx = blockIdx.x * 256 + threadIdx.x;
  if (idx >= G_ * nodes) return;
  int g = idx / nodes, node = idx % nodes;
  int s0 = off[node], s1 = off[node + 1];
  const float* esg = es + (size_t)g * nodes;
  float edval = edv[(size_t)g * nodes + node];
  float m = -FLT_MAX;
  for (int s = s0; s < s1; s++) {
    float a = esg[adj[s]] + edval;
    a = (a >= 0.f) ? a : 0.2f * a;
    m = fmaxf(m, a);
  }
  float den = 0.f;
  float* wg = wgt + (size_t)g * tot;
  for (int s = s0; s < s1; s++) {
    float a = esg[adj[s]] + edval;
    a = (a >= 0.f) ? a : 0.2f * a;
    float ex = expf(a - m);
    den += ex;
    wg[s] = ex;
  }
  float inv = (s1 > s0) ? 1.f / den : 0.f;
  for (int s = s0; s < s1; s++) wg[s] *= inv;
}

// ---------------- GAT aggregation: pure weighted gather (wave per (g,node)) ----------------
__global__ __launch_bounds__(256) void k_gat_aggr2(const bf16* __restrict__ z, const float* __restrict__ wgt,
                                                   const int* __restrict__ off, const int* __restrict__ adj,
                                                   const float* __restrict__ bias, bf16* __restrict__ out,
                                                   int nodes, int tot) {
  int wid = threadIdx.x >> 6, lane = threadIdx.x & 63;
  int idx = blockIdx.x * 4 + wid;
  if (idx >= G_ * nodes) return;
  int g = idx / nodes, node = idx % nodes;
  int s0 = off[node], s1 = off[node + 1];
  int deg = s1 - s0;
  const bf16* zg = z + (size_t)g * nodes * 64;
  const float* wg = wgt + (size_t)g * tot;
  int adjv = 0;
  float wv = 0.f;
  if (lane < deg) {
    adjv = adj[s0 + lane];
    wv = wg[s0 + lane];
  }
  float num = 0.f;
  int dmax = deg < 64 ? deg : 64;
  for (int s = 0; s < dmax; s++) {
    int src = __shfl(adjv, s);
    float w = __shfl(wv, s);
    num += w * b2f(zg[(size_t)src * 64 + lane]);
  }
  for (int s = s0 + 64; s < s1; s++) {  // rare deep-degree tail
    num += wg[s] * b2f(zg[(size_t)adj[s] * 64 + lane]);
  }
  out[(size_t)idx * 64 + lane] = f2b(fmaxf(num + bias[lane], 0.f));
}

// ---------------- CSR build ----------------
__global__ __launch_bounds__(256) void k_csr_count(const int* __restrict__ ind, int ner, int nn,
                                                   int* __restrict__ cnt, int* __restrict__ srcA,
                                                   int* __restrict__ dstA) {
  int i = blockIdx.x * 256 + threadIdx.x;
  int tot = ner + nn;
  if (i >= tot) return;
  int s_, d_;
  if (i < ner) { s_ = ind[i]; d_ = ind[ner + i]; }
  else { s_ = d_ = i - ner; }
  srcA[i] = s_; dstA[i] = d_;
  if (d_ >= 0 && d_ < nn) atomicAdd(&cnt[d_], 1);
}

__global__ __launch_bounds__(1024) void k_scan(const int* __restrict__ cnt, int* __restrict__ off, int n) {
  __shared__ int a[1024];
  int t = threadIdx.x;
  int c0 = (2 * t < n) ? cnt[2 * t] : 0;
  int c1 = (2 * t + 1 < n) ? cnt[2 * t + 1] : 0;
  a[t] = c0 + c1;
  __syncthreads();
  for (int d = 1; d < 1024; d <<= 1) {
    int u = (t >= d) ? a[t - d] : 0;
    __syncthreads();
    a[t] += u;
    __syncthreads();
  }
  int excl = (t > 0) ? a[t - 1] : 0;
  if (2 * t < n) off[2 * t] = excl;
  if (2 * t + 1 < n) off[2 * t + 1] = excl + c0;
  if (t == 0) off[n] = a[1023];
}

__global__ __launch_bounds__(256) void k_csr_fill(const int* __restrict__ srcA, const int* __restrict__ dstA,
                                                  const int* __restrict__ off, int* __restrict__ cur,
                                                  int* __restrict__ adj, int tot, int nn) {
  int i = blockIdx.x * 256 + threadIdx.x;
  if (i >= tot) return;
  int d_ = dstA[i];
  if (d_ < 0 || d_ >= nn) return;
  int pos = atomicAdd(&cur[d_], 1);
  adj[off[d_] + pos] = srcA[i];
}

// ---------------- per-batch: cumsum + residual + relu + head (wave per node) ----------------
template <bool XB>
__global__ __launch_bounds__(256) void k_out(const float* __restrict__ yx, const float* __restrict__ last,
                                             const float* __restrict__ oW, const float* __restrict__ ob_,
                                             float* __restrict__ dout, int nodes) {
  int wid = threadIdx.x >> 6, lane = threadIdx.x & 63;
  int node = blockIdx.x * 4 + wid;
  if (node >= nodes) return;
  float lw = oW[lane];
  float ob = ob_[0];
  float lv = last[(size_t)node * 64 + lane];
  float acc = 0.f;
  for (int tt = 0; tt < T_; tt++) {
    acc += yx[((size_t)tt * nodes + node) * 64 + lane];
    float v = fmaxf(acc + lv, 0.f);
    float p = v * lw;
#pragma unroll
    for (int o2 = 32; o2; o2 >>= 1) p += __shfl_down(p, o2);
    if (lane == 0) {
      float o = p + ob;
      if (XB) o = fminf(fmaxf(o / 6.f + 0.5f, 0.f), 1.f);
      else o = tanhf(o);
      dout[(size_t)tt * nodes + node] = o;
    }
  }
}

// ===================================================================================
extern "C" void kernel_launch(void* const* d_in, const int* in_sizes, int n_in,
                              void* d_out, int out_size, void* d_ws, size_t ws_size,
                              hipStream_t stream) {
  float* dout = (float*)d_out;

  if (n_in != 57) {
    k_sentinel<<<ceilDiv(out_size, 256), 256, 0, stream>>>(dout, out_size, 20000.f + 128.f * n_in);
    return;
  }
  static const int expSz[57] = {
      288000, 288000, 288000, 288000,
      256, 64, 192, 64, 128, 32, 96, 32,
      3000000,
      12288, 128, 128, 128, 12288, 128, 128, 128,
      4096, 64, 6000000, 6000000, 4096, 64, 6000000, 6000000,
      24576, 128,
      12288, 128, 128, 128, 12288, 128, 128, 128,
      4096, 64, 6000000, 6000000, 4096, 64, 6000000, 6000000,
      24576, 128,
      6144, 64, 4096, 64, 64, 1, 4000, 8000};
  for (int i = 0; i < 57; i++) {
    if (in_sizes[i] != expSz[i]) {
      k_sentinel<<<ceilDiv(out_size, 256), 256, 0, stream>>>(dout, out_size, 4096.f + 64.f * i);
      return;
    }
  }

  auto ff = [&](int i) { return (const float*)d_in[i]; };
  const float *x_in = ff(0), *e_in = ff(1), *b_in = ff(2), *a_in = ff(3);
  const float *enc0W = ff(4), *enc0b = ff(5), *enc1W = ff(6), *enc1b = ff(7);
  const float *enc2W = ff(8), *enc2b = ff(9), *enc3W = ff(10), *enc3b = ff(11);
  const float* inci = ff(12);
  const float *concW = ff(49), *concb = ff(50), *resW = ff(51), *resb = ff(52);
  const float *outW = ff(53), *outb = ff(54);
  const int* edge_ind = (const int*)d_in[55];
  const int* node_ind = (const int*)d_in[56];

  // ---- workspace layout, 256B-aligned ----
  char* base = (char*)d_ws;
  size_t off = 0;
  auto A = [&](size_t bytes) { void* p = base + off; off = (off + bytes + 255) & ~(size_t)255; return p; };
  char* SCR = (char*)A(21504000);
  bf16* xbuf = (bf16*)A(9216000);
  bf16* ebuf = (bf16*)A(12288000);
  float* lastx = (float*)A(768000);
  float* laste = (float*)A(1024000);
  float* es = (float*)A(384000);
  float* edv = (float*)A(384000);
  float* wgt = (float*)A((size_t)G_ * (M_ + E_) * 4);  // 1.152 MB, softmax weights
  bf16* wAll = (bf16*)A(217088);  // fused weight region (see k_wprep)
  int* cntN = (int*)A((size_t)(N_ + N_ + E_ + E_) * 4);
  int* curN = cntN + N_;
  int* cntE = curN + N_;
  int* curE = cntE + E_;
  int* offN = (int*)A((N_ + 1) * 4);
  int* offE = (int*)A((E_ + 1) * 4);
  int* srcN = (int*)A((E_ + N_) * 4);
  int* dstN = (int*)A((E_ + N_) * 4);
  int* adjN = (int*)A((E_ + N_) * 4);
  int* srcE = (int*)A((M_ + E_) * 4);
  int* dstE = (int*)A((M_ + E_) * 4);
  int* adjE = (int*)A((M_ + E_) * 4);
  size_t required = off;

  if (ws_size < required) {
    k_sentinel<<<ceilDiv(out_size, 256), 256, 0, stream>>>(dout, out_size, 1000.f + (float)(ws_size >> 20));
    return;
  }

  // SCR aliases (liveness-checked)
  bf16* matb = (bf16*)SCR;
  bf16* tlinT = (bf16*)(SCR + 6553600);
  bf16* traw = (bf16*)(SCR + 13107200);
  bf16* tmat = (bf16*)(SCR + 13107200);
  bf16* zbuf = (bf16*)SCR;
  bf16* bscr = (bf16*)SCR;
  bf16* cx1 = (bf16*)SCR;
  bf16* ce1 = (bf16*)(SCR + 9216000);
  float* zres = (float*)SCR;

  const int totN = E_ + N_;   // 3500
  const int totE = M_ + E_;   // 6000

  // ---- fused weight prep ----
  k_wprep<<<ceilDiv(108544, 256), 256, 0, stream>>>(ff(13), ff(17), ff(31), ff(35), concW, resW,
                                                    ff(29), ff(47), wAll);

  // ---- CSR build ----
  hipMemsetAsync(cntN, 0, (size_t)(N_ + N_ + E_ + E_) * sizeof(int), stream);
  k_csr_count<<<ceilDiv(totN, 256), 256, 0, stream>>>(edge_ind, E_, N_, cntN, srcN, dstN);
  k_scan<<<1, 1024, 0, stream>>>(cntN, offN, N_);
  k_csr_fill<<<ceilDiv(totN, 256), 256, 0, stream>>>(srcN, dstN, offN, curN, adjN, totN, N_);
  k_csr_count<<<ceilDiv(totE, 256), 256, 0, stream>>>(node_ind, M_, E_, cntE, srcE, dstE);
  k_scan<<<1, 1024, 0, stream>>>(cntE, offE, E_);
  k_csr_fill<<<ceilDiv(totE, 256), 256, 0, stream>>>(srcE, dstE, offE, curE, adjE, totE, E_);

  // ---- encoders ----
  k_enc<4, 64, true><<<ceilDiv(G_ * N_ * 64, 256), 256, 0, stream>>>(x_in, enc0W, enc0b, xbuf, lastx, N_);
  k_enc<3, 64, true><<<ceilDiv(G_ * E_ * 64, 256), 256, 0, stream>>>(e_in, enc1W, enc1b, ebuf, laste, E_);

  auto stblock = [&](int sb, int sbi) {
    const float *gxas = ff(sb + 1), *gxad = ff(sb + 2), *gxb = ff(sb + 3);
    const float *geas = ff(sb + 5), *gead = ff(sb + 6), *geb = ff(sb + 7);
    const float *neW = ff(sb + 8), *neb = ff(sb + 9), *nw = ff(sb + 10), *np_ = ff(sb + 11);
    const float *enW = ff(sb + 12), *enb = ff(sb + 13), *ew = ff(sb + 14), *ep = ff(sb + 15);
    const float* tpb = ff(sb + 17);
    for (int l = 0; l < 2; l++) {
      const bf16* gxw_t = wAll + sbi * 24576 + l * 6144;
      const bf16* gew_t = wAll + sbi * 24576 + 12288 + l * 6144;
      // ---- node side: xe = NodeEdge(e); x = relu(GAT([x,xe])) ----
      k_lin_ne<<<ceilDiv(E_ * G_ * 32, 256), 256, 0, stream>>>(ebuf, neW + l * 2048, neb + l * 32, traw, E_);
      k_trans<<<dim3(48, KPN / 32), dim3(32, 8), 0, stream>>>(traw, tlinT, E_, KPN);
      k_mat<<<ceilDiv(N_ * KPN, 256), 256, 0, stream>>>(nw + (size_t)l * N_ * E_, np_ + (size_t)l * N_ * E_, inci, matb, N_, E_, KPN);
      k_mgemm64<<<dim3(24, ceilDiv(N_, 64)), 256, 0, stream>>>(matb, tlinT, tmat, N_, KPN, 1536);
      k_mgemm<1, 64, false><<<dim3(1, ceilDiv(G_ * N_, 128)), 256, 0, stream>>>(xbuf, tmat, gxw_t, zbuf, G_ * N_, 96, 64, N_, nullptr, 0);
      k_esed<<<ceilDiv(G_ * N_, 4), 256, 0, stream>>>(zbuf, gxas + l * 64, gxad + l * 64, es, edv, G_ * N_);
      k_gat_w<<<ceilDiv(G_ * N_, 256), 256, 0, stream>>>(es, edv, offN, adjN, wgt, N_, totN);
      k_gat_aggr2<<<ceilDiv(G_ * N_, 4), 256, 0, stream>>>(zbuf, wgt, offN, adjN, gxb + l * 64, xbuf, N_, totN);
      // ---- edge side: ex = NodeEdge(x); e = relu(GAT([e,ex])) ----
      k_lin_ne<<<ceilDiv(N_ * G_ * 32, 256), 256, 0, stream>>>(xbuf, enW + l * 2048, enb + l * 32, traw, N_);
      k_trans<<<dim3(48, KPE / 32), dim3(32, 8), 0, stream>>>(traw, tlinT, N_, KPE);
      k_matT<<<dim3(ceilDiv(E_, 32), KPE / 32), dim3(32, 8), 0, stream>>>(ew + (size_t)l * E_ * N_, ep + (size_t)l * E_ * N_, inci, matb);
      k_mgemm64<<<dim3(24, ceilDiv(E_, 64)), 256, 0, stream>>>(matb, tlinT, tmat, E_, KPE, 1536);
      k_mgemm<1, 64, false><<<dim3(1, ceilDiv(G_ * E_, 128)), 256, 0, stream>>>(ebuf, tmat, gew_t, zbuf, G_ * E_, 96, 64, E_, nullptr, 0);
      k_esed<<<ceilDiv(G_ * E_, 4), 256, 0, stream>>>(zbuf, geas + l * 64, gead + l * 64, es, edv, G_ * E_);
      k_gat_w<<<ceilDiv(G_ * E_, 256), 256, 0, stream>>>(es, edv, offE, adjE, wgt, E_, totE);
      k_gat_aggr2<<<ceilDiv(G_ * E_, 4), 256, 0, stream>>>(zbuf, wgt, offE, adjE, geb + l * 64, ebuf, E_, totE);
    }
    // ---- temporal convs: shifted-view MFMA GEMMs ----
    const bf16* cw0 = wAll + 59392 + sbi * 24576;
    const bf16* cw1 = cw0 + 12288;
    k_cgemm<1><<<ceilDiv(G_ * N_, 128), 256, 0, stream>>>(xbuf, cw0, tpb, cx1, G_ * N_, N_);
    k_cgemm<1><<<ceilDiv(G_ * E_, 128), 256, 0, stream>>>(ebuf, cw0, tpb, ce1, G_ * E_, E_);
    k_cgemm<2><<<ceilDiv(G_ * N_, 128), 256, 0, stream>>>(cx1, cw1, tpb + 64, xbuf, G_ * N_, N_);
    k_cgemm<2><<<ceilDiv(G_ * E_, 128), 256, 0, stream>>>(ce1, cw1, tpb + 64, ebuf, G_ * E_, E_);
  };

  stblock(13, 0);

  // ---- conc (shared weights; in-place: gridDim.x==1 row ownership) ----
  const bf16* concT = wAll + 49152;
  k_enc<4, 32, false><<<ceilDiv(G_ * N_ * 32, 256), 256, 0, stream>>>(b_in, enc2W, enc2b, bscr, nullptr, N_);
  k_mgemm<2, 64, false><<<dim3(1, ceilDiv(G_ * N_, 128)), 256, 0, stream>>>(xbuf, bscr, concT, xbuf, G_ * N_, 96, 64, 0, concb, 1);
  k_enc<3, 32, false><<<ceilDiv(G_ * E_ * 32, 256), 256, 0, stream>>>(a_in, enc3W, enc3b, bscr, nullptr, E_);
  k_mgemm<2, 64, false><<<dim3(1, ceilDiv(G_ * E_, 128)), 256, 0, stream>>>(ebuf, bscr, concT, ebuf, G_ * E_, 96, 64, 0, concb, 1);

  stblock(31, 1);

  // ---- final per batch ----
  const bf16* resT = wAll + 55296;
  for (int b = 0; b < B_; b++) {
    k_mgemm<0, 64, true><<<dim3(1, ceilDiv(T_ * N_, 128)), 256, 0, stream>>>(
        xbuf + (size_t)b * T_ * N_ * 64, nullptr, resT, zres, T_ * N_, 64, 64, 0, resb, 0);
    k_out<true><<<ceilDiv(N_, 4), 256, 0, stream>>>(
        zres, lastx + (size_t)b * N_ * 64, outW, outb, dout + (size_t)b * T_ * N_, N_);
  }
  for (int b = 0; b < B_; b++) {
    k_mgemm<0, 64, true><<<dim3(1, ceilDiv(T_ * E_, 128)), 256, 0, stream>>>(
        ebuf + (size_t)b * T_ * E_ * 64, nullptr, resT, zres, T_ * E_, 64, 64, 0, resb, 0);
    k_out<false><<<ceilDiv(E_, 4), 256, 0, stream>>>(
        zres, laste + (size_t)b * E_ * 64, outW, outb, dout + (size_t)(B_ * T_ * N_) + (size_t)b * T_ * E_, E_);
  }
}

// Round 10
// 1334.161 us; speedup vs baseline: 3.6457x; 1.0055x over previous
//
#include <hip/hip_runtime.h>
#include <hip/hip_bf16.h>
#include <cfloat>
#include <math.h>

typedef __hip_bfloat16 bf16;
typedef __attribute__((ext_vector_type(8))) short short8v;
typedef __attribute__((ext_vector_type(4))) float f32x4;

constexpr int B_ = 2, T_ = 24, N_ = 1500, E_ = 2000, M_ = 4000, G_ = 48;
constexpr int KPN = 2048;  // padded K for node-side einsum (K=E_=2000), 64-multiple
constexpr int KPE = 1536;  // padded K for edge-side einsum (K=N_=1500), 64-multiple

__device__ __forceinline__ float b2f(bf16 v) { return __bfloat162float(v); }
__device__ __forceinline__ bf16 f2b(float v) { return __float2bfloat16(v); }
static inline int ceilDiv(int a, int b) { return (a + b - 1) / b; }

// ---------------- diagnostics (host-assert sentinel only) ----------------
__global__ __launch_bounds__(256) void k_sentinel(float* __restrict__ out, int n, float val) {
  int i = blockIdx.x * 256 + threadIdx.x;
  if (i < n) out[i] = val;
}

// ---------------- fused weight prep: all transposed bf16 weights in one pass ----------------
__global__ __launch_bounds__(256) void k_wprep(const float* __restrict__ g0, const float* __restrict__ e0,
                                               const float* __restrict__ g1, const float* __restrict__ e1,
                                               const float* __restrict__ cw, const float* __restrict__ rw,
                                               const float* __restrict__ t0, const float* __restrict__ t1,
                                               bf16* __restrict__ out) {
  int i = blockIdx.x * 256 + threadIdx.x;
  if (i >= 108544) return;
  float v;
  if (i < 49152) {
    int which = i / 12288, r = i % 12288;
    const float* W = which == 0 ? g0 : which == 1 ? e0 : which == 2 ? g1 : e1;
    int l = r / 6144, j = r % 6144;
    int n = j / 96, k = j % 96;
    v = W[l * 6144 + k * 64 + n];
  } else if (i < 55296) {
    int j = i - 49152, n = j / 96, k = j % 96;
    v = cw[k * 64 + n];
  } else if (i < 59392) {
    int j = i - 55296, n = j / 64, k = j % 64;
    v = rw[k * 64 + n];
  } else {
    int r = i - 59392;
    int which = r / 24576;
    const float* W = which ? t1 : t0;
    int rr = r % 24576;
    int l = rr / 12288, j = rr % 12288;
    int ii = j & 63, o = (j >> 6) & 63, k = j >> 12;
    v = W[l * 12288 + o * 192 + ii * 3 + k];
  }
  out[i] = f2b(v);
}

// ---------------- encoders ----------------
template <int DIN, int DOUT, bool SAVE>
__global__ __launch_bounds__(256) void k_enc(const float* __restrict__ in, const float* __restrict__ W,
                                             const float* __restrict__ bias, bf16* __restrict__ out,
                                             float* __restrict__ last, int nodes) {
  int idx = blockIdx.x * 256 + threadIdx.x;
  if (idx >= G_ * nodes * DOUT) return;
  int d = idx % DOUT;
  int row = idx / DOUT;
  int node = row % nodes;
  int g = row / nodes;
  const float* ir = in + (size_t)row * DIN;
  float acc = bias[d];
#pragma unroll
  for (int i = 0; i < DIN; i++) acc += ir[i] * W[i * DOUT + d];
  if (SAVE) {
    if (g % T_ == T_ - 1) last[((size_t)(g / T_) * nodes + node) * DOUT + d] = acc;  // pre-relu
  }
  out[idx] = f2b(fmaxf(acc, 0.f));
}

// ---------------- NodeEdge linear: relu(act @ W(64x32) + b) -> traw[node][g*32+f] bf16 ----
__global__ __launch_bounds__(256) void k_lin_ne(const bf16* __restrict__ act, const float* __restrict__ W,
                                                const float* __restrict__ bias, bf16* __restrict__ outT,
                                                int nodes) {
  __shared__ float Ws[2048];
  __shared__ float bs[32];
  for (int i = threadIdx.x; i < 2048; i += 256) Ws[i] = W[i];
  if (threadIdx.x < 32) bs[threadIdx.x] = bias[threadIdx.x];
  __syncthreads();
  int idx = blockIdx.x * 256 + threadIdx.x;
  if (idx >= nodes * G_ * 32) return;
  int f = idx & 31;
  int rem = idx >> 5;
  int g = rem % G_;
  int node = rem / G_;
  const bf16* row = act + ((size_t)g * nodes + node) * 64;
  float acc = bs[f];
#pragma unroll
  for (int i = 0; i < 64; i++) acc += b2f(row[i]) * Ws[i * 32 + f];
  outT[idx] = f2b(fmaxf(acc, 0.f));
}

// ---------------- bf16 transpose: in[K][1536] -> out[1536][Kp] (zero-padded) ----------------
__global__ void k_trans(const bf16* __restrict__ in, bf16* __restrict__ out, int K, int Kp) {
  __shared__ float tl[32][33];
  int c0 = blockIdx.x * 32, k0 = blockIdx.y * 32;
  for (int r = threadIdx.y; r < 32; r += 8) {
    int k = k0 + r, c = c0 + threadIdx.x;
    tl[r][threadIdx.x] = (k < K) ? b2f(in[(size_t)k * 1536 + c]) : 0.f;
  }
  __syncthreads();
  for (int r = threadIdx.y; r < 32; r += 8) {
    int c = c0 + r, k = k0 + threadIdx.x;
    if (k < Kp) out[(size_t)c * Kp + k] = f2b(tl[threadIdx.x][r]);
  }
}

// ---------------- masked incidence (padded): mat[n][k<E?val:0], [N_][Kp] ----------------
__global__ __launch_bounds__(256) void k_mat(const float* __restrict__ w, const float* __restrict__ p,
                                             const float* __restrict__ inci, bf16* __restrict__ mat,
                                             int rows, int K, int Kp) {
  int i = blockIdx.x * 256 + threadIdx.x;
  if (i >= rows * Kp) return;
  int row = i / Kp, k = i % Kp;
  float v = 0.f;
  if (k < K) {
    size_t o = (size_t)row * K + k;
    v = w[o] * fabsf(inci[o]) + p[o];
  }
  mat[i] = f2b(v);
}

// transposed variant: mat[e*KPE + n] = |inci[n][e]|*w[e*N+n] + p[e*N+n], zero-pad n>=N_
__global__ void k_matT(const float* __restrict__ w, const float* __restrict__ p,
                       const float* __restrict__ inci, bf16* __restrict__ mat) {
  __shared__ float tl[32][33];
  int e0 = blockIdx.x * 32, n0 = blockIdx.y * 32;
  for (int r = threadIdx.y; r < 32; r += 8) {
    int n = n0 + r, e = e0 + threadIdx.x;
    tl[r][threadIdx.x] = (n < N_ && e < E_) ? fabsf(inci[(size_t)n * E_ + e]) : 0.f;
  }
  __syncthreads();
  for (int r = threadIdx.y; r < 32; r += 8) {
    int e = e0 + r, n = n0 + threadIdx.x;
    if (e < E_ && n < KPE) {
      size_t o = (size_t)e * N_ + n;
      mat[(size_t)e * KPE + n] = (n < N_) ? f2b(tl[threadIdx.x][r] * w[o] + p[o]) : f2b(0.f);
    }
  }
}

// ---------------- 64x64-tile MFMA GEMM, depth-2 pipelined (2 phases/iter, Kp%64==0) ----------
__global__ __launch_bounds__(256) void k_mgemm64(const bf16* __restrict__ A0, const bf16* __restrict__ Bt,
                                                 bf16* __restrict__ Cp, int Mm, int Kp, int Nn) {
  __shared__ __align__(16) short As[2][4][64][8];
  __shared__ __align__(16) short Bs[2][4][64][8];
  int tid = threadIdx.x;
  int bm = blockIdx.y * 64, bn = blockIdx.x * 64;
  int lane = tid & 63, wid = tid >> 6;
  int wr = wid >> 1, wc = wid & 1;
  f32x4 acc[2][2];
#pragma unroll
  for (int i = 0; i < 2; i++)
#pragma unroll
    for (int j = 0; j < 2; j++) acc[i][j] = f32x4{0.f, 0.f, 0.f, 0.f};

  const int sr = tid >> 2;
  const int sc = tid & 3;
  const int kb = lane >> 4, lr = lane & 15;
  const int gmA = bm + sr, gnB = bn + sr;
  const bool va_ok = (gmA < Mm), vb_ok = (gnB < Nn);
  const bf16* ap = A0 + (size_t)gmA * Kp + sc * 8;
  const bf16* bp = Bt + (size_t)gnB * Kp + sc * 8;
  const uint4 z4 = {0, 0, 0, 0};

  // named depth-2 register pipeline: slot A covers k0, slot B covers k0+32
  uint4 vaA = va_ok ? *reinterpret_cast<const uint4*>(ap) : z4;
  uint4 vbA = vb_ok ? *reinterpret_cast<const uint4*>(bp) : z4;
  uint4 vaB = va_ok ? *reinterpret_cast<const uint4*>(ap + 32) : z4;
  uint4 vbB = vb_ok ? *reinterpret_cast<const uint4*>(bp + 32) : z4;

  for (int k0 = 0; k0 < Kp; k0 += 64) {
    // ---- phase A (LDS buffer 0, k = k0..k0+32) ----
    *reinterpret_cast<uint4*>(&As[0][sc][sr][0]) = vaA;
    *reinterpret_cast<uint4*>(&Bs[0][sc][sr][0]) = vbA;
    __syncthreads();
    if (k0 + 64 < Kp) {  // issue next-iter phase-A loads; consumed one full iter later
      vaA = va_ok ? *reinterpret_cast<const uint4*>(ap + k0 + 64) : z4;
      vbA = vb_ok ? *reinterpret_cast<const uint4*>(bp + k0 + 64) : z4;
    }
    {
      short8v a0 = *reinterpret_cast<const short8v*>(&As[0][kb][wr * 32 + lr][0]);
      short8v a1 = *reinterpret_cast<const short8v*>(&As[0][kb][wr * 32 + 16 + lr][0]);
      short8v b0 = *reinterpret_cast<const short8v*>(&Bs[0][kb][wc * 32 + lr][0]);
      short8v b1 = *reinterpret_cast<const short8v*>(&Bs[0][kb][wc * 32 + 16 + lr][0]);
      __builtin_amdgcn_s_setprio(1);
      acc[0][0] = __builtin_amdgcn_mfma_f32_16x16x32_bf16(a0, b0, acc[0][0], 0, 0, 0);
      acc[0][1] = __builtin_amdgcn_mfma_f32_16x16x32_bf16(a0, b1, acc[0][1], 0, 0, 0);
      acc[1][0] = __builtin_amdgcn_mfma_f32_16x16x32_bf16(a1, b0, acc[1][0], 0, 0, 0);
      acc[1][1] = __builtin_amdgcn_mfma_f32_16x16x32_bf16(a1, b1, acc[1][1], 0, 0, 0);
      __builtin_amdgcn_s_setprio(0);
    }
    // ---- phase B (LDS buffer 1, k = k0+32..k0+64) ----
    *reinterpret_cast<uint4*>(&As[1][sc][sr][0]) = vaB;
    *reinterpret_cast<uint4*>(&Bs[1][sc][sr][0]) = vbB;
    __syncthreads();
    if (k0 + 96 < Kp) {
      vaB = va_ok ? *reinterpret_cast<const uint4*>(ap + k0 + 96) : z4;
      vbB = vb_ok ? *reinterpret_cast<const uint4*>(bp + k0 + 96) : z4;
    }
    {
      short8v a0 = *reinterpret_cast<const short8v*>(&As[1][kb][wr * 32 + lr][0]);
      short8v a1 = *reinterpret_cast<const short8v*>(&As[1][kb][wr * 32 + 16 + lr][0]);
      short8v b0 = *reinterpret_cast<const short8v*>(&Bs[1][kb][wc * 32 + lr][0]);
      short8v b1 = *reinterpret_cast<const short8v*>(&Bs[1][kb][wc * 32 + 16 + lr][0]);
      __builtin_amdgcn_s_setprio(1);
      acc[0][0] = __builtin_amdgcn_mfma_f32_16x16x32_bf16(a0, b0, acc[0][0], 0, 0, 0);
      acc[0][1] = __builtin_amdgcn_mfma_f32_16x16x32_bf16(a0, b1, acc[0][1], 0, 0, 0);
      acc[1][0] = __builtin_amdgcn_mfma_f32_16x16x32_bf16(a1, b0, acc[1][0], 0, 0, 0);
      acc[1][1] = __builtin_amdgcn_mfma_f32_16x16x32_bf16(a1, b1, acc[1][1], 0, 0, 0);
      __builtin_amdgcn_s_setprio(0);
    }
  }
#pragma unroll
  for (int mi = 0; mi < 2; mi++) {
    int r0 = bm + wr * 32 + mi * 16 + (lane >> 4) * 4;
#pragma unroll
    for (int ni = 0; ni < 2; ni++) {
      int col = bn + wc * 32 + ni * 16 + lr;
      if (col >= Nn) continue;
#pragma unroll
      for (int i = 0; i < 4; i++) {
        int r = r0 + i;
        if (r < Mm) Cp[(size_t)r * Nn + col] = f2b(acc[mi][ni][i]);
      }
    }
  }
}

// ---------------- MFMA GEMM (128-row tile): z / conc / res GEMMs ----------------
template <int AMODE, int BNt, bool CF32b>
__global__ __launch_bounds__(256) void k_mgemm(const bf16* __restrict__ A0, const bf16* __restrict__ A1,
                                               const bf16* __restrict__ Bt, void* __restrict__ Cp,
                                               int Mm, int Kp, int Nn, int nodes,
                                               const float* __restrict__ bias, int relu) {
  constexpr int BM = 128;
  constexpr int WTN = BNt / 32;
  __shared__ __align__(16) short As[4][BM][8];
  __shared__ __align__(16) short Bs[4][BNt][8];
  int tid = threadIdx.x;
  int bm = blockIdx.y * BM;
  int bn = blockIdx.x * BNt;
  int lane = tid & 63;
  int wid = tid >> 6;
  int wr = wid >> 1, wc = wid & 1;
  f32x4 acc[4][WTN];
#pragma unroll
  for (int i = 0; i < 4; i++)
#pragma unroll
    for (int j = 0; j < WTN; j++) acc[i][j] = f32x4{0.f, 0.f, 0.f, 0.f};

  const int ar = tid >> 1;
  const int ah = tid & 1;
  const int kb = lane >> 4;
  const int lr = lane & 15;

  for (int k0 = 0; k0 < Kp; k0 += 32) {
    uint4 va0 = {0, 0, 0, 0}, va1 = {0, 0, 0, 0};
    int gm = bm + ar;
    if (gm < Mm) {
      int ks = k0 + ah * 16;
      const bf16* src;
      if (AMODE == 0) src = A0 + (size_t)gm * Kp + ks;
      else if (ks < 64) src = A0 + (size_t)gm * 64 + ks;
      else if (AMODE == 1) {
        int g = gm / nodes, nd = gm % nodes;
        src = A1 + ((size_t)nd * G_ + g) * 32 + (ks - 64);
      } else {
        src = A1 + (size_t)gm * 32 + (ks - 64);
      }
      const uint4* p = reinterpret_cast<const uint4*>(src);
      va0 = p[0];
      va1 = p[1];
    }
    *reinterpret_cast<uint4*>(&As[ah * 2 + 0][ar][0]) = va0;
    *reinterpret_cast<uint4*>(&As[ah * 2 + 1][ar][0]) = va1;
    if (BNt == 128) {
      int br = tid >> 1, bh = tid & 1;
      uint4 vb0 = {0, 0, 0, 0}, vb1 = {0, 0, 0, 0};
      int gn = bn + br;
      if (gn < Nn) {
        const uint4* p = reinterpret_cast<const uint4*>(Bt + (size_t)gn * Kp + k0 + bh * 16);
        vb0 = p[0];
        vb1 = p[1];
      }
      *reinterpret_cast<uint4*>(&Bs[bh * 2 + 0][br][0]) = vb0;
      *reinterpret_cast<uint4*>(&Bs[bh * 2 + 1][br][0]) = vb1;
    } else {
      int br = tid >> 2, bk = tid & 3;
      uint4 vb0 = {0, 0, 0, 0};
      int gn = bn + br;
      if (gn < Nn) vb0 = *reinterpret_cast<const uint4*>(Bt + (size_t)gn * Kp + k0 + bk * 8);
      *reinterpret_cast<uint4*>(&Bs[bk][br][0]) = vb0;
    }
    __syncthreads();
    short8v a[4], b[WTN];
#pragma unroll
    for (int mi = 0; mi < 4; mi++)
      a[mi] = *reinterpret_cast<const short8v*>(&As[kb][wr * 64 + mi * 16 + lr][0]);
#pragma unroll
    for (int ni = 0; ni < WTN; ni++)
      b[ni] = *reinterpret_cast<const short8v*>(&Bs[kb][wc * (BNt / 2) + ni * 16 + lr][0]);
#pragma unroll
    for (int mi = 0; mi < 4; mi++)
#pragma unroll
      for (int ni = 0; ni < WTN; ni++)
        acc[mi][ni] = __builtin_amdgcn_mfma_f32_16x16x32_bf16(a[mi], b[ni], acc[mi][ni], 0, 0, 0);
    __syncthreads();
  }
#pragma unroll
  for (int mi = 0; mi < 4; mi++) {
    int r0 = bm + wr * 64 + mi * 16 + (lane >> 4) * 4;
#pragma unroll
    for (int ni = 0; ni < WTN; ni++) {
      int col = bn + wc * (BNt / 2) + ni * 16 + lr;
      float bv = bias ? bias[col] : 0.f;
#pragma unroll
      for (int i = 0; i < 4; i++) {
        int r = r0 + i;
        if (r < Mm) {
          float v = acc[mi][ni][i] + bv;
          if (relu) v = fmaxf(v, 0.f);
          if (CF32b) ((float*)Cp)[(size_t)r * Nn + col] = v;
          else ((bf16*)Cp)[(size_t)r * Nn + col] = f2b(v);
        }
      }
    }
  }
}

// ---------------- causal dilated conv as MFMA GEMM over row-shifted views ----------------
template <int DIL>
__global__ __launch_bounds__(256) void k_cgemm(const bf16* __restrict__ A, const bf16* __restrict__ Wc,
                                               const float* __restrict__ bias, bf16* __restrict__ C,
                                               int Mm, int nodes) {
  __shared__ __align__(16) short As[4][128][8];
  __shared__ __align__(16) short Bs[4][64][8];
  int tid = threadIdx.x;
  int bm = blockIdx.x * 128;
  int lane = tid & 63;
  int wid = tid >> 6;
  int wr = wid >> 1, wc = wid & 1;
  f32x4 acc[4][2];
#pragma unroll
  for (int i = 0; i < 4; i++)
#pragma unroll
    for (int j = 0; j < 2; j++) acc[i][j] = f32x4{0.f, 0.f, 0.f, 0.f};

  const int ar = tid >> 1;
  const int ah = tid & 1;
  const int kb = lane >> 4;
  const int lr = lane & 15;
  const int gm = bm + ar;
  const int t = (gm / nodes) % T_;

#pragma unroll
  for (int k = 0; k < 3; k++) {
    const int sh = (k - 2) * DIL;
    const bool valid = (gm < Mm) && (t + sh >= 0);
    const bf16* arow = A + ((size_t)gm + (size_t)sh * nodes) * 64;
    const bf16* Bt = Wc + k * 4096;
#pragma unroll
    for (int k0 = 0; k0 < 64; k0 += 32) {
      uint4 va0 = {0, 0, 0, 0}, va1 = {0, 0, 0, 0};
      if (valid) {
        const uint4* p = reinterpret_cast<const uint4*>(arow + k0 + ah * 16);
        va0 = p[0];
        va1 = p[1];
      }
      *reinterpret_cast<uint4*>(&As[ah * 2 + 0][ar][0]) = va0;
      *reinterpret_cast<uint4*>(&As[ah * 2 + 1][ar][0]) = va1;
      {
        int br = tid >> 2, bk = tid & 3;
        uint4 vb = *reinterpret_cast<const uint4*>(Bt + (size_t)br * 64 + k0 + bk * 8);
        *reinterpret_cast<uint4*>(&Bs[bk][br][0]) = vb;
      }
      __syncthreads();
      short8v a[4], b[2];
#pragma unroll
      for (int mi = 0; mi < 4; mi++)
        a[mi] = *reinterpret_cast<const short8v*>(&As[kb][wr * 64 + mi * 16 + lr][0]);
#pragma unroll
      for (int ni = 0; ni < 2; ni++)
        b[ni] = *reinterpret_cast<const short8v*>(&Bs[kb][wc * 32 + ni * 16 + lr][0]);
#pragma unroll
      for (int mi = 0; mi < 4; mi++)
#pragma unroll
        for (int ni = 0; ni < 2; ni++)
          acc[mi][ni] = __builtin_amdgcn_mfma_f32_16x16x32_bf16(a[mi], b[ni], acc[mi][ni], 0, 0, 0);
      __syncthreads();
    }
  }
#pragma unroll
  for (int mi = 0; mi < 4; mi++) {
    int r0 = bm + wr * 64 + mi * 16 + (lane >> 4) * 4;
#pragma unroll
    for (int ni = 0; ni < 2; ni++) {
      int col = wc * 32 + ni * 16 + lr;
      float bv = bias[col];
#pragma unroll
      for (int i = 0; i < 4; i++) {
        int r = r0 + i;
        if (r < Mm) C[(size_t)r * 64 + col] = f2b(fmaxf(acc[mi][ni][i] + bv, 0.f));
      }
    }
  }
}

// ---------------- es/ed = z . a_s , z . a_d (wave per row) ----------------
__global__ __launch_bounds__(256) void k_esed(const bf16* __restrict__ z, const float* __restrict__ as_,
                                              const float* __restrict__ ad_, float* __restrict__ es,
                                              float* __restrict__ ed, int rows) {
  int wid = threadIdx.x >> 6, lane = threadIdx.x & 63;
  int row = blockIdx.x * 4 + wid;
  if (row >= rows) return;
  float zv = b2f(z[(size_t)row * 64 + lane]);
  float vs = zv * as_[lane];
  float vd = zv * ad_[lane];
#pragma unroll
  for (int off = 32; off; off >>= 1) { vs += __shfl_down(vs, off); vd += __shfl_down(vd, off); }
  if (lane == 0) { es[row] = vs; ed[row] = vd; }
}

// ---------------- GAT softmax weights: thread per (g,node), normalized exp weights ----------
__global__ __launch_bounds__(256) void k_gat_w(const float* __restrict__ es, const float* __restrict__ edv,
                                               const int* __restrict__ off, const int* __restrict__ adj,
                                               float* __restrict__ wgt, int nodes, int tot) {
  int idx = blockIdx.x * 256 + threadIdx.x;
  if (idx >= G_ * nodes) return;
  int g = idx / nodes, node = idx % nodes;
  int s0 = off[node], s1 = off[node + 1];
  const float* esg = es + (size_t)g * nodes;
  float edval = edv[(size_t)g * nodes + node];
  float m = -FLT_MAX;
  for (int s = s0; s < s1; s++) {
    float a = esg[adj[s]] + edval;
    a = (a >= 0.f) ? a : 0.2f * a;
    m = fmaxf(m, a);
  }
  float den = 0.f;
  float* wg = wgt + (size_t)g * tot;
  for (int s = s0; s < s1; s++) {
    float a = esg[adj[s]] + edval;
    a = (a >= 0.f) ? a : 0.2f * a;
    float ex = expf(a - m);
    den += ex;
    wg[s] = ex;
  }
  float inv = (s1 > s0) ? 1.f / den : 0.f;
  for (int s = s0; s < s1; s++) wg[s] *= inv;
}

// ---------------- GAT aggregation: pure weighted gather (wave per (g,node)) ----------------
__global__ __launch_bounds__(256) void k_gat_aggr2(const bf16* __restrict__ z, const float* __restrict__ wgt,
                                                   const int* __restrict__ off, const int* __restrict__ adj,
                                                   const float* __restrict__ bias, bf16* __restrict__ out,
                                                   int nodes, int tot) {
  int wid = threadIdx.x >> 6, lane = threadIdx.x & 63;
  int idx = blockIdx.x * 4 + wid;
  if (idx >= G_ * nodes) return;
  int g = idx / nodes, node = idx % nodes;
  int s0 = off[node], s1 = off[node + 1];
  int deg = s1 - s0;
  const bf16* zg = z + (size_t)g * nodes * 64;
  const float* wg = wgt + (size_t)g * tot;
  int adjv = 0;
  float wv = 0.f;
  if (lane < deg) {
    adjv = adj[s0 + lane];
    wv = wg[s0 + lane];
  }
  float num = 0.f;
  int dmax = deg < 64 ? deg : 64;
  for (int s = 0; s < dmax; s++) {
    int src = __shfl(adjv, s);
    float w = __shfl(wv, s);
    num += w * b2f(zg[(size_t)src * 64 + lane]);
  }
  for (int s = s0 + 64; s < s1; s++) {
    num += wg[s] * b2f(zg[(size_t)adj[s] * 64 + lane]);
  }
  out[(size_t)idx * 64 + lane] = f2b(fmaxf(num + bias[lane], 0.f));
}

// ---------------- CSR build ----------------
__global__ __launch_bounds__(256) void k_csr_count(const int* __restrict__ ind, int ner, int nn,
                                                   int* __restrict__ cnt, int* __restrict__ srcA,
                                                   int* __restrict__ dstA) {
  int i = blockIdx.x * 256 + threadIdx.x;
  int tot = ner + nn;
  if (i >= tot) return;
  int s_, d_;
  if (i < ner) { s_ = ind[i]; d_ = ind[ner + i]; }
  else { s_ = d_ = i - ner; }
  srcA[i] = s_; dstA[i] = d_;
  if (d_ >= 0 && d_ < nn) atomicAdd(&cnt[d_], 1);
}

__global__ __launch_bounds__(1024) void k_scan(const int* __restrict__ cnt, int* __restrict__ off, int n) {
  __shared__ int a[1024];
  int t = threadIdx.x;
  int c0 = (2 * t < n) ? cnt[2 * t] : 0;
  int c1 = (2 * t + 1 < n) ? cnt[2 * t + 1] : 0;
  a[t] = c0 + c1;
  __syncthreads();
  for (int d = 1; d < 1024; d <<= 1) {
    int u = (t >= d) ? a[t - d] : 0;
    __syncthreads();
    a[t] += u;
    __syncthreads();
  }
  int excl = (t > 0) ? a[t - 1] : 0;
  if (2 * t < n) off[2 * t] = excl;
  if (2 * t + 1 < n) off[2 * t + 1] = excl + c0;
  if (t == 0) off[n] = a[1023];
}

__global__ __launch_bounds__(256) void k_csr_fill(const int* __restrict__ srcA, const int* __restrict__ dstA,
                                                  const int* __restrict__ off, int* __restrict__ cur,
                                                  int* __restrict__ adj, int tot, int nn) {
  int i = blockIdx.x * 256 + threadIdx.x;
  if (i >= tot) return;
  int d_ = dstA[i];
  if (d_ < 0 || d_ >= nn) return;
  int pos = atomicAdd(&cur[d_], 1);
  adj[off[d_] + pos] = srcA[i];
}

// ---------------- per-batch: cumsum + residual + relu + head (wave per node) ----------------
template <bool XB>
__global__ __launch_bounds__(256) void k_out(const float* __restrict__ yx, const float* __restrict__ last,
                                             const float* __restrict__ oW, const float* __restrict__ ob_,
                                             float* __restrict__ dout, int nodes) {
  int wid = threadIdx.x >> 6, lane = threadIdx.x & 63;
  int node = blockIdx.x * 4 + wid;
  if (node >= nodes) return;
  float lw = oW[lane];
  float ob = ob_[0];
  float lv = last[(size_t)node * 64 + lane];
  float acc = 0.f;
  for (int tt = 0; tt < T_; tt++) {
    acc += yx[((size_t)tt * nodes + node) * 64 + lane];
    float v = fmaxf(acc + lv, 0.f);
    float p = v * lw;
#pragma unroll
    for (int o2 = 32; o2; o2 >>= 1) p += __shfl_down(p, o2);
    if (lane == 0) {
      float o = p + ob;
      if (XB) o = fminf(fmaxf(o / 6.f + 0.5f, 0.f), 1.f);
      else o = tanhf(o);
      dout[(size_t)tt * nodes + node] = o;
    }
  }
}

// ===================================================================================
extern "C" void kernel_launch(void* const* d_in, const int* in_sizes, int n_in,
                              void* d_out, int out_size, void* d_ws, size_t ws_size,
                              hipStream_t stream) {
  float* dout = (float*)d_out;

  if (n_in != 57) {
    k_sentinel<<<ceilDiv(out_size, 256), 256, 0, stream>>>(dout, out_size, 20000.f + 128.f * n_in);
    return;
  }
  static const int expSz[57] = {
      288000, 288000, 288000, 288000,
      256, 64, 192, 64, 128, 32, 96, 32,
      3000000,
      12288, 128, 128, 128, 12288, 128, 128, 128,
      4096, 64, 6000000, 6000000, 4096, 64, 6000000, 6000000,
      24576, 128,
      12288, 128, 128, 128, 12288, 128, 128, 128,
      4096, 64, 6000000, 6000000, 4096, 64, 6000000, 6000000,
      24576, 128,
      6144, 64, 4096, 64, 64, 1, 4000, 8000};
  for (int i = 0; i < 57; i++) {
    if (in_sizes[i] != expSz[i]) {
      k_sentinel<<<ceilDiv(out_size, 256), 256, 0, stream>>>(dout, out_size, 4096.f + 64.f * i);
      return;
    }
  }

  auto ff = [&](int i) { return (const float*)d_in[i]; };
  const float *x_in = ff(0), *e_in = ff(1), *b_in = ff(2), *a_in = ff(3);
  const float *enc0W = ff(4), *enc0b = ff(5), *enc1W = ff(6), *enc1b = ff(7);
  const float *enc2W = ff(8), *enc2b = ff(9), *enc3W = ff(10), *enc3b = ff(11);
  const float* inci = ff(12);
  const float *concW = ff(49), *concb = ff(50), *resW = ff(51), *resb = ff(52);
  const float *outW = ff(53), *outb = ff(54);
  const int* edge_ind = (const int*)d_in[55];
  const int* node_ind = (const int*)d_in[56];

  // ---- workspace layout, 256B-aligned ----
  char* base = (char*)d_ws;
  size_t off = 0;
  auto A = [&](size_t bytes) { void* p = base + off; off = (off + bytes + 255) & ~(size_t)255; return p; };
  char* SCR = (char*)A(21504000);
  bf16* xbuf = (bf16*)A(9216000);
  bf16* ebuf = (bf16*)A(12288000);
  float* lastx = (float*)A(768000);
  float* laste = (float*)A(1024000);
  float* es = (float*)A(384000);
  float* edv = (float*)A(384000);
  float* wgt = (float*)A((size_t)G_ * (M_ + E_) * 4);
  bf16* wAll = (bf16*)A(217088);
  int* cntN = (int*)A((size_t)(N_ + N_ + E_ + E_) * 4);
  int* curN = cntN + N_;
  int* cntE = curN + N_;
  int* curE = cntE + E_;
  int* offN = (int*)A((N_ + 1) * 4);
  int* offE = (int*)A((E_ + 1) * 4);
  int* srcN = (int*)A((E_ + N_) * 4);
  int* dstN = (int*)A((E_ + N_) * 4);
  int* adjN = (int*)A((E_ + N_) * 4);
  int* srcE = (int*)A((M_ + E_) * 4);
  int* dstE = (int*)A((M_ + E_) * 4);
  int* adjE = (int*)A((M_ + E_) * 4);
  size_t required = off;

  if (ws_size < required) {
    k_sentinel<<<ceilDiv(out_size, 256), 256, 0, stream>>>(dout, out_size, 1000.f + (float)(ws_size >> 20));
    return;
  }

  // SCR aliases (liveness-checked; KPN=2048: matb 6.14MB, tlinT 6.29MB fits @6.5536M..12.85M)
  bf16* matb = (bf16*)SCR;
  bf16* tlinT = (bf16*)(SCR + 6553600);
  bf16* traw = (bf16*)(SCR + 13107200);
  bf16* tmat = (bf16*)(SCR + 13107200);
  bf16* zbuf = (bf16*)SCR;
  bf16* bscr = (bf16*)SCR;
  bf16* cx1 = (bf16*)SCR;
  bf16* ce1 = (bf16*)(SCR + 9216000);
  float* zres = (float*)SCR;

  const int totN = E_ + N_;   // 3500
  const int totE = M_ + E_;   // 6000

  // ---- fused weight prep ----
  k_wprep<<<ceilDiv(108544, 256), 256, 0, stream>>>(ff(13), ff(17), ff(31), ff(35), concW, resW,
                                                    ff(29), ff(47), wAll);

  // ---- CSR build ----
  hipMemsetAsync(cntN, 0, (size_t)(N_ + N_ + E_ + E_) * sizeof(int), stream);
  k_csr_count<<<ceilDiv(totN, 256), 256, 0, stream>>>(edge_ind, E_, N_, cntN, srcN, dstN);
  k_scan<<<1, 1024, 0, stream>>>(cntN, offN, N_);
  k_csr_fill<<<ceilDiv(totN, 256), 256, 0, stream>>>(srcN, dstN, offN, curN, adjN, totN, N_);
  k_csr_count<<<ceilDiv(totE, 256), 256, 0, stream>>>(node_ind, M_, E_, cntE, srcE, dstE);
  k_scan<<<1, 1024, 0, stream>>>(cntE, offE, E_);
  k_csr_fill<<<ceilDiv(totE, 256), 256, 0, stream>>>(srcE, dstE, offE, curE, adjE, totE, E_);

  // ---- encoders ----
  k_enc<4, 64, true><<<ceilDiv(G_ * N_ * 64, 256), 256, 0, stream>>>(x_in, enc0W, enc0b, xbuf, lastx, N_);
  k_enc<3, 64, true><<<ceilDiv(G_ * E_ * 64, 256), 256, 0, stream>>>(e_in, enc1W, enc1b, ebuf, laste, E_);

  auto stblock = [&](int sb, int sbi) {
    const float *gxas = ff(sb + 1), *gxad = ff(sb + 2), *gxb = ff(sb + 3);
    const float *geas = ff(sb + 5), *gead = ff(sb + 6), *geb = ff(sb + 7);
    const float *neW = ff(sb + 8), *neb = ff(sb + 9), *nw = ff(sb + 10), *np_ = ff(sb + 11);
    const float *enW = ff(sb + 12), *enb = ff(sb + 13), *ew = ff(sb + 14), *ep = ff(sb + 15);
    const float* tpb = ff(sb + 17);
    for (int l = 0; l < 2; l++) {
      const bf16* gxw_t = wAll + sbi * 24576 + l * 6144;
      const bf16* gew_t = wAll + sbi * 24576 + 12288 + l * 6144;
      // ---- node side: xe = NodeEdge(e); x = relu(GAT([x,xe])) ----
      k_lin_ne<<<ceilDiv(E_ * G_ * 32, 256), 256, 0, stream>>>(ebuf, neW + l * 2048, neb + l * 32, traw, E_);
      k_trans<<<dim3(48, KPN / 32), dim3(32, 8), 0, stream>>>(traw, tlinT, E_, KPN);
      k_mat<<<ceilDiv(N_ * KPN, 256), 256, 0, stream>>>(nw + (size_t)l * N_ * E_, np_ + (size_t)l * N_ * E_, inci, matb, N_, E_, KPN);
      k_mgemm64<<<dim3(24, ceilDiv(N_, 64)), 256, 0, stream>>>(matb, tlinT, tmat, N_, KPN, 1536);
      k_mgemm<1, 64, false><<<dim3(1, ceilDiv(G_ * N_, 128)), 256, 0, stream>>>(xbuf, tmat, gxw_t, zbuf, G_ * N_, 96, 64, N_, nullptr, 0);
      k_esed<<<ceilDiv(G_ * N_, 4), 256, 0, stream>>>(zbuf, gxas + l * 64, gxad + l * 64, es, edv, G_ * N_);
      k_gat_w<<<ceilDiv(G_ * N_, 256), 256, 0, stream>>>(es, edv, offN, adjN, wgt, N_, totN);
      k_gat_aggr2<<<ceilDiv(G_ * N_, 4), 256, 0, stream>>>(zbuf, wgt, offN, adjN, gxb + l * 64, xbuf, N_, totN);
      // ---- edge side: ex = NodeEdge(x); e = relu(GAT([e,ex])) ----
      k_lin_ne<<<ceilDiv(N_ * G_ * 32, 256), 256, 0, stream>>>(xbuf, enW + l * 2048, enb + l * 32, traw, N_);
      k_trans<<<dim3(48, KPE / 32), dim3(32, 8), 0, stream>>>(traw, tlinT, N_, KPE);
      k_matT<<<dim3(ceilDiv(E_, 32), KPE / 32), dim3(32, 8), 0, stream>>>(ew + (size_t)l * E_ * N_, ep + (size_t)l * E_ * N_, inci, matb);
      k_mgemm64<<<dim3(24, ceilDiv(E_, 64)), 256, 0, stream>>>(matb, tlinT, tmat, E_, KPE, 1536);
      k_mgemm<1, 64, false><<<dim3(1, ceilDiv(G_ * E_, 128)), 256, 0, stream>>>(ebuf, tmat, gew_t, zbuf, G_ * E_, 96, 64, E_, nullptr, 0);
      k_esed<<<ceilDiv(G_ * E_, 4), 256, 0, stream>>>(zbuf, geas + l * 64, gead + l * 64, es, edv, G_ * E_);
      k_gat_w<<<ceilDiv(G_ * E_, 256), 256, 0, stream>>>(es, edv, offE, adjE, wgt, E_, totE);
      k_gat_aggr2<<<ceilDiv(G_ * E_, 4), 256, 0, stream>>>(zbuf, wgt, offE, adjE, geb + l * 64, ebuf, E_, totE);
    }
    // ---- temporal convs: shifted-view MFMA GEMMs ----
    const bf16* cw0 = wAll + 59392 + sbi * 24576;
    const bf16* cw1 = cw0 + 12288;
    k_cgemm<1><<<ceilDiv(G_ * N_, 128), 256, 0, stream>>>(xbuf, cw0, tpb, cx1, G_ * N_, N_);
    k_cgemm<1><<<ceilDiv(G_ * E_, 128), 256, 0, stream>>>(ebuf, cw0, tpb, ce1, G_ * E_, E_);
    k_cgemm<2><<<ceilDiv(G_ * N_, 128), 256, 0, stream>>>(cx1, cw1, tpb + 64, xbuf, G_ * N_, N_);
    k_cgemm<2><<<ceilDiv(G_ * E_, 128), 256, 0, stream>>>(ce1, cw1, tpb + 64, ebuf, G_ * E_, E_);
  };

  stblock(13, 0);

  // ---- conc (shared weights; in-place: gridDim.x==1 row ownership) ----
  const bf16* concT = wAll + 49152;
  k_enc<4, 32, false><<<ceilDiv(G_ * N_ * 32, 256), 256, 0, stream>>>(b_in, enc2W, enc2b, bscr, nullptr, N_);
  k_mgemm<2, 64, false><<<dim3(1, ceilDiv(G_ * N_, 128)), 256, 0, stream>>>(xbuf, bscr, concT, xbuf, G_ * N_, 96, 64, 0, concb, 1);
  k_enc<3, 32, false><<<ceilDiv(G_ * E_ * 32, 256), 256, 0, stream>>>(a_in, enc3W, enc3b, bscr, nullptr, E_);
  k_mgemm<2, 64, false><<<dim3(1, ceilDiv(G_ * E_, 128)), 256, 0, stream>>>(ebuf, bscr, concT, ebuf, G_ * E_, 96, 64, 0, concb, 1);

  stblock(31, 1);

  // ---- final per batch ----
  const bf16* resT = wAll + 55296;
  for (int b = 0; b < B_; b++) {
    k_mgemm<0, 64, true><<<dim3(1, ceilDiv(T_ * N_, 128)), 256, 0, stream>>>(
        xbuf + (size_t)b * T_ * N_ * 64, nullptr, resT, zres, T_ * N_, 64, 64, 0, resb, 0);
    k_out<true><<<ceilDiv(N_, 4), 256, 0, stream>>>(
        zres, lastx + (size_t)b * N_ * 64, outW, outb, dout + (size_t)b * T_ * N_, N_);
  }
  for (int b = 0; b < B_; b++) {
    k_mgemm<0, 64, true><<<dim3(1, ceilDiv(T_ * E_, 128)), 256, 0, stream>>>(
        ebuf + (size_t)b * T_ * E_ * 64, nullptr, resT, zres, T_ * E_, 64, 64, 0, resb, 0);
    k_out<false><<<ceilDiv(E_, 4), 256, 0, stream>>>(
        zres, laste + (size_t)b * E_ * 64, outW, outb, dout + (size_t)(B_ * T_ * N_) + (size_t)b * T_ * E_, E_);
  }
}

// Round 11
// 1331.311 us; speedup vs baseline: 3.6536x; 1.0021x over previous
//
#include <hip/hip_runtime.h>
#include <hip/hip_bf16.h>
#include <cfloat>
#include <math.h>

typedef __hip_bfloat16 bf16;
typedef __attribute__((ext_vector_type(8))) short short8v;
typedef __attribute__((ext_vector_type(4))) float f32x4;

constexpr int B_ = 2, T_ = 24, N_ = 1500, E_ = 2000, M_ = 4000, G_ = 48;
constexpr int KPN = 2048;  // padded K for node-side einsum (K=E_=2000), 64-multiple
constexpr int KPE = 1536;  // padded K for edge-side einsum (K=N_=1500), 64-multiple

__device__ __forceinline__ float b2f(bf16 v) { return __bfloat162float(v); }
__device__ __forceinline__ bf16 f2b(float v) { return __float2bfloat16(v); }
static inline int ceilDiv(int a, int b) { return (a + b - 1) / b; }

// ---------------- diagnostics (host-assert sentinel only) ----------------
__global__ __launch_bounds__(256) void k_sentinel(float* __restrict__ out, int n, float val) {
  int i = blockIdx.x * 256 + threadIdx.x;
  if (i < n) out[i] = val;
}

// ---------------- fused weight prep: all transposed bf16 weights in one pass ----------------
__global__ __launch_bounds__(256) void k_wprep(const float* __restrict__ g0, const float* __restrict__ e0,
                                               const float* __restrict__ g1, const float* __restrict__ e1,
                                               const float* __restrict__ cw, const float* __restrict__ rw,
                                               const float* __restrict__ t0, const float* __restrict__ t1,
                                               bf16* __restrict__ out) {
  int i = blockIdx.x * 256 + threadIdx.x;
  if (i >= 108544) return;
  float v;
  if (i < 49152) {
    int which = i / 12288, r = i % 12288;
    const float* W = which == 0 ? g0 : which == 1 ? e0 : which == 2 ? g1 : e1;
    int l = r / 6144, j = r % 6144;
    int n = j / 96, k = j % 96;
    v = W[l * 6144 + k * 64 + n];
  } else if (i < 55296) {
    int j = i - 49152, n = j / 96, k = j % 96;
    v = cw[k * 64 + n];
  } else if (i < 59392) {
    int j = i - 55296, n = j / 64, k = j % 64;
    v = rw[k * 64 + n];
  } else {
    int r = i - 59392;
    int which = r / 24576;
    const float* W = which ? t1 : t0;
    int rr = r % 24576;
    int l = rr / 12288, j = rr % 12288;
    int ii = j & 63, o = (j >> 6) & 63, k = j >> 12;
    v = W[l * 12288 + o * 192 + ii * 3 + k];
  }
  out[i] = f2b(v);
}

// ---------------- encoders ----------------
template <int DIN, int DOUT, bool SAVE>
__global__ __launch_bounds__(256) void k_enc(const float* __restrict__ in, const float* __restrict__ W,
                                             const float* __restrict__ bias, bf16* __restrict__ out,
                                             float* __restrict__ last, int nodes) {
  int idx = blockIdx.x * 256 + threadIdx.x;
  if (idx >= G_ * nodes * DOUT) return;
  int d = idx % DOUT;
  int row = idx / DOUT;
  int node = row % nodes;
  int g = row / nodes;
  const float* ir = in + (size_t)row * DIN;
  float acc = bias[d];
#pragma unroll
  for (int i = 0; i < DIN; i++) acc += ir[i] * W[i * DOUT + d];
  if (SAVE) {
    if (g % T_ == T_ - 1) last[((size_t)(g / T_) * nodes + node) * DOUT + d] = acc;  // pre-relu
  }
  out[idx] = f2b(fmaxf(acc, 0.f));
}

// ---------------- NodeEdge linear: relu(act @ W(64x32) + b) -> traw[node][g*32+f] bf16 ----
__global__ __launch_bounds__(256) void k_lin_ne(const bf16* __restrict__ act, const float* __restrict__ W,
                                                const float* __restrict__ bias, bf16* __restrict__ outT,
                                                int nodes) {
  __shared__ float Ws[2048];
  __shared__ float bs[32];
  for (int i = threadIdx.x; i < 2048; i += 256) Ws[i] = W[i];
  if (threadIdx.x < 32) bs[threadIdx.x] = bias[threadIdx.x];
  __syncthreads();
  int idx = blockIdx.x * 256 + threadIdx.x;
  if (idx >= nodes * G_ * 32) return;
  int f = idx & 31;
  int rem = idx >> 5;
  int g = rem % G_;
  int node = rem / G_;
  const bf16* row = act + ((size_t)g * nodes + node) * 64;
  float acc = bs[f];
#pragma unroll
  for (int i = 0; i < 64; i++) acc += b2f(row[i]) * Ws[i * 32 + f];
  outT[idx] = f2b(fmaxf(acc, 0.f));
}

// ---------------- bf16 transpose: in[K][1536] -> out[1536][Kp] (zero-padded) ----------------
__global__ void k_trans(const bf16* __restrict__ in, bf16* __restrict__ out, int K, int Kp) {
  __shared__ float tl[32][33];
  int c0 = blockIdx.x * 32, k0 = blockIdx.y * 32;
  for (int r = threadIdx.y; r < 32; r += 8) {
    int k = k0 + r, c = c0 + threadIdx.x;
    tl[r][threadIdx.x] = (k < K) ? b2f(in[(size_t)k * 1536 + c]) : 0.f;
  }
  __syncthreads();
  for (int r = threadIdx.y; r < 32; r += 8) {
    int c = c0 + r, k = k0 + threadIdx.x;
    if (k < Kp) out[(size_t)c * Kp + k] = f2b(tl[threadIdx.x][r]);
  }
}

// ---------------- masked incidence (padded): mat[n][k<E?val:0], [N_][Kp] ----------------
__global__ __launch_bounds__(256) void k_mat(const float* __restrict__ w, const float* __restrict__ p,
                                             const float* __restrict__ inci, bf16* __restrict__ mat,
                                             int rows, int K, int Kp) {
  int i = blockIdx.x * 256 + threadIdx.x;
  if (i >= rows * Kp) return;
  int row = i / Kp, k = i % Kp;
  float v = 0.f;
  if (k < K) {
    size_t o = (size_t)row * K + k;
    v = w[o] * fabsf(inci[o]) + p[o];
  }
  mat[i] = f2b(v);
}

// transposed variant: mat[e*KPE + n] = |inci[n][e]|*w[e*N+n] + p[e*N+n], zero-pad n>=N_
__global__ void k_matT(const float* __restrict__ w, const float* __restrict__ p,
                       const float* __restrict__ inci, bf16* __restrict__ mat) {
  __shared__ float tl[32][33];
  int e0 = blockIdx.x * 32, n0 = blockIdx.y * 32;
  for (int r = threadIdx.y; r < 32; r += 8) {
    int n = n0 + r, e = e0 + threadIdx.x;
    tl[r][threadIdx.x] = (n < N_ && e < E_) ? fabsf(inci[(size_t)n * E_ + e]) : 0.f;
  }
  __syncthreads();
  for (int r = threadIdx.y; r < 32; r += 8) {
    int e = e0 + r, n = n0 + threadIdx.x;
    if (e < E_ && n < KPE) {
      size_t o = (size_t)e * N_ + n;
      mat[(size_t)e * KPE + n] = (n < N_) ? f2b(tl[threadIdx.x][r] * w[o] + p[o]) : f2b(0.f);
    }
  }
}

// ---------------- 64x64-tile MFMA GEMM, depth-4 pipeline (loads 2 phases in flight) --------
// Hazard schedule (body p, p even): write L[(p+1)&3]; compute L[p&3]; BAR; write L[(p+2)&3];
// compute L[(p+1)&3]; BAR.  Every buffer is written >=1 barrier before compute; WAR gaps >=3
// barriers.  Register pairs: r1 holds ld(p+1), r2 holds ld(p+2) at body start.
__global__ __launch_bounds__(256) void k_mgemm64(const bf16* __restrict__ A0, const bf16* __restrict__ Bt,
                                                 bf16* __restrict__ Cp, int Mm, int Kp, int Nn) {
  __shared__ __align__(16) short As[4][4][64][8];
  __shared__ __align__(16) short Bs[4][4][64][8];
  int tid = threadIdx.x;
  int bm = blockIdx.y * 64, bn = blockIdx.x * 64;
  int lane = tid & 63, wid = tid >> 6;
  int wr = wid >> 1, wc = wid & 1;
  f32x4 acc[2][2];
#pragma unroll
  for (int i = 0; i < 2; i++)
#pragma unroll
    for (int j = 0; j < 2; j++) acc[i][j] = f32x4{0.f, 0.f, 0.f, 0.f};

  const int sr = tid >> 2;
  const int sc = tid & 3;
  const int kb = lane >> 4, lr = lane & 15;
  const int gmA = bm + sr, gnB = bn + sr;
  const bool va_ok = (gmA < Mm), vb_ok = (gnB < Nn);
  const bf16* ap = A0 + (size_t)gmA * Kp + sc * 8;
  const bf16* bp = Bt + (size_t)gnB * Kp + sc * 8;
  const uint4 z4 = {0, 0, 0, 0};
  const int P = Kp >> 5;  // phases (even, >= 4)

  // prologue
  uint4 va0 = va_ok ? *reinterpret_cast<const uint4*>(ap) : z4;        // ld(0)
  uint4 vb0 = vb_ok ? *reinterpret_cast<const uint4*>(bp) : z4;
  uint4 va1 = va_ok ? *reinterpret_cast<const uint4*>(ap + 32) : z4;   // ld(1) -> r1
  uint4 vb1 = vb_ok ? *reinterpret_cast<const uint4*>(bp + 32) : z4;
  *reinterpret_cast<uint4*>(&As[0][sc][sr][0]) = va0;
  *reinterpret_cast<uint4*>(&Bs[0][sc][sr][0]) = vb0;
  uint4 va2 = va_ok ? *reinterpret_cast<const uint4*>(ap + 64) : z4;   // ld(2) -> r2
  uint4 vb2 = vb_ok ? *reinterpret_cast<const uint4*>(bp + 64) : z4;
  __syncthreads();

  for (int p = 0; p < P; p += 2) {
    // write L[(p+1)&3] = r1 (=ld(p+1)); refill r1 = ld(p+3)
    *reinterpret_cast<uint4*>(&As[(p + 1) & 3][sc][sr][0]) = va1;
    *reinterpret_cast<uint4*>(&Bs[(p + 1) & 3][sc][sr][0]) = vb1;
    if (p + 3 < P) {
      va1 = va_ok ? *reinterpret_cast<const uint4*>(ap + (p + 3) * 32) : z4;
      vb1 = vb_ok ? *reinterpret_cast<const uint4*>(bp + (p + 3) * 32) : z4;
    }
    {  // compute phase p from L[p&3]
      int bf = p & 3;
      short8v a0 = *reinterpret_cast<const short8v*>(&As[bf][kb][wr * 32 + lr][0]);
      short8v a1 = *reinterpret_cast<const short8v*>(&As[bf][kb][wr * 32 + 16 + lr][0]);
      short8v b0 = *reinterpret_cast<const short8v*>(&Bs[bf][kb][wc * 32 + lr][0]);
      short8v b1 = *reinterpret_cast<const short8v*>(&Bs[bf][kb][wc * 32 + 16 + lr][0]);
      __builtin_amdgcn_s_setprio(1);
      acc[0][0] = __builtin_amdgcn_mfma_f32_16x16x32_bf16(a0, b0, acc[0][0], 0, 0, 0);
      acc[0][1] = __builtin_amdgcn_mfma_f32_16x16x32_bf16(a0, b1, acc[0][1], 0, 0, 0);
      acc[1][0] = __builtin_amdgcn_mfma_f32_16x16x32_bf16(a1, b0, acc[1][0], 0, 0, 0);
      acc[1][1] = __builtin_amdgcn_mfma_f32_16x16x32_bf16(a1, b1, acc[1][1], 0, 0, 0);
      __builtin_amdgcn_s_setprio(0);
    }
    __syncthreads();
    // write L[(p+2)&3] = r2 (=ld(p+2)); refill r2 = ld(p+4)
    *reinterpret_cast<uint4*>(&As[(p + 2) & 3][sc][sr][0]) = va2;
    *reinterpret_cast<uint4*>(&Bs[(p + 2) & 3][sc][sr][0]) = vb2;
    if (p + 4 < P) {
      va2 = va_ok ? *reinterpret_cast<const uint4*>(ap + (p + 4) * 32) : z4;
      vb2 = vb_ok ? *reinterpret_cast<const uint4*>(bp + (p + 4) * 32) : z4;
    }
    {  // compute phase p+1 from L[(p+1)&3]
      int bf = (p + 1) & 3;
      short8v a0 = *reinterpret_cast<const short8v*>(&As[bf][kb][wr * 32 + lr][0]);
      short8v a1 = *reinterpret_cast<const short8v*>(&As[bf][kb][wr * 32 + 16 + lr][0]);
      short8v b0 = *reinterpret_cast<const short8v*>(&Bs[bf][kb][wc * 32 + lr][0]);
      short8v b1 = *reinterpret_cast<const short8v*>(&Bs[bf][kb][wc * 32 + 16 + lr][0]);
      __builtin_amdgcn_s_setprio(1);
      acc[0][0] = __builtin_amdgcn_mfma_f32_16x16x32_bf16(a0, b0, acc[0][0], 0, 0, 0);
      acc[0][1] = __builtin_amdgcn_mfma_f32_16x16x32_bf16(a0, b1, acc[0][1], 0, 0, 0);
      acc[1][0] = __builtin_amdgcn_mfma_f32_16x16x32_bf16(a1, b0, acc[1][0], 0, 0, 0);
      acc[1][1] = __builtin_amdgcn_mfma_f32_16x16x32_bf16(a1, b1, acc[1][1], 0, 0, 0);
      __builtin_amdgcn_s_setprio(0);
    }
    __syncthreads();
  }
#pragma unroll
  for (int mi = 0; mi < 2; mi++) {
    int r0 = bm + wr * 32 + mi * 16 + (lane >> 4) * 4;
#pragma unroll
    for (int ni = 0; ni < 2; ni++) {
      int col = bn + wc * 32 + ni * 16 + lr;
      if (col >= Nn) continue;
#pragma unroll
      for (int i = 0; i < 2 + 2; i++) {
        int r = r0 + i;
        if (r < Mm) Cp[(size_t)r * Nn + col] = f2b(acc[mi][ni][i]);
      }
    }
  }
}

// ---------------- MFMA GEMM (128-row tile): z / conc / res GEMMs ----------------
template <int AMODE, int BNt, bool CF32b>
__global__ __launch_bounds__(256) void k_mgemm(const bf16* __restrict__ A0, const bf16* __restrict__ A1,
                                               const bf16* __restrict__ Bt, void* __restrict__ Cp,
                                               int Mm, int Kp, int Nn, int nodes,
                                               const float* __restrict__ bias, int relu) {
  constexpr int BM = 128;
  constexpr int WTN = BNt / 32;
  __shared__ __align__(16) short As[4][BM][8];
  __shared__ __align__(16) short Bs[4][BNt][8];
  int tid = threadIdx.x;
  int bm = blockIdx.y * BM;
  int bn = blockIdx.x * BNt;
  int lane = tid & 63;
  int wid = tid >> 6;
  int wr = wid >> 1, wc = wid & 1;
  f32x4 acc[4][WTN];
#pragma unroll
  for (int i = 0; i < 4; i++)
#pragma unroll
    for (int j = 0; j < WTN; j++) acc[i][j] = f32x4{0.f, 0.f, 0.f, 0.f};

  const int ar = tid >> 1;
  const int ah = tid & 1;
  const int kb = lane >> 4;
  const int lr = lane & 15;

  for (int k0 = 0; k0 < Kp; k0 += 32) {
    uint4 va0 = {0, 0, 0, 0}, va1 = {0, 0, 0, 0};
    int gm = bm + ar;
    if (gm < Mm) {
      int ks = k0 + ah * 16;
      const bf16* src;
      if (AMODE == 0) src = A0 + (size_t)gm * Kp + ks;
      else if (ks < 64) src = A0 + (size_t)gm * 64 + ks;
      else if (AMODE == 1) {
        int g = gm / nodes, nd = gm % nodes;
        src = A1 + ((size_t)nd * G_ + g) * 32 + (ks - 64);
      } else {
        src = A1 + (size_t)gm * 32 + (ks - 64);
      }
      const uint4* p = reinterpret_cast<const uint4*>(src);
      va0 = p[0];
      va1 = p[1];
    }
    *reinterpret_cast<uint4*>(&As[ah * 2 + 0][ar][0]) = va0;
    *reinterpret_cast<uint4*>(&As[ah * 2 + 1][ar][0]) = va1;
    if (BNt == 128) {
      int br = tid >> 1, bh = tid & 1;
      uint4 vb0 = {0, 0, 0, 0}, vb1 = {0, 0, 0, 0};
      int gn = bn + br;
      if (gn < Nn) {
        const uint4* p = reinterpret_cast<const uint4*>(Bt + (size_t)gn * Kp + k0 + bh * 16);
        vb0 = p[0];
        vb1 = p[1];
      }
      *reinterpret_cast<uint4*>(&Bs[bh * 2 + 0][br][0]) = vb0;
      *reinterpret_cast<uint4*>(&Bs[bh * 2 + 1][br][0]) = vb1;
    } else {
      int br = tid >> 2, bk = tid & 3;
      uint4 vb0 = {0, 0, 0, 0};
      int gn = bn + br;
      if (gn < Nn) vb0 = *reinterpret_cast<const uint4*>(Bt + (size_t)gn * Kp + k0 + bk * 8);
      *reinterpret_cast<uint4*>(&Bs[bk][br][0]) = vb0;
    }
    __syncthreads();
    short8v a[4], b[WTN];
#pragma unroll
    for (int mi = 0; mi < 4; mi++)
      a[mi] = *reinterpret_cast<const short8v*>(&As[kb][wr * 64 + mi * 16 + lr][0]);
#pragma unroll
    for (int ni = 0; ni < WTN; ni++)
      b[ni] = *reinterpret_cast<const short8v*>(&Bs[kb][wc * (BNt / 2) + ni * 16 + lr][0]);
#pragma unroll
    for (int mi = 0; mi < 4; mi++)
#pragma unroll
      for (int ni = 0; ni < WTN; ni++)
        acc[mi][ni] = __builtin_amdgcn_mfma_f32_16x16x32_bf16(a[mi], b[ni], acc[mi][ni], 0, 0, 0);
    __syncthreads();
  }
#pragma unroll
  for (int mi = 0; mi < 4; mi++) {
    int r0 = bm + wr * 64 + mi * 16 + (lane >> 4) * 4;
#pragma unroll
    for (int ni = 0; ni < WTN; ni++) {
      int col = bn + wc * (BNt / 2) + ni * 16 + lr;
      float bv = bias ? bias[col] : 0.f;
#pragma unroll
      for (int i = 0; i < 4; i++) {
        int r = r0 + i;
        if (r < Mm) {
          float v = acc[mi][ni][i] + bv;
          if (relu) v = fmaxf(v, 0.f);
          if (CF32b) ((float*)Cp)[(size_t)r * Nn + col] = v;
          else ((bf16*)Cp)[(size_t)r * Nn + col] = f2b(v);
        }
      }
    }
  }
}

// ---------------- causal dilated conv as MFMA GEMM over row-shifted views ----------------
template <int DIL>
__global__ __launch_bounds__(256) void k_cgemm(const bf16* __restrict__ A, const bf16* __restrict__ Wc,
                                               const float* __restrict__ bias, bf16* __restrict__ C,
                                               int Mm, int nodes) {
  __shared__ __align__(16) short As[4][128][8];
  __shared__ __align__(16) short Bs[4][64][8];
  int tid = threadIdx.x;
  int bm = blockIdx.x * 128;
  int lane = tid & 63;
  int wid = tid >> 6;
  int wr = wid >> 1, wc = wid & 1;
  f32x4 acc[4][2];
#pragma unroll
  for (int i = 0; i < 4; i++)
#pragma unroll
    for (int j = 0; j < 2; j++) acc[i][j] = f32x4{0.f, 0.f, 0.f, 0.f};

  const int ar = tid >> 1;
  const int ah = tid & 1;
  const int kb = lane >> 4;
  const int lr = lane & 15;
  const int gm = bm + ar;
  const int t = (gm / nodes) % T_;

#pragma unroll
  for (int k = 0; k < 3; k++) {
    const int sh = (k - 2) * DIL;
    const bool valid = (gm < Mm) && (t + sh >= 0);
    const bf16* arow = A + ((size_t)gm + (size_t)sh * nodes) * 64;
    const bf16* Bt = Wc + k * 4096;
#pragma unroll
    for (int k0 = 0; k0 < 64; k0 += 32) {
      uint4 va0 = {0, 0, 0, 0}, va1 = {0, 0, 0, 0};
      if (valid) {
        const uint4* p = reinterpret_cast<const uint4*>(arow + k0 + ah * 16);
        va0 = p[0];
        va1 = p[1];
      }
      *reinterpret_cast<uint4*>(&As[ah * 2 + 0][ar][0]) = va0;
      *reinterpret_cast<uint4*>(&As[ah * 2 + 1][ar][0]) = va1;
      {
        int br = tid >> 2, bk = tid & 3;
        uint4 vb = *reinterpret_cast<const uint4*>(Bt + (size_t)br * 64 + k0 + bk * 8);
        *reinterpret_cast<uint4*>(&Bs[bk][br][0]) = vb;
      }
      __syncthreads();
      short8v a[4], b[2];
#pragma unroll
      for (int mi = 0; mi < 4; mi++)
        a[mi] = *reinterpret_cast<const short8v*>(&As[kb][wr * 64 + mi * 16 + lr][0]);
#pragma unroll
      for (int ni = 0; ni < 2; ni++)
        b[ni] = *reinterpret_cast<const short8v*>(&Bs[kb][wc * 32 + ni * 16 + lr][0]);
#pragma unroll
      for (int mi = 0; mi < 4; mi++)
#pragma unroll
        for (int ni = 0; ni < 2; ni++)
          acc[mi][ni] = __builtin_amdgcn_mfma_f32_16x16x32_bf16(a[mi], b[ni], acc[mi][ni], 0, 0, 0);
      __syncthreads();
    }
  }
#pragma unroll
  for (int mi = 0; mi < 4; mi++) {
    int r0 = bm + wr * 64 + mi * 16 + (lane >> 4) * 4;
#pragma unroll
    for (int ni = 0; ni < 2; ni++) {
      int col = wc * 32 + ni * 16 + lr;
      float bv = bias[col];
#pragma unroll
      for (int i = 0; i < 4; i++) {
        int r = r0 + i;
        if (r < Mm) C[(size_t)r * 64 + col] = f2b(fmaxf(acc[mi][ni][i] + bv, 0.f));
      }
    }
  }
}

// ---------------- es/ed = z . a_s , z . a_d (wave per row) ----------------
__global__ __launch_bounds__(256) void k_esed(const bf16* __restrict__ z, const float* __restrict__ as_,
                                              const float* __restrict__ ad_, float* __restrict__ es,
                                              float* __restrict__ ed, int rows) {
  int wid = threadIdx.x >> 6, lane = threadIdx.x & 63;
  int row = blockIdx.x * 4 + wid;
  if (row >= rows) return;
  float zv = b2f(z[(size_t)row * 64 + lane]);
  float vs = zv * as_[lane];
  float vd = zv * ad_[lane];
#pragma unroll
  for (int off = 32; off; off >>= 1) { vs += __shfl_down(vs, off); vd += __shfl_down(vd, off); }
  if (lane == 0) { es[row] = vs; ed[row] = vd; }
}

// ---------------- fused GAT softmax + aggregation (wave per (g,node)) ----------------
// Lanes 0..deg-1 own one edge each (deg<=64 fast path); softmax via wave shfl reductions;
// aggregation broadcasts (adj, w) from lane s while all 64 lanes gather feature `lane`.
__global__ __launch_bounds__(256) void k_gat(const bf16* __restrict__ z, const float* __restrict__ es,
                                             const float* __restrict__ edv, const int* __restrict__ off,
                                             const int* __restrict__ adj, const float* __restrict__ bias,
                                             bf16* __restrict__ out, int nodes) {
  int wid = threadIdx.x >> 6, lane = threadIdx.x & 63;
  int idx = blockIdx.x * 4 + wid;
  if (idx >= G_ * nodes) return;
  int g = idx / nodes, node = idx % nodes;
  int s0 = off[node], s1 = off[node + 1];
  int deg = s1 - s0;
  const float* esg = es + (size_t)g * nodes;
  const bf16* zg = z + (size_t)g * nodes * 64;
  float edval = edv[(size_t)g * nodes + node];
  float num = 0.f;
  if (deg <= 64) {
    int adjv = 0;
    float a = -FLT_MAX;
    if (lane < deg) {
      adjv = adj[s0 + lane];
      float t = esg[adjv] + edval;
      a = (t >= 0.f) ? t : 0.2f * t;
    }
    float m = a;
#pragma unroll
    for (int o = 32; o; o >>= 1) m = fmaxf(m, __shfl_xor(m, o));
    float ex = (lane < deg) ? expf(a - m) : 0.f;
    float den = ex;
#pragma unroll
    for (int o = 32; o; o >>= 1) den += __shfl_xor(den, o);
    float w = ex / den;
    for (int s = 0; s < deg; s++) {
      int src = __shfl(adjv, s);
      float ww = __shfl(w, s);
      num += ww * b2f(zg[(size_t)src * 64 + lane]);
    }
  } else {  // vanishingly rare deep-degree path (all lanes redundant-scalar)
    float m = -FLT_MAX;
    for (int s = s0; s < s1; s++) {
      float t = esg[adj[s]] + edval;
      t = (t >= 0.f) ? t : 0.2f * t;
      m = fmaxf(m, t);
    }
    float den = 0.f;
    for (int s = s0; s < s1; s++) {
      float t = esg[adj[s]] + edval;
      t = (t >= 0.f) ? t : 0.2f * t;
      den += expf(t - m);
    }
    for (int s = s0; s < s1; s++) {
      int src = adj[s];
      float t = esg[src] + edval;
      t = (t >= 0.f) ? t : 0.2f * t;
      num += (expf(t - m) / den) * b2f(zg[(size_t)src * 64 + lane]);
    }
  }
  out[(size_t)idx * 64 + lane] = f2b(fmaxf(num + bias[lane], 0.f));
}

// ---------------- CSR build ----------------
__global__ __launch_bounds__(256) void k_csr_count(const int* __restrict__ ind, int ner, int nn,
                                                   int* __restrict__ cnt, int* __restrict__ srcA,
                                                   int* __restrict__ dstA) {
  int i = blockIdx.x * 256 + threadIdx.x;
  int tot = ner + nn;
  if (i >= tot) return;
  int s_, d_;
  if (i < ner) { s_ = ind[i]; d_ = ind[ner + i]; }
  else { s_ = d_ = i - ner; }
  srcA[i] = s_; dstA[i] = d_;
  if (d_ >= 0 && d_ < nn) atomicAdd(&cnt[d_], 1);
}

__global__ __launch_bounds__(1024) void k_scan(const int* __restrict__ cnt, int* __restrict__ off, int n) {
  __shared__ int a[1024];
  int t = threadIdx.x;
  int c0 = (2 * t < n) ? cnt[2 * t] : 0;
  int c1 = (2 * t + 1 < n) ? cnt[2 * t + 1] : 0;
  a[t] = c0 + c1;
  __syncthreads();
  for (int d = 1; d < 1024; d <<= 1) {
    int u = (t >= d) ? a[t - d] : 0;
    __syncthreads();
    a[t] += u;
    __syncthreads();
  }
  int excl = (t > 0) ? a[t - 1] : 0;
  if (2 * t < n) off[2 * t] = excl;
  if (2 * t + 1 < n) off[2 * t + 1] = excl + c0;
  if (t == 0) off[n] = a[1023];
}

__global__ __launch_bounds__(256) void k_csr_fill(const int* __restrict__ srcA, const int* __restrict__ dstA,
                                                  const int* __restrict__ off, int* __restrict__ cur,
                                                  int* __restrict__ adj, int tot, int nn) {
  int i = blockIdx.x * 256 + threadIdx.x;
  if (i >= tot) return;
  int d_ = dstA[i];
  if (d_ < 0 || d_ >= nn) return;
  int pos = atomicAdd(&cur[d_], 1);
  adj[off[d_] + pos] = srcA[i];
}

// ---------------- per-batch: cumsum + residual + relu + head (wave per node) ----------------
template <bool XB>
__global__ __launch_bounds__(256) void k_out(const float* __restrict__ yx, const float* __restrict__ last,
                                             const float* __restrict__ oW, const float* __restrict__ ob_,
                                             float* __restrict__ dout, int nodes) {
  int wid = threadIdx.x >> 6, lane = threadIdx.x & 63;
  int node = blockIdx.x * 4 + wid;
  if (node >= nodes) return;
  float lw = oW[lane];
  float ob = ob_[0];
  float lv = last[(size_t)node * 64 + lane];
  float acc = 0.f;
  for (int tt = 0; tt < T_; tt++) {
    acc += yx[((size_t)tt * nodes + node) * 64 + lane];
    float v = fmaxf(acc + lv, 0.f);
    float p = v * lw;
#pragma unroll
    for (int o2 = 32; o2; o2 >>= 1) p += __shfl_down(p, o2);
    if (lane == 0) {
      float o = p + ob;
      if (XB) o = fminf(fmaxf(o / 6.f + 0.5f, 0.f), 1.f);
      else o = tanhf(o);
      dout[(size_t)tt * nodes + node] = o;
    }
  }
}

// ===================================================================================
extern "C" void kernel_launch(void* const* d_in, const int* in_sizes, int n_in,
                              void* d_out, int out_size, void* d_ws, size_t ws_size,
                              hipStream_t stream) {
  float* dout = (float*)d_out;

  if (n_in != 57) {
    k_sentinel<<<ceilDiv(out_size, 256), 256, 0, stream>>>(dout, out_size, 20000.f + 128.f * n_in);
    return;
  }
  static const int expSz[57] = {
      288000, 288000, 288000, 288000,
      256, 64, 192, 64, 128, 32, 96, 32,
      3000000,
      12288, 128, 128, 128, 12288, 128, 128, 128,
      4096, 64, 6000000, 6000000, 4096, 64, 6000000, 6000000,
      24576, 128,
      12288, 128, 128, 128, 12288, 128, 128, 128,
      4096, 64, 6000000, 6000000, 4096, 64, 6000000, 6000000,
      24576, 128,
      6144, 64, 4096, 64, 64, 1, 4000, 8000};
  for (int i = 0; i < 57; i++) {
    if (in_sizes[i] != expSz[i]) {
      k_sentinel<<<ceilDiv(out_size, 256), 256, 0, stream>>>(dout, out_size, 4096.f + 64.f * i);
      return;
    }
  }

  auto ff = [&](int i) { return (const float*)d_in[i]; };
  const float *x_in = ff(0), *e_in = ff(1), *b_in = ff(2), *a_in = ff(3);
  const float *enc0W = ff(4), *enc0b = ff(5), *enc1W = ff(6), *enc1b = ff(7);
  const float *enc2W = ff(8), *enc2b = ff(9), *enc3W = ff(10), *enc3b = ff(11);
  const float* inci = ff(12);
  const float *concW = ff(49), *concb = ff(50), *resW = ff(51), *resb = ff(52);
  const float *outW = ff(53), *outb = ff(54);
  const int* edge_ind = (const int*)d_in[55];
  const int* node_ind = (const int*)d_in[56];

  // ---- workspace layout, 256B-aligned ----
  char* base = (char*)d_ws;
  size_t off = 0;
  auto A = [&](size_t bytes) { void* p = base + off; off = (off + bytes + 255) & ~(size_t)255; return p; };
  char* SCR = (char*)A(21504000);
  bf16* xbuf = (bf16*)A(9216000);
  bf16* ebuf = (bf16*)A(12288000);
  float* lastx = (float*)A(768000);
  float* laste = (float*)A(1024000);
  float* es = (float*)A(384000);
  float* edv = (float*)A(384000);
  bf16* wAll = (bf16*)A(217088);
  int* cntN = (int*)A((size_t)(N_ + N_ + E_ + E_) * 4);
  int* curN = cntN + N_;
  int* cntE = curN + N_;
  int* curE = cntE + E_;
  int* offN = (int*)A((N_ + 1) * 4);
  int* offE = (int*)A((E_ + 1) * 4);
  int* srcN = (int*)A((E_ + N_) * 4);
  int* dstN = (int*)A((E_ + N_) * 4);
  int* adjN = (int*)A((E_ + N_) * 4);
  int* srcE = (int*)A((M_ + E_) * 4);
  int* dstE = (int*)A((M_ + E_) * 4);
  int* adjE = (int*)A((M_ + E_) * 4);
  size_t required = off;

  if (ws_size < required) {
    k_sentinel<<<ceilDiv(out_size, 256), 256, 0, stream>>>(dout, out_size, 1000.f + (float)(ws_size >> 20));
    return;
  }

  // SCR aliases (liveness-checked; KPN=2048: matb 6.14MB, tlinT 6.29MB fits @6.5536M..12.85M)
  bf16* matb = (bf16*)SCR;
  bf16* tlinT = (bf16*)(SCR + 6553600);
  bf16* traw = (bf16*)(SCR + 13107200);
  bf16* tmat = (bf16*)(SCR + 13107200);
  bf16* zbuf = (bf16*)SCR;
  bf16* bscr = (bf16*)SCR;
  bf16* cx1 = (bf16*)SCR;
  bf16* ce1 = (bf16*)(SCR + 9216000);
  float* zres = (float*)SCR;

  const int totN = E_ + N_;   // 3500
  const int totE = M_ + E_;   // 6000

  // ---- fused weight prep ----
  k_wprep<<<ceilDiv(108544, 256), 256, 0, stream>>>(ff(13), ff(17), ff(31), ff(35), concW, resW,
                                                    ff(29), ff(47), wAll);

  // ---- CSR build ----
  hipMemsetAsync(cntN, 0, (size_t)(N_ + N_ + E_ + E_) * sizeof(int), stream);
  k_csr_count<<<ceilDiv(totN, 256), 256, 0, stream>>>(edge_ind, E_, N_, cntN, srcN, dstN);
  k_scan<<<1, 1024, 0, stream>>>(cntN, offN, N_);
  k_csr_fill<<<ceilDiv(totN, 256), 256, 0, stream>>>(srcN, dstN, offN, curN, adjN, totN, N_);
  k_csr_count<<<ceilDiv(totE, 256), 256, 0, stream>>>(node_ind, M_, E_, cntE, srcE, dstE);
  k_scan<<<1, 1024, 0, stream>>>(cntE, offE, E_);
  k_csr_fill<<<ceilDiv(totE, 256), 256, 0, stream>>>(srcE, dstE, offE, curE, adjE, totE, E_);

  // ---- encoders ----
  k_enc<4, 64, true><<<ceilDiv(G_ * N_ * 64, 256), 256, 0, stream>>>(x_in, enc0W, enc0b, xbuf, lastx, N_);
  k_enc<3, 64, true><<<ceilDiv(G_ * E_ * 64, 256), 256, 0, stream>>>(e_in, enc1W, enc1b, ebuf, laste, E_);

  auto stblock = [&](int sb, int sbi) {
    const float *gxas = ff(sb + 1), *gxad = ff(sb + 2), *gxb = ff(sb + 3);
    const float *geas = ff(sb + 5), *gead = ff(sb + 6), *geb = ff(sb + 7);
    const float *neW = ff(sb + 8), *neb = ff(sb + 9), *nw = ff(sb + 10), *np_ = ff(sb + 11);
    const float *enW = ff(sb + 12), *enb = ff(sb + 13), *ew = ff(sb + 14), *ep = ff(sb + 15);
    const float* tpb = ff(sb + 17);
    for (int l = 0; l < 2; l++) {
      const bf16* gxw_t = wAll + sbi * 24576 + l * 6144;
      const bf16* gew_t = wAll + sbi * 24576 + 12288 + l * 6144;
      // ---- node side: xe = NodeEdge(e); x = relu(GAT([x,xe])) ----
      k_lin_ne<<<ceilDiv(E_ * G_ * 32, 256), 256, 0, stream>>>(ebuf, neW + l * 2048, neb + l * 32, traw, E_);
      k_trans<<<dim3(48, KPN / 32), dim3(32, 8), 0, stream>>>(traw, tlinT, E_, KPN);
      k_mat<<<ceilDiv(N_ * KPN, 256), 256, 0, stream>>>(nw + (size_t)l * N_ * E_, np_ + (size_t)l * N_ * E_, inci, matb, N_, E_, KPN);
      k_mgemm64<<<dim3(24, ceilDiv(N_, 64)), 256, 0, stream>>>(matb, tlinT, tmat, N_, KPN, 1536);
      k_mgemm<1, 64, false><<<dim3(1, ceilDiv(G_ * N_, 128)), 256, 0, stream>>>(xbuf, tmat, gxw_t, zbuf, G_ * N_, 96, 64, N_, nullptr, 0);
      k_esed<<<ceilDiv(G_ * N_, 4), 256, 0, stream>>>(zbuf, gxas + l * 64, gxad + l * 64, es, edv, G_ * N_);
      k_gat<<<ceilDiv(G_ * N_, 4), 256, 0, stream>>>(zbuf, es, edv, offN, adjN, gxb + l * 64, xbuf, N_);
      // ---- edge side: ex = NodeEdge(x); e = relu(GAT([e,ex])) ----
      k_lin_ne<<<ceilDiv(N_ * G_ * 32, 256), 256, 0, stream>>>(xbuf, enW + l * 2048, enb + l * 32, traw, N_);
      k_trans<<<dim3(48, KPE / 32), dim3(32, 8), 0, stream>>>(traw, tlinT, N_, KPE);
      k_matT<<<dim3(ceilDiv(E_, 32), KPE / 32), dim3(32, 8), 0, stream>>>(ew + (size_t)l * E_ * N_, ep + (size_t)l * E_ * N_, inci, matb);
      k_mgemm64<<<dim3(24, ceilDiv(E_, 64)), 256, 0, stream>>>(matb, tlinT, tmat, E_, KPE, 1536);
      k_mgemm<1, 64, false><<<dim3(1, ceilDiv(G_ * E_, 128)), 256, 0, stream>>>(ebuf, tmat, gew_t, zbuf, G_ * E_, 96, 64, E_, nullptr, 0);
      k_esed<<<ceilDiv(G_ * E_, 4), 256, 0, stream>>>(zbuf, geas + l * 64, gead + l * 64, es, edv, G_ * E_);
      k_gat<<<ceilDiv(G_ * E_, 4), 256, 0, stream>>>(zbuf, es, edv, offE, adjE, geb + l * 64, ebuf, E_);
    }
    // ---- temporal convs: shifted-view MFMA GEMMs ----
    const bf16* cw0 = wAll + 59392 + sbi * 24576;
    const bf16* cw1 = cw0 + 12288;
    k_cgemm<1><<<ceilDiv(G_ * N_, 128), 256, 0, stream>>>(xbuf, cw0, tpb, cx1, G_ * N_, N_);
    k_cgemm<1><<<ceilDiv(G_ * E_, 128), 256, 0, stream>>>(ebuf, cw0, tpb, ce1, G_ * E_, E_);
    k_cgemm<2><<<ceilDiv(G_ * N_, 128), 256, 0, stream>>>(cx1, cw1, tpb + 64, xbuf, G_ * N_, N_);
    k_cgemm<2><<<ceilDiv(G_ * E_, 128), 256, 0, stream>>>(ce1, cw1, tpb + 64, ebuf, G_ * E_, E_);
  };

  stblock(13, 0);

  // ---- conc (shared weights; in-place: gridDim.x==1 row ownership) ----
  const bf16* concT = wAll + 49152;
  k_enc<4, 32, false><<<ceilDiv(G_ * N_ * 32, 256), 256, 0, stream>>>(b_in, enc2W, enc2b, bscr, nullptr, N_);
  k_mgemm<2, 64, false><<<dim3(1, ceilDiv(G_ * N_, 128)), 256, 0, stream>>>(xbuf, bscr, concT, xbuf, G_ * N_, 96, 64, 0, concb, 1);
  k_enc<3, 32, false><<<ceilDiv(G_ * E_ * 32, 256), 256, 0, stream>>>(a_in, enc3W, enc3b, bscr, nullptr, E_);
  k_mgemm<2, 64, false><<<dim3(1, ceilDiv(G_ * E_, 128)), 256, 0, stream>>>(ebuf, bscr, concT, ebuf, G_ * E_, 96, 64, 0, concb, 1);

  stblock(31, 1);

  // ---- final per batch ----
  const bf16* resT = wAll + 55296;
  for (int b = 0; b < B_; b++) {
    k_mgemm<0, 64, true><<<dim3(1, ceilDiv(T_ * N_, 128)), 256, 0, stream>>>(
        xbuf + (size_t)b * T_ * N_ * 64, nullptr, resT, zres, T_ * N_, 64, 64, 0, resb, 0);
    k_out<true><<<ceilDiv(N_, 4), 256, 0, stream>>>(
        zres, lastx + (size_t)b * N_ * 64, outW, outb, dout + (size_t)b * T_ * N_, N_);
  }
  for (int b = 0; b < B_; b++) {
    k_mgemm<0, 64, true><<<dim3(1, ceilDiv(T_ * E_, 128)), 256, 0, stream>>>(
        ebuf + (size_t)b * T_ * E_ * 64, nullptr, resT, zres, T_ * E_, 64, 64, 0, resb, 0);
    k_out<false><<<ceilDiv(E_, 4), 256, 0, stream>>>(
        zres, laste + (size_t)b * E_ * 64, outW, outb, dout + (size_t)(B_ * T_ * N_) + (size_t)b * T_ * E_, E_);
  }
}

// Round 12
// 1243.731 us; speedup vs baseline: 3.9108x; 1.0704x over previous
//
#include <hip/hip_runtime.h>
#include <hip/hip_bf16.h>
#include <cfloat>
#include <math.h>

typedef __hip_bfloat16 bf16;
typedef __attribute__((ext_vector_type(8))) short short8v;
typedef __attribute__((ext_vector_type(4))) float f32x4;

constexpr int B_ = 2, T_ = 24, N_ = 1500, E_ = 2000, M_ = 4000, G_ = 48;
constexpr int KPN = 2048;  // padded K for node-side einsum (K=E_=2000), 64-multiple
constexpr int KPE = 1536;  // padded K for edge-side einsum (K=N_=1500), 64-multiple

__device__ __forceinline__ float b2f(bf16 v) { return __bfloat162float(v); }
__device__ __forceinline__ bf16 f2b(float v) { return __float2bfloat16(v); }
static inline int ceilDiv(int a, int b) { return (a + b - 1) / b; }

// ---------------- diagnostics (host-assert sentinel only) ----------------
__global__ __launch_bounds__(256) void k_sentinel(float* __restrict__ out, int n, float val) {
  int i = blockIdx.x * 256 + threadIdx.x;
  if (i < n) out[i] = val;
}

// ---------------- fused weight prep: all transposed bf16 weights in one pass ----------------
__global__ __launch_bounds__(256) void k_wprep(const float* __restrict__ g0, const float* __restrict__ e0,
                                               const float* __restrict__ g1, const float* __restrict__ e1,
                                               const float* __restrict__ cw, const float* __restrict__ rw,
                                               const float* __restrict__ t0, const float* __restrict__ t1,
                                               bf16* __restrict__ out) {
  int i = blockIdx.x * 256 + threadIdx.x;
  if (i >= 108544) return;
  float v;
  if (i < 49152) {
    int which = i / 12288, r = i % 12288;
    const float* W = which == 0 ? g0 : which == 1 ? e0 : which == 2 ? g1 : e1;
    int l = r / 6144, j = r % 6144;
    int n = j / 96, k = j % 96;
    v = W[l * 6144 + k * 64 + n];
  } else if (i < 55296) {
    int j = i - 49152, n = j / 96, k = j % 96;
    v = cw[k * 64 + n];
  } else if (i < 59392) {
    int j = i - 55296, n = j / 64, k = j % 64;
    v = rw[k * 64 + n];
  } else {
    int r = i - 59392;
    int which = r / 24576;
    const float* W = which ? t1 : t0;
    int rr = r % 24576;
    int l = rr / 12288, j = rr % 12288;
    int ii = j & 63, o = (j >> 6) & 63, k = j >> 12;
    v = W[l * 12288 + o * 192 + ii * 3 + k];
  }
  out[i] = f2b(v);
}

// ---------------- encoders ----------------
template <int DIN, int DOUT, bool SAVE>
__global__ __launch_bounds__(256) void k_enc(const float* __restrict__ in, const float* __restrict__ W,
                                             const float* __restrict__ bias, bf16* __restrict__ out,
                                             float* __restrict__ last, int nodes) {
  int idx = blockIdx.x * 256 + threadIdx.x;
  if (idx >= G_ * nodes * DOUT) return;
  int d = idx % DOUT;
  int row = idx / DOUT;
  int node = row % nodes;
  int g = row / nodes;
  const float* ir = in + (size_t)row * DIN;
  float acc = bias[d];
#pragma unroll
  for (int i = 0; i < DIN; i++) acc += ir[i] * W[i * DOUT + d];
  if (SAVE) {
    if (g % T_ == T_ - 1) last[((size_t)(g / T_) * nodes + node) * DOUT + d] = acc;  // pre-relu
  }
  out[idx] = f2b(fmaxf(acc, 0.f));
}

// ---------------- NodeEdge linear: relu(act @ W(64x32) + b) -> traw[node][g*32+f] bf16 ----
__global__ __launch_bounds__(256) void k_lin_ne(const bf16* __restrict__ act, const float* __restrict__ W,
                                                const float* __restrict__ bias, bf16* __restrict__ outT,
                                                int nodes) {
  __shared__ float Ws[2048];
  __shared__ float bs[32];
  for (int i = threadIdx.x; i < 2048; i += 256) Ws[i] = W[i];
  if (threadIdx.x < 32) bs[threadIdx.x] = bias[threadIdx.x];
  __syncthreads();
  int idx = blockIdx.x * 256 + threadIdx.x;
  if (idx >= nodes * G_ * 32) return;
  int f = idx & 31;
  int rem = idx >> 5;
  int g = rem % G_;
  int node = rem / G_;
  const bf16* row = act + ((size_t)g * nodes + node) * 64;
  float acc = bs[f];
#pragma unroll
  for (int i = 0; i < 64; i++) acc += b2f(row[i]) * Ws[i * 32 + f];
  outT[idx] = f2b(fmaxf(acc, 0.f));
}

// ---------------- bf16 transpose: in[K][1536] -> out[1536][Kp] (zero-padded) ----------------
__global__ void k_trans(const bf16* __restrict__ in, bf16* __restrict__ out, int K, int Kp) {
  __shared__ float tl[32][33];
  int c0 = blockIdx.x * 32, k0 = blockIdx.y * 32;
  for (int r = threadIdx.y; r < 32; r += 8) {
    int k = k0 + r, c = c0 + threadIdx.x;
    tl[r][threadIdx.x] = (k < K) ? b2f(in[(size_t)k * 1536 + c]) : 0.f;
  }
  __syncthreads();
  for (int r = threadIdx.y; r < 32; r += 8) {
    int c = c0 + r, k = k0 + threadIdx.x;
    if (k < Kp) out[(size_t)c * Kp + k] = f2b(tl[threadIdx.x][r]);
  }
}

// ---------------- masked incidence (padded): mat[n][k<E?val:0], [N_][Kp] ----------------
__global__ __launch_bounds__(256) void k_mat(const float* __restrict__ w, const float* __restrict__ p,
                                             const float* __restrict__ inci, bf16* __restrict__ mat,
                                             int rows, int K, int Kp) {
  int i = blockIdx.x * 256 + threadIdx.x;
  if (i >= rows * Kp) return;
  int row = i / Kp, k = i % Kp;
  float v = 0.f;
  if (k < K) {
    size_t o = (size_t)row * K + k;
    v = w[o] * fabsf(inci[o]) + p[o];
  }
  mat[i] = f2b(v);
}

// transposed variant: mat[e*KPE + n] = |inci[n][e]|*w[e*N+n] + p[e*N+n], zero-pad n>=N_
__global__ void k_matT(const float* __restrict__ w, const float* __restrict__ p,
                       const float* __restrict__ inci, bf16* __restrict__ mat) {
  __shared__ float tl[32][33];
  int e0 = blockIdx.x * 32, n0 = blockIdx.y * 32;
  for (int r = threadIdx.y; r < 32; r += 8) {
    int n = n0 + r, e = e0 + threadIdx.x;
    tl[r][threadIdx.x] = (n < N_ && e < E_) ? fabsf(inci[(size_t)n * E_ + e]) : 0.f;
  }
  __syncthreads();
  for (int r = threadIdx.y; r < 32; r += 8) {
    int e = e0 + r, n = n0 + threadIdx.x;
    if (e < E_ && n < KPE) {
      size_t o = (size_t)e * N_ + n;
      mat[(size_t)e * KPE + n] = (n < N_) ? f2b(tl[threadIdx.x][r] * w[o] + p[o]) : f2b(0.f);
    }
  }
}

// ---------------- 64x64-tile MFMA GEMM, depth-4 pipeline + bijective XCD swizzle ----------
// 1D grid, nwg = gx*gy, nwg%8==0. l = (bid&7)*(nwg/8) + bid>>3 ; by = l%gy (A-panel fastest),
// bx = l/gy -> each XCD chunk keeps its 64-col B panel L2-resident across all A panels.
__global__ __launch_bounds__(256) void k_mgemm64(const bf16* __restrict__ A0, const bf16* __restrict__ Bt,
                                                 bf16* __restrict__ Cp, int Mm, int Kp, int Nn, int gy) {
  __shared__ __align__(16) short As[4][4][64][8];
  __shared__ __align__(16) short Bs[4][4][64][8];
  int tid = threadIdx.x;
  int nwg = gridDim.x;
  int bid = blockIdx.x;
  int l = (bid & 7) * (nwg >> 3) + (bid >> 3);
  int bm = (l % gy) * 64, bn = (l / gy) * 64;
  int lane = tid & 63, wid = tid >> 6;
  int wr = wid >> 1, wc = wid & 1;
  f32x4 acc[2][2];
#pragma unroll
  for (int i = 0; i < 2; i++)
#pragma unroll
    for (int j = 0; j < 2; j++) acc[i][j] = f32x4{0.f, 0.f, 0.f, 0.f};

  const int sr = tid >> 2;
  const int sc = tid & 3;
  const int kb = lane >> 4, lr = lane & 15;
  const int gmA = bm + sr, gnB = bn + sr;
  const bool va_ok = (gmA < Mm), vb_ok = (gnB < Nn);
  const bf16* ap = A0 + (size_t)gmA * Kp + sc * 8;
  const bf16* bp = Bt + (size_t)gnB * Kp + sc * 8;
  const uint4 z4 = {0, 0, 0, 0};
  const int P = Kp >> 5;  // phases (even, >= 4)

  // prologue
  uint4 va0 = va_ok ? *reinterpret_cast<const uint4*>(ap) : z4;
  uint4 vb0 = vb_ok ? *reinterpret_cast<const uint4*>(bp) : z4;
  uint4 va1 = va_ok ? *reinterpret_cast<const uint4*>(ap + 32) : z4;
  uint4 vb1 = vb_ok ? *reinterpret_cast<const uint4*>(bp + 32) : z4;
  *reinterpret_cast<uint4*>(&As[0][sc][sr][0]) = va0;
  *reinterpret_cast<uint4*>(&Bs[0][sc][sr][0]) = vb0;
  uint4 va2 = va_ok ? *reinterpret_cast<const uint4*>(ap + 64) : z4;
  uint4 vb2 = vb_ok ? *reinterpret_cast<const uint4*>(bp + 64) : z4;
  __syncthreads();

  for (int p = 0; p < P; p += 2) {
    *reinterpret_cast<uint4*>(&As[(p + 1) & 3][sc][sr][0]) = va1;
    *reinterpret_cast<uint4*>(&Bs[(p + 1) & 3][sc][sr][0]) = vb1;
    if (p + 3 < P) {
      va1 = va_ok ? *reinterpret_cast<const uint4*>(ap + (p + 3) * 32) : z4;
      vb1 = vb_ok ? *reinterpret_cast<const uint4*>(bp + (p + 3) * 32) : z4;
    }
    {
      int bf = p & 3;
      short8v a0 = *reinterpret_cast<const short8v*>(&As[bf][kb][wr * 32 + lr][0]);
      short8v a1 = *reinterpret_cast<const short8v*>(&As[bf][kb][wr * 32 + 16 + lr][0]);
      short8v b0 = *reinterpret_cast<const short8v*>(&Bs[bf][kb][wc * 32 + lr][0]);
      short8v b1 = *reinterpret_cast<const short8v*>(&Bs[bf][kb][wc * 32 + 16 + lr][0]);
      __builtin_amdgcn_s_setprio(1);
      acc[0][0] = __builtin_amdgcn_mfma_f32_16x16x32_bf16(a0, b0, acc[0][0], 0, 0, 0);
      acc[0][1] = __builtin_amdgcn_mfma_f32_16x16x32_bf16(a0, b1, acc[0][1], 0, 0, 0);
      acc[1][0] = __builtin_amdgcn_mfma_f32_16x16x32_bf16(a1, b0, acc[1][0], 0, 0, 0);
      acc[1][1] = __builtin_amdgcn_mfma_f32_16x16x32_bf16(a1, b1, acc[1][1], 0, 0, 0);
      __builtin_amdgcn_s_setprio(0);
    }
    __syncthreads();
    *reinterpret_cast<uint4*>(&As[(p + 2) & 3][sc][sr][0]) = va2;
    *reinterpret_cast<uint4*>(&Bs[(p + 2) & 3][sc][sr][0]) = vb2;
    if (p + 4 < P) {
      va2 = va_ok ? *reinterpret_cast<const uint4*>(ap + (p + 4) * 32) : z4;
      vb2 = vb_ok ? *reinterpret_cast<const uint4*>(bp + (p + 4) * 32) : z4;
    }
    {
      int bf = (p + 1) & 3;
      short8v a0 = *reinterpret_cast<const short8v*>(&As[bf][kb][wr * 32 + lr][0]);
      short8v a1 = *reinterpret_cast<const short8v*>(&As[bf][kb][wr * 32 + 16 + lr][0]);
      short8v b0 = *reinterpret_cast<const short8v*>(&Bs[bf][kb][wc * 32 + lr][0]);
      short8v b1 = *reinterpret_cast<const short8v*>(&Bs[bf][kb][wc * 32 + 16 + lr][0]);
      __builtin_amdgcn_s_setprio(1);
      acc[0][0] = __builtin_amdgcn_mfma_f32_16x16x32_bf16(a0, b0, acc[0][0], 0, 0, 0);
      acc[0][1] = __builtin_amdgcn_mfma_f32_16x16x32_bf16(a0, b1, acc[0][1], 0, 0, 0);
      acc[1][0] = __builtin_amdgcn_mfma_f32_16x16x32_bf16(a1, b0, acc[1][0], 0, 0, 0);
      acc[1][1] = __builtin_amdgcn_mfma_f32_16x16x32_bf16(a1, b1, acc[1][1], 0, 0, 0);
      __builtin_amdgcn_s_setprio(0);
    }
    __syncthreads();
  }
#pragma unroll
  for (int mi = 0; mi < 2; mi++) {
    int r0 = bm + wr * 32 + mi * 16 + (lane >> 4) * 4;
#pragma unroll
    for (int ni = 0; ni < 2; ni++) {
      int col = bn + wc * 32 + ni * 16 + lr;
      if (col >= Nn) continue;
#pragma unroll
      for (int i = 0; i < 4; i++) {
        int r = r0 + i;
        if (r < Mm) Cp[(size_t)r * Nn + col] = f2b(acc[mi][ni][i]);
      }
    }
  }
}

// ---------------- MFMA GEMM (128-row tile): z / conc / res GEMMs ----------------
template <int AMODE, int BNt, bool CF32b>
__global__ __launch_bounds__(256) void k_mgemm(const bf16* __restrict__ A0, const bf16* __restrict__ A1,
                                               const bf16* __restrict__ Bt, void* __restrict__ Cp,
                                               int Mm, int Kp, int Nn, int nodes,
                                               const float* __restrict__ bias, int relu) {
  constexpr int BM = 128;
  constexpr int WTN = BNt / 32;
  __shared__ __align__(16) short As[4][BM][8];
  __shared__ __align__(16) short Bs[4][BNt][8];
  int tid = threadIdx.x;
  int bm = blockIdx.y * BM;
  int bn = blockIdx.x * BNt;
  int lane = tid & 63;
  int wid = tid >> 6;
  int wr = wid >> 1, wc = wid & 1;
  f32x4 acc[4][WTN];
#pragma unroll
  for (int i = 0; i < 4; i++)
#pragma unroll
    for (int j = 0; j < WTN; j++) acc[i][j] = f32x4{0.f, 0.f, 0.f, 0.f};

  const int ar = tid >> 1;
  const int ah = tid & 1;
  const int kb = lane >> 4;
  const int lr = lane & 15;

  for (int k0 = 0; k0 < Kp; k0 += 32) {
    uint4 va0 = {0, 0, 0, 0}, va1 = {0, 0, 0, 0};
    int gm = bm + ar;
    if (gm < Mm) {
      int ks = k0 + ah * 16;
      const bf16* src;
      if (AMODE == 0) src = A0 + (size_t)gm * Kp + ks;
      else if (ks < 64) src = A0 + (size_t)gm * 64 + ks;
      else if (AMODE == 1) {
        int g = gm / nodes, nd = gm % nodes;
        src = A1 + ((size_t)nd * G_ + g) * 32 + (ks - 64);
      } else {
        src = A1 + (size_t)gm * 32 + (ks - 64);
      }
      const uint4* p = reinterpret_cast<const uint4*>(src);
      va0 = p[0];
      va1 = p[1];
    }
    *reinterpret_cast<uint4*>(&As[ah * 2 + 0][ar][0]) = va0;
    *reinterpret_cast<uint4*>(&As[ah * 2 + 1][ar][0]) = va1;
    if (BNt == 128) {
      int br = tid >> 1, bh = tid & 1;
      uint4 vb0 = {0, 0, 0, 0}, vb1 = {0, 0, 0, 0};
      int gn = bn + br;
      if (gn < Nn) {
        const uint4* p = reinterpret_cast<const uint4*>(Bt + (size_t)gn * Kp + k0 + bh * 16);
        vb0 = p[0];
        vb1 = p[1];
      }
      *reinterpret_cast<uint4*>(&Bs[bh * 2 + 0][br][0]) = vb0;
      *reinterpret_cast<uint4*>(&Bs[bh * 2 + 1][br][0]) = vb1;
    } else {
      int br = tid >> 2, bk = tid & 3;
      uint4 vb0 = {0, 0, 0, 0};
      int gn = bn + br;
      if (gn < Nn) vb0 = *reinterpret_cast<const uint4*>(Bt + (size_t)gn * Kp + k0 + bk * 8);
      *reinterpret_cast<uint4*>(&Bs[bk][br][0]) = vb0;
    }
    __syncthreads();
    short8v a[4], b[WTN];
#pragma unroll
    for (int mi = 0; mi < 4; mi++)
      a[mi] = *reinterpret_cast<const short8v*>(&As[kb][wr * 64 + mi * 16 + lr][0]);
#pragma unroll
    for (int ni = 0; ni < WTN; ni++)
      b[ni] = *reinterpret_cast<const short8v*>(&Bs[kb][wc * (BNt / 2) + ni * 16 + lr][0]);
#pragma unroll
    for (int mi = 0; mi < 4; mi++)
#pragma unroll
      for (int ni = 0; ni < WTN; ni++)
        acc[mi][ni] = __builtin_amdgcn_mfma_f32_16x16x32_bf16(a[mi], b[ni], acc[mi][ni], 0, 0, 0);
    __syncthreads();
  }
#pragma unroll
  for (int mi = 0; mi < 4; mi++) {
    int r0 = bm + wr * 64 + mi * 16 + (lane >> 4) * 4;
#pragma unroll
    for (int ni = 0; ni < WTN; ni++) {
      int col = bn + wc * (BNt / 2) + ni * 16 + lr;
      float bv = bias ? bias[col] : 0.f;
#pragma unroll
      for (int i = 0; i < 4; i++) {
        int r = r0 + i;
        if (r < Mm) {
          float v = acc[mi][ni][i] + bv;
          if (relu) v = fmaxf(v, 0.f);
          if (CF32b) ((float*)Cp)[(size_t)r * Nn + col] = v;
          else ((bf16*)Cp)[(size_t)r * Nn + col] = f2b(v);
        }
      }
    }
  }
}

// ---------------- causal dilated conv as MFMA GEMM over row-shifted views ----------------
template <int DIL>
__global__ __launch_bounds__(256) void k_cgemm(const bf16* __restrict__ A, const bf16* __restrict__ Wc,
                                               const float* __restrict__ bias, bf16* __restrict__ C,
                                               int Mm, int nodes) {
  __shared__ __align__(16) short As[4][128][8];
  __shared__ __align__(16) short Bs[4][64][8];
  int tid = threadIdx.x;
  int bm = blockIdx.x * 128;
  int lane = tid & 63;
  int wid = tid >> 6;
  int wr = wid >> 1, wc = wid & 1;
  f32x4 acc[4][2];
#pragma unroll
  for (int i = 0; i < 4; i++)
#pragma unroll
    for (int j = 0; j < 2; j++) acc[i][j] = f32x4{0.f, 0.f, 0.f, 0.f};

  const int ar = tid >> 1;
  const int ah = tid & 1;
  const int kb = lane >> 4;
  const int lr = lane & 15;
  const int gm = bm + ar;
  const int t = (gm / nodes) % T_;

#pragma unroll
  for (int k = 0; k < 3; k++) {
    const int sh = (k - 2) * DIL;
    const bool valid = (gm < Mm) && (t + sh >= 0);
    const bf16* arow = A + ((size_t)gm + (size_t)sh * nodes) * 64;
    const bf16* Bt = Wc + k * 4096;
#pragma unroll
    for (int k0 = 0; k0 < 64; k0 += 32) {
      uint4 va0 = {0, 0, 0, 0}, va1 = {0, 0, 0, 0};
      if (valid) {
        const uint4* p = reinterpret_cast<const uint4*>(arow + k0 + ah * 16);
        va0 = p[0];
        va1 = p[1];
      }
      *reinterpret_cast<uint4*>(&As[ah * 2 + 0][ar][0]) = va0;
      *reinterpret_cast<uint4*>(&As[ah * 2 + 1][ar][0]) = va1;
      {
        int br = tid >> 2, bk = tid & 3;
        uint4 vb = *reinterpret_cast<const uint4*>(Bt + (size_t)br * 64 + k0 + bk * 8);
        *reinterpret_cast<uint4*>(&Bs[bk][br][0]) = vb;
      }
      __syncthreads();
      short8v a[4], b[2];
#pragma unroll
      for (int mi = 0; mi < 4; mi++)
        a[mi] = *reinterpret_cast<const short8v*>(&As[kb][wr * 64 + mi * 16 + lr][0]);
#pragma unroll
      for (int ni = 0; ni < 2; ni++)
        b[ni] = *reinterpret_cast<const short8v*>(&Bs[kb][wc * 32 + ni * 16 + lr][0]);
#pragma unroll
      for (int mi = 0; mi < 4; mi++)
#pragma unroll
        for (int ni = 0; ni < 2; ni++)
          acc[mi][ni] = __builtin_amdgcn_mfma_f32_16x16x32_bf16(a[mi], b[ni], acc[mi][ni], 0, 0, 0);
      __syncthreads();
    }
  }
#pragma unroll
  for (int mi = 0; mi < 4; mi++) {
    int r0 = bm + wr * 64 + mi * 16 + (lane >> 4) * 4;
#pragma unroll
    for (int ni = 0; ni < 2; ni++) {
      int col = wc * 32 + ni * 16 + lr;
      float bv = bias[col];
#pragma unroll
      for (int i = 0; i < 4; i++) {
        int r = r0 + i;
        if (r < Mm) C[(size_t)r * 64 + col] = f2b(fmaxf(acc[mi][ni][i] + bv, 0.f));
      }
    }
  }
}

// ---------------- es/ed = z . a_s , z . a_d (wave per row) ----------------
__global__ __launch_bounds__(256) void k_esed(const bf16* __restrict__ z, const float* __restrict__ as_,
                                              const float* __restrict__ ad_, float* __restrict__ es,
                                              float* __restrict__ ed, int rows) {
  int wid = threadIdx.x >> 6, lane = threadIdx.x & 63;
  int row = blockIdx.x * 4 + wid;
  if (row >= rows) return;
  float zv = b2f(z[(size_t)row * 64 + lane]);
  float vs = zv * as_[lane];
  float vd = zv * ad_[lane];
#pragma unroll
  for (int off = 32; off; off >>= 1) { vs += __shfl_down(vs, off); vd += __shfl_down(vd, off); }
  if (lane == 0) { es[row] = vs; ed[row] = vd; }
}

// ---------------- GAT softmax weights: thread per (g,node), normalized exp weights ----------
__global__ __launch_bounds__(256) void k_gat_w(const float* __restrict__ es, const float* __restrict__ edv,
                                               const int* __restrict__ off, const int* __restrict__ adj,
                                               float* __restrict__ wgt, int nodes, int tot) {
  int idx = blockIdx.x * 256 + threadIdx.x;
  if (idx >= G_ * nodes) return;
  int g = idx / nodes, node = idx % nodes;
  int s0 = off[node], s1 = off[node + 1];
  const float* esg = es + (size_t)g * nodes;
  float edval = edv[(size_t)g * nodes + node];
  float m = -FLT_MAX;
  for (int s = s0; s < s1; s++) {
    float a = esg[adj[s]] + edval;
    a = (a >= 0.f) ? a : 0.2f * a;
    m = fmaxf(m, a);
  }
  float den = 0.f;
  float* wg = wgt + (size_t)g * tot;
  for (int s = s0; s < s1; s++) {
    float a = esg[adj[s]] + edval;
    a = (a >= 0.f) ? a : 0.2f * a;
    float ex = expf(a - m);
    den += ex;
    wg[s] = ex;
  }
  float inv = (s1 > s0) ? 1.f / den : 0.f;
  for (int s = s0; s < s1; s++) wg[s] *= inv;
}

// ---------------- GAT aggregation: thread per (g,node,4-feature chunk) ----------------
// 16 threads cover a node's 64 features; per edge each thread gathers short4 (8B) of z ->
// 16 consecutive threads read one 128B z-row coalesced. No shuffles, no idle lanes.
__global__ __launch_bounds__(256) void k_gat_aggr3(const bf16* __restrict__ z, const float* __restrict__ wgt,
                                                   const int* __restrict__ off, const int* __restrict__ adj,
                                                   const float* __restrict__ bias, bf16* __restrict__ out,
                                                   int nodes, int tot) {
  int idx = blockIdx.x * 256 + threadIdx.x;
  if (idx >= G_ * nodes * 16) return;
  int c = idx & 15;
  int rest = idx >> 4;
  int node = rest % nodes;
  int g = rest / nodes;
  int s0 = off[node], s1 = off[node + 1];
  const bf16* zg = z + (size_t)g * nodes * 64 + c * 4;
  const float* wg = wgt + (size_t)g * tot;
  float n0 = 0.f, n1 = 0.f, n2 = 0.f, n3 = 0.f;
  for (int s = s0; s < s1; s++) {
    int src = adj[s];
    float w = wg[s];
    bf16 v[4];
    *reinterpret_cast<uint2*>(v) = *reinterpret_cast<const uint2*>(zg + (size_t)src * 64);
    n0 += w * b2f(v[0]);
    n1 += w * b2f(v[1]);
    n2 += w * b2f(v[2]);
    n3 += w * b2f(v[3]);
  }
  bf16 ov[4];
  ov[0] = f2b(fmaxf(n0 + bias[c * 4 + 0], 0.f));
  ov[1] = f2b(fmaxf(n1 + bias[c * 4 + 1], 0.f));
  ov[2] = f2b(fmaxf(n2 + bias[c * 4 + 2], 0.f));
  ov[3] = f2b(fmaxf(n3 + bias[c * 4 + 3], 0.f));
  *reinterpret_cast<uint2*>(out + (size_t)rest * 64 + c * 4) = *reinterpret_cast<uint2*>(ov);
}

// ---------------- CSR build ----------------
__global__ __launch_bounds__(256) void k_csr_count(const int* __restrict__ ind, int ner, int nn,
                                                   int* __restrict__ cnt, int* __restrict__ srcA,
                                                   int* __restrict__ dstA) {
  int i = blockIdx.x * 256 + threadIdx.x;
  int tot = ner + nn;
  if (i >= tot) return;
  int s_, d_;
  if (i < ner) { s_ = ind[i]; d_ = ind[ner + i]; }
  else { s_ = d_ = i - ner; }
  srcA[i] = s_; dstA[i] = d_;
  if (d_ >= 0 && d_ < nn) atomicAdd(&cnt[d_], 1);
}

__global__ __launch_bounds__(1024) void k_scan(const int* __restrict__ cnt, int* __restrict__ off, int n) {
  __shared__ int a[1024];
  int t = threadIdx.x;
  int c0 = (2 * t < n) ? cnt[2 * t] : 0;
  int c1 = (2 * t + 1 < n) ? cnt[2 * t + 1] : 0;
  a[t] = c0 + c1;
  __syncthreads();
  for (int d = 1; d < 1024; d <<= 1) {
    int u = (t >= d) ? a[t - d] : 0;
    __syncthreads();
    a[t] += u;
    __syncthreads();
  }
  int excl = (t > 0) ? a[t - 1] : 0;
  if (2 * t < n) off[2 * t] = excl;
  if (2 * t + 1 < n) off[2 * t + 1] = excl + c0;
  if (t == 0) off[n] = a[1023];
}

__global__ __launch_bounds__(256) void k_csr_fill(const int* __restrict__ srcA, const int* __restrict__ dstA,
                                                  const int* __restrict__ off, int* __restrict__ cur,
                                                  int* __restrict__ adj, int tot, int nn) {
  int i = blockIdx.x * 256 + threadIdx.x;
  if (i >= tot) return;
  int d_ = dstA[i];
  if (d_ < 0 || d_ >= nn) return;
  int pos = atomicAdd(&cur[d_], 1);
  adj[off[d_] + pos] = srcA[i];
}

// ---------------- per-batch: cumsum + residual + relu + head (wave per node) ----------------
template <bool XB>
__global__ __launch_bounds__(256) void k_out(const float* __restrict__ yx, const float* __restrict__ last,
                                             const float* __restrict__ oW, const float* __restrict__ ob_,
                                             float* __restrict__ dout, int nodes) {
  int wid = threadIdx.x >> 6, lane = threadIdx.x & 63;
  int node = blockIdx.x * 4 + wid;
  if (node >= nodes) return;
  float lw = oW[lane];
  float ob = ob_[0];
  float lv = last[(size_t)node * 64 + lane];
  float acc = 0.f;
  for (int tt = 0; tt < T_; tt++) {
    acc += yx[((size_t)tt * nodes + node) * 64 + lane];
    float v = fmaxf(acc + lv, 0.f);
    float p = v * lw;
#pragma unroll
    for (int o2 = 32; o2; o2 >>= 1) p += __shfl_down(p, o2);
    if (lane == 0) {
      float o = p + ob;
      if (XB) o = fminf(fmaxf(o / 6.f + 0.5f, 0.f), 1.f);
      else o = tanhf(o);
      dout[(size_t)tt * nodes + node] = o;
    }
  }
}

// ===================================================================================
extern "C" void kernel_launch(void* const* d_in, const int* in_sizes, int n_in,
                              void* d_out, int out_size, void* d_ws, size_t ws_size,
                              hipStream_t stream) {
  float* dout = (float*)d_out;

  if (n_in != 57) {
    k_sentinel<<<ceilDiv(out_size, 256), 256, 0, stream>>>(dout, out_size, 20000.f + 128.f * n_in);
    return;
  }
  static const int expSz[57] = {
      288000, 288000, 288000, 288000,
      256, 64, 192, 64, 128, 32, 96, 32,
      3000000,
      12288, 128, 128, 128, 12288, 128, 128, 128,
      4096, 64, 6000000, 6000000, 4096, 64, 6000000, 6000000,
      24576, 128,
      12288, 128, 128, 128, 12288, 128, 128, 128,
      4096, 64, 6000000, 6000000, 4096, 64, 6000000, 6000000,
      24576, 128,
      6144, 64, 4096, 64, 64, 1, 4000, 8000};
  for (int i = 0; i < 57; i++) {
    if (in_sizes[i] != expSz[i]) {
      k_sentinel<<<ceilDiv(out_size, 256), 256, 0, stream>>>(dout, out_size, 4096.f + 64.f * i);
      return;
    }
  }

  auto ff = [&](int i) { return (const float*)d_in[i]; };
  const float *x_in = ff(0), *e_in = ff(1), *b_in = ff(2), *a_in = ff(3);
  const float *enc0W = ff(4), *enc0b = ff(5), *enc1W = ff(6), *enc1b = ff(7);
  const float *enc2W = ff(8), *enc2b = ff(9), *enc3W = ff(10), *enc3b = ff(11);
  const float* inci = ff(12);
  const float *concW = ff(49), *concb = ff(50), *resW = ff(51), *resb = ff(52);
  const float *outW = ff(53), *outb = ff(54);
  const int* edge_ind = (const int*)d_in[55];
  const int* node_ind = (const int*)d_in[56];

  // ---- workspace layout, 256B-aligned ----
  char* base = (char*)d_ws;
  size_t off = 0;
  auto A = [&](size_t bytes) { void* p = base + off; off = (off + bytes + 255) & ~(size_t)255; return p; };
  char* SCR = (char*)A(21504000);
  bf16* xbuf = (bf16*)A(9216000);
  bf16* ebuf = (bf16*)A(12288000);
  float* lastx = (float*)A(768000);
  float* laste = (float*)A(1024000);
  float* es = (float*)A(384000);
  float* edv = (float*)A(384000);
  float* wgt = (float*)A((size_t)G_ * (M_ + E_) * 4);  // softmax weights
  bf16* wAll = (bf16*)A(217088);
  int* cntN = (int*)A((size_t)(N_ + N_ + E_ + E_) * 4);
  int* curN = cntN + N_;
  int* cntE = curN + N_;
  int* curE = cntE + E_;
  int* offN = (int*)A((N_ + 1) * 4);
  int* offE = (int*)A((E_ + 1) * 4);
  int* srcN = (int*)A((E_ + N_) * 4);
  int* dstN = (int*)A((E_ + N_) * 4);
  int* adjN = (int*)A((E_ + N_) * 4);
  int* srcE = (int*)A((M_ + E_) * 4);
  int* dstE = (int*)A((M_ + E_) * 4);
  int* adjE = (int*)A((M_ + E_) * 4);
  size_t required = off;

  if (ws_size < required) {
    k_sentinel<<<ceilDiv(out_size, 256), 256, 0, stream>>>(dout, out_size, 1000.f + (float)(ws_size >> 20));
    return;
  }

  // SCR aliases (liveness-checked)
  bf16* matb = (bf16*)SCR;
  bf16* tlinT = (bf16*)(SCR + 6553600);
  bf16* traw = (bf16*)(SCR + 13107200);
  bf16* tmat = (bf16*)(SCR + 13107200);
  bf16* zbuf = (bf16*)SCR;
  bf16* bscr = (bf16*)SCR;
  bf16* cx1 = (bf16*)SCR;
  bf16* ce1 = (bf16*)(SCR + 9216000);
  float* zres = (float*)SCR;

  const int totN = E_ + N_;   // 3500
  const int totE = M_ + E_;   // 6000

  // ---- fused weight prep ----
  k_wprep<<<ceilDiv(108544, 256), 256, 0, stream>>>(ff(13), ff(17), ff(31), ff(35), concW, resW,
                                                    ff(29), ff(47), wAll);

  // ---- CSR build ----
  hipMemsetAsync(cntN, 0, (size_t)(N_ + N_ + E_ + E_) * sizeof(int), stream);
  k_csr_count<<<ceilDiv(totN, 256), 256, 0, stream>>>(edge_ind, E_, N_, cntN, srcN, dstN);
  k_scan<<<1, 1024, 0, stream>>>(cntN, offN, N_);
  k_csr_fill<<<ceilDiv(totN, 256), 256, 0, stream>>>(srcN, dstN, offN, curN, adjN, totN, N_);
  k_csr_count<<<ceilDiv(totE, 256), 256, 0, stream>>>(node_ind, M_, E_, cntE, srcE, dstE);
  k_scan<<<1, 1024, 0, stream>>>(cntE, offE, E_);
  k_csr_fill<<<ceilDiv(totE, 256), 256, 0, stream>>>(srcE, dstE, offE, curE, adjE, totE, E_);

  // ---- encoders ----
  k_enc<4, 64, true><<<ceilDiv(G_ * N_ * 64, 256), 256, 0, stream>>>(x_in, enc0W, enc0b, xbuf, lastx, N_);
  k_enc<3, 64, true><<<ceilDiv(G_ * E_ * 64, 256), 256, 0, stream>>>(e_in, enc1W, enc1b, ebuf, laste, E_);

  auto stblock = [&](int sb, int sbi) {
    const float *gxas = ff(sb + 1), *gxad = ff(sb + 2), *gxb = ff(sb + 3);
    const float *geas = ff(sb + 5), *gead = ff(sb + 6), *geb = ff(sb + 7);
    const float *neW = ff(sb + 8), *neb = ff(sb + 9), *nw = ff(sb + 10), *np_ = ff(sb + 11);
    const float *enW = ff(sb + 12), *enb = ff(sb + 13), *ew = ff(sb + 14), *ep = ff(sb + 15);
    const float* tpb = ff(sb + 17);
    for (int l = 0; l < 2; l++) {
      const bf16* gxw_t = wAll + sbi * 24576 + l * 6144;
      const bf16* gew_t = wAll + sbi * 24576 + 12288 + l * 6144;
      // ---- node side: xe = NodeEdge(e); x = relu(GAT([x,xe])) ----
      k_lin_ne<<<ceilDiv(E_ * G_ * 32, 256), 256, 0, stream>>>(ebuf, neW + l * 2048, neb + l * 32, traw, E_);
      k_trans<<<dim3(48, KPN / 32), dim3(32, 8), 0, stream>>>(traw, tlinT, E_, KPN);
      k_mat<<<ceilDiv(N_ * KPN, 256), 256, 0, stream>>>(nw + (size_t)l * N_ * E_, np_ + (size_t)l * N_ * E_, inci, matb, N_, E_, KPN);
      k_mgemm64<<<dim3(24 * 24), 256, 0, stream>>>(matb, tlinT, tmat, N_, KPN, 1536, 24);
      k_mgemm<1, 64, false><<<dim3(1, ceilDiv(G_ * N_, 128)), 256, 0, stream>>>(xbuf, tmat, gxw_t, zbuf, G_ * N_, 96, 64, N_, nullptr, 0);
      k_esed<<<ceilDiv(G_ * N_, 4), 256, 0, stream>>>(zbuf, gxas + l * 64, gxad + l * 64, es, edv, G_ * N_);
      k_gat_w<<<ceilDiv(G_ * N_, 256), 256, 0, stream>>>(es, edv, offN, adjN, wgt, N_, totN);
      k_gat_aggr3<<<ceilDiv(G_ * N_ * 16, 256), 256, 0, stream>>>(zbuf, wgt, offN, adjN, gxb + l * 64, xbuf, N_, totN);
      // ---- edge side: ex = NodeEdge(x); e = relu(GAT([e,ex])) ----
      k_lin_ne<<<ceilDiv(N_ * G_ * 32, 256), 256, 0, stream>>>(xbuf, enW + l * 2048, enb + l * 32, traw, N_);
      k_trans<<<dim3(48, KPE / 32), dim3(32, 8), 0, stream>>>(traw, tlinT, N_, KPE);
      k_matT<<<dim3(ceilDiv(E_, 32), KPE / 32), dim3(32, 8), 0, stream>>>(ew + (size_t)l * E_ * N_, ep + (size_t)l * E_ * N_, inci, matb);
      k_mgemm64<<<dim3(24 * 32), 256, 0, stream>>>(matb, tlinT, tmat, E_, KPE, 1536, 32);
      k_mgemm<1, 64, false><<<dim3(1, ceilDiv(G_ * E_, 128)), 256, 0, stream>>>(ebuf, tmat, gew_t, zbuf, G_ * E_, 96, 64, E_, nullptr, 0);
      k_esed<<<ceilDiv(G_ * E_, 4), 256, 0, stream>>>(zbuf, geas + l * 64, gead + l * 64, es, edv, G_ * E_);
      k_gat_w<<<ceilDiv(G_ * E_, 256), 256, 0, stream>>>(es, edv, offE, adjE, wgt, E_, totE);
      k_gat_aggr3<<<ceilDiv(G_ * E_ * 16, 256), 256, 0, stream>>>(zbuf, wgt, offE, adjE, geb + l * 64, ebuf, E_, totE);
    }
    // ---- temporal convs: shifted-view MFMA GEMMs ----
    const bf16* cw0 = wAll + 59392 + sbi * 24576;
    const bf16* cw1 = cw0 + 12288;
    k_cgemm<1><<<ceilDiv(G_ * N_, 128), 256, 0, stream>>>(xbuf, cw0, tpb, cx1, G_ * N_, N_);
    k_cgemm<1><<<ceilDiv(G_ * E_, 128), 256, 0, stream>>>(ebuf, cw0, tpb, ce1, G_ * E_, E_);
    k_cgemm<2><<<ceilDiv(G_ * N_, 128), 256, 0, stream>>>(cx1, cw1, tpb + 64, xbuf, G_ * N_, N_);
    k_cgemm<2><<<ceilDiv(G_ * E_, 128), 256, 0, stream>>>(ce1, cw1, tpb + 64, ebuf, G_ * E_, E_);
  };

  stblock(13, 0);

  // ---- conc (shared weights; in-place: gridDim.x==1 row ownership) ----
  const bf16* concT = wAll + 49152;
  k_enc<4, 32, false><<<ceilDiv(G_ * N_ * 32, 256), 256, 0, stream>>>(b_in, enc2W, enc2b, bscr, nullptr, N_);
  k_mgemm<2, 64, false><<<dim3(1, ceilDiv(G_ * N_, 128)), 256, 0, stream>>>(xbuf, bscr, concT, xbuf, G_ * N_, 96, 64, 0, concb, 1);
  k_enc<3, 32, false><<<ceilDiv(G_ * E_ * 32, 256), 256, 0, stream>>>(a_in, enc3W, enc3b, bscr, nullptr, E_);
  k_mgemm<2, 64, false><<<dim3(1, ceilDiv(G_ * E_, 128)), 256, 0, stream>>>(ebuf, bscr, concT, ebuf, G_ * E_, 96, 64, 0, concb, 1);

  stblock(31, 1);

  // ---- final per batch ----
  const bf16* resT = wAll + 55296;
  for (int b = 0; b < B_; b++) {
    k_mgemm<0, 64, true><<<dim3(1, ceilDiv(T_ * N_, 128)), 256, 0, stream>>>(
        xbuf + (size_t)b * T_ * N_ * 64, nullptr, resT, zres, T_ * N_, 64, 64, 0, resb, 0);
    k_out<true><<<ceilDiv(N_, 4), 256, 0, stream>>>(
        zres, lastx + (size_t)b * N_ * 64, outW, outb, dout + (size_t)b * T_ * N_, N_);
  }
  for (int b = 0; b < B_; b++) {
    k_mgemm<0, 64, true><<<dim3(1, ceilDiv(T_ * E_, 128)), 256, 0, stream>>>(
        ebuf + (size_t)b * T_ * E_ * 64, nullptr, resT, zres, T_ * E_, 64, 64, 0, resb, 0);
    k_out<false><<<ceilDiv(E_, 4), 256, 0, stream>>>(
        zres, laste + (size_t)b * E_ * 64, outW, outb, dout + (size_t)(B_ * T_ * N_) + (size_t)b * T_ * E_, E_);
  }
}

// Round 14
// 1184.327 us; speedup vs baseline: 4.1070x; 1.0502x over previous
//
#include <hip/hip_runtime.h>
#include <hip/hip_bf16.h>
#include <cfloat>
#include <math.h>

typedef __hip_bfloat16 bf16;
typedef __attribute__((ext_vector_type(8))) short short8v;
typedef __attribute__((ext_vector_type(4))) float f32x4;

constexpr int B_ = 2, T_ = 24, N_ = 1500, E_ = 2000, M_ = 4000, G_ = 48;
constexpr int KPN = 2048;  // padded K for node-side einsum (K=E_=2000), 64-multiple
constexpr int KPE = 1536;  // padded K for edge-side einsum (K=N_=1500), 64-multiple

__device__ __forceinline__ float b2f(bf16 v) { return __bfloat162float(v); }
__device__ __forceinline__ bf16 f2b(float v) { return __float2bfloat16(v); }
static inline int ceilDiv(int a, int b) { return (a + b - 1) / b; }

// ---------------- diagnostics (host-assert sentinel only) ----------------
__global__ __launch_bounds__(256) void k_sentinel(float* __restrict__ out, int n, float val) {
  int i = blockIdx.x * 256 + threadIdx.x;
  if (i < n) out[i] = val;
}

// ---------------- fused weight prep: all transposed bf16 weights in one pass ----------------
__global__ __launch_bounds__(256) void k_wprep(const float* __restrict__ g0, const float* __restrict__ e0,
                                               const float* __restrict__ g1, const float* __restrict__ e1,
                                               const float* __restrict__ cw, const float* __restrict__ rw,
                                               const float* __restrict__ t0, const float* __restrict__ t1,
                                               bf16* __restrict__ out) {
  int i = blockIdx.x * 256 + threadIdx.x;
  if (i >= 108544) return;
  float v;
  if (i < 49152) {
    int which = i / 12288, r = i % 12288;
    const float* W = which == 0 ? g0 : which == 1 ? e0 : which == 2 ? g1 : e1;
    int l = r / 6144, j = r % 6144;
    int n = j / 96, k = j % 96;
    v = W[l * 6144 + k * 64 + n];
  } else if (i < 55296) {
    int j = i - 49152, n = j / 96, k = j % 96;
    v = cw[k * 64 + n];
  } else if (i < 59392) {
    int j = i - 55296, n = j / 64, k = j % 64;
    v = rw[k * 64 + n];
  } else {
    int r = i - 59392;
    int which = r / 24576;
    const float* W = which ? t1 : t0;
    int rr = r % 24576;
    int l = rr / 12288, j = rr % 12288;
    int ii = j & 63, o = (j >> 6) & 63, k = j >> 12;
    v = W[l * 12288 + o * 192 + ii * 3 + k];
  }
  out[i] = f2b(v);
}

// ---------------- encoders ----------------
template <int DIN, int DOUT, bool SAVE>
__global__ __launch_bounds__(256) void k_enc(const float* __restrict__ in, const float* __restrict__ W,
                                             const float* __restrict__ bias, bf16* __restrict__ out,
                                             float* __restrict__ last, int nodes) {
  int idx = blockIdx.x * 256 + threadIdx.x;
  if (idx >= G_ * nodes * DOUT) return;
  int d = idx % DOUT;
  int row = idx / DOUT;
  int node = row % nodes;
  int g = row / nodes;
  const float* ir = in + (size_t)row * DIN;
  float acc = bias[d];
#pragma unroll
  for (int i = 0; i < DIN; i++) acc += ir[i] * W[i * DOUT + d];
  if (SAVE) {
    if (g % T_ == T_ - 1) last[((size_t)(g / T_) * nodes + node) * DOUT + d] = acc;  // pre-relu
  }
  out[idx] = f2b(fmaxf(acc, 0.f));
}

// ---------------- NodeEdge linear: relu(act @ W(64x32) + b) -> traw[node][g*32+f] bf16 ----
__global__ __launch_bounds__(256) void k_lin_ne(const bf16* __restrict__ act, const float* __restrict__ W,
                                                const float* __restrict__ bias, bf16* __restrict__ outT,
                                                int nodes) {
  __shared__ float Ws[2048];
  __shared__ float bs[32];
  for (int i = threadIdx.x; i < 2048; i += 256) Ws[i] = W[i];
  if (threadIdx.x < 32) bs[threadIdx.x] = bias[threadIdx.x];
  __syncthreads();
  int idx = blockIdx.x * 256 + threadIdx.x;
  if (idx >= nodes * G_ * 32) return;
  int f = idx & 31;
  int rem = idx >> 5;
  int g = rem % G_;
  int node = rem / G_;
  const bf16* row = act + ((size_t)g * nodes + node) * 64;
  float acc = bs[f];
#pragma unroll
  for (int i = 0; i < 64; i++) acc += b2f(row[i]) * Ws[i * 32 + f];
  outT[idx] = f2b(fmaxf(acc, 0.f));
}

// ---------------- bf16 transpose: in[K][1536] -> out[1536][Kp] (zero-padded) ----------------
__global__ void k_trans(const bf16* __restrict__ in, bf16* __restrict__ out, int K, int Kp) {
  __shared__ float tl[32][33];
  int c0 = blockIdx.x * 32, k0 = blockIdx.y * 32;
  for (int r = threadIdx.y; r < 32; r += 8) {
    int k = k0 + r, c = c0 + threadIdx.x;
    tl[r][threadIdx.x] = (k < K) ? b2f(in[(size_t)k * 1536 + c]) : 0.f;
  }
  __syncthreads();
  for (int r = threadIdx.y; r < 32; r += 8) {
    int c = c0 + r, k = k0 + threadIdx.x;
    if (k < Kp) out[(size_t)c * Kp + k] = f2b(tl[threadIdx.x][r]);
  }
}

// ---------------- masked incidence (padded): mat[n][k<E?val:0], [N_][Kp] ----------------
__global__ __launch_bounds__(256) void k_mat(const float* __restrict__ w, const float* __restrict__ p,
                                             const float* __restrict__ inci, bf16* __restrict__ mat,
                                             int rows, int K, int Kp) {
  int i = blockIdx.x * 256 + threadIdx.x;
  if (i >= rows * Kp) return;
  int row = i / Kp, k = i % Kp;
  float v = 0.f;
  if (k < K) {
    size_t o = (size_t)row * K + k;
    v = w[o] * fabsf(inci[o]) + p[o];
  }
  mat[i] = f2b(v);
}

// transposed variant: mat[e*KPE + n] = |inci[n][e]|*w[e*N+n] + p[e*N+n], zero-pad n>=N_
__global__ void k_matT(const float* __restrict__ w, const float* __restrict__ p,
                       const float* __restrict__ inci, bf16* __restrict__ mat) {
  __shared__ float tl[32][33];
  int e0 = blockIdx.x * 32, n0 = blockIdx.y * 32;
  for (int r = threadIdx.y; r < 32; r += 8) {
    int n = n0 + r, e = e0 + threadIdx.x;
    tl[r][threadIdx.x] = (n < N_ && e < E_) ? fabsf(inci[(size_t)n * E_ + e]) : 0.f;
  }
  __syncthreads();
  for (int r = threadIdx.y; r < 32; r += 8) {
    int e = e0 + r, n = n0 + threadIdx.x;
    if (e < E_ && n < KPE) {
      size_t o = (size_t)e * N_ + n;
      mat[(size_t)e * KPE + n] = (n < N_) ? f2b(tl[threadIdx.x][r] * w[o] + p[o]) : f2b(0.f);
    }
  }
}

// ---------------- 64x64-tile MFMA GEMM, depth-4 pipeline + bijective XCD swizzle ----------
__global__ __launch_bounds__(256) void k_mgemm64(const bf16* __restrict__ A0, const bf16* __restrict__ Bt,
                                                 bf16* __restrict__ Cp, int Mm, int Kp, int Nn, int gy) {
  __shared__ __align__(16) short As[4][4][64][8];
  __shared__ __align__(16) short Bs[4][4][64][8];
  int tid = threadIdx.x;
  int nwg = gridDim.x;
  int bid = blockIdx.x;
  int l = (bid & 7) * (nwg >> 3) + (bid >> 3);
  int bm = (l % gy) * 64, bn = (l / gy) * 64;
  int lane = tid & 63, wid = tid >> 6;
  int wr = wid >> 1, wc = wid & 1;
  f32x4 acc[2][2];
#pragma unroll
  for (int i = 0; i < 2; i++)
#pragma unroll
    for (int j = 0; j < 2; j++) acc[i][j] = f32x4{0.f, 0.f, 0.f, 0.f};

  const int sr = tid >> 2;
  const int sc = tid & 3;
  const int kb = lane >> 4, lr = lane & 15;
  const int gmA = bm + sr, gnB = bn + sr;
  const bool va_ok = (gmA < Mm), vb_ok = (gnB < Nn);
  const bf16* ap = A0 + (size_t)gmA * Kp + sc * 8;
  const bf16* bp = Bt + (size_t)gnB * Kp + sc * 8;
  const uint4 z4 = {0, 0, 0, 0};
  const int P = Kp >> 5;

  uint4 va0 = va_ok ? *reinterpret_cast<const uint4*>(ap) : z4;
  uint4 vb0 = vb_ok ? *reinterpret_cast<const uint4*>(bp) : z4;
  uint4 va1 = va_ok ? *reinterpret_cast<const uint4*>(ap + 32) : z4;
  uint4 vb1 = vb_ok ? *reinterpret_cast<const uint4*>(bp + 32) : z4;
  *reinterpret_cast<uint4*>(&As[0][sc][sr][0]) = va0;
  *reinterpret_cast<uint4*>(&Bs[0][sc][sr][0]) = vb0;
  uint4 va2 = va_ok ? *reinterpret_cast<const uint4*>(ap + 64) : z4;
  uint4 vb2 = vb_ok ? *reinterpret_cast<const uint4*>(bp + 64) : z4;
  __syncthreads();

  for (int p = 0; p < P; p += 2) {
    *reinterpret_cast<uint4*>(&As[(p + 1) & 3][sc][sr][0]) = va1;
    *reinterpret_cast<uint4*>(&Bs[(p + 1) & 3][sc][sr][0]) = vb1;
    if (p + 3 < P) {
      va1 = va_ok ? *reinterpret_cast<const uint4*>(ap + (p + 3) * 32) : z4;
      vb1 = vb_ok ? *reinterpret_cast<const uint4*>(bp + (p + 3) * 32) : z4;
    }
    {
      int bf = p & 3;
      short8v a0 = *reinterpret_cast<const short8v*>(&As[bf][kb][wr * 32 + lr][0]);
      short8v a1 = *reinterpret_cast<const short8v*>(&As[bf][kb][wr * 32 + 16 + lr][0]);
      short8v b0 = *reinterpret_cast<const short8v*>(&Bs[bf][kb][wc * 32 + lr][0]);
      short8v b1 = *reinterpret_cast<const short8v*>(&Bs[bf][kb][wc * 32 + 16 + lr][0]);
      __builtin_amdgcn_s_setprio(1);
      acc[0][0] = __builtin_amdgcn_mfma_f32_16x16x32_bf16(a0, b0, acc[0][0], 0, 0, 0);
      acc[0][1] = __builtin_amdgcn_mfma_f32_16x16x32_bf16(a0, b1, acc[0][1], 0, 0, 0);
      acc[1][0] = __builtin_amdgcn_mfma_f32_16x16x32_bf16(a1, b0, acc[1][0], 0, 0, 0);
      acc[1][1] = __builtin_amdgcn_mfma_f32_16x16x32_bf16(a1, b1, acc[1][1], 0, 0, 0);
      __builtin_amdgcn_s_setprio(0);
    }
    __syncthreads();
    *reinterpret_cast<uint4*>(&As[(p + 2) & 3][sc][sr][0]) = va2;
    *reinterpret_cast<uint4*>(&Bs[(p + 2) & 3][sc][sr][0]) = vb2;
    if (p + 4 < P) {
      va2 = va_ok ? *reinterpret_cast<const uint4*>(ap + (p + 4) * 32) : z4;
      vb2 = vb_ok ? *reinterpret_cast<const uint4*>(bp + (p + 4) * 32) : z4;
    }
    {
      int bf = (p + 1) & 3;
      short8v a0 = *reinterpret_cast<const short8v*>(&As[bf][kb][wr * 32 + lr][0]);
      short8v a1 = *reinterpret_cast<const short8v*>(&As[bf][kb][wr * 32 + 16 + lr][0]);
      short8v b0 = *reinterpret_cast<const short8v*>(&Bs[bf][kb][wc * 32 + lr][0]);
      short8v b1 = *reinterpret_cast<const short8v*>(&Bs[bf][kb][wc * 32 + 16 + lr][0]);
      __builtin_amdgcn_s_setprio(1);
      acc[0][0] = __builtin_amdgcn_mfma_f32_16x16x32_bf16(a0, b0, acc[0][0], 0, 0, 0);
      acc[0][1] = __builtin_amdgcn_mfma_f32_16x16x32_bf16(a0, b1, acc[0][1], 0, 0, 0);
      acc[1][0] = __builtin_amdgcn_mfma_f32_16x16x32_bf16(a1, b0, acc[1][0], 0, 0, 0);
      acc[1][1] = __builtin_amdgcn_mfma_f32_16x16x32_bf16(a1, b1, acc[1][1], 0, 0, 0);
      __builtin_amdgcn_s_setprio(0);
    }
    __syncthreads();
  }
#pragma unroll
  for (int mi = 0; mi < 2; mi++) {
    int r0 = bm + wr * 32 + mi * 16 + (lane >> 4) * 4;
#pragma unroll
    for (int ni = 0; ni < 2; ni++) {
      int col = bn + wc * 32 + ni * 16 + lr;
      if (col >= Nn) continue;
#pragma unroll
      for (int i = 0; i < 4; i++) {
        int r = r0 + i;
        if (r < Mm) Cp[(size_t)r * Nn + col] = f2b(acc[mi][ni][i]);
      }
    }
  }
}

// ---------------- MFMA GEMM (128-row tile): z / conc / res GEMMs ----------------
// ESED=true (AMODE 1 z-GEMM): epilogue also emits es[r]=z.as, edv[r]=z.ad (f32, plain stores;
// rows are block-exclusive because gridDim.x==1).
template <int AMODE, int BNt, bool CF32b, bool ESED>
__global__ __launch_bounds__(256) void k_mgemm(const bf16* __restrict__ A0, const bf16* __restrict__ A1,
                                               const bf16* __restrict__ Bt, void* __restrict__ Cp,
                                               int Mm, int Kp, int Nn, int nodes,
                                               const float* __restrict__ bias, int relu,
                                               const float* __restrict__ asv, const float* __restrict__ adv,
                                               float* __restrict__ esOut, float* __restrict__ edOut) {
  constexpr int BM = 128;
  constexpr int WTN = BNt / 32;
  __shared__ __align__(16) short As[4][BM][8];
  __shared__ __align__(16) short Bs[4][BNt][8];
  __shared__ float smr[2][BM][2];
  int tid = threadIdx.x;
  int bm = blockIdx.y * BM;
  int bn = blockIdx.x * BNt;
  int lane = tid & 63;
  int wid = tid >> 6;
  int wr = wid >> 1, wc = wid & 1;
  f32x4 acc[4][WTN];
#pragma unroll
  for (int i = 0; i < 4; i++)
#pragma unroll
    for (int j = 0; j < WTN; j++) acc[i][j] = f32x4{0.f, 0.f, 0.f, 0.f};

  const int ar = tid >> 1;
  const int ah = tid & 1;
  const int kb = lane >> 4;
  const int lr = lane & 15;

  for (int k0 = 0; k0 < Kp; k0 += 32) {
    uint4 va0 = {0, 0, 0, 0}, va1 = {0, 0, 0, 0};
    int gm = bm + ar;
    if (gm < Mm) {
      int ks = k0 + ah * 16;
      const bf16* src;
      if (AMODE == 0) src = A0 + (size_t)gm * Kp + ks;
      else if (ks < 64) src = A0 + (size_t)gm * 64 + ks;
      else if (AMODE == 1) {
        int g = gm / nodes, nd = gm % nodes;
        src = A1 + ((size_t)nd * G_ + g) * 32 + (ks - 64);
      } else {
        src = A1 + (size_t)gm * 32 + (ks - 64);
      }
      const uint4* p = reinterpret_cast<const uint4*>(src);
      va0 = p[0];
      va1 = p[1];
    }
    *reinterpret_cast<uint4*>(&As[ah * 2 + 0][ar][0]) = va0;
    *reinterpret_cast<uint4*>(&As[ah * 2 + 1][ar][0]) = va1;
    if (BNt == 128) {
      int br = tid >> 1, bh = tid & 1;
      uint4 vb0 = {0, 0, 0, 0}, vb1 = {0, 0, 0, 0};
      int gn = bn + br;
      if (gn < Nn) {
        const uint4* p = reinterpret_cast<const uint4*>(Bt + (size_t)gn * Kp + k0 + bh * 16);
        vb0 = p[0];
        vb1 = p[1];
      }
      *reinterpret_cast<uint4*>(&Bs[bh * 2 + 0][br][0]) = vb0;
      *reinterpret_cast<uint4*>(&Bs[bh * 2 + 1][br][0]) = vb1;
    } else {
      int br = tid >> 2, bk = tid & 3;
      uint4 vb0 = {0, 0, 0, 0};
      int gn = bn + br;
      if (gn < Nn) vb0 = *reinterpret_cast<const uint4*>(Bt + (size_t)gn * Kp + k0 + bk * 8);
      *reinterpret_cast<uint4*>(&Bs[bk][br][0]) = vb0;
    }
    __syncthreads();
    short8v a[4], b[WTN];
#pragma unroll
    for (int mi = 0; mi < 4; mi++)
      a[mi] = *reinterpret_cast<const short8v*>(&As[kb][wr * 64 + mi * 16 + lr][0]);
#pragma unroll
    for (int ni = 0; ni < WTN; ni++)
      b[ni] = *reinterpret_cast<const short8v*>(&Bs[kb][wc * (BNt / 2) + ni * 16 + lr][0]);
#pragma unroll
    for (int mi = 0; mi < 4; mi++)
#pragma unroll
      for (int ni = 0; ni < WTN; ni++)
        acc[mi][ni] = __builtin_amdgcn_mfma_f32_16x16x32_bf16(a[mi], b[ni], acc[mi][ni], 0, 0, 0);
    __syncthreads();
  }
#pragma unroll
  for (int mi = 0; mi < 4; mi++) {
    int r0 = bm + wr * 64 + mi * 16 + (lane >> 4) * 4;
#pragma unroll
    for (int ni = 0; ni < WTN; ni++) {
      int col = bn + wc * (BNt / 2) + ni * 16 + lr;
      float bv = bias ? bias[col] : 0.f;
#pragma unroll
      for (int i = 0; i < 4; i++) {
        int r = r0 + i;
        if (r < Mm) {
          float v = acc[mi][ni][i] + bv;
          if (relu) v = fmaxf(v, 0.f);
          if (CF32b) ((float*)Cp)[(size_t)r * Nn + col] = v;
          else ((bf16*)Cp)[(size_t)r * Nn + col] = f2b(v);
        }
      }
    }
  }
  if (ESED) {
    float asc0 = asv[wc * 32 + lr];
    float asc1 = asv[wc * 32 + 16 + lr];
    float adc0 = adv[wc * 32 + lr];
    float adc1 = adv[wc * 32 + 16 + lr];
#pragma unroll
    for (int mi = 0; mi < 4; mi++) {
#pragma unroll
      for (int i = 0; i < 4; i++) {
        float pe = acc[mi][0][i] * asc0 + acc[mi][1][i] * asc1;
        float pd = acc[mi][0][i] * adc0 + acc[mi][1][i] * adc1;
#pragma unroll
        for (int o = 8; o; o >>= 1) { pe += __shfl_xor(pe, o); pd += __shfl_xor(pd, o); }
        if (lr == 0) {
          int rl = wr * 64 + mi * 16 + (lane >> 4) * 4 + i;
          smr[wc][rl][0] = pe;
          smr[wc][rl][1] = pd;
        }
      }
    }
    __syncthreads();
    if (tid < BM) {
      int r = bm + tid;
      if (r < Mm) {
        esOut[r] = smr[0][tid][0] + smr[1][tid][0];
        edOut[r] = smr[0][tid][1] + smr[1][tid][1];
      }
    }
  }
}

// ---------------- causal dilated conv: depth-4 pipelined MFMA, B weights in registers ------
template <int DIL>
__global__ __launch_bounds__(256) void k_cgemm(const bf16* __restrict__ A, const bf16* __restrict__ Wc,
                                               const float* __restrict__ bias, bf16* __restrict__ C,
                                               int Mm, int nodes) {
  __shared__ __align__(16) short As[4][4][128][8];
  int tid = threadIdx.x;
  int bm = blockIdx.x * 128;
  int lane = tid & 63, wid = tid >> 6;
  int wr = wid >> 1, wc = wid & 1;
  const int ar = tid >> 1, ah = tid & 1;
  const int kb = lane >> 4, lr = lane & 15;
  const int gm = bm + ar;
  const int t = (gm / nodes) % T_;
  const uint4 z4 = {0, 0, 0, 0};

  // B fragments: bfr[tap][kc][ni], col = wc*32 + ni*16 + lr (one-time global load)
  short8v bfr[3][2][2];
#pragma unroll
  for (int tap = 0; tap < 3; tap++)
#pragma unroll
    for (int kc = 0; kc < 2; kc++)
#pragma unroll
      for (int ni = 0; ni < 2; ni++) {
        int col = wc * 32 + ni * 16 + lr;
        bfr[tap][kc][ni] = *reinterpret_cast<const short8v*>(Wc + tap * 4096 + (size_t)col * 64 + kc * 32 + kb * 8);
      }

  f32x4 acc[4][2];
#pragma unroll
  for (int i = 0; i < 4; i++)
#pragma unroll
    for (int j = 0; j < 2; j++) acc[i][j] = f32x4{0.f, 0.f, 0.f, 0.f};

#define CG_LDA(p, vx, vy)                                                          \
  {                                                                                \
    const int sh_ = (((p) >> 1) - 2) * DIL;                                        \
    if ((gm < Mm) && (t + sh_ >= 0)) {                                             \
      const uint4* pp = reinterpret_cast<const uint4*>(                            \
          A + ((size_t)gm + (size_t)sh_ * nodes) * 64 + ((p) & 1) * 32 + ah * 16); \
      vx = pp[0];                                                                  \
      vy = pp[1];                                                                  \
    } else {                                                                       \
      vx = z4;                                                                     \
      vy = z4;                                                                     \
    }                                                                              \
  }
#define CG_WR(buf, vx, vy)                                     \
  *reinterpret_cast<uint4*>(&As[buf][ah * 2 + 0][ar][0]) = vx; \
  *reinterpret_cast<uint4*>(&As[buf][ah * 2 + 1][ar][0]) = vy;
#define CG_MFMA(q)                                                                                         \
  {                                                                                                        \
    short8v a0_ = *reinterpret_cast<const short8v*>(&As[(q) & 3][kb][wr * 64 + 0 + lr][0]);                \
    short8v a1_ = *reinterpret_cast<const short8v*>(&As[(q) & 3][kb][wr * 64 + 16 + lr][0]);               \
    short8v a2_ = *reinterpret_cast<const short8v*>(&As[(q) & 3][kb][wr * 64 + 32 + lr][0]);               \
    short8v a3_ = *reinterpret_cast<const short8v*>(&As[(q) & 3][kb][wr * 64 + 48 + lr][0]);               \
    __builtin_amdgcn_s_setprio(1);                                                                         \
    acc[0][0] = __builtin_amdgcn_mfma_f32_16x16x32_bf16(a0_, bfr[(q) >> 1][(q) & 1][0], acc[0][0], 0, 0, 0); \
    acc[0][1] = __builtin_amdgcn_mfma_f32_16x16x32_bf16(a0_, bfr[(q) >> 1][(q) & 1][1], acc[0][1], 0, 0, 0); \
    acc[1][0] = __builtin_amdgcn_mfma_f32_16x16x32_bf16(a1_, bfr[(q) >> 1][(q) & 1][0], acc[1][0], 0, 0, 0); \
    acc[1][1] = __builtin_amdgcn_mfma_f32_16x16x32_bf16(a1_, bfr[(q) >> 1][(q) & 1][1], acc[1][1], 0, 0, 0); \
    acc[2][0] = __builtin_amdgcn_mfma_f32_16x16x32_bf16(a2_, bfr[(q) >> 1][(q) & 1][0], acc[2][0], 0, 0, 0); \
    acc[2][1] = __builtin_amdgcn_mfma_f32_16x16x32_bf16(a2_, bfr[(q) >> 1][(q) & 1][1], acc[2][1], 0, 0, 0); \
    acc[3][0] = __builtin_amdgcn_mfma_f32_16x16x32_bf16(a3_, bfr[(q) >> 1][(q) & 1][0], acc[3][0], 0, 0, 0); \
    acc[3][1] = __builtin_amdgcn_mfma_f32_16x16x32_bf16(a3_, bfr[(q) >> 1][(q) & 1][1], acc[3][1], 0, 0, 0); \
    __builtin_amdgcn_s_setprio(0);                                                                         \
  }
  // body for phases p, p+1 with literal p (all indices compile-time after expansion)
#define CG_BODY(p, lastPair)                  \
  CG_WR(((p) + 1) & 3, r1x, r1y);             \
  if (!(lastPair)) CG_LDA((p) + 3, r1x, r1y); \
  CG_MFMA(p);                                 \
  __syncthreads();                            \
  CG_WR(((p) + 2) & 3, r2x, r2y);             \
  if (!(lastPair)) CG_LDA((p) + 4, r2x, r2y); \
  CG_MFMA((p) + 1);                           \
  __syncthreads();

  // prologue: ld(0)->L0, r1=ld(1), r2=ld(2)
  uint4 p0x, p0y, r1x, r1y, r2x, r2y;
  CG_LDA(0, p0x, p0y);
  CG_LDA(1, r1x, r1y);
  CG_WR(0, p0x, p0y);
  CG_LDA(2, r2x, r2y);
  __syncthreads();

  CG_BODY(0, false)
  CG_BODY(2, false)  // CG_LDA(5)/CG_LDA(6) guarded: 5<6 ok, 6 -> lastPair? no: p+4=6 == out of range
  CG_BODY(4, true)

#undef CG_LDA
#undef CG_WR
#undef CG_MFMA
#undef CG_BODY

#pragma unroll
  for (int mi = 0; mi < 4; mi++) {
    int r0 = bm + wr * 64 + mi * 16 + (lane >> 4) * 4;
#pragma unroll
    for (int ni = 0; ni < 2; ni++) {
      int col = wc * 32 + ni * 16 + lr;
      float bv = bias[col];
#pragma unroll
      for (int i = 0; i < 4; i++) {
        int r = r0 + i;
        if (r < Mm) C[(size_t)r * 64 + col] = f2b(fmaxf(acc[mi][ni][i] + bv, 0.f));
      }
    }
  }
}

// ---------------- GAT softmax weights: thread per (g,node), normalized exp weights ----------
__global__ __launch_bounds__(256) void k_gat_w(const float* __restrict__ es, const float* __restrict__ edv,
                                               const int* __restrict__ off, const int* __restrict__ adj,
                                               float* __restrict__ wgt, int nodes, int tot) {
  int idx = blockIdx.x * 256 + threadIdx.x;
  if (idx >= G_ * nodes) return;
  int g = idx / nodes, node = idx % nodes;
  int s0 = off[node], s1 = off[node + 1];
  const float* esg = es + (size_t)g * nodes;
  float edval = edv[(size_t)g * nodes + node];
  float m = -FLT_MAX;
  for (int s = s0; s < s1; s++) {
    float a = esg[adj[s]] + edval;
    a = (a >= 0.f) ? a : 0.2f * a;
    m = fmaxf(m, a);
  }
  float den = 0.f;
  float* wg = wgt + (size_t)g * tot;
  for (int s = s0; s < s1; s++) {
    float a = esg[adj[s]] + edval;
    a = (a >= 0.f) ? a : 0.2f * a;
    float ex = expf(a - m);
    den += ex;
    wg[s] = ex;
  }
  float inv = (s1 > s0) ? 1.f / den : 0.f;
  for (int s = s0; s < s1; s++) wg[s] *= inv;
}

// ---------------- GAT aggregation: thread per (g,node,4-feature chunk) ----------------
__global__ __launch_bounds__(256) void k_gat_aggr3(const bf16* __restrict__ z, const float* __restrict__ wgt,
                                                   const int* __restrict__ off, const int* __restrict__ adj,
                                                   const float* __restrict__ bias, bf16* __restrict__ out,
                                                   int nodes, int tot) {
  int idx = blockIdx.x * 256 + threadIdx.x;
  if (idx >= G_ * nodes * 16) return;
  int c = idx & 15;
  int rest = idx >> 4;
  int node = rest % nodes;
  int g = rest / nodes;
  int s0 = off[node], s1 = off[node + 1];
  const bf16* zg = z + (size_t)g * nodes * 64 + c * 4;
  const float* wg = wgt + (size_t)g * tot;
  float n0 = 0.f, n1 = 0.f, n2 = 0.f, n3 = 0.f;
  for (int s = s0; s < s1; s++) {
    int src = adj[s];
    float w = wg[s];
    bf16 v[4];
    *reinterpret_cast<uint2*>(v) = *reinterpret_cast<const uint2*>(zg + (size_t)src * 64);
    n0 += w * b2f(v[0]);
    n1 += w * b2f(v[1]);
    n2 += w * b2f(v[2]);
    n3 += w * b2f(v[3]);
  }
  bf16 ov[4];
  ov[0] = f2b(fmaxf(n0 + bias[c * 4 + 0], 0.f));
  ov[1] = f2b(fmaxf(n1 + bias[c * 4 + 1], 0.f));
  ov[2] = f2b(fmaxf(n2 + bias[c * 4 + 2], 0.f));
  ov[3] = f2b(fmaxf(n3 + bias[c * 4 + 3], 0.f));
  *reinterpret_cast<uint2*>(out + (size_t)rest * 64 + c * 4) = *reinterpret_cast<uint2*>(ov);
}

// ---------------- CSR build ----------------
__global__ __launch_bounds__(256) void k_csr_count(const int* __restrict__ ind, int ner, int nn,
                                                   int* __restrict__ cnt, int* __restrict__ srcA,
                                                   int* __restrict__ dstA) {
  int i = blockIdx.x * 256 + threadIdx.x;
  int tot = ner + nn;
  if (i >= tot) return;
  int s_, d_;
  if (i < ner) { s_ = ind[i]; d_ = ind[ner + i]; }
  else { s_ = d_ = i - ner; }
  srcA[i] = s_; dstA[i] = d_;
  if (d_ >= 0 && d_ < nn) atomicAdd(&cnt[d_], 1);
}

__global__ __launch_bounds__(1024) void k_scan(const int* __restrict__ cnt, int* __restrict__ off, int n) {
  __shared__ int a[1024];
  int t = threadIdx.x;
  int c0 = (2 * t < n) ? cnt[2 * t] : 0;
  int c1 = (2 * t + 1 < n) ? cnt[2 * t + 1] : 0;
  a[t] = c0 + c1;
  __syncthreads();
  for (int d = 1; d < 1024; d <<= 1) {
    int u = (t >= d) ? a[t - d] : 0;
    __syncthreads();
    a[t] += u;
    __syncthreads();
  }
  int excl = (t > 0) ? a[t - 1] : 0;
  if (2 * t < n) off[2 * t] = excl;
  if (2 * t + 1 < n) off[2 * t + 1] = excl + c0;
  if (t == 0) off[n] = a[1023];
}

__global__ __launch_bounds__(256) void k_csr_fill(const int* __restrict__ srcA, const int* __restrict__ dstA,
                                                  const int* __restrict__ off, int* __restrict__ cur,
                                                  int* __restrict__ adj, int tot, int nn) {
  int i = blockIdx.x * 256 + threadIdx.x;
  if (i >= tot) return;
  int d_ = dstA[i];
  if (d_ < 0 || d_ >= nn) return;
  int pos = atomicAdd(&cur[d_], 1);
  adj[off[d_] + pos] = srcA[i];
}

// ---------------- per-batch: cumsum + residual + relu + head (wave per node) ----------------
template <bool XB>
__global__ __launch_bounds__(256) void k_out(const float* __restrict__ yx, const float* __restrict__ last,
                                             const float* __restrict__ oW, const float* __restrict__ ob_,
                                             float* __restrict__ dout, int nodes) {
  int wid = threadIdx.x >> 6, lane = threadIdx.x & 63;
  int node = blockIdx.x * 4 + wid;
  if (node >= nodes) return;
  float lw = oW[lane];
  float ob = ob_[0];
  float lv = last[(size_t)node * 64 + lane];
  float acc = 0.f;
  for (int tt = 0; tt < T_; tt++) {
    acc += yx[((size_t)tt * nodes + node) * 64 + lane];
    float v = fmaxf(acc + lv, 0.f);
    float p = v * lw;
#pragma unroll
    for (int o2 = 32; o2; o2 >>= 1) p += __shfl_down(p, o2);
    if (lane == 0) {
      float o = p + ob;
      if (XB) o = fminf(fmaxf(o / 6.f + 0.5f, 0.f), 1.f);
      else o = tanhf(o);
      dout[(size_t)tt * nodes + node] = o;
    }
  }
}

// ===================================================================================
extern "C" void kernel_launch(void* const* d_in, const int* in_sizes, int n_in,
                              void* d_out, int out_size, void* d_ws, size_t ws_size,
                              hipStream_t stream) {
  float* dout = (float*)d_out;

  if (n_in != 57) {
    k_sentinel<<<ceilDiv(out_size, 256), 256, 0, stream>>>(dout, out_size, 20000.f + 128.f * n_in);
    return;
  }
  static const int expSz[57] = {
      288000, 288000, 288000, 288000,
      256, 64, 192, 64, 128, 32, 96, 32,
      3000000,
      12288, 128, 128, 128, 12288, 128, 128, 128,
      4096, 64, 6000000, 6000000, 4096, 64, 6000000, 6000000,
      24576, 128,
      12288, 128, 128, 128, 12288, 128, 128, 128,
      4096, 64, 6000000, 6000000, 4096, 64, 6000000, 6000000,
      24576, 128,
      6144, 64, 4096, 64, 64, 1, 4000, 8000};
  for (int i = 0; i < 57; i++) {
    if (in_sizes[i] != expSz[i]) {
      k_sentinel<<<ceilDiv(out_size, 256), 256, 0, stream>>>(dout, out_size, 4096.f + 64.f * i);
      return;
    }
  }

  auto ff = [&](int i) { return (const float*)d_in[i]; };
  const float *x_in = ff(0), *e_in = ff(1), *b_in = ff(2), *a_in = ff(3);
  const float *enc0W = ff(4), *enc0b = ff(5), *enc1W = ff(6), *enc1b = ff(7);
  const float *enc2W = ff(8), *enc2b = ff(9), *enc3W = ff(10), *enc3b = ff(11);
  const float* inci = ff(12);
  const float *concW = ff(49), *concb = ff(50), *resW = ff(51), *resb = ff(52);
  const float *outW = ff(53), *outb = ff(54);
  const int* edge_ind = (const int*)d_in[55];
  const int* node_ind = (const int*)d_in[56];

  // ---- workspace layout, 256B-aligned ----
  char* base = (char*)d_ws;
  size_t off = 0;
  auto A = [&](size_t bytes) { void* p = base + off; off = (off + bytes + 255) & ~(size_t)255; return p; };
  char* SCR = (char*)A(21504000);
  bf16* xbuf = (bf16*)A(9216000);
  bf16* ebuf = (bf16*)A(12288000);
  float* lastx = (float*)A(768000);
  float* laste = (float*)A(1024000);
  float* es = (float*)A(384000);
  float* edv = (float*)A(384000);
  float* wgt = (float*)A((size_t)G_ * (M_ + E_) * 4);
  bf16* wAll = (bf16*)A(217088);
  int* cntN = (int*)A((size_t)(N_ + N_ + E_ + E_) * 4);
  int* curN = cntN + N_;
  int* cntE = curN + N_;
  int* curE = cntE + E_;
  int* offN = (int*)A((N_ + 1) * 4);
  int* offE = (int*)A((E_ + 1) * 4);
  int* srcN = (int*)A((E_ + N_) * 4);
  int* dstN = (int*)A((E_ + N_) * 4);
  int* adjN = (int*)A((E_ + N_) * 4);
  int* srcE = (int*)A((M_ + E_) * 4);
  int* dstE = (int*)A((M_ + E_) * 4);
  int* adjE = (int*)A((M_ + E_) * 4);
  size_t required = off;

  if (ws_size < required) {
    k_sentinel<<<ceilDiv(out_size, 256), 256, 0, stream>>>(dout, out_size, 1000.f + (float)(ws_size >> 20));
    return;
  }

  // SCR aliases (liveness-checked)
  bf16* matb = (bf16*)SCR;
  bf16* tlinT = (bf16*)(SCR + 6553600);
  bf16* traw = (bf16*)(SCR + 13107200);
  bf16* tmat = (bf16*)(SCR + 13107200);
  bf16* zbuf = (bf16*)SCR;
  bf16* bscr = (bf16*)SCR;
  bf16* cx1 = (bf16*)SCR;
  bf16* ce1 = (bf16*)(SCR + 9216000);
  float* zres = (float*)SCR;

  const int totN = E_ + N_;   // 3500
  const int totE = M_ + E_;   // 6000

  // ---- fused weight prep ----
  k_wprep<<<ceilDiv(108544, 256), 256, 0, stream>>>(ff(13), ff(17), ff(31), ff(35), concW, resW,
                                                    ff(29), ff(47), wAll);

  // ---- CSR build ----
  hipMemsetAsync(cntN, 0, (size_t)(N_ + N_ + E_ + E_) * sizeof(int), stream);
  k_csr_count<<<ceilDiv(totN, 256), 256, 0, stream>>>(edge_ind, E_, N_, cntN, srcN, dstN);
  k_scan<<<1, 1024, 0, stream>>>(cntN, offN, N_);
  k_csr_fill<<<ceilDiv(totN, 256), 256, 0, stream>>>(srcN, dstN, offN, curN, adjN, totN, N_);
  k_csr_count<<<ceilDiv(totE, 256), 256, 0, stream>>>(node_ind, M_, E_, cntE, srcE, dstE);
  k_scan<<<1, 1024, 0, stream>>>(cntE, offE, E_);
  k_csr_fill<<<ceilDiv(totE, 256), 256, 0, stream>>>(srcE, dstE, offE, curE, adjE, totE, E_);

  // ---- encoders ----
  k_enc<4, 64, true><<<ceilDiv(G_ * N_ * 64, 256), 256, 0, stream>>>(x_in, enc0W, enc0b, xbuf, lastx, N_);
  k_enc<3, 64, true><<<ceilDiv(G_ * E_ * 64, 256), 256, 0, stream>>>(e_in, enc1W, enc1b, ebuf, laste, E_);

  auto stblock = [&](int sb, int sbi) {
    const float *gxas = ff(sb + 1), *gxad = ff(sb + 2), *gxb = ff(sb + 3);
    const float *geas = ff(sb + 5), *gead = ff(sb + 6), *geb = ff(sb + 7);
    const float *neW = ff(sb + 8), *neb = ff(sb + 9), *nw = ff(sb + 10), *np_ = ff(sb + 11);
    const float *enW = ff(sb + 12), *enb = ff(sb + 13), *ew = ff(sb + 14), *ep = ff(sb + 15);
    const float* tpb = ff(sb + 17);
    for (int l = 0; l < 2; l++) {
      const bf16* gxw_t = wAll + sbi * 24576 + l * 6144;
      const bf16* gew_t = wAll + sbi * 24576 + 12288 + l * 6144;
      // ---- node side: xe = NodeEdge(e); x = relu(GAT([x,xe])) ----
      k_lin_ne<<<ceilDiv(E_ * G_ * 32, 256), 256, 0, stream>>>(ebuf, neW + l * 2048, neb + l * 32, traw, E_);
      k_trans<<<dim3(48, KPN / 32), dim3(32, 8), 0, stream>>>(traw, tlinT, E_, KPN);
      k_mat<<<ceilDiv(N_ * KPN, 256), 256, 0, stream>>>(nw + (size_t)l * N_ * E_, np_ + (size_t)l * N_ * E_, inci, matb, N_, E_, KPN);
      k_mgemm64<<<dim3(24 * 24), 256, 0, stream>>>(matb, tlinT, tmat, N_, KPN, 1536, 24);
      k_mgemm<1, 64, false, true><<<dim3(1, ceilDiv(G_ * N_, 128)), 256, 0, stream>>>(
          xbuf, tmat, gxw_t, zbuf, G_ * N_, 96, 64, N_, nullptr, 0, gxas + l * 64, gxad + l * 64, es, edv);
      k_gat_w<<<ceilDiv(G_ * N_, 256), 256, 0, stream>>>(es, edv, offN, adjN, wgt, N_, totN);
      k_gat_aggr3<<<ceilDiv(G_ * N_ * 16, 256), 256, 0, stream>>>(zbuf, wgt, offN, adjN, gxb + l * 64, xbuf, N_, totN);
      // ---- edge side: ex = NodeEdge(x); e = relu(GAT([e,ex])) ----
      k_lin_ne<<<ceilDiv(N_ * G_ * 32, 256), 256, 0, stream>>>(xbuf, enW + l * 2048, enb + l * 32, traw, N_);
      k_trans<<<dim3(48, KPE / 32), dim3(32, 8), 0, stream>>>(traw, tlinT, N_, KPE);
      k_matT<<<dim3(ceilDiv(E_, 32), KPE / 32), dim3(32, 8), 0, stream>>>(ew + (size_t)l * E_ * N_, ep + (size_t)l * E_ * N_, inci, matb);
      k_mgemm64<<<dim3(24 * 32), 256, 0, stream>>>(matb, tlinT, tmat, E_, KPE, 1536, 32);
      k_mgemm<1, 64, false, true><<<dim3(1, ceilDiv(G_ * E_, 128)), 256, 0, stream>>>(
          ebuf, tmat, gew_t, zbuf, G_ * E_, 96, 64, E_, nullptr, 0, geas + l * 64, gead + l * 64, es, edv);
      k_gat_w<<<ceilDiv(G_ * E_, 256), 256, 0, stream>>>(es, edv, offE, adjE, wgt, E_, totE);
      k_gat_aggr3<<<ceilDiv(G_ * E_ * 16, 256), 256, 0, stream>>>(zbuf, wgt, offE, adjE, geb + l * 64, ebuf, E_, totE);
    }
    // ---- temporal convs: shifted-view MFMA GEMMs ----
    const bf16* cw0 = wAll + 59392 + sbi * 24576;
    const bf16* cw1 = cw0 + 12288;
    k_cgemm<1><<<ceilDiv(G_ * N_, 128), 256, 0, stream>>>(xbuf, cw0, tpb, cx1, G_ * N_, N_);
    k_cgemm<1><<<ceilDiv(G_ * E_, 128), 256, 0, stream>>>(ebuf, cw0, tpb, ce1, G_ * E_, E_);
    k_cgemm<2><<<ceilDiv(G_ * N_, 128), 256, 0, stream>>>(cx1, cw1, tpb + 64, xbuf, G_ * N_, N_);
    k_cgemm<2><<<ceilDiv(G_ * E_, 128), 256, 0, stream>>>(ce1, cw1, tpb + 64, ebuf, G_ * E_, E_);
  };

  stblock(13, 0);

  // ---- conc (shared weights; in-place: gridDim.x==1 row ownership) ----
  const bf16* concT = wAll + 49152;
  k_enc<4, 32, false><<<ceilDiv(G_ * N_ * 32, 256), 256, 0, stream>>>(b_in, enc2W, enc2b, bscr, nullptr, N_);
  k_mgemm<2, 64, false, false><<<dim3(1, ceilDiv(G_ * N_, 128)), 256, 0, stream>>>(
      xbuf, bscr, concT, xbuf, G_ * N_, 96, 64, 0, concb, 1, nullptr, nullptr, nullptr, nullptr);
  k_enc<3, 32, false><<<ceilDiv(G_ * E_ * 32, 256), 256, 0, stream>>>(a_in, enc3W, enc3b, bscr, nullptr, E_);
  k_mgemm<2, 64, false, false><<<dim3(1, ceilDiv(G_ * E_, 128)), 256, 0, stream>>>(
      ebuf, bscr, concT, ebuf, G_ * E_, 96, 64, 0, concb, 1, nullptr, nullptr, nullptr, nullptr);

  stblock(31, 1);

  // ---- final per batch ----
  const bf16* resT = wAll + 55296;
  for (int b = 0; b < B_; b++) {
    k_mgemm<0, 64, true, false><<<dim3(1, ceilDiv(T_ * N_, 128)), 256, 0, stream>>>(
        xbuf + (size_t)b * T_ * N_ * 64, nullptr, resT, zres, T_ * N_, 64, 64, 0, resb, 0,
        nullptr, nullptr, nullptr, nullptr);
    k_out<true><<<ceilDiv(N_, 4), 256, 0, stream>>>(
        zres, lastx + (size_t)b * N_ * 64, outW, outb, dout + (size_t)b * T_ * N_, N_);
  }
  for (int b = 0; b < B_; b++) {
    k_mgemm<0, 64, true, false><<<dim3(1, ceilDiv(T_ * E_, 128)), 256, 0, stream>>>(
        ebuf + (size_t)b * T_ * E_ * 64, nullptr, resT, zres, T_ * E_, 64, 64, 0, resb, 0,
        nullptr, nullptr, nullptr, nullptr);
    k_out<false><<<ceilDiv(E_, 4), 256, 0, stream>>>(
        zres, laste + (size_t)b * E_ * 64, outW, outb, dout + (size_t)(B_ * T_ * N_) + (size_t)b * T_ * E_, E_);
  }
}

// Round 15
// 1050.112 us; speedup vs baseline: 4.6319x; 1.1278x over previous
//
#include <hip/hip_runtime.h>
#include <hip/hip_bf16.h>
#include <cfloat>
#include <math.h>

typedef __hip_bfloat16 bf16;
typedef __attribute__((ext_vector_type(8))) short short8v;
typedef __attribute__((ext_vector_type(4))) float f32x4;

constexpr int B_ = 2, T_ = 24, N_ = 1500, E_ = 2000, M_ = 4000, G_ = 48;
constexpr int KPN = 2048;  // padded K for node-side einsum (K=E_=2000), 64-multiple
constexpr int KPE = 1536;  // padded K for edge-side einsum (K=N_=1500), 64-multiple

__device__ __forceinline__ float b2f(bf16 v) { return __bfloat162float(v); }
__device__ __forceinline__ bf16 f2b(float v) { return __float2bfloat16(v); }
static inline int ceilDiv(int a, int b) { return (a + b - 1) / b; }

// ---------------- diagnostics (host-assert sentinel only) ----------------
__global__ __launch_bounds__(256) void k_sentinel(float* __restrict__ out, int n, float val) {
  int i = blockIdx.x * 256 + threadIdx.x;
  if (i < n) out[i] = val;
}

// ---------------- fused weight prep: all transposed bf16 weights in one pass ----------------
__global__ __launch_bounds__(256) void k_wprep(const float* __restrict__ g0, const float* __restrict__ e0,
                                               const float* __restrict__ g1, const float* __restrict__ e1,
                                               const float* __restrict__ cw, const float* __restrict__ rw,
                                               const float* __restrict__ t0, const float* __restrict__ t1,
                                               bf16* __restrict__ out) {
  int i = blockIdx.x * 256 + threadIdx.x;
  if (i >= 108544) return;
  float v;
  if (i < 49152) {
    int which = i / 12288, r = i % 12288;
    const float* W = which == 0 ? g0 : which == 1 ? e0 : which == 2 ? g1 : e1;
    int l = r / 6144, j = r % 6144;
    int n = j / 96, k = j % 96;
    v = W[l * 6144 + k * 64 + n];
  } else if (i < 55296) {
    int j = i - 49152, n = j / 96, k = j % 96;
    v = cw[k * 64 + n];
  } else if (i < 59392) {
    int j = i - 55296, n = j / 64, k = j % 64;
    v = rw[k * 64 + n];
  } else {
    int r = i - 59392;
    int which = r / 24576;
    const float* W = which ? t1 : t0;
    int rr = r % 24576;
    int l = rr / 12288, j = rr % 12288;
    int ii = j & 63, o = (j >> 6) & 63, k = j >> 12;
    v = W[l * 12288 + o * 192 + ii * 3 + k];
  }
  out[i] = f2b(v);
}

// ---------------- encoders ----------------
template <int DIN, int DOUT, bool SAVE>
__global__ __launch_bounds__(256) void k_enc(const float* __restrict__ in, const float* __restrict__ W,
                                             const float* __restrict__ bias, bf16* __restrict__ out,
                                             float* __restrict__ last, int nodes) {
  int idx = blockIdx.x * 256 + threadIdx.x;
  if (idx >= G_ * nodes * DOUT) return;
  int d = idx % DOUT;
  int row = idx / DOUT;
  int node = row % nodes;
  int g = row / nodes;
  const float* ir = in + (size_t)row * DIN;
  float acc = bias[d];
#pragma unroll
  for (int i = 0; i < DIN; i++) acc += ir[i] * W[i * DOUT + d];
  if (SAVE) {
    if (g % T_ == T_ - 1) last[((size_t)(g / T_) * nodes + node) * DOUT + d] = acc;  // pre-relu
  }
  out[idx] = f2b(fmaxf(acc, 0.f));
}

// ---------------- fused NodeEdge linear + transpose: tlinT[col=g*32+f][node] bf16 ----------
// block = (64-node strip, one g). Zero-pads node in [nodes, Kp).
__global__ __launch_bounds__(256) void k_lin_neT(const bf16* __restrict__ act, const float* __restrict__ W,
                                                 const float* __restrict__ bias, bf16* __restrict__ outT,
                                                 int nodes, int Kp) {
  __shared__ float As[64][65];
  __shared__ float Ws[2048];
  __shared__ float bs[32];
  int g = blockIdx.y;
  int n0 = blockIdx.x * 64;
  int t = threadIdx.x;
  for (int i = t; i < 2048; i += 256) Ws[i] = W[i];
  if (t < 32) bs[t] = bias[t];
  {
    int r = t >> 2, ch = t & 3;  // row 0..63, 16-elem chunk 0..3
    int node = n0 + r;
    short tmp[16];
    if (node < nodes) {
      const bf16* src = act + ((size_t)g * nodes + node) * 64 + ch * 16;
      *reinterpret_cast<uint4*>(tmp) = *reinterpret_cast<const uint4*>(src);
      *reinterpret_cast<uint4*>(tmp + 8) = *reinterpret_cast<const uint4*>(src + 8);
#pragma unroll
      for (int j = 0; j < 16; j++) As[r][ch * 16 + j] = b2f(*reinterpret_cast<bf16*>(&tmp[j]));
    } else {
#pragma unroll
      for (int j = 0; j < 16; j++) As[r][ch * 16 + j] = 0.f;
    }
  }
  __syncthreads();
  int nd = t & 63, fq = t >> 6;
  float acc[8];
#pragma unroll
  for (int j = 0; j < 8; j++) acc[j] = bs[fq * 8 + j];
  for (int i = 0; i < 64; i++) {
    float a = As[nd][i];
#pragma unroll
    for (int j = 0; j < 8; j++) acc[j] += a * Ws[i * 32 + fq * 8 + j];
  }
  bool valid = (n0 + nd) < nodes;
#pragma unroll
  for (int j = 0; j < 8; j++) {
    float v = valid ? fmaxf(acc[j], 0.f) : 0.f;
    outT[(size_t)(g * 32 + fq * 8 + j) * Kp + n0 + nd] = f2b(v);
  }
}

// ---------------- masked incidence (padded): mat[n][k<E?val:0], [N_][Kp] ----------------
__global__ __launch_bounds__(256) void k_mat(const float* __restrict__ w, const float* __restrict__ p,
                                             const float* __restrict__ inci, bf16* __restrict__ mat,
                                             int rows, int K, int Kp) {
  int i = blockIdx.x * 256 + threadIdx.x;
  if (i >= rows * Kp) return;
  int row = i / Kp, k = i % Kp;
  float v = 0.f;
  if (k < K) {
    size_t o = (size_t)row * K + k;
    v = w[o] * fabsf(inci[o]) + p[o];
  }
  mat[i] = f2b(v);
}

// transposed variant: mat[e*KPE + n] = |inci[n][e]|*w[e*N+n] + p[e*N+n], zero-pad n>=N_
__global__ void k_matT(const float* __restrict__ w, const float* __restrict__ p,
                       const float* __restrict__ inci, bf16* __restrict__ mat) {
  __shared__ float tl[32][33];
  int e0 = blockIdx.x * 32, n0 = blockIdx.y * 32;
  for (int r = threadIdx.y; r < 32; r += 8) {
    int n = n0 + r, e = e0 + threadIdx.x;
    tl[r][threadIdx.x] = (n < N_ && e < E_) ? fabsf(inci[(size_t)n * E_ + e]) : 0.f;
  }
  __syncthreads();
  for (int r = threadIdx.y; r < 32; r += 8) {
    int e = e0 + r, n = n0 + threadIdx.x;
    if (e < E_ && n < KPE) {
      size_t o = (size_t)e * N_ + n;
      mat[(size_t)e * KPE + n] = (n < N_) ? f2b(tl[threadIdx.x][r] * w[o] + p[o]) : f2b(0.f);
    }
  }
}

// ---------------- 64x64-tile MFMA GEMM, depth-4 pipeline + bijective XCD swizzle ----------
__global__ __launch_bounds__(256) void k_mgemm64(const bf16* __restrict__ A0, const bf16* __restrict__ Bt,
                                                 bf16* __restrict__ Cp, int Mm, int Kp, int Nn, int gy) {
  __shared__ __align__(16) short As[4][4][64][8];
  __shared__ __align__(16) short Bs[4][4][64][8];
  int tid = threadIdx.x;
  int nwg = gridDim.x;
  int bid = blockIdx.x;
  int l = (bid & 7) * (nwg >> 3) + (bid >> 3);
  int bm = (l % gy) * 64, bn = (l / gy) * 64;
  int lane = tid & 63, wid = tid >> 6;
  int wr = wid >> 1, wc = wid & 1;
  f32x4 acc[2][2];
#pragma unroll
  for (int i = 0; i < 2; i++)
#pragma unroll
    for (int j = 0; j < 2; j++) acc[i][j] = f32x4{0.f, 0.f, 0.f, 0.f};

  const int sr = tid >> 2;
  const int sc = tid & 3;
  const int kb = lane >> 4, lr = lane & 15;
  const int gmA = bm + sr, gnB = bn + sr;
  const bool va_ok = (gmA < Mm), vb_ok = (gnB < Nn);
  const bf16* ap = A0 + (size_t)gmA * Kp + sc * 8;
  const bf16* bp = Bt + (size_t)gnB * Kp + sc * 8;
  const uint4 z4 = {0, 0, 0, 0};
  const int P = Kp >> 5;

  uint4 va0 = va_ok ? *reinterpret_cast<const uint4*>(ap) : z4;
  uint4 vb0 = vb_ok ? *reinterpret_cast<const uint4*>(bp) : z4;
  uint4 va1 = va_ok ? *reinterpret_cast<const uint4*>(ap + 32) : z4;
  uint4 vb1 = vb_ok ? *reinterpret_cast<const uint4*>(bp + 32) : z4;
  *reinterpret_cast<uint4*>(&As[0][sc][sr][0]) = va0;
  *reinterpret_cast<uint4*>(&Bs[0][sc][sr][0]) = vb0;
  uint4 va2 = va_ok ? *reinterpret_cast<const uint4*>(ap + 64) : z4;
  uint4 vb2 = vb_ok ? *reinterpret_cast<const uint4*>(bp + 64) : z4;
  __syncthreads();

  for (int p = 0; p < P; p += 2) {
    *reinterpret_cast<uint4*>(&As[(p + 1) & 3][sc][sr][0]) = va1;
    *reinterpret_cast<uint4*>(&Bs[(p + 1) & 3][sc][sr][0]) = vb1;
    if (p + 3 < P) {
      va1 = va_ok ? *reinterpret_cast<const uint4*>(ap + (p + 3) * 32) : z4;
      vb1 = vb_ok ? *reinterpret_cast<const uint4*>(bp + (p + 3) * 32) : z4;
    }
    {
      int bf = p & 3;
      short8v a0 = *reinterpret_cast<const short8v*>(&As[bf][kb][wr * 32 + lr][0]);
      short8v a1 = *reinterpret_cast<const short8v*>(&As[bf][kb][wr * 32 + 16 + lr][0]);
      short8v b0 = *reinterpret_cast<const short8v*>(&Bs[bf][kb][wc * 32 + lr][0]);
      short8v b1 = *reinterpret_cast<const short8v*>(&Bs[bf][kb][wc * 32 + 16 + lr][0]);
      __builtin_amdgcn_s_setprio(1);
      acc[0][0] = __builtin_amdgcn_mfma_f32_16x16x32_bf16(a0, b0, acc[0][0], 0, 0, 0);
      acc[0][1] = __builtin_amdgcn_mfma_f32_16x16x32_bf16(a0, b1, acc[0][1], 0, 0, 0);
      acc[1][0] = __builtin_amdgcn_mfma_f32_16x16x32_bf16(a1, b0, acc[1][0], 0, 0, 0);
      acc[1][1] = __builtin_amdgcn_mfma_f32_16x16x32_bf16(a1, b1, acc[1][1], 0, 0, 0);
      __builtin_amdgcn_s_setprio(0);
    }
    __syncthreads();
    *reinterpret_cast<uint4*>(&As[(p + 2) & 3][sc][sr][0]) = va2;
    *reinterpret_cast<uint4*>(&Bs[(p + 2) & 3][sc][sr][0]) = vb2;
    if (p + 4 < P) {
      va2 = va_ok ? *reinterpret_cast<const uint4*>(ap + (p + 4) * 32) : z4;
      vb2 = vb_ok ? *reinterpret_cast<const uint4*>(bp + (p + 4) * 32) : z4;
    }
    {
      int bf = (p + 1) & 3;
      short8v a0 = *reinterpret_cast<const short8v*>(&As[bf][kb][wr * 32 + lr][0]);
      short8v a1 = *reinterpret_cast<const short8v*>(&As[bf][kb][wr * 32 + 16 + lr][0]);
      short8v b0 = *reinterpret_cast<const short8v*>(&Bs[bf][kb][wc * 32 + lr][0]);
      short8v b1 = *reinterpret_cast<const short8v*>(&Bs[bf][kb][wc * 32 + 16 + lr][0]);
      __builtin_amdgcn_s_setprio(1);
      acc[0][0] = __builtin_amdgcn_mfma_f32_16x16x32_bf16(a0, b0, acc[0][0], 0, 0, 0);
      acc[0][1] = __builtin_amdgcn_mfma_f32_16x16x32_bf16(a0, b1, acc[0][1], 0, 0, 0);
      acc[1][0] = __builtin_amdgcn_mfma_f32_16x16x32_bf16(a1, b0, acc[1][0], 0, 0, 0);
      acc[1][1] = __builtin_amdgcn_mfma_f32_16x16x32_bf16(a1, b1, acc[1][1], 0, 0, 0);
      __builtin_amdgcn_s_setprio(0);
    }
    __syncthreads();
  }
#pragma unroll
  for (int mi = 0; mi < 2; mi++) {
    int r0 = bm + wr * 32 + mi * 16 + (lane >> 4) * 4;
#pragma unroll
    for (int ni = 0; ni < 2; ni++) {
      int col = bn + wc * 32 + ni * 16 + lr;
      if (col >= Nn) continue;
#pragma unroll
      for (int i = 0; i < 4; i++) {
        int r = r0 + i;
        if (r < Mm) Cp[(size_t)r * Nn + col] = f2b(acc[mi][ni][i]);
      }
    }
  }
}

// ---------------- MFMA GEMM (128-row tile): z / conc / res GEMMs ----------------
// ESED=true (AMODE 1 z-GEMM): epilogue also emits es[r]=z.as, edv[r]=z.ad.
template <int AMODE, int BNt, bool CF32b, bool ESED>
__global__ __launch_bounds__(256) void k_mgemm(const bf16* __restrict__ A0, const bf16* __restrict__ A1,
                                               const bf16* __restrict__ Bt, void* __restrict__ Cp,
                                               int Mm, int Kp, int Nn, int nodes,
                                               const float* __restrict__ bias, int relu,
                                               const float* __restrict__ asv, const float* __restrict__ adv,
                                               float* __restrict__ esOut, float* __restrict__ edOut) {
  constexpr int BM = 128;
  constexpr int WTN = BNt / 32;
  __shared__ __align__(16) short As[4][BM][8];
  __shared__ __align__(16) short Bs[4][BNt][8];
  __shared__ float smr[2][BM][2];
  int tid = threadIdx.x;
  int bm = blockIdx.y * BM;
  int bn = blockIdx.x * BNt;
  int lane = tid & 63;
  int wid = tid >> 6;
  int wr = wid >> 1, wc = wid & 1;
  f32x4 acc[4][WTN];
#pragma unroll
  for (int i = 0; i < 4; i++)
#pragma unroll
    for (int j = 0; j < WTN; j++) acc[i][j] = f32x4{0.f, 0.f, 0.f, 0.f};

  const int ar = tid >> 1;
  const int ah = tid & 1;
  const int kb = lane >> 4;
  const int lr = lane & 15;

  for (int k0 = 0; k0 < Kp; k0 += 32) {
    uint4 va0 = {0, 0, 0, 0}, va1 = {0, 0, 0, 0};
    int gm = bm + ar;
    if (gm < Mm) {
      int ks = k0 + ah * 16;
      const bf16* src;
      if (AMODE == 0) src = A0 + (size_t)gm * Kp + ks;
      else if (ks < 64) src = A0 + (size_t)gm * 64 + ks;
      else if (AMODE == 1) {
        int g = gm / nodes, nd = gm % nodes;
        src = A1 + ((size_t)nd * G_ + g) * 32 + (ks - 64);
      } else {
        src = A1 + (size_t)gm * 32 + (ks - 64);
      }
      const uint4* p = reinterpret_cast<const uint4*>(src);
      va0 = p[0];
      va1 = p[1];
    }
    *reinterpret_cast<uint4*>(&As[ah * 2 + 0][ar][0]) = va0;
    *reinterpret_cast<uint4*>(&As[ah * 2 + 1][ar][0]) = va1;
    if (BNt == 128) {
      int br = tid >> 1, bh = tid & 1;
      uint4 vb0 = {0, 0, 0, 0}, vb1 = {0, 0, 0, 0};
      int gn = bn + br;
      if (gn < Nn) {
        const uint4* p = reinterpret_cast<const uint4*>(Bt + (size_t)gn * Kp + k0 + bh * 16);
        vb0 = p[0];
        vb1 = p[1];
      }
      *reinterpret_cast<uint4*>(&Bs[bh * 2 + 0][br][0]) = vb0;
      *reinterpret_cast<uint4*>(&Bs[bh * 2 + 1][br][0]) = vb1;
    } else {
      int br = tid >> 2, bk = tid & 3;
      uint4 vb0 = {0, 0, 0, 0};
      int gn = bn + br;
      if (gn < Nn) vb0 = *reinterpret_cast<const uint4*>(Bt + (size_t)gn * Kp + k0 + bk * 8);
      *reinterpret_cast<uint4*>(&Bs[bk][br][0]) = vb0;
    }
    __syncthreads();
    short8v a[4], b[WTN];
#pragma unroll
    for (int mi = 0; mi < 4; mi++)
      a[mi] = *reinterpret_cast<const short8v*>(&As[kb][wr * 64 + mi * 16 + lr][0]);
#pragma unroll
    for (int ni = 0; ni < WTN; ni++)
      b[ni] = *reinterpret_cast<const short8v*>(&Bs[kb][wc * (BNt / 2) + ni * 16 + lr][0]);
#pragma unroll
    for (int mi = 0; mi < 4; mi++)
#pragma unroll
      for (int ni = 0; ni < WTN; ni++)
        acc[mi][ni] = __builtin_amdgcn_mfma_f32_16x16x32_bf16(a[mi], b[ni], acc[mi][ni], 0, 0, 0);
    __syncthreads();
  }
#pragma unroll
  for (int mi = 0; mi < 4; mi++) {
    int r0 = bm + wr * 64 + mi * 16 + (lane >> 4) * 4;
#pragma unroll
    for (int ni = 0; ni < WTN; ni++) {
      int col = bn + wc * (BNt / 2) + ni * 16 + lr;
      float bv = bias ? bias[col] : 0.f;
#pragma unroll
      for (int i = 0; i < 4; i++) {
        int r = r0 + i;
        if (r < Mm) {
          float v = acc[mi][ni][i] + bv;
          if (relu) v = fmaxf(v, 0.f);
          if (CF32b) ((float*)Cp)[(size_t)r * Nn + col] = v;
          else ((bf16*)Cp)[(size_t)r * Nn + col] = f2b(v);
        }
      }
    }
  }
  if (ESED) {
    float asc0 = asv[wc * 32 + lr];
    float asc1 = asv[wc * 32 + 16 + lr];
    float adc0 = adv[wc * 32 + lr];
    float adc1 = adv[wc * 32 + 16 + lr];
#pragma unroll
    for (int mi = 0; mi < 4; mi++) {
#pragma unroll
      for (int i = 0; i < 4; i++) {
        float pe = acc[mi][0][i] * asc0 + acc[mi][1][i] * asc1;
        float pd = acc[mi][0][i] * adc0 + acc[mi][1][i] * adc1;
#pragma unroll
        for (int o = 8; o; o >>= 1) { pe += __shfl_xor(pe, o); pd += __shfl_xor(pd, o); }
        if (lr == 0) {
          int rl = wr * 64 + mi * 16 + (lane >> 4) * 4 + i;
          smr[wc][rl][0] = pe;
          smr[wc][rl][1] = pd;
        }
      }
    }
    __syncthreads();
    if (tid < BM) {
      int r = bm + tid;
      if (r < Mm) {
        esOut[r] = smr[0][tid][0] + smr[1][tid][0];
        edOut[r] = smr[0][tid][1] + smr[1][tid][1];
      }
    }
  }
}

// ---------------- causal dilated conv: depth-4 pipelined MFMA, B weights in registers ------
template <int DIL>
__global__ __launch_bounds__(256) void k_cgemm(const bf16* __restrict__ A, const bf16* __restrict__ Wc,
                                               const float* __restrict__ bias, bf16* __restrict__ C,
                                               int Mm, int nodes) {
  __shared__ __align__(16) short As[4][4][128][8];
  int tid = threadIdx.x;
  int bm = blockIdx.x * 128;
  int lane = tid & 63, wid = tid >> 6;
  int wr = wid >> 1, wc = wid & 1;
  const int ar = tid >> 1, ah = tid & 1;
  const int kb = lane >> 4, lr = lane & 15;
  const int gm = bm + ar;
  const int t = (gm / nodes) % T_;
  const uint4 z4 = {0, 0, 0, 0};

  short8v bfr[3][2][2];
#pragma unroll
  for (int tap = 0; tap < 3; tap++)
#pragma unroll
    for (int kc = 0; kc < 2; kc++)
#pragma unroll
      for (int ni = 0; ni < 2; ni++) {
        int col = wc * 32 + ni * 16 + lr;
        bfr[tap][kc][ni] = *reinterpret_cast<const short8v*>(Wc + tap * 4096 + (size_t)col * 64 + kc * 32 + kb * 8);
      }

  f32x4 acc[4][2];
#pragma unroll
  for (int i = 0; i < 4; i++)
#pragma unroll
    for (int j = 0; j < 2; j++) acc[i][j] = f32x4{0.f, 0.f, 0.f, 0.f};

#define CG_LDA(p, vx, vy)                                                          \
  {                                                                                \
    const int sh_ = (((p) >> 1) - 2) * DIL;                                        \
    if ((gm < Mm) && (t + sh_ >= 0)) {                                             \
      const uint4* pp = reinterpret_cast<const uint4*>(                            \
          A + ((size_t)gm + (size_t)sh_ * nodes) * 64 + ((p) & 1) * 32 + ah * 16); \
      vx = pp[0];                                                                  \
      vy = pp[1];                                                                  \
    } else {                                                                       \
      vx = z4;                                                                     \
      vy = z4;                                                                     \
    }                                                                              \
  }
#define CG_WR(buf, vx, vy)                                     \
  *reinterpret_cast<uint4*>(&As[buf][ah * 2 + 0][ar][0]) = vx; \
  *reinterpret_cast<uint4*>(&As[buf][ah * 2 + 1][ar][0]) = vy;
#define CG_MFMA(q)                                                                                         \
  {                                                                                                        \
    short8v a0_ = *reinterpret_cast<const short8v*>(&As[(q) & 3][kb][wr * 64 + 0 + lr][0]);                \
    short8v a1_ = *reinterpret_cast<const short8v*>(&As[(q) & 3][kb][wr * 64 + 16 + lr][0]);               \
    short8v a2_ = *reinterpret_cast<const short8v*>(&As[(q) & 3][kb][wr * 64 + 32 + lr][0]);               \
    short8v a3_ = *reinterpret_cast<const short8v*>(&As[(q) & 3][kb][wr * 64 + 48 + lr][0]);               \
    __builtin_amdgcn_s_setprio(1);                                                                         \
    acc[0][0] = __builtin_amdgcn_mfma_f32_16x16x32_bf16(a0_, bfr[(q) >> 1][(q) & 1][0], acc[0][0], 0, 0, 0); \
    acc[0][1] = __builtin_amdgcn_mfma_f32_16x16x32_bf16(a0_, bfr[(q) >> 1][(q) & 1][1], acc[0][1], 0, 0, 0); \
    acc[1][0] = __builtin_amdgcn_mfma_f32_16x16x32_bf16(a1_, bfr[(q) >> 1][(q) & 1][0], acc[1][0], 0, 0, 0); \
    acc[1][1] = __builtin_amdgcn_mfma_f32_16x16x32_bf16(a1_, bfr[(q) >> 1][(q) & 1][1], acc[1][1], 0, 0, 0); \
    acc[2][0] = __builtin_amdgcn_mfma_f32_16x16x32_bf16(a2_, bfr[(q) >> 1][(q) & 1][0], acc[2][0], 0, 0, 0); \
    acc[2][1] = __builtin_amdgcn_mfma_f32_16x16x32_bf16(a2_, bfr[(q) >> 1][(q) & 1][1], acc[2][1], 0, 0, 0); \
    acc[3][0] = __builtin_amdgcn_mfma_f32_16x16x32_bf16(a3_, bfr[(q) >> 1][(q) & 1][0], acc[3][0], 0, 0, 0); \
    acc[3][1] = __builtin_amdgcn_mfma_f32_16x16x32_bf16(a3_, bfr[(q) >> 1][(q) & 1][1], acc[3][1], 0, 0, 0); \
    __builtin_amdgcn_s_setprio(0);                                                                         \
  }
#define CG_BODY(p, lastPair)                  \
  CG_WR(((p) + 1) & 3, r1x, r1y);             \
  if (!(lastPair)) CG_LDA((p) + 3, r1x, r1y); \
  CG_MFMA(p);                                 \
  __syncthreads();                            \
  CG_WR(((p) + 2) & 3, r2x, r2y);             \
  if (!(lastPair)) CG_LDA((p) + 4, r2x, r2y); \
  CG_MFMA((p) + 1);                           \
  __syncthreads();

  uint4 p0x, p0y, r1x, r1y, r2x, r2y;
  CG_LDA(0, p0x, p0y);
  CG_LDA(1, r1x, r1y);
  CG_WR(0, p0x, p0y);
  CG_LDA(2, r2x, r2y);
  __syncthreads();

  CG_BODY(0, false)
  CG_BODY(2, false)
  CG_BODY(4, true)

#undef CG_LDA
#undef CG_WR
#undef CG_MFMA
#undef CG_BODY

#pragma unroll
  for (int mi = 0; mi < 4; mi++) {
    int r0 = bm + wr * 64 + mi * 16 + (lane >> 4) * 4;
#pragma unroll
    for (int ni = 0; ni < 2; ni++) {
      int col = wc * 32 + ni * 16 + lr;
      float bv = bias[col];
#pragma unroll
      for (int i = 0; i < 4; i++) {
        int r = r0 + i;
        if (r < Mm) C[(size_t)r * 64 + col] = f2b(fmaxf(acc[mi][ni][i] + bv, 0.f));
      }
    }
  }
}

// ---------------- GAT softmax weights: thread per (g,node), normalized exp weights ----------
__global__ __launch_bounds__(256) void k_gat_w(const float* __restrict__ es, const float* __restrict__ edv,
                                               const int* __restrict__ off, const int* __restrict__ adj,
                                               float* __restrict__ wgt, int nodes, int tot) {
  int idx = blockIdx.x * 256 + threadIdx.x;
  if (idx >= G_ * nodes) return;
  int g = idx / nodes, node = idx % nodes;
  int s0 = off[node], s1 = off[node + 1];
  const float* esg = es + (size_t)g * nodes;
  float edval = edv[(size_t)g * nodes + node];
  float m = -FLT_MAX;
  for (int s = s0; s < s1; s++) {
    float a = esg[adj[s]] + edval;
    a = (a >= 0.f) ? a : 0.2f * a;
    m = fmaxf(m, a);
  }
  float den = 0.f;
  float* wg = wgt + (size_t)g * tot;
  for (int s = s0; s < s1; s++) {
    float a = esg[adj[s]] + edval;
    a = (a >= 0.f) ? a : 0.2f * a;
    float ex = expf(a - m);
    den += ex;
    wg[s] = ex;
  }
  float inv = (s1 > s0) ? 1.f / den : 0.f;
  for (int s = s0; s < s1; s++) wg[s] *= inv;
}

// ---------------- GAT aggregation: thread per (g,node,4-feature chunk) ----------------
__global__ __launch_bounds__(256) void k_gat_aggr3(const bf16* __restrict__ z, const float* __restrict__ wgt,
                                                   const int* __restrict__ off, const int* __restrict__ adj,
                                                   const float* __restrict__ bias, bf16* __restrict__ out,
                                                   int nodes, int tot) {
  int idx = blockIdx.x * 256 + threadIdx.x;
  if (idx >= G_ * nodes * 16) return;
  int c = idx & 15;
  int rest = idx >> 4;
  int node = rest % nodes;
  int g = rest / nodes;
  int s0 = off[node], s1 = off[node + 1];
  const bf16* zg = z + (size_t)g * nodes * 64 + c * 4;
  const float* wg = wgt + (size_t)g * tot;
  float n0 = 0.f, n1 = 0.f, n2 = 0.f, n3 = 0.f;
  for (int s = s0; s < s1; s++) {
    int src = adj[s];
    float w = wg[s];
    bf16 v[4];
    *reinterpret_cast<uint2*>(v) = *reinterpret_cast<const uint2*>(zg + (size_t)src * 64);
    n0 += w * b2f(v[0]);
    n1 += w * b2f(v[1]);
    n2 += w * b2f(v[2]);
    n3 += w * b2f(v[3]);
  }
  bf16 ov[4];
  ov[0] = f2b(fmaxf(n0 + bias[c * 4 + 0], 0.f));
  ov[1] = f2b(fmaxf(n1 + bias[c * 4 + 1], 0.f));
  ov[2] = f2b(fmaxf(n2 + bias[c * 4 + 2], 0.f));
  ov[3] = f2b(fmaxf(n3 + bias[c * 4 + 3], 0.f));
  *reinterpret_cast<uint2*>(out + (size_t)rest * 64 + c * 4) = *reinterpret_cast<uint2*>(ov);
}

// ---------------- fused CSR build: 2 blocks, one per graph ----------------
// Each block: LDS count -> Hillis-Steele scan (nn<=2048) -> fill (cnt doubles as cursor=off).
__global__ __launch_bounds__(1024) void k_csr(const int* __restrict__ indN, const int* __restrict__ indE,
                                              int* __restrict__ offN, int* __restrict__ adjN,
                                              int* __restrict__ offE, int* __restrict__ adjE) {
  __shared__ int cnt[2048];
  __shared__ int a[1024];
  const int* ind;
  int ner, nn;
  int *off, *adj;
  if (blockIdx.x == 0) { ind = indN; ner = E_; nn = N_; off = offN; adj = adjN; }
  else { ind = indE; ner = M_; nn = E_; off = offE; adj = adjE; }
  int tot = ner + nn;
  int t = threadIdx.x;
  for (int i = t; i < nn; i += 1024) cnt[i] = 0;
  __syncthreads();
  for (int i = t; i < tot; i += 1024) {
    int d = (i < ner) ? ind[ner + i] : (i - ner);
    if (d >= 0 && d < nn) atomicAdd(&cnt[d], 1);
  }
  __syncthreads();
  int c0 = (2 * t < nn) ? cnt[2 * t] : 0;
  int c1 = (2 * t + 1 < nn) ? cnt[2 * t + 1] : 0;
  a[t] = c0 + c1;
  __syncthreads();
  for (int d = 1; d < 1024; d <<= 1) {
    int u = (t >= d) ? a[t - d] : 0;
    __syncthreads();
    a[t] += u;
    __syncthreads();
  }
  int excl = (t > 0) ? a[t - 1] : 0;
  if (2 * t < nn) { cnt[2 * t] = excl; off[2 * t] = excl; }
  if (2 * t + 1 < nn) { cnt[2 * t + 1] = excl + c0; off[2 * t + 1] = excl + c0; }
  if (t == 0) off[nn] = a[1023];
  __syncthreads();
  for (int i = t; i < tot; i += 1024) {
    int s, d;
    if (i < ner) { s = ind[i]; d = ind[ner + i]; }
    else { s = d = i - ner; }
    if (d >= 0 && d < nn) {
      int pos = atomicAdd(&cnt[d], 1);
      adj[pos] = s;
    }
  }
}

// ---------------- per-batch: cumsum + residual + relu + head (wave per node) ----------------
template <bool XB>
__global__ __launch_bounds__(256) void k_out(const float* __restrict__ yx, const float* __restrict__ last,
                                             const float* __restrict__ oW, const float* __restrict__ ob_,
                                             float* __restrict__ dout, int nodes) {
  int wid = threadIdx.x >> 6, lane = threadIdx.x & 63;
  int node = blockIdx.x * 4 + wid;
  if (node >= nodes) return;
  float lw = oW[lane];
  float ob = ob_[0];
  float lv = last[(size_t)node * 64 + lane];
  float acc = 0.f;
  for (int tt = 0; tt < T_; tt++) {
    acc += yx[((size_t)tt * nodes + node) * 64 + lane];
    float v = fmaxf(acc + lv, 0.f);
    float p = v * lw;
#pragma unroll
    for (int o2 = 32; o2; o2 >>= 1) p += __shfl_down(p, o2);
    if (lane == 0) {
      float o = p + ob;
      if (XB) o = fminf(fmaxf(o / 6.f + 0.5f, 0.f), 1.f);
      else o = tanhf(o);
      dout[(size_t)tt * nodes + node] = o;
    }
  }
}

// ===================================================================================
extern "C" void kernel_launch(void* const* d_in, const int* in_sizes, int n_in,
                              void* d_out, int out_size, void* d_ws, size_t ws_size,
                              hipStream_t stream) {
  float* dout = (float*)d_out;

  if (n_in != 57) {
    k_sentinel<<<ceilDiv(out_size, 256), 256, 0, stream>>>(dout, out_size, 20000.f + 128.f * n_in);
    return;
  }
  static const int expSz[57] = {
      288000, 288000, 288000, 288000,
      256, 64, 192, 64, 128, 32, 96, 32,
      3000000,
      12288, 128, 128, 128, 12288, 128, 128, 128,
      4096, 64, 6000000, 6000000, 4096, 64, 6000000, 6000000,
      24576, 128,
      12288, 128, 128, 128, 12288, 128, 128, 128,
      4096, 64, 6000000, 6000000, 4096, 64, 6000000, 6000000,
      24576, 128,
      6144, 64, 4096, 64, 64, 1, 4000, 8000};
  for (int i = 0; i < 57; i++) {
    if (in_sizes[i] != expSz[i]) {
      k_sentinel<<<ceilDiv(out_size, 256), 256, 0, stream>>>(dout, out_size, 4096.f + 64.f * i);
      return;
    }
  }

  auto ff = [&](int i) { return (const float*)d_in[i]; };
  const float *x_in = ff(0), *e_in = ff(1), *b_in = ff(2), *a_in = ff(3);
  const float *enc0W = ff(4), *enc0b = ff(5), *enc1W = ff(6), *enc1b = ff(7);
  const float *enc2W = ff(8), *enc2b = ff(9), *enc3W = ff(10), *enc3b = ff(11);
  const float* inci = ff(12);
  const float *concW = ff(49), *concb = ff(50), *resW = ff(51), *resb = ff(52);
  const float *outW = ff(53), *outb = ff(54);
  const int* edge_ind = (const int*)d_in[55];
  const int* node_ind = (const int*)d_in[56];

  // ---- workspace layout, 256B-aligned ----
  char* base = (char*)d_ws;
  size_t off = 0;
  auto A = [&](size_t bytes) { void* p = base + off; off = (off + bytes + 255) & ~(size_t)255; return p; };
  char* SCR = (char*)A(21504000);
  bf16* xbuf = (bf16*)A(9216000);
  bf16* ebuf = (bf16*)A(12288000);
  float* lastx = (float*)A(768000);
  float* laste = (float*)A(1024000);
  float* es = (float*)A(384000);
  float* edv = (float*)A(384000);
  float* wgt = (float*)A((size_t)G_ * (M_ + E_) * 4);
  bf16* wAll = (bf16*)A(217088);
  int* offN = (int*)A((N_ + 1) * 4);
  int* offE = (int*)A((E_ + 1) * 4);
  int* adjN = (int*)A((E_ + N_) * 4);
  int* adjE = (int*)A((M_ + E_) * 4);
  size_t required = off;

  if (ws_size < required) {
    k_sentinel<<<ceilDiv(out_size, 256), 256, 0, stream>>>(dout, out_size, 1000.f + (float)(ws_size >> 20));
    return;
  }

  // SCR aliases (liveness-checked)
  bf16* matb = (bf16*)SCR;
  bf16* tlinT = (bf16*)(SCR + 6553600);
  bf16* tmat = (bf16*)(SCR + 13107200);
  bf16* zbuf = (bf16*)SCR;
  bf16* bscr = (bf16*)SCR;
  bf16* cx1 = (bf16*)SCR;
  bf16* ce1 = (bf16*)(SCR + 9216000);
  float* zres = (float*)SCR;

  const int totN = E_ + N_;   // 3500
  const int totE = M_ + E_;   // 6000

  // ---- fused weight prep + fused CSR build ----
  k_wprep<<<ceilDiv(108544, 256), 256, 0, stream>>>(ff(13), ff(17), ff(31), ff(35), concW, resW,
                                                    ff(29), ff(47), wAll);
  k_csr<<<2, 1024, 0, stream>>>(edge_ind, node_ind, offN, adjN, offE, adjE);

  // ---- encoders ----
  k_enc<4, 64, true><<<ceilDiv(G_ * N_ * 64, 256), 256, 0, stream>>>(x_in, enc0W, enc0b, xbuf, lastx, N_);
  k_enc<3, 64, true><<<ceilDiv(G_ * E_ * 64, 256), 256, 0, stream>>>(e_in, enc1W, enc1b, ebuf, laste, E_);

  auto stblock = [&](int sb, int sbi) {
    const float *gxas = ff(sb + 1), *gxad = ff(sb + 2), *gxb = ff(sb + 3);
    const float *geas = ff(sb + 5), *gead = ff(sb + 6), *geb = ff(sb + 7);
    const float *neW = ff(sb + 8), *neb = ff(sb + 9), *nw = ff(sb + 10), *np_ = ff(sb + 11);
    const float *enW = ff(sb + 12), *enb = ff(sb + 13), *ew = ff(sb + 14), *ep = ff(sb + 15);
    const float* tpb = ff(sb + 17);
    for (int l = 0; l < 2; l++) {
      const bf16* gxw_t = wAll + sbi * 24576 + l * 6144;
      const bf16* gew_t = wAll + sbi * 24576 + 12288 + l * 6144;
      // ---- node side: xe = NodeEdge(e); x = relu(GAT([x,xe])) ----
      k_lin_neT<<<dim3(KPN / 64, G_), 256, 0, stream>>>(ebuf, neW + l * 2048, neb + l * 32, tlinT, E_, KPN);
      k_mat<<<ceilDiv(N_ * KPN, 256), 256, 0, stream>>>(nw + (size_t)l * N_ * E_, np_ + (size_t)l * N_ * E_, inci, matb, N_, E_, KPN);
      k_mgemm64<<<dim3(24 * 24), 256, 0, stream>>>(matb, tlinT, tmat, N_, KPN, 1536, 24);
      k_mgemm<1, 64, false, true><<<dim3(1, ceilDiv(G_ * N_, 128)), 256, 0, stream>>>(
          xbuf, tmat, gxw_t, zbuf, G_ * N_, 96, 64, N_, nullptr, 0, gxas + l * 64, gxad + l * 64, es, edv);
      k_gat_w<<<ceilDiv(G_ * N_, 256), 256, 0, stream>>>(es, edv, offN, adjN, wgt, N_, totN);
      k_gat_aggr3<<<ceilDiv(G_ * N_ * 16, 256), 256, 0, stream>>>(zbuf, wgt, offN, adjN, gxb + l * 64, xbuf, N_, totN);
      // ---- edge side: ex = NodeEdge(x); e = relu(GAT([e,ex])) ----
      k_lin_neT<<<dim3(KPE / 64, G_), 256, 0, stream>>>(xbuf, enW + l * 2048, enb + l * 32, tlinT, N_, KPE);
      k_matT<<<dim3(ceilDiv(E_, 32), KPE / 32), dim3(32, 8), 0, stream>>>(ew + (size_t)l * E_ * N_, ep + (size_t)l * E_ * N_, inci, matb);
      k_mgemm64<<<dim3(24 * 32), 256, 0, stream>>>(matb, tlinT, tmat, E_, KPE, 1536, 32);
      k_mgemm<1, 64, false, true><<<dim3(1, ceilDiv(G_ * E_, 128)), 256, 0, stream>>>(
          ebuf, tmat, gew_t, zbuf, G_ * E_, 96, 64, E_, nullptr, 0, geas + l * 64, gead + l * 64, es, edv);
      k_gat_w<<<ceilDiv(G_ * E_, 256), 256, 0, stream>>>(es, edv, offE, adjE, wgt, E_, totE);
      k_gat_aggr3<<<ceilDiv(G_ * E_ * 16, 256), 256, 0, stream>>>(zbuf, wgt, offE, adjE, geb + l * 64, ebuf, E_, totE);
    }
    // ---- temporal convs: shifted-view MFMA GEMMs ----
    const bf16* cw0 = wAll + 59392 + sbi * 24576;
    const bf16* cw1 = cw0 + 12288;
    k_cgemm<1><<<ceilDiv(G_ * N_, 128), 256, 0, stream>>>(xbuf, cw0, tpb, cx1, G_ * N_, N_);
    k_cgemm<1><<<ceilDiv(G_ * E_, 128), 256, 0, stream>>>(ebuf, cw0, tpb, ce1, G_ * E_, E_);
    k_cgemm<2><<<ceilDiv(G_ * N_, 128), 256, 0, stream>>>(cx1, cw1, tpb + 64, xbuf, G_ * N_, N_);
    k_cgemm<2><<<ceilDiv(G_ * E_, 128), 256, 0, stream>>>(ce1, cw1, tpb + 64, ebuf, G_ * E_, E_);
  };

  stblock(13, 0);

  // ---- conc (shared weights; in-place: gridDim.x==1 row ownership) ----
  const bf16* concT = wAll + 49152;
  k_enc<4, 32, false><<<ceilDiv(G_ * N_ * 32, 256), 256, 0, stream>>>(b_in, enc2W, enc2b, bscr, nullptr, N_);
  k_mgemm<2, 64, false, false><<<dim3(1, ceilDiv(G_ * N_, 128)), 256, 0, stream>>>(
      xbuf, bscr, concT, xbuf, G_ * N_, 96, 64, 0, concb, 1, nullptr, nullptr, nullptr, nullptr);
  k_enc<3, 32, false><<<ceilDiv(G_ * E_ * 32, 256), 256, 0, stream>>>(a_in, enc3W, enc3b, bscr, nullptr, E_);
  k_mgemm<2, 64, false, false><<<dim3(1, ceilDiv(G_ * E_, 128)), 256, 0, stream>>>(
      ebuf, bscr, concT, ebuf, G_ * E_, 96, 64, 0, concb, 1, nullptr, nullptr, nullptr, nullptr);

  stblock(31, 1);

  // ---- final per batch ----
  const bf16* resT = wAll + 55296;
  for (int b = 0; b < B_; b++) {
    k_mgemm<0, 64, true, false><<<dim3(1, ceilDiv(T_ * N_, 128)), 256, 0, stream>>>(
        xbuf + (size_t)b * T_ * N_ * 64, nullptr, resT, zres, T_ * N_, 64, 64, 0, resb, 0,
        nullptr, nullptr, nullptr, nullptr);
    k_out<true><<<ceilDiv(N_, 4), 256, 0, stream>>>(
        zres, lastx + (size_t)b * N_ * 64, outW, outb, dout + (size_t)b * T_ * N_, N_);
  }
  for (int b = 0; b < B_; b++) {
    k_mgemm<0, 64, true, false><<<dim3(1, ceilDiv(T_ * E_, 128)), 256, 0, stream>>>(
        ebuf + (size_t)b * T_ * E_ * 64, nullptr, resT, zres, T_ * E_, 64, 64, 0, resb, 0,
        nullptr, nullptr, nullptr, nullptr);
    k_out<false><<<ceilDiv(E_, 4), 256, 0, stream>>>(
        zres, laste + (size_t)b * E_ * 64, outW, outb, dout + (size_t)(B_ * T_ * N_) + (size_t)b * T_ * E_, E_);
  }
}

// Round 16
// 1018.672 us; speedup vs baseline: 4.7749x; 1.0309x over previous
//
#include <hip/hip_runtime.h>
#include <hip/hip_bf16.h>
#include <cfloat>
#include <math.h>

typedef __hip_bfloat16 bf16;
typedef __attribute__((ext_vector_type(8))) short short8v;
typedef __attribute__((ext_vector_type(4))) float f32x4;

constexpr int B_ = 2, T_ = 24, N_ = 1500, E_ = 2000, M_ = 4000, G_ = 48;
constexpr int KPN = 2048;
constexpr int KPE = 1536;

__device__ __forceinline__ float b2f(bf16 v) { return __bfloat162float(v); }
__device__ __forceinline__ bf16 f2b(float v) { return __float2bfloat16(v); }
static inline int ceilDiv(int a, int b) { return (a + b - 1) / b; }

// ---------------- diagnostics ----------------
__global__ __launch_bounds__(256) void k_sentinel(float* __restrict__ out, int n, float val) {
  int i = blockIdx.x * 256 + threadIdx.x;
  if (i < n) out[i] = val;
}

// ---------------- fused weight prep ----------------
__global__ __launch_bounds__(256) void k_wprep(const float* __restrict__ g0, const float* __restrict__ e0,
                                               const float* __restrict__ g1, const float* __restrict__ e1,
                                               const float* __restrict__ cw, const float* __restrict__ rw,
                                               const float* __restrict__ t0, const float* __restrict__ t1,
                                               bf16* __restrict__ out) {
  int i = blockIdx.x * 256 + threadIdx.x;
  if (i >= 108544) return;
  float v;
  if (i < 49152) {
    int which = i / 12288, r = i % 12288;
    const float* W = which == 0 ? g0 : which == 1 ? e0 : which == 2 ? g1 : e1;
    int l = r / 6144, j = r % 6144;
    int n = j / 96, k = j % 96;
    v = W[l * 6144 + k * 64 + n];
  } else if (i < 55296) {
    int j = i - 49152, n = j / 96, k = j % 96;
    v = cw[k * 64 + n];
  } else if (i < 59392) {
    int j = i - 55296, n = j / 64, k = j % 64;
    v = rw[k * 64 + n];
  } else {
    int r = i - 59392;
    int which = r / 24576;
    const float* W = which ? t1 : t0;
    int rr = r % 24576;
    int l = rr / 12288, j = rr % 12288;
    int ii = j & 63, o = (j >> 6) & 63, k = j >> 12;
    v = W[l * 12288 + o * 192 + ii * 3 + k];
  }
  out[i] = f2b(v);
}

// ---------------- encoders ----------------
template <int DIN, int DOUT, bool SAVE>
__global__ __launch_bounds__(256) void k_enc(const float* __restrict__ in, const float* __restrict__ W,
                                             const float* __restrict__ bias, bf16* __restrict__ out,
                                             float* __restrict__ last, int nodes) {
  int idx = blockIdx.x * 256 + threadIdx.x;
  if (idx >= G_ * nodes * DOUT) return;
  int d = idx % DOUT;
  int row = idx / DOUT;
  int node = row % nodes;
  int g = row / nodes;
  const float* ir = in + (size_t)row * DIN;
  float acc = bias[d];
#pragma unroll
  for (int i = 0; i < DIN; i++) acc += ir[i] * W[i * DOUT + d];
  if (SAVE) {
    if (g % T_ == T_ - 1) last[((size_t)(g / T_) * nodes + node) * DOUT + d] = acc;
  }
  out[idx] = f2b(fmaxf(acc, 0.f));
}

// ---------------- fused NodeEdge linear + transpose ----------------
__global__ __launch_bounds__(256) void k_lin_neT(const bf16* __restrict__ act, const float* __restrict__ W,
                                                 const float* __restrict__ bias, bf16* __restrict__ outT,
                                                 int nodes, int Kp) {
  __shared__ float As[64][65];
  __shared__ float Ws[2048];
  __shared__ float bs[32];
  int g = blockIdx.y;
  int n0 = blockIdx.x * 64;
  int t = threadIdx.x;
  for (int i = t; i < 2048; i += 256) Ws[i] = W[i];
  if (t < 32) bs[t] = bias[t];
  {
    int r = t >> 2, ch = t & 3;
    int node = n0 + r;
    short tmp[16];
    if (node < nodes) {
      const bf16* src = act + ((size_t)g * nodes + node) * 64 + ch * 16;
      *reinterpret_cast<uint4*>(tmp) = *reinterpret_cast<const uint4*>(src);
      *reinterpret_cast<uint4*>(tmp + 8) = *reinterpret_cast<const uint4*>(src + 8);
#pragma unroll
      for (int j = 0; j < 16; j++) As[r][ch * 16 + j] = b2f(*reinterpret_cast<bf16*>(&tmp[j]));
    } else {
#pragma unroll
      for (int j = 0; j < 16; j++) As[r][ch * 16 + j] = 0.f;
    }
  }
  __syncthreads();
  int nd = t & 63, fq = t >> 6;
  float acc[8];
#pragma unroll
  for (int j = 0; j < 8; j++) acc[j] = bs[fq * 8 + j];
  for (int i = 0; i < 64; i++) {
    float a = As[nd][i];
#pragma unroll
    for (int j = 0; j < 8; j++) acc[j] += a * Ws[i * 32 + fq * 8 + j];
  }
  bool valid = (n0 + nd) < nodes;
#pragma unroll
  for (int j = 0; j < 8; j++) {
    float v = valid ? fmaxf(acc[j], 0.f) : 0.f;
    outT[(size_t)(g * 32 + fq * 8 + j) * Kp + n0 + nd] = f2b(v);
  }
}

// ---------------- masked incidence ----------------
__global__ __launch_bounds__(256) void k_mat(const float* __restrict__ w, const float* __restrict__ p,
                                             const float* __restrict__ inci, bf16* __restrict__ mat,
                                             int rows, int K, int Kp) {
  int i = blockIdx.x * 256 + threadIdx.x;
  if (i >= rows * Kp) return;
  int row = i / Kp, k = i % Kp;
  float v = 0.f;
  if (k < K) {
    size_t o = (size_t)row * K + k;
    v = w[o] * fabsf(inci[o]) + p[o];
  }
  mat[i] = f2b(v);
}

__global__ void k_matT(const float* __restrict__ w, const float* __restrict__ p,
                       const float* __restrict__ inci, bf16* __restrict__ mat) {
  __shared__ float tl[32][33];
  int e0 = blockIdx.x * 32, n0 = blockIdx.y * 32;
  for (int r = threadIdx.y; r < 32; r += 8) {
    int n = n0 + r, e = e0 + threadIdx.x;
    tl[r][threadIdx.x] = (n < N_ && e < E_) ? fabsf(inci[(size_t)n * E_ + e]) : 0.f;
  }
  __syncthreads();
  for (int r = threadIdx.y; r < 32; r += 8) {
    int e = e0 + r, n = n0 + threadIdx.x;
    if (e < E_ && n < KPE) {
      size_t o = (size_t)e * N_ + n;
      mat[(size_t)e * KPE + n] = (n < N_) ? f2b(tl[threadIdx.x][r] * w[o] + p[o]) : f2b(0.f);
    }
  }
}

// ---------------- 64x64-tile MFMA GEMM, depth-4 pipeline + XCD swizzle (einsums) ----------
__global__ __launch_bounds__(256) void k_mgemm64(const bf16* __restrict__ A0, const bf16* __restrict__ Bt,
                                                 bf16* __restrict__ Cp, int Mm, int Kp, int Nn, int gy) {
  __shared__ __align__(16) short As[4][4][64][8];
  __shared__ __align__(16) short Bs[4][4][64][8];
  int tid = threadIdx.x;
  int nwg = gridDim.x;
  int bid = blockIdx.x;
  int l = (bid & 7) * (nwg >> 3) + (bid >> 3);
  int bm = (l % gy) * 64, bn = (l / gy) * 64;
  int lane = tid & 63, wid = tid >> 6;
  int wr = wid >> 1, wc = wid & 1;
  f32x4 acc[2][2];
#pragma unroll
  for (int i = 0; i < 2; i++)
#pragma unroll
    for (int j = 0; j < 2; j++) acc[i][j] = f32x4{0.f, 0.f, 0.f, 0.f};

  const int sr = tid >> 2;
  const int sc = tid & 3;
  const int kb = lane >> 4, lr = lane & 15;
  const int gmA = bm + sr, gnB = bn + sr;
  const bool va_ok = (gmA < Mm), vb_ok = (gnB < Nn);
  const bf16* ap = A0 + (size_t)gmA * Kp + sc * 8;
  const bf16* bp = Bt + (size_t)gnB * Kp + sc * 8;
  const uint4 z4 = {0, 0, 0, 0};
  const int P = Kp >> 5;

  uint4 va0 = va_ok ? *reinterpret_cast<const uint4*>(ap) : z4;
  uint4 vb0 = vb_ok ? *reinterpret_cast<const uint4*>(bp) : z4;
  uint4 va1 = va_ok ? *reinterpret_cast<const uint4*>(ap + 32) : z4;
  uint4 vb1 = vb_ok ? *reinterpret_cast<const uint4*>(bp + 32) : z4;
  *reinterpret_cast<uint4*>(&As[0][sc][sr][0]) = va0;
  *reinterpret_cast<uint4*>(&Bs[0][sc][sr][0]) = vb0;
  uint4 va2 = va_ok ? *reinterpret_cast<const uint4*>(ap + 64) : z4;
  uint4 vb2 = vb_ok ? *reinterpret_cast<const uint4*>(bp + 64) : z4;
  __syncthreads();

  for (int p = 0; p < P; p += 2) {
    *reinterpret_cast<uint4*>(&As[(p + 1) & 3][sc][sr][0]) = va1;
    *reinterpret_cast<uint4*>(&Bs[(p + 1) & 3][sc][sr][0]) = vb1;
    if (p + 3 < P) {
      va1 = va_ok ? *reinterpret_cast<const uint4*>(ap + (p + 3) * 32) : z4;
      vb1 = vb_ok ? *reinterpret_cast<const uint4*>(bp + (p + 3) * 32) : z4;
    }
    {
      int bf = p & 3;
      short8v a0 = *reinterpret_cast<const short8v*>(&As[bf][kb][wr * 32 + lr][0]);
      short8v a1 = *reinterpret_cast<const short8v*>(&As[bf][kb][wr * 32 + 16 + lr][0]);
      short8v b0 = *reinterpret_cast<const short8v*>(&Bs[bf][kb][wc * 32 + lr][0]);
      short8v b1 = *reinterpret_cast<const short8v*>(&Bs[bf][kb][wc * 32 + 16 + lr][0]);
      __builtin_amdgcn_s_setprio(1);
      acc[0][0] = __builtin_amdgcn_mfma_f32_16x16x32_bf16(a0, b0, acc[0][0], 0, 0, 0);
      acc[0][1] = __builtin_amdgcn_mfma_f32_16x16x32_bf16(a0, b1, acc[0][1], 0, 0, 0);
      acc[1][0] = __builtin_amdgcn_mfma_f32_16x16x32_bf16(a1, b0, acc[1][0], 0, 0, 0);
      acc[1][1] = __builtin_amdgcn_mfma_f32_16x16x32_bf16(a1, b1, acc[1][1], 0, 0, 0);
      __builtin_amdgcn_s_setprio(0);
    }
    __syncthreads();
    *reinterpret_cast<uint4*>(&As[(p + 2) & 3][sc][sr][0]) = va2;
    *reinterpret_cast<uint4*>(&Bs[(p + 2) & 3][sc][sr][0]) = vb2;
    if (p + 4 < P) {
      va2 = va_ok ? *reinterpret_cast<const uint4*>(ap + (p + 4) * 32) : z4;
      vb2 = vb_ok ? *reinterpret_cast<const uint4*>(bp + (p + 4) * 32) : z4;
    }
    {
      int bf = (p + 1) & 3;
      short8v a0 = *reinterpret_cast<const short8v*>(&As[bf][kb][wr * 32 + lr][0]);
      short8v a1 = *reinterpret_cast<const short8v*>(&As[bf][kb][wr * 32 + 16 + lr][0]);
      short8v b0 = *reinterpret_cast<const short8v*>(&Bs[bf][kb][wc * 32 + lr][0]);
      short8v b1 = *reinterpret_cast<const short8v*>(&Bs[bf][kb][wc * 32 + 16 + lr][0]);
      __builtin_amdgcn_s_setprio(1);
      acc[0][0] = __builtin_amdgcn_mfma_f32_16x16x32_bf16(a0, b0, acc[0][0], 0, 0, 0);
      acc[0][1] = __builtin_amdgcn_mfma_f32_16x16x32_bf16(a0, b1, acc[0][1], 0, 0, 0);
      acc[1][0] = __builtin_amdgcn_mfma_f32_16x16x32_bf16(a1, b0, acc[1][0], 0, 0, 0);
      acc[1][1] = __builtin_amdgcn_mfma_f32_16x16x32_bf16(a1, b1, acc[1][1], 0, 0, 0);
      __builtin_amdgcn_s_setprio(0);
    }
    __syncthreads();
  }
#pragma unroll
  for (int mi = 0; mi < 2; mi++) {
    int r0 = bm + wr * 32 + mi * 16 + (lane >> 4) * 4;
#pragma unroll
    for (int ni = 0; ni < 2; ni++) {
      int col = bn + wc * 32 + ni * 16 + lr;
      if (col >= Nn) continue;
#pragma unroll
      for (int i = 0; i < 4; i++) {
        int r = r0 + i;
        if (r < Mm) Cp[(size_t)r * Nn + col] = f2b(acc[mi][ni][i]);
      }
    }
  }
}

// ---------------- single-stage MFMA GEMM for K<=96 (z / conc / res) ----------------
// Entire K staged once; ONE barrier; 2-3x8 MFMAs back-to-back. N fixed 64, BM=128.
// AMODE as before. In-place C==A0 safe iff gridDim.x==1. ESED: es/ed epilogue.
template <int AMODE, int KOCT, bool CF32b, bool ESED>
__global__ __launch_bounds__(256) void k_mgemm96(const bf16* __restrict__ A0, const bf16* __restrict__ A1,
                                                 const bf16* __restrict__ Bt, void* __restrict__ Cp,
                                                 int Mm, int nodes,
                                                 const float* __restrict__ bias, int relu,
                                                 const float* __restrict__ asv, const float* __restrict__ adv,
                                                 float* __restrict__ esOut, float* __restrict__ edOut) {
  constexpr int KP = KOCT * 8;
  __shared__ __align__(16) short As[KOCT][128][8];
  __shared__ __align__(16) short Bs[KOCT][64][8];
  __shared__ float smr[2][128][2];
  int tid = threadIdx.x;
  int bm = blockIdx.y * 128;
  int lane = tid & 63, wid = tid >> 6;
  int wr = wid >> 1, wc = wid & 1;
  const int kb = lane >> 4, lr = lane & 15;
  const uint4 z4 = {0, 0, 0, 0};

  // ---- stage A: thread (ar=tid>>1, ah=tid&1) loads KOCT/4 chunks of 16 k ----
  {
    int ar = tid >> 1, ah = tid & 1;
    int gm = bm + ar;
    bool ok = (gm < Mm);
    int gdiv = 0, gmod = 0;
    if (AMODE == 1 && ok) { gdiv = gm / nodes; gmod = gm % nodes; }
#pragma unroll
    for (int c = 0; c < KOCT / 4; c++) {
      int ks = c * 32 + ah * 16;
      uint4 va0 = z4, va1 = z4;
      if (ok) {
        const bf16* src;
        if (AMODE == 0) src = A0 + (size_t)gm * KP + ks;
        else if (ks < 64) src = A0 + (size_t)gm * 64 + ks;
        else if (AMODE == 1) src = A1 + ((size_t)gmod * G_ + gdiv) * 32 + (ks - 64);
        else src = A1 + (size_t)gm * 32 + (ks - 64);
        const uint4* p = reinterpret_cast<const uint4*>(src);
        va0 = p[0];
        va1 = p[1];
      }
      *reinterpret_cast<uint4*>(&As[c * 4 + ah * 2 + 0][ar][0]) = va0;
      *reinterpret_cast<uint4*>(&As[c * 4 + ah * 2 + 1][ar][0]) = va1;
    }
  }
  // ---- stage B: thread (br=tid>>2, bk=tid&3) loads KOCT/4 octets ----
  {
    int br = tid >> 2, bk = tid & 3;
#pragma unroll
    for (int c = 0; c < KOCT / 4; c++) {
      int o = c * 4 + bk;
      uint4 vb = *reinterpret_cast<const uint4*>(Bt + (size_t)br * KP + o * 8);
      *reinterpret_cast<uint4*>(&Bs[o][br][0]) = vb;
    }
  }
  __syncthreads();

  f32x4 acc[4][2];
#pragma unroll
  for (int i = 0; i < 4; i++)
#pragma unroll
    for (int j = 0; j < 2; j++) acc[i][j] = f32x4{0.f, 0.f, 0.f, 0.f};

#pragma unroll
  for (int c = 0; c < KOCT / 4; c++) {
    short8v a[4], b[2];
#pragma unroll
    for (int mi = 0; mi < 4; mi++)
      a[mi] = *reinterpret_cast<const short8v*>(&As[c * 4 + kb][wr * 64 + mi * 16 + lr][0]);
#pragma unroll
    for (int ni = 0; ni < 2; ni++)
      b[ni] = *reinterpret_cast<const short8v*>(&Bs[c * 4 + kb][wc * 32 + ni * 16 + lr][0]);
    __builtin_amdgcn_s_setprio(1);
#pragma unroll
    for (int mi = 0; mi < 4; mi++)
#pragma unroll
      for (int ni = 0; ni < 2; ni++)
        acc[mi][ni] = __builtin_amdgcn_mfma_f32_16x16x32_bf16(a[mi], b[ni], acc[mi][ni], 0, 0, 0);
    __builtin_amdgcn_s_setprio(0);
  }

#pragma unroll
  for (int mi = 0; mi < 4; mi++) {
    int r0 = bm + wr * 64 + mi * 16 + (lane >> 4) * 4;
#pragma unroll
    for (int ni = 0; ni < 2; ni++) {
      int col = wc * 32 + ni * 16 + lr;
      float bv = bias ? bias[col] : 0.f;
#pragma unroll
      for (int i = 0; i < 4; i++) {
        int r = r0 + i;
        if (r < Mm) {
          float v = acc[mi][ni][i] + bv;
          if (relu) v = fmaxf(v, 0.f);
          if (CF32b) ((float*)Cp)[(size_t)r * 64 + col] = v;
          else ((bf16*)Cp)[(size_t)r * 64 + col] = f2b(v);
        }
      }
    }
  }
  if (ESED) {
    float asc0 = asv[wc * 32 + lr];
    float asc1 = asv[wc * 32 + 16 + lr];
    float adc0 = adv[wc * 32 + lr];
    float adc1 = adv[wc * 32 + 16 + lr];
#pragma unroll
    for (int mi = 0; mi < 4; mi++) {
#pragma unroll
      for (int i = 0; i < 4; i++) {
        float pe = acc[mi][0][i] * asc0 + acc[mi][1][i] * asc1;
        float pd = acc[mi][0][i] * adc0 + acc[mi][1][i] * adc1;
#pragma unroll
        for (int o = 8; o; o >>= 1) { pe += __shfl_xor(pe, o); pd += __shfl_xor(pd, o); }
        if (lr == 0) {
          int rl = wr * 64 + mi * 16 + (lane >> 4) * 4 + i;
          smr[wc][rl][0] = pe;
          smr[wc][rl][1] = pd;
        }
      }
    }
    __syncthreads();
    if (tid < 128) {
      int r = bm + tid;
      if (r < Mm) {
        esOut[r] = smr[0][tid][0] + smr[1][tid][0];
        edOut[r] = smr[0][tid][1] + smr[1][tid][1];
      }
    }
  }
}

// ---------------- causal dilated conv: merged x/e grids, depth-4 pipeline ----------------
template <int DIL>
__global__ __launch_bounds__(256) void k_cgemm2(const bf16* __restrict__ Ax, bf16* __restrict__ Cx,
                                                int Mx, int nx, const bf16* __restrict__ Ae,
                                                bf16* __restrict__ Ce, int Me, int ne, int nbx,
                                                const bf16* __restrict__ Wc, const float* __restrict__ bias) {
  __shared__ __align__(16) short As[4][4][128][8];
  int tid = threadIdx.x;
  int bid = blockIdx.x;
  const bf16* A;
  bf16* C;
  int Mm, nodes, bm;
  if (bid < nbx) { A = Ax; C = Cx; Mm = Mx; nodes = nx; bm = bid * 128; }
  else { A = Ae; C = Ce; Mm = Me; nodes = ne; bm = (bid - nbx) * 128; }
  int lane = tid & 63, wid = tid >> 6;
  int wr = wid >> 1, wc = wid & 1;
  const int ar = tid >> 1, ah = tid & 1;
  const int kb = lane >> 4, lr = lane & 15;
  const int gm = bm + ar;
  const int t = (gm / nodes) % T_;
  const uint4 z4 = {0, 0, 0, 0};

  short8v bfr[3][2][2];
#pragma unroll
  for (int tap = 0; tap < 3; tap++)
#pragma unroll
    for (int kc = 0; kc < 2; kc++)
#pragma unroll
      for (int ni = 0; ni < 2; ni++) {
        int col = wc * 32 + ni * 16 + lr;
        bfr[tap][kc][ni] = *reinterpret_cast<const short8v*>(Wc + tap * 4096 + (size_t)col * 64 + kc * 32 + kb * 8);
      }

  f32x4 acc[4][2];
#pragma unroll
  for (int i = 0; i < 4; i++)
#pragma unroll
    for (int j = 0; j < 2; j++) acc[i][j] = f32x4{0.f, 0.f, 0.f, 0.f};

#define CG_LDA(p, vx, vy)                                                          \
  {                                                                                \
    const int sh_ = (((p) >> 1) - 2) * DIL;                                        \
    if ((gm < Mm) && (t + sh_ >= 0)) {                                             \
      const uint4* pp = reinterpret_cast<const uint4*>(                            \
          A + ((size_t)gm + (size_t)sh_ * nodes) * 64 + ((p) & 1) * 32 + ah * 16); \
      vx = pp[0];                                                                  \
      vy = pp[1];                                                                  \
    } else {                                                                       \
      vx = z4;                                                                     \
      vy = z4;                                                                     \
    }                                                                              \
  }
#define CG_WR(buf, vx, vy)                                     \
  *reinterpret_cast<uint4*>(&As[buf][ah * 2 + 0][ar][0]) = vx; \
  *reinterpret_cast<uint4*>(&As[buf][ah * 2 + 1][ar][0]) = vy;
#define CG_MFMA(q)                                                                                         \
  {                                                                                                        \
    short8v a0_ = *reinterpret_cast<const short8v*>(&As[(q) & 3][kb][wr * 64 + 0 + lr][0]);                \
    short8v a1_ = *reinterpret_cast<const short8v*>(&As[(q) & 3][kb][wr * 64 + 16 + lr][0]);               \
    short8v a2_ = *reinterpret_cast<const short8v*>(&As[(q) & 3][kb][wr * 64 + 32 + lr][0]);               \
    short8v a3_ = *reinterpret_cast<const short8v*>(&As[(q) & 3][kb][wr * 64 + 48 + lr][0]);               \
    __builtin_amdgcn_s_setprio(1);                                                                         \
    acc[0][0] = __builtin_amdgcn_mfma_f32_16x16x32_bf16(a0_, bfr[(q) >> 1][(q) & 1][0], acc[0][0], 0, 0, 0); \
    acc[0][1] = __builtin_amdgcn_mfma_f32_16x16x32_bf16(a0_, bfr[(q) >> 1][(q) & 1][1], acc[0][1], 0, 0, 0); \
    acc[1][0] = __builtin_amdgcn_mfma_f32_16x16x32_bf16(a1_, bfr[(q) >> 1][(q) & 1][0], acc[1][0], 0, 0, 0); \
    acc[1][1] = __builtin_amdgcn_mfma_f32_16x16x32_bf16(a1_, bfr[(q) >> 1][(q) & 1][1], acc[1][1], 0, 0, 0); \
    acc[2][0] = __builtin_amdgcn_mfma_f32_16x16x32_bf16(a2_, bfr[(q) >> 1][(q) & 1][0], acc[2][0], 0, 0, 0); \
    acc[2][1] = __builtin_amdgcn_mfma_f32_16x16x32_bf16(a2_, bfr[(q) >> 1][(q) & 1][1], acc[2][1], 0, 0, 0); \
    acc[3][0] = __builtin_amdgcn_mfma_f32_16x16x32_bf16(a3_, bfr[(q) >> 1][(q) & 1][0], acc[3][0], 0, 0, 0); \
    acc[3][1] = __builtin_amdgcn_mfma_f32_16x16x32_bf16(a3_, bfr[(q) >> 1][(q) & 1][1], acc[3][1], 0, 0, 0); \
    __builtin_amdgcn_s_setprio(0);                                                                         \
  }
#define CG_BODY(p, lastPair)                  \
  CG_WR(((p) + 1) & 3, r1x, r1y);             \
  if (!(lastPair)) CG_LDA((p) + 3, r1x, r1y); \
  CG_MFMA(p);                                 \
  __syncthreads();                            \
  CG_WR(((p) + 2) & 3, r2x, r2y);             \
  if (!(lastPair)) CG_LDA((p) + 4, r2x, r2y); \
  CG_MFMA((p) + 1);                           \
  __syncthreads();

  uint4 p0x, p0y, r1x, r1y, r2x, r2y;
  CG_LDA(0, p0x, p0y);
  CG_LDA(1, r1x, r1y);
  CG_WR(0, p0x, p0y);
  CG_LDA(2, r2x, r2y);
  __syncthreads();

  CG_BODY(0, false)
  CG_BODY(2, false)
  CG_BODY(4, true)

#undef CG_LDA
#undef CG_WR
#undef CG_MFMA
#undef CG_BODY

#pragma unroll
  for (int mi = 0; mi < 4; mi++) {
    int r0 = bm + wr * 64 + mi * 16 + (lane >> 4) * 4;
#pragma unroll
    for (int ni = 0; ni < 2; ni++) {
      int col = wc * 32 + ni * 16 + lr;
      float bv = bias[col];
#pragma unroll
      for (int i = 0; i < 4; i++) {
        int r = r0 + i;
        if (r < Mm) C[(size_t)r * 64 + col] = f2b(fmaxf(acc[mi][ni][i] + bv, 0.f));
      }
    }
  }
}

// ---------------- GAT softmax weights ----------------
__global__ __launch_bounds__(256) void k_gat_w(const float* __restrict__ es, const float* __restrict__ edv,
                                               const int* __restrict__ off, const int* __restrict__ adj,
                                               float* __restrict__ wgt, int nodes, int tot) {
  int idx = blockIdx.x * 256 + threadIdx.x;
  if (idx >= G_ * nodes) return;
  int g = idx / nodes, node = idx % nodes;
  int s0 = off[node], s1 = off[node + 1];
  const float* esg = es + (size_t)g * nodes;
  float edval = edv[(size_t)g * nodes + node];
  float m = -FLT_MAX;
  for (int s = s0; s < s1; s++) {
    float a = esg[adj[s]] + edval;
    a = (a >= 0.f) ? a : 0.2f * a;
    m = fmaxf(m, a);
  }
  float den = 0.f;
  float* wg = wgt + (size_t)g * tot;
  for (int s = s0; s < s1; s++) {
    float a = esg[adj[s]] + edval;
    a = (a >= 0.f) ? a : 0.2f * a;
    float ex = expf(a - m);
    den += ex;
    wg[s] = ex;
  }
  float inv = (s1 > s0) ? 1.f / den : 0.f;
  for (int s = s0; s < s1; s++) wg[s] *= inv;
}

// ---------------- GAT aggregation ----------------
__global__ __launch_bounds__(256) void k_gat_aggr3(const bf16* __restrict__ z, const float* __restrict__ wgt,
                                                   const int* __restrict__ off, const int* __restrict__ adj,
                                                   const float* __restrict__ bias, bf16* __restrict__ out,
                                                   int nodes, int tot) {
  int idx = blockIdx.x * 256 + threadIdx.x;
  if (idx >= G_ * nodes * 16) return;
  int c = idx & 15;
  int rest = idx >> 4;
  int node = rest % nodes;
  int g = rest / nodes;
  int s0 = off[node], s1 = off[node + 1];
  const bf16* zg = z + (size_t)g * nodes * 64 + c * 4;
  const float* wg = wgt + (size_t)g * tot;
  float n0 = 0.f, n1 = 0.f, n2 = 0.f, n3 = 0.f;
  for (int s = s0; s < s1; s++) {
    int src = adj[s];
    float w = wg[s];
    bf16 v[4];
    *reinterpret_cast<uint2*>(v) = *reinterpret_cast<const uint2*>(zg + (size_t)src * 64);
    n0 += w * b2f(v[0]);
    n1 += w * b2f(v[1]);
    n2 += w * b2f(v[2]);
    n3 += w * b2f(v[3]);
  }
  bf16 ov[4];
  ov[0] = f2b(fmaxf(n0 + bias[c * 4 + 0], 0.f));
  ov[1] = f2b(fmaxf(n1 + bias[c * 4 + 1], 0.f));
  ov[2] = f2b(fmaxf(n2 + bias[c * 4 + 2], 0.f));
  ov[3] = f2b(fmaxf(n3 + bias[c * 4 + 3], 0.f));
  *reinterpret_cast<uint2*>(out + (size_t)rest * 64 + c * 4) = *reinterpret_cast<uint2*>(ov);
}

// ---------------- fused CSR build ----------------
__global__ __launch_bounds__(1024) void k_csr(const int* __restrict__ indN, const int* __restrict__ indE,
                                              int* __restrict__ offN, int* __restrict__ adjN,
                                              int* __restrict__ offE, int* __restrict__ adjE) {
  __shared__ int cnt[2048];
  __shared__ int a[1024];
  const int* ind;
  int ner, nn;
  int *off, *adj;
  if (blockIdx.x == 0) { ind = indN; ner = E_; nn = N_; off = offN; adj = adjN; }
  else { ind = indE; ner = M_; nn = E_; off = offE; adj = adjE; }
  int tot = ner + nn;
  int t = threadIdx.x;
  for (int i = t; i < nn; i += 1024) cnt[i] = 0;
  __syncthreads();
  for (int i = t; i < tot; i += 1024) {
    int d = (i < ner) ? ind[ner + i] : (i - ner);
    if (d >= 0 && d < nn) atomicAdd(&cnt[d], 1);
  }
  __syncthreads();
  int c0 = (2 * t < nn) ? cnt[2 * t] : 0;
  int c1 = (2 * t + 1 < nn) ? cnt[2 * t + 1] : 0;
  a[t] = c0 + c1;
  __syncthreads();
  for (int d = 1; d < 1024; d <<= 1) {
    int u = (t >= d) ? a[t - d] : 0;
    __syncthreads();
    a[t] += u;
    __syncthreads();
  }
  int excl = (t > 0) ? a[t - 1] : 0;
  if (2 * t < nn) { cnt[2 * t] = excl; off[2 * t] = excl; }
  if (2 * t + 1 < nn) { cnt[2 * t + 1] = excl + c0; off[2 * t + 1] = excl + c0; }
  if (t == 0) off[nn] = a[1023];
  __syncthreads();
  for (int i = t; i < tot; i += 1024) {
    int s, d;
    if (i < ner) { s = ind[i]; d = ind[ner + i]; }
    else { s = d = i - ner; }
    if (d >= 0 && d < nn) {
      int pos = atomicAdd(&cnt[d], 1);
      adj[pos] = s;
    }
  }
}

// ---------------- cumsum + residual + relu + head (wave per (b,node), batched) ----------
template <bool XB>
__global__ __launch_bounds__(256) void k_out(const float* __restrict__ yx, const float* __restrict__ last,
                                             const float* __restrict__ oW, const float* __restrict__ ob_,
                                             float* __restrict__ dout, int nodes, int batches) {
  int wid = threadIdx.x >> 6, lane = threadIdx.x & 63;
  int idx = blockIdx.x * 4 + wid;
  if (idx >= batches * nodes) return;
  int b = idx / nodes, node = idx % nodes;
  const float* yb = yx + (size_t)b * T_ * nodes * 64;
  float lw = oW[lane];
  float ob = ob_[0];
  float lv = last[(size_t)idx * 64 + lane];
  float acc = 0.f;
  for (int tt = 0; tt < T_; tt++) {
    acc += yb[((size_t)tt * nodes + node) * 64 + lane];
    float v = fmaxf(acc + lv, 0.f);
    float p = v * lw;
#pragma unroll
    for (int o2 = 32; o2; o2 >>= 1) p += __shfl_down(p, o2);
    if (lane == 0) {
      float o = p + ob;
      if (XB) o = fminf(fmaxf(o / 6.f + 0.5f, 0.f), 1.f);
      else o = tanhf(o);
      dout[(size_t)b * T_ * nodes + (size_t)tt * nodes + node] = o;
    }
  }
}

// ===================================================================================
extern "C" void kernel_launch(void* const* d_in, const int* in_sizes, int n_in,
                              void* d_out, int out_size, void* d_ws, size_t ws_size,
                              hipStream_t stream) {
  float* dout = (float*)d_out;

  if (n_in != 57) {
    k_sentinel<<<ceilDiv(out_size, 256), 256, 0, stream>>>(dout, out_size, 20000.f + 128.f * n_in);
    return;
  }
  static const int expSz[57] = {
      288000, 288000, 288000, 288000,
      256, 64, 192, 64, 128, 32, 96, 32,
      3000000,
      12288, 128, 128, 128, 12288, 128, 128, 128,
      4096, 64, 6000000, 6000000, 4096, 64, 6000000, 6000000,
      24576, 128,
      12288, 128, 128, 128, 12288, 128, 128, 128,
      4096, 64, 6000000, 6000000, 4096, 64, 6000000, 6000000,
      24576, 128,
      6144, 64, 4096, 64, 64, 1, 4000, 8000};
  for (int i = 0; i < 57; i++) {
    if (in_sizes[i] != expSz[i]) {
      k_sentinel<<<ceilDiv(out_size, 256), 256, 0, stream>>>(dout, out_size, 4096.f + 64.f * i);
      return;
    }
  }

  auto ff = [&](int i) { return (const float*)d_in[i]; };
  const float *x_in = ff(0), *e_in = ff(1), *b_in = ff(2), *a_in = ff(3);
  const float *enc0W = ff(4), *enc0b = ff(5), *enc1W = ff(6), *enc1b = ff(7);
  const float *enc2W = ff(8), *enc2b = ff(9), *enc3W = ff(10), *enc3b = ff(11);
  const float* inci = ff(12);
  const float *concW = ff(49), *concb = ff(50), *resW = ff(51), *resb = ff(52);
  const float *outW = ff(53), *outb = ff(54);
  const int* edge_ind = (const int*)d_in[55];
  const int* node_ind = (const int*)d_in[56];

  // ---- workspace layout, 256B-aligned ----
  char* base = (char*)d_ws;
  size_t off = 0;
  auto A = [&](size_t bytes) { void* p = base + off; off = (off + bytes + 255) & ~(size_t)255; return p; };
  char* SCR = (char*)A(21504000);
  bf16* xbuf = (bf16*)A(9216000);
  bf16* ebuf = (bf16*)A(12288000);
  float* lastx = (float*)A(768000);
  float* laste = (float*)A(1024000);
  float* es = (float*)A(384000);
  float* edv = (float*)A(384000);
  float* wgt = (float*)A((size_t)G_ * (M_ + E_) * 4);
  bf16* wAll = (bf16*)A(217088);
  int* offN = (int*)A((N_ + 1) * 4);
  int* offE = (int*)A((E_ + 1) * 4);
  int* adjN = (int*)A((E_ + N_) * 4);
  int* adjE = (int*)A((M_ + E_) * 4);
  size_t required = off;

  if (ws_size < required) {
    k_sentinel<<<ceilDiv(out_size, 256), 256, 0, stream>>>(dout, out_size, 1000.f + (float)(ws_size >> 20));
    return;
  }

  // SCR aliases (liveness-checked)
  bf16* matb = (bf16*)SCR;
  bf16* tlinT = (bf16*)(SCR + 6553600);
  bf16* tmat = (bf16*)(SCR + 13107200);
  bf16* zbuf = (bf16*)SCR;
  bf16* bscr = (bf16*)SCR;
  bf16* cx1 = (bf16*)SCR;
  bf16* ce1 = (bf16*)(SCR + 9216000);
  float* zres = (float*)SCR;

  const int totN = E_ + N_;
  const int totE = M_ + E_;
  const int nbx = ceilDiv(G_ * N_, 128);  // 563
  const int nbe = ceilDiv(G_ * E_, 128);  // 750

  k_wprep<<<ceilDiv(108544, 256), 256, 0, stream>>>(ff(13), ff(17), ff(31), ff(35), concW, resW,
                                                    ff(29), ff(47), wAll);
  k_csr<<<2, 1024, 0, stream>>>(edge_ind, node_ind, offN, adjN, offE, adjE);

  k_enc<4, 64, true><<<ceilDiv(G_ * N_ * 64, 256), 256, 0, stream>>>(x_in, enc0W, enc0b, xbuf, lastx, N_);
  k_enc<3, 64, true><<<ceilDiv(G_ * E_ * 64, 256), 256, 0, stream>>>(e_in, enc1W, enc1b, ebuf, laste, E_);

  auto stblock = [&](int sb, int sbi) {
    const float *gxas = ff(sb + 1), *gxad = ff(sb + 2), *gxb = ff(sb + 3);
    const float *geas = ff(sb + 5), *gead = ff(sb + 6), *geb = ff(sb + 7);
    const float *neW = ff(sb + 8), *neb = ff(sb + 9), *nw = ff(sb + 10), *np_ = ff(sb + 11);
    const float *enW = ff(sb + 12), *enb = ff(sb + 13), *ew = ff(sb + 14), *ep = ff(sb + 15);
    const float* tpb = ff(sb + 17);
    for (int l = 0; l < 2; l++) {
      const bf16* gxw_t = wAll + sbi * 24576 + l * 6144;
      const bf16* gew_t = wAll + sbi * 24576 + 12288 + l * 6144;
      // ---- node side ----
      k_lin_neT<<<dim3(KPN / 64, G_), 256, 0, stream>>>(ebuf, neW + l * 2048, neb + l * 32, tlinT, E_, KPN);
      k_mat<<<ceilDiv(N_ * KPN, 256), 256, 0, stream>>>(nw + (size_t)l * N_ * E_, np_ + (size_t)l * N_ * E_, inci, matb, N_, E_, KPN);
      k_mgemm64<<<dim3(24 * 24), 256, 0, stream>>>(matb, tlinT, tmat, N_, KPN, 1536, 24);
      k_mgemm96<1, 12, false, true><<<dim3(1, nbx), 256, 0, stream>>>(
          xbuf, tmat, gxw_t, zbuf, G_ * N_, N_, nullptr, 0, gxas + l * 64, gxad + l * 64, es, edv);
      k_gat_w<<<ceilDiv(G_ * N_, 256), 256, 0, stream>>>(es, edv, offN, adjN, wgt, N_, totN);
      k_gat_aggr3<<<ceilDiv(G_ * N_ * 16, 256), 256, 0, stream>>>(zbuf, wgt, offN, adjN, gxb + l * 64, xbuf, N_, totN);
      // ---- edge side ----
      k_lin_neT<<<dim3(KPE / 64, G_), 256, 0, stream>>>(xbuf, enW + l * 2048, enb + l * 32, tlinT, N_, KPE);
      k_matT<<<dim3(ceilDiv(E_, 32), KPE / 32), dim3(32, 8), 0, stream>>>(ew + (size_t)l * E_ * N_, ep + (size_t)l * E_ * N_, inci, matb);
      k_mgemm64<<<dim3(24 * 32), 256, 0, stream>>>(matb, tlinT, tmat, E_, KPE, 1536, 32);
      k_mgemm96<1, 12, false, true><<<dim3(1, nbe), 256, 0, stream>>>(
          ebuf, tmat, gew_t, zbuf, G_ * E_, E_, nullptr, 0, geas + l * 64, gead + l * 64, es, edv);
      k_gat_w<<<ceilDiv(G_ * E_, 256), 256, 0, stream>>>(es, edv, offE, adjE, wgt, E_, totE);
      k_gat_aggr3<<<ceilDiv(G_ * E_ * 16, 256), 256, 0, stream>>>(zbuf, wgt, offE, adjE, geb + l * 64, ebuf, E_, totE);
    }
    // ---- temporal convs (merged x/e) ----
    const bf16* cw0 = wAll + 59392 + sbi * 24576;
    const bf16* cw1 = cw0 + 12288;
    k_cgemm2<1><<<nbx + nbe, 256, 0, stream>>>(xbuf, cx1, G_ * N_, N_, ebuf, ce1, G_ * E_, E_, nbx, cw0, tpb);
    k_cgemm2<2><<<nbx + nbe, 256, 0, stream>>>(cx1, xbuf, G_ * N_, N_, ce1, ebuf, G_ * E_, E_, nbx, cw1, tpb + 64);
  };

  stblock(13, 0);

  // ---- conc (shared weights; in-place: gridDim.x==1 row ownership) ----
  const bf16* concT = wAll + 49152;
  k_enc<4, 32, false><<<ceilDiv(G_ * N_ * 32, 256), 256, 0, stream>>>(b_in, enc2W, enc2b, bscr, nullptr, N_);
  k_mgemm96<2, 12, false, false><<<dim3(1, nbx), 256, 0, stream>>>(
      xbuf, bscr, concT, xbuf, G_ * N_, 0, concb, 1, nullptr, nullptr, nullptr, nullptr);
  k_enc<3, 32, false><<<ceilDiv(G_ * E_ * 32, 256), 256, 0, stream>>>(a_in, enc3W, enc3b, bscr, nullptr, E_);
  k_mgemm96<2, 12, false, false><<<dim3(1, nbe), 256, 0, stream>>>(
      ebuf, bscr, concT, ebuf, G_ * E_, 0, concb, 1, nullptr, nullptr, nullptr, nullptr);

  stblock(31, 1);

  // ---- final: N side in one pass (zres 18.4MB fits SCR), E side per batch ----
  const bf16* resT = wAll + 55296;
  k_mgemm96<0, 8, true, false><<<dim3(1, nbx), 256, 0, stream>>>(
      xbuf, nullptr, resT, zres, G_ * N_, 0, resb, 0, nullptr, nullptr, nullptr, nullptr);
  k_out<true><<<ceilDiv(B_ * N_, 4), 256, 0, stream>>>(zres, lastx, outW, outb, dout, N_, B_);
  for (int b = 0; b < B_; b++) {
    k_mgemm96<0, 8, true, false><<<dim3(1, ceilDiv(T_ * E_, 128)), 256, 0, stream>>>(
        ebuf + (size_t)b * T_ * E_ * 64, nullptr, resT, zres, T_ * E_, 0, resb, 0,
        nullptr, nullptr, nullptr, nullptr);
    k_out<false><<<ceilDiv(E_, 4), 256, 0, stream>>>(
        zres, laste + (size_t)b * E_ * 64, outW, outb, dout + (size_t)(B_ * T_ * N_) + (size_t)b * T_ * E_, E_, 1);
  }
}

// Round 17
// 952.699 us; speedup vs baseline: 5.1055x; 1.0692x over previous
//
#include <hip/hip_runtime.h>
#include <hip/hip_bf16.h>
#include <cfloat>
#include <math.h>

typedef __hip_bfloat16 bf16;
typedef __attribute__((ext_vector_type(8))) short short8v;
typedef __attribute__((ext_vector_type(4))) float f32x4;

constexpr int B_ = 2, T_ = 24, N_ = 1500, E_ = 2000, M_ = 4000, G_ = 48;
constexpr int KPN = 2048;
constexpr int KPE = 1536;

__device__ __forceinline__ float b2f(bf16 v) { return __bfloat162float(v); }
__device__ __forceinline__ bf16 f2b(float v) { return __float2bfloat16(v); }
static inline int ceilDiv(int a, int b) { return (a + b - 1) / b; }

// ---------------- diagnostics ----------------
__global__ __launch_bounds__(256) void k_sentinel(float* __restrict__ out, int n, float val) {
  int i = blockIdx.x * 256 + threadIdx.x;
  if (i < n) out[i] = val;
}

// ---------------- device bodies for the fused prologue ----------------
__device__ __forceinline__ void wprep_body(int i, const float* g0, const float* e0, const float* g1,
                                           const float* e1, const float* cw, const float* rw,
                                           const float* t0, const float* t1, bf16* out) {
  if (i >= 108544) return;
  float v;
  if (i < 49152) {
    int which = i / 12288, r = i % 12288;
    const float* W = which == 0 ? g0 : which == 1 ? e0 : which == 2 ? g1 : e1;
    int l = r / 6144, j = r % 6144;
    int n = j / 96, k = j % 96;
    v = W[l * 6144 + k * 64 + n];
  } else if (i < 55296) {
    int j = i - 49152, n = j / 96, k = j % 96;
    v = cw[k * 64 + n];
  } else if (i < 59392) {
    int j = i - 55296, n = j / 64, k = j % 64;
    v = rw[k * 64 + n];
  } else {
    int r = i - 59392;
    int which = r / 24576;
    const float* W = which ? t1 : t0;
    int rr = r % 24576;
    int l = rr / 12288, j = rr % 12288;
    int ii = j & 63, o = (j >> 6) & 63, k = j >> 12;
    v = W[l * 12288 + o * 192 + ii * 3 + k];
  }
  out[i] = f2b(v);
}

__device__ __forceinline__ void enc_body(int idx, int din, const float* in, const float* W,
                                         const float* bias, bf16* out, float* last, int nodes) {
  if (idx >= G_ * nodes * 64) return;
  int d = idx & 63;
  int row = idx >> 6;
  int node = row % nodes;
  int g = row / nodes;
  const float* ir = in + (size_t)row * din;
  float acc = bias[d];
  for (int i = 0; i < din; i++) acc += ir[i] * W[i * 64 + d];
  if (g % T_ == T_ - 1) last[((size_t)(g / T_) * nodes + node) * 64 + d] = acc;
  out[idx] = f2b(fmaxf(acc, 0.f));
}

// ---------------- fused prologue: wprep + enc(x) + enc(e) ----------------
constexpr int NB_W = (108544 + 255) / 256;          // 424
constexpr int NB_EX = G_ * N_ * 64 / 256;           // 18000
constexpr int NB_EE = G_ * E_ * 64 / 256;           // 24000
__global__ __launch_bounds__(256) void k_begin(const float* __restrict__ g0, const float* __restrict__ e0,
                                               const float* __restrict__ g1, const float* __restrict__ e1,
                                               const float* __restrict__ cw, const float* __restrict__ rw,
                                               const float* __restrict__ t0, const float* __restrict__ t1,
                                               bf16* __restrict__ wAll,
                                               const float* __restrict__ x_in, const float* __restrict__ encxW,
                                               const float* __restrict__ encxB, bf16* __restrict__ xbuf,
                                               float* __restrict__ lastx,
                                               const float* __restrict__ e_in, const float* __restrict__ enceW,
                                               const float* __restrict__ enceB, bf16* __restrict__ ebuf,
                                               float* __restrict__ laste) {
  int bid = blockIdx.x, tid = threadIdx.x;
  if (bid < NB_W) {
    wprep_body(bid * 256 + tid, g0, e0, g1, e1, cw, rw, t0, t1, wAll);
  } else if (bid < NB_W + NB_EX) {
    enc_body((bid - NB_W) * 256 + tid, 4, x_in, encxW, encxB, xbuf, lastx, N_);
  } else {
    enc_body((bid - NB_W - NB_EX) * 256 + tid, 3, e_in, enceW, enceB, ebuf, laste, E_);
  }
}

// ---------------- encoders (conc phase, no SAVE) ----------------
template <int DIN, int DOUT>
__global__ __launch_bounds__(256) void k_enc2(const float* __restrict__ in, const float* __restrict__ W,
                                              const float* __restrict__ bias, bf16* __restrict__ out,
                                              int nodes) {
  int idx = blockIdx.x * 256 + threadIdx.x;
  if (idx >= G_ * nodes * DOUT) return;
  int d = idx % DOUT;
  int row = idx / DOUT;
  const float* ir = in + (size_t)row * DIN;
  float acc = bias[d];
#pragma unroll
  for (int i = 0; i < DIN; i++) acc += ir[i] * W[i * DOUT + d];
  out[idx] = f2b(fmaxf(acc, 0.f));
}

// ---------------- device body: fused NodeEdge linear + transpose ----------------
__device__ __forceinline__ void lin_neT_body(float* sh, int g, int n0, int t, const bf16* act,
                                             const float* W, const float* bias, bf16* outT,
                                             int nodes, int Kp) {
  float* As = sh;             // [64][65]
  float* Ws = sh + 4160;      // [2048]
  float* bs = sh + 4160 + 2048;
  for (int i = t; i < 2048; i += 256) Ws[i] = W[i];
  if (t < 32) bs[t] = bias[t];
  {
    int r = t >> 2, ch = t & 3;
    int node = n0 + r;
    short tmp[16];
    if (node < nodes) {
      const bf16* src = act + ((size_t)g * nodes + node) * 64 + ch * 16;
      *reinterpret_cast<uint4*>(tmp) = *reinterpret_cast<const uint4*>(src);
      *reinterpret_cast<uint4*>(tmp + 8) = *reinterpret_cast<const uint4*>(src + 8);
#pragma unroll
      for (int j = 0; j < 16; j++) As[r * 65 + ch * 16 + j] = b2f(*reinterpret_cast<bf16*>(&tmp[j]));
    } else {
#pragma unroll
      for (int j = 0; j < 16; j++) As[r * 65 + ch * 16 + j] = 0.f;
    }
  }
  __syncthreads();
  int nd = t & 63, fq = t >> 6;
  float acc[8];
#pragma unroll
  for (int j = 0; j < 8; j++) acc[j] = bs[fq * 8 + j];
  for (int i = 0; i < 64; i++) {
    float a = As[nd * 65 + i];
#pragma unroll
    for (int j = 0; j < 8; j++) acc[j] += a * Ws[i * 32 + fq * 8 + j];
  }
  bool valid = (n0 + nd) < nodes;
#pragma unroll
  for (int j = 0; j < 8; j++) {
    float v = valid ? fmaxf(acc[j], 0.f) : 0.f;
    outT[(size_t)(g * 32 + fq * 8 + j) * Kp + n0 + nd] = f2b(v);
  }
}

// ---------------- fused node-side prep: lin_neT(ebuf) || mat ----------------
constexpr int NBL_N = (KPN / 64) * G_;                   // 1536
constexpr int NBM_N = (N_ * KPN + 255) / 256;            // 12000
__global__ __launch_bounds__(256) void k_prepN(const bf16* __restrict__ act, const float* __restrict__ W,
                                               const float* __restrict__ bias, bf16* __restrict__ outT,
                                               const float* __restrict__ w, const float* __restrict__ p,
                                               const float* __restrict__ inci, bf16* __restrict__ mat) {
  __shared__ float sh[4160 + 2048 + 32];
  int bid = blockIdx.x, tid = threadIdx.x;
  if (bid < NBL_N) {
    lin_neT_body(sh, bid / (KPN / 64), (bid % (KPN / 64)) * 64, tid, act, W, bias, outT, E_, KPN);
  } else {
    int i = (bid - NBL_N) * 256 + tid;
    if (i < N_ * KPN) {
      int row = i / KPN, k = i % KPN;
      float v = 0.f;
      if (k < E_) {
        size_t o = (size_t)row * E_ + k;
        v = w[o] * fabsf(inci[o]) + p[o];
      }
      mat[i] = f2b(v);
    }
  }
}

// ---------------- fused edge-side prep: lin_neT(xbuf) || matT ----------------
constexpr int NBL_E = (KPE / 64) * G_;                   // 1152
constexpr int NBT_E = 63 * (KPE / 32);                   // 63*48 = 3024
__global__ __launch_bounds__(256) void k_prepE(const bf16* __restrict__ act, const float* __restrict__ W,
                                               const float* __restrict__ bias, bf16* __restrict__ outT,
                                               const float* __restrict__ w, const float* __restrict__ p,
                                               const float* __restrict__ inci, bf16* __restrict__ mat) {
  __shared__ float sh[4160 + 2048 + 32];
  int bid = blockIdx.x, tid = threadIdx.x;
  if (bid < NBL_E) {
    lin_neT_body(sh, bid / (KPE / 64), (bid % (KPE / 64)) * 64, tid, act, W, bias, outT, N_, KPE);
  } else {
    float* tl = sh;  // [32][33]
    int mt = bid - NBL_E;
    int e0 = (mt % 63) * 32, n0 = (mt / 63) * 32;
    int tx = tid & 31, ty = tid >> 5;
    for (int r = ty; r < 32; r += 8) {
      int n = n0 + r, e = e0 + tx;
      tl[r * 33 + tx] = (n < N_ && e < E_) ? fabsf(inci[(size_t)n * E_ + e]) : 0.f;
    }
    __syncthreads();
    for (int r = ty; r < 32; r += 8) {
      int e = e0 + r, n = n0 + tx;
      if (e < E_ && n < KPE) {
        size_t o = (size_t)e * N_ + n;
        mat[(size_t)e * KPE + n] = (n < N_) ? f2b(tl[tx * 33 + r] * w[o] + p[o]) : f2b(0.f);
      }
    }
  }
}

// ---------------- 64x64-tile MFMA GEMM, depth-4 pipeline + XCD swizzle (einsums) ----------
__global__ __launch_bounds__(256) void k_mgemm64(const bf16* __restrict__ A0, const bf16* __restrict__ Bt,
                                                 bf16* __restrict__ Cp, int Mm, int Kp, int Nn, int gy) {
  __shared__ __align__(16) short As[4][4][64][8];
  __shared__ __align__(16) short Bs[4][4][64][8];
  int tid = threadIdx.x;
  int nwg = gridDim.x;
  int bid = blockIdx.x;
  int l = (bid & 7) * (nwg >> 3) + (bid >> 3);
  int bm = (l % gy) * 64, bn = (l / gy) * 64;
  int lane = tid & 63, wid = tid >> 6;
  int wr = wid >> 1, wc = wid & 1;
  f32x4 acc[2][2];
#pragma unroll
  for (int i = 0; i < 2; i++)
#pragma unroll
    for (int j = 0; j < 2; j++) acc[i][j] = f32x4{0.f, 0.f, 0.f, 0.f};

  const int sr = tid >> 2;
  const int sc = tid & 3;
  const int kb = lane >> 4, lr = lane & 15;
  const int gmA = bm + sr, gnB = bn + sr;
  const bool va_ok = (gmA < Mm), vb_ok = (gnB < Nn);
  const bf16* ap = A0 + (size_t)gmA * Kp + sc * 8;
  const bf16* bp = Bt + (size_t)gnB * Kp + sc * 8;
  const uint4 z4 = {0, 0, 0, 0};
  const int P = Kp >> 5;

  uint4 va0 = va_ok ? *reinterpret_cast<const uint4*>(ap) : z4;
  uint4 vb0 = vb_ok ? *reinterpret_cast<const uint4*>(bp) : z4;
  uint4 va1 = va_ok ? *reinterpret_cast<const uint4*>(ap + 32) : z4;
  uint4 vb1 = vb_ok ? *reinterpret_cast<const uint4*>(bp + 32) : z4;
  *reinterpret_cast<uint4*>(&As[0][sc][sr][0]) = va0;
  *reinterpret_cast<uint4*>(&Bs[0][sc][sr][0]) = vb0;
  uint4 va2 = va_ok ? *reinterpret_cast<const uint4*>(ap + 64) : z4;
  uint4 vb2 = vb_ok ? *reinterpret_cast<const uint4*>(bp + 64) : z4;
  __syncthreads();

  for (int p = 0; p < P; p += 2) {
    *reinterpret_cast<uint4*>(&As[(p + 1) & 3][sc][sr][0]) = va1;
    *reinterpret_cast<uint4*>(&Bs[(p + 1) & 3][sc][sr][0]) = vb1;
    if (p + 3 < P) {
      va1 = va_ok ? *reinterpret_cast<const uint4*>(ap + (p + 3) * 32) : z4;
      vb1 = vb_ok ? *reinterpret_cast<const uint4*>(bp + (p + 3) * 32) : z4;
    }
    {
      int bf = p & 3;
      short8v a0 = *reinterpret_cast<const short8v*>(&As[bf][kb][wr * 32 + lr][0]);
      short8v a1 = *reinterpret_cast<const short8v*>(&As[bf][kb][wr * 32 + 16 + lr][0]);
      short8v b0 = *reinterpret_cast<const short8v*>(&Bs[bf][kb][wc * 32 + lr][0]);
      short8v b1 = *reinterpret_cast<const short8v*>(&Bs[bf][kb][wc * 32 + 16 + lr][0]);
      __builtin_amdgcn_s_setprio(1);
      acc[0][0] = __builtin_amdgcn_mfma_f32_16x16x32_bf16(a0, b0, acc[0][0], 0, 0, 0);
      acc[0][1] = __builtin_amdgcn_mfma_f32_16x16x32_bf16(a0, b1, acc[0][1], 0, 0, 0);
      acc[1][0] = __builtin_amdgcn_mfma_f32_16x16x32_bf16(a1, b0, acc[1][0], 0, 0, 0);
      acc[1][1] = __builtin_amdgcn_mfma_f32_16x16x32_bf16(a1, b1, acc[1][1], 0, 0, 0);
      __builtin_amdgcn_s_setprio(0);
    }
    __syncthreads();
    *reinterpret_cast<uint4*>(&As[(p + 2) & 3][sc][sr][0]) = va2;
    *reinterpret_cast<uint4*>(&Bs[(p + 2) & 3][sc][sr][0]) = vb2;
    if (p + 4 < P) {
      va2 = va_ok ? *reinterpret_cast<const uint4*>(ap + (p + 4) * 32) : z4;
      vb2 = vb_ok ? *reinterpret_cast<const uint4*>(bp + (p + 4) * 32) : z4;
    }
    {
      int bf = (p + 1) & 3;
      short8v a0 = *reinterpret_cast<const short8v*>(&As[bf][kb][wr * 32 + lr][0]);
      short8v a1 = *reinterpret_cast<const short8v*>(&As[bf][kb][wr * 32 + 16 + lr][0]);
      short8v b0 = *reinterpret_cast<const short8v*>(&Bs[bf][kb][wc * 32 + lr][0]);
      short8v b1 = *reinterpret_cast<const short8v*>(&Bs[bf][kb][wc * 32 + 16 + lr][0]);
      __builtin_amdgcn_s_setprio(1);
      acc[0][0] = __builtin_amdgcn_mfma_f32_16x16x32_bf16(a0, b0, acc[0][0], 0, 0, 0);
      acc[0][1] = __builtin_amdgcn_mfma_f32_16x16x32_bf16(a0, b1, acc[0][1], 0, 0, 0);
      acc[1][0] = __builtin_amdgcn_mfma_f32_16x16x32_bf16(a1, b0, acc[1][0], 0, 0, 0);
      acc[1][1] = __builtin_amdgcn_mfma_f32_16x16x32_bf16(a1, b1, acc[1][1], 0, 0, 0);
      __builtin_amdgcn_s_setprio(0);
    }
    __syncthreads();
  }
#pragma unroll
  for (int mi = 0; mi < 2; mi++) {
    int r0 = bm + wr * 32 + mi * 16 + (lane >> 4) * 4;
#pragma unroll
    for (int ni = 0; ni < 2; ni++) {
      int col = bn + wc * 32 + ni * 16 + lr;
      if (col >= Nn) continue;
#pragma unroll
      for (int i = 0; i < 4; i++) {
        int r = r0 + i;
        if (r < Mm) Cp[(size_t)r * Nn + col] = f2b(acc[mi][ni][i]);
      }
    }
  }
}

// ---------------- single-stage MFMA GEMM for K<=96 (z / conc / res) ----------------
template <int AMODE, int KOCT, bool CF32b, bool ESED>
__global__ __launch_bounds__(256) void k_mgemm96(const bf16* __restrict__ A0, const bf16* __restrict__ A1,
                                                 const bf16* __restrict__ Bt, void* __restrict__ Cp,
                                                 int Mm, int nodes,
                                                 const float* __restrict__ bias, int relu,
                                                 const float* __restrict__ asv, const float* __restrict__ adv,
                                                 float* __restrict__ esOut, float* __restrict__ edOut) {
  constexpr int KP = KOCT * 8;
  __shared__ __align__(16) short As[KOCT][128][8];
  __shared__ __align__(16) short Bs[KOCT][64][8];
  __shared__ float smr[2][128][2];
  int tid = threadIdx.x;
  int bm = blockIdx.y * 128;
  int lane = tid & 63, wid = tid >> 6;
  int wr = wid >> 1, wc = wid & 1;
  const int kb = lane >> 4, lr = lane & 15;
  const uint4 z4 = {0, 0, 0, 0};

  {
    int ar = tid >> 1, ah = tid & 1;
    int gm = bm + ar;
    bool ok = (gm < Mm);
    int gdiv = 0, gmod = 0;
    if (AMODE == 1 && ok) { gdiv = gm / nodes; gmod = gm % nodes; }
#pragma unroll
    for (int c = 0; c < KOCT / 4; c++) {
      int ks = c * 32 + ah * 16;
      uint4 va0 = z4, va1 = z4;
      if (ok) {
        const bf16* src;
        if (AMODE == 0) src = A0 + (size_t)gm * KP + ks;
        else if (ks < 64) src = A0 + (size_t)gm * 64 + ks;
        else if (AMODE == 1) src = A1 + ((size_t)gmod * G_ + gdiv) * 32 + (ks - 64);
        else src = A1 + (size_t)gm * 32 + (ks - 64);
        const uint4* p = reinterpret_cast<const uint4*>(src);
        va0 = p[0];
        va1 = p[1];
      }
      *reinterpret_cast<uint4*>(&As[c * 4 + ah * 2 + 0][ar][0]) = va0;
      *reinterpret_cast<uint4*>(&As[c * 4 + ah * 2 + 1][ar][0]) = va1;
    }
  }
  {
    int br = tid >> 2, bk = tid & 3;
#pragma unroll
    for (int c = 0; c < KOCT / 4; c++) {
      int o = c * 4 + bk;
      uint4 vb = *reinterpret_cast<const uint4*>(Bt + (size_t)br * KP + o * 8);
      *reinterpret_cast<uint4*>(&Bs[o][br][0]) = vb;
    }
  }
  __syncthreads();

  f32x4 acc[4][2];
#pragma unroll
  for (int i = 0; i < 4; i++)
#pragma unroll
    for (int j = 0; j < 2; j++) acc[i][j] = f32x4{0.f, 0.f, 0.f, 0.f};

#pragma unroll
  for (int c = 0; c < KOCT / 4; c++) {
    short8v a[4], b[2];
#pragma unroll
    for (int mi = 0; mi < 4; mi++)
      a[mi] = *reinterpret_cast<const short8v*>(&As[c * 4 + kb][wr * 64 + mi * 16 + lr][0]);
#pragma unroll
    for (int ni = 0; ni < 2; ni++)
      b[ni] = *reinterpret_cast<const short8v*>(&Bs[c * 4 + kb][wc * 32 + ni * 16 + lr][0]);
    __builtin_amdgcn_s_setprio(1);
#pragma unroll
    for (int mi = 0; mi < 4; mi++)
#pragma unroll
      for (int ni = 0; ni < 2; ni++)
        acc[mi][ni] = __builtin_amdgcn_mfma_f32_16x16x32_bf16(a[mi], b[ni], acc[mi][ni], 0, 0, 0);
    __builtin_amdgcn_s_setprio(0);
  }

#pragma unroll
  for (int mi = 0; mi < 4; mi++) {
    int r0 = bm + wr * 64 + mi * 16 + (lane >> 4) * 4;
#pragma unroll
    for (int ni = 0; ni < 2; ni++) {
      int col = wc * 32 + ni * 16 + lr;
      float bv = bias ? bias[col] : 0.f;
#pragma unroll
      for (int i = 0; i < 4; i++) {
        int r = r0 + i;
        if (r < Mm) {
          float v = acc[mi][ni][i] + bv;
          if (relu) v = fmaxf(v, 0.f);
          if (CF32b) ((float*)Cp)[(size_t)r * 64 + col] = v;
          else ((bf16*)Cp)[(size_t)r * 64 + col] = f2b(v);
        }
      }
    }
  }
  if (ESED) {
    float asc0 = asv[wc * 32 + lr];
    float asc1 = asv[wc * 32 + 16 + lr];
    float adc0 = adv[wc * 32 + lr];
    float adc1 = adv[wc * 32 + 16 + lr];
#pragma unroll
    for (int mi = 0; mi < 4; mi++) {
#pragma unroll
      for (int i = 0; i < 4; i++) {
        float pe = acc[mi][0][i] * asc0 + acc[mi][1][i] * asc1;
        float pd = acc[mi][0][i] * adc0 + acc[mi][1][i] * adc1;
#pragma unroll
        for (int o = 8; o; o >>= 1) { pe += __shfl_xor(pe, o); pd += __shfl_xor(pd, o); }
        if (lr == 0) {
          int rl = wr * 64 + mi * 16 + (lane >> 4) * 4 + i;
          smr[wc][rl][0] = pe;
          smr[wc][rl][1] = pd;
        }
      }
    }
    __syncthreads();
    if (tid < 128) {
      int r = bm + tid;
      if (r < Mm) {
        esOut[r] = smr[0][tid][0] + smr[1][tid][0];
        edOut[r] = smr[0][tid][1] + smr[1][tid][1];
      }
    }
  }
}

// ---------------- causal dilated conv: merged x/e grids, depth-4 pipeline ----------------
template <int DIL>
__global__ __launch_bounds__(256) void k_cgemm2(const bf16* __restrict__ Ax, bf16* __restrict__ Cx,
                                                int Mx, int nx, const bf16* __restrict__ Ae,
                                                bf16* __restrict__ Ce, int Me, int ne, int nbx,
                                                const bf16* __restrict__ Wc, const float* __restrict__ bias) {
  __shared__ __align__(16) short As[4][4][128][8];
  int tid = threadIdx.x;
  int bid = blockIdx.x;
  const bf16* A;
  bf16* C;
  int Mm, nodes, bm;
  if (bid < nbx) { A = Ax; C = Cx; Mm = Mx; nodes = nx; bm = bid * 128; }
  else { A = Ae; C = Ce; Mm = Me; nodes = ne; bm = (bid - nbx) * 128; }
  int lane = tid & 63, wid = tid >> 6;
  int wr = wid >> 1, wc = wid & 1;
  const int ar = tid >> 1, ah = tid & 1;
  const int kb = lane >> 4, lr = lane & 15;
  const int gm = bm + ar;
  const int t = (gm / nodes) % T_;
  const uint4 z4 = {0, 0, 0, 0};

  short8v bfr[3][2][2];
#pragma unroll
  for (int tap = 0; tap < 3; tap++)
#pragma unroll
    for (int kc = 0; kc < 2; kc++)
#pragma unroll
      for (int ni = 0; ni < 2; ni++) {
        int col = wc * 32 + ni * 16 + lr;
        bfr[tap][kc][ni] = *reinterpret_cast<const short8v*>(Wc + tap * 4096 + (size_t)col * 64 + kc * 32 + kb * 8);
      }

  f32x4 acc[4][2];
#pragma unroll
  for (int i = 0; i < 4; i++)
#pragma unroll
    for (int j = 0; j < 2; j++) acc[i][j] = f32x4{0.f, 0.f, 0.f, 0.f};

#define CG_LDA(p, vx, vy)                                                          \
  {                                                                                \
    const int sh_ = (((p) >> 1) - 2) * DIL;                                        \
    if ((gm < Mm) && (t + sh_ >= 0)) {                                             \
      const uint4* pp = reinterpret_cast<const uint4*>(                            \
          A + ((size_t)gm + (size_t)sh_ * nodes) * 64 + ((p) & 1) * 32 + ah * 16); \
      vx = pp[0];                                                                  \
      vy = pp[1];                                                                  \
    } else {                                                                       \
      vx = z4;                                                                     \
      vy = z4;                                                                     \
    }                                                                              \
  }
#define CG_WR(buf, vx, vy)                                     \
  *reinterpret_cast<uint4*>(&As[buf][ah * 2 + 0][ar][0]) = vx; \
  *reinterpret_cast<uint4*>(&As[buf][ah * 2 + 1][ar][0]) = vy;
#define CG_MFMA(q)                                                                                         \
  {                                                                                                        \
    short8v a0_ = *reinterpret_cast<const short8v*>(&As[(q) & 3][kb][wr * 64 + 0 + lr][0]);                \
    short8v a1_ = *reinterpret_cast<const short8v*>(&As[(q) & 3][kb][wr * 64 + 16 + lr][0]);               \
    short8v a2_ = *reinterpret_cast<const short8v*>(&As[(q) & 3][kb][wr * 64 + 32 + lr][0]);               \
    short8v a3_ = *reinterpret_cast<const short8v*>(&As[(q) & 3][kb][wr * 64 + 48 + lr][0]);               \
    __builtin_amdgcn_s_setprio(1);                                                                         \
    acc[0][0] = __builtin_amdgcn_mfma_f32_16x16x32_bf16(a0_, bfr[(q) >> 1][(q) & 1][0], acc[0][0], 0, 0, 0); \
    acc[0][1] = __builtin_amdgcn_mfma_f32_16x16x32_bf16(a0_, bfr[(q) >> 1][(q) & 1][1], acc[0][1], 0, 0, 0); \
    acc[1][0] = __builtin_amdgcn_mfma_f32_16x16x32_bf16(a1_, bfr[(q) >> 1][(q) & 1][0], acc[1][0], 0, 0, 0); \
    acc[1][1] = __builtin_amdgcn_mfma_f32_16x16x32_bf16(a1_, bfr[(q) >> 1][(q) & 1][1], acc[1][1], 0, 0, 0); \
    acc[2][0] = __builtin_amdgcn_mfma_f32_16x16x32_bf16(a2_, bfr[(q) >> 1][(q) & 1][0], acc[2][0], 0, 0, 0); \
    acc[2][1] = __builtin_amdgcn_mfma_f32_16x16x32_bf16(a2_, bfr[(q) >> 1][(q) & 1][1], acc[2][1], 0, 0, 0); \
    acc[3][0] = __builtin_amdgcn_mfma_f32_16x16x32_bf16(a3_, bfr[(q) >> 1][(q) & 1][0], acc[3][0], 0, 0, 0); \
    acc[3][1] = __builtin_amdgcn_mfma_f32_16x16x32_bf16(a3_, bfr[(q) >> 1][(q) & 1][1], acc[3][1], 0, 0, 0); \
    __builtin_amdgcn_s_setprio(0);                                                                         \
  }
#define CG_BODY(p, lastPair)                  \
  CG_WR(((p) + 1) & 3, r1x, r1y);             \
  if (!(lastPair)) CG_LDA((p) + 3, r1x, r1y); \
  CG_MFMA(p);                                 \
  __syncthreads();                            \
  CG_WR(((p) + 2) & 3, r2x, r2y);             \
  if (!(lastPair)) CG_LDA((p) + 4, r2x, r2y); \
  CG_MFMA((p) + 1);                           \
  __syncthreads();

  uint4 p0x, p0y, r1x, r1y, r2x, r2y;
  CG_LDA(0, p0x, p0y);
  CG_LDA(1, r1x, r1y);
  CG_WR(0, p0x, p0y);
  CG_LDA(2, r2x, r2y);
  __syncthreads();

  CG_BODY(0, false)
  CG_BODY(2, false)
  CG_BODY(4, true)

#undef CG_LDA
#undef CG_WR
#undef CG_MFMA
#undef CG_BODY

#pragma unroll
  for (int mi = 0; mi < 4; mi++) {
    int r0 = bm + wr * 64 + mi * 16 + (lane >> 4) * 4;
#pragma unroll
    for (int ni = 0; ni < 2; ni++) {
      int col = wc * 32 + ni * 16 + lr;
      float bv = bias[col];
#pragma unroll
      for (int i = 0; i < 4; i++) {
        int r = r0 + i;
        if (r < Mm) C[(size_t)r * 64 + col] = f2b(fmaxf(acc[mi][ni][i] + bv, 0.f));
      }
    }
  }
}

// ---------------- GAT softmax weights ----------------
__global__ __launch_bounds__(256) void k_gat_w(const float* __restrict__ es, const float* __restrict__ edv,
                                               const int* __restrict__ off, const int* __restrict__ adj,
                                               float* __restrict__ wgt, int nodes, int tot) {
  int idx = blockIdx.x * 256 + threadIdx.x;
  if (idx >= G_ * nodes) return;
  int g = idx / nodes, node = idx % nodes;
  int s0 = off[node], s1 = off[node + 1];
  const float* esg = es + (size_t)g * nodes;
  float edval = edv[(size_t)g * nodes + node];
  float m = -FLT_MAX;
  for (int s = s0; s < s1; s++) {
    float a = esg[adj[s]] + edval;
    a = (a >= 0.f) ? a : 0.2f * a;
    m = fmaxf(m, a);
  }
  float den = 0.f;
  float* wg = wgt + (size_t)g * tot;
  for (int s = s0; s < s1; s++) {
    float a = esg[adj[s]] + edval;
    a = (a >= 0.f) ? a : 0.2f * a;
    float ex = expf(a - m);
    den += ex;
    wg[s] = ex;
  }
  float inv = (s1 > s0) ? 1.f / den : 0.f;
  for (int s = s0; s < s1; s++) wg[s] *= inv;
}

// ---------------- GAT aggregation ----------------
__global__ __launch_bounds__(256) void k_gat_aggr3(const bf16* __restrict__ z, const float* __restrict__ wgt,
                                                   const int* __restrict__ off, const int* __restrict__ adj,
                                                   const float* __restrict__ bias, bf16* __restrict__ out,
                                                   int nodes, int tot) {
  int idx = blockIdx.x * 256 + threadIdx.x;
  if (idx >= G_ * nodes * 16) return;
  int c = idx & 15;
  int rest = idx >> 4;
  int node = rest % nodes;
  int g = rest / nodes;
  int s0 = off[node], s1 = off[node + 1];
  const bf16* zg = z + (size_t)g * nodes * 64 + c * 4;
  const float* wg = wgt + (size_t)g * tot;
  float n0 = 0.f, n1 = 0.f, n2 = 0.f, n3 = 0.f;
  for (int s = s0; s < s1; s++) {
    int src = adj[s];
    float w = wg[s];
    bf16 v[4];
    *reinterpret_cast<uint2*>(v) = *reinterpret_cast<const uint2*>(zg + (size_t)src * 64);
    n0 += w * b2f(v[0]);
    n1 += w * b2f(v[1]);
    n2 += w * b2f(v[2]);
    n3 += w * b2f(v[3]);
  }
  bf16 ov[4];
  ov[0] = f2b(fmaxf(n0 + bias[c * 4 + 0], 0.f));
  ov[1] = f2b(fmaxf(n1 + bias[c * 4 + 1], 0.f));
  ov[2] = f2b(fmaxf(n2 + bias[c * 4 + 2], 0.f));
  ov[3] = f2b(fmaxf(n3 + bias[c * 4 + 3], 0.f));
  *reinterpret_cast<uint2*>(out + (size_t)rest * 64 + c * 4) = *reinterpret_cast<uint2*>(ov);
}

// ---------------- fused CSR build ----------------
__global__ __launch_bounds__(1024) void k_csr(const int* __restrict__ indN, const int* __restrict__ indE,
                                              int* __restrict__ offN, int* __restrict__ adjN,
                                              int* __restrict__ offE, int* __restrict__ adjE) {
  __shared__ int cnt[2048];
  __shared__ int a[1024];
  const int* ind;
  int ner, nn;
  int *off, *adj;
  if (blockIdx.x == 0) { ind = indN; ner = E_; nn = N_; off = offN; adj = adjN; }
  else { ind = indE; ner = M_; nn = E_; off = offE; adj = adjE; }
  int tot = ner + nn;
  int t = threadIdx.x;
  for (int i = t; i < nn; i += 1024) cnt[i] = 0;
  __syncthreads();
  for (int i = t; i < tot; i += 1024) {
    int d = (i < ner) ? ind[ner + i] : (i - ner);
    if (d >= 0 && d < nn) atomicAdd(&cnt[d], 1);
  }
  __syncthreads();
  int c0 = (2 * t < nn) ? cnt[2 * t] : 0;
  int c1 = (2 * t + 1 < nn) ? cnt[2 * t + 1] : 0;
  a[t] = c0 + c1;
  __syncthreads();
  for (int d = 1; d < 1024; d <<= 1) {
    int u = (t >= d) ? a[t - d] : 0;
    __syncthreads();
    a[t] += u;
    __syncthreads();
  }
  int excl = (t > 0) ? a[t - 1] : 0;
  if (2 * t < nn) { cnt[2 * t] = excl; off[2 * t] = excl; }
  if (2 * t + 1 < nn) { cnt[2 * t + 1] = excl + c0; off[2 * t + 1] = excl + c0; }
  if (t == 0) off[nn] = a[1023];
  __syncthreads();
  for (int i = t; i < tot; i += 1024) {
    int s, d;
    if (i < ner) { s = ind[i]; d = ind[ner + i]; }
    else { s = d = i - ner; }
    if (d >= 0 && d < nn) {
      int pos = atomicAdd(&cnt[d], 1);
      adj[pos] = s;
    }
  }
}

// ---------------- cumsum + residual + relu + head ----------------
template <bool XB>
__global__ __launch_bounds__(256) void k_out(const float* __restrict__ yx, const float* __restrict__ last,
                                             const float* __restrict__ oW, const float* __restrict__ ob_,
                                             float* __restrict__ dout, int nodes, int batches) {
  int wid = threadIdx.x >> 6, lane = threadIdx.x & 63;
  int idx = blockIdx.x * 4 + wid;
  if (idx >= batches * nodes) return;
  int b = idx / nodes, node = idx % nodes;
  const float* yb = yx + (size_t)b * T_ * nodes * 64;
  float lw = oW[lane];
  float ob = ob_[0];
  float lv = last[(size_t)idx * 64 + lane];
  float acc = 0.f;
  for (int tt = 0; tt < T_; tt++) {
    acc += yb[((size_t)tt * nodes + node) * 64 + lane];
    float v = fmaxf(acc + lv, 0.f);
    float p = v * lw;
#pragma unroll
    for (int o2 = 32; o2; o2 >>= 1) p += __shfl_down(p, o2);
    if (lane == 0) {
      float o = p + ob;
      if (XB) o = fminf(fmaxf(o / 6.f + 0.5f, 0.f), 1.f);
      else o = tanhf(o);
      dout[(size_t)b * T_ * nodes + (size_t)tt * nodes + node] = o;
    }
  }
}

// ===================================================================================
extern "C" void kernel_launch(void* const* d_in, const int* in_sizes, int n_in,
                              void* d_out, int out_size, void* d_ws, size_t ws_size,
                              hipStream_t stream) {
  float* dout = (float*)d_out;

  if (n_in != 57) {
    k_sentinel<<<ceilDiv(out_size, 256), 256, 0, stream>>>(dout, out_size, 20000.f + 128.f * n_in);
    return;
  }
  static const int expSz[57] = {
      288000, 288000, 288000, 288000,
      256, 64, 192, 64, 128, 32, 96, 32,
      3000000,
      12288, 128, 128, 128, 12288, 128, 128, 128,
      4096, 64, 6000000, 6000000, 4096, 64, 6000000, 6000000,
      24576, 128,
      12288, 128, 128, 128, 12288, 128, 128, 128,
      4096, 64, 6000000, 6000000, 4096, 64, 6000000, 6000000,
      24576, 128,
      6144, 64, 4096, 64, 64, 1, 4000, 8000};
  for (int i = 0; i < 57; i++) {
    if (in_sizes[i] != expSz[i]) {
      k_sentinel<<<ceilDiv(out_size, 256), 256, 0, stream>>>(dout, out_size, 4096.f + 64.f * i);
      return;
    }
  }

  auto ff = [&](int i) { return (const float*)d_in[i]; };
  const float *x_in = ff(0), *e_in = ff(1), *b_in = ff(2), *a_in = ff(3);
  const float *enc0W = ff(4), *enc0b = ff(5), *enc1W = ff(6), *enc1b = ff(7);
  const float *enc2W = ff(8), *enc2b = ff(9), *enc3W = ff(10), *enc3b = ff(11);
  const float* inci = ff(12);
  const float *concW = ff(49), *concb = ff(50), *resW = ff(51), *resb = ff(52);
  const float *outW = ff(53), *outb = ff(54);
  const int* edge_ind = (const int*)d_in[55];
  const int* node_ind = (const int*)d_in[56];

  // ---- workspace layout, 256B-aligned ----
  char* base = (char*)d_ws;
  size_t off = 0;
  auto A = [&](size_t bytes) { void* p = base + off; off = (off + bytes + 255) & ~(size_t)255; return p; };
  char* SCR = (char*)A(21504000);
  bf16* xbuf = (bf16*)A(9216000);
  bf16* ebuf = (bf16*)A(12288000);
  float* lastx = (float*)A(768000);
  float* laste = (float*)A(1024000);
  float* es = (float*)A(384000);
  float* edv = (float*)A(384000);
  float* wgt = (float*)A((size_t)G_ * (M_ + E_) * 4);
  bf16* wAll = (bf16*)A(217088);
  int* offN = (int*)A((N_ + 1) * 4);
  int* offE = (int*)A((E_ + 1) * 4);
  int* adjN = (int*)A((E_ + N_) * 4);
  int* adjE = (int*)A((M_ + E_) * 4);
  size_t required = off;

  if (ws_size < required) {
    k_sentinel<<<ceilDiv(out_size, 256), 256, 0, stream>>>(dout, out_size, 1000.f + (float)(ws_size >> 20));
    return;
  }

  // SCR aliases (liveness-checked)
  bf16* matb = (bf16*)SCR;
  bf16* tlinT = (bf16*)(SCR + 6553600);
  bf16* tmat = (bf16*)(SCR + 13107200);
  bf16* zbuf = (bf16*)SCR;
  bf16* bscr = (bf16*)SCR;
  bf16* cx1 = (bf16*)SCR;
  bf16* ce1 = (bf16*)(SCR + 9216000);
  float* zres = (float*)SCR;

  const int totN = E_ + N_;
  const int totE = M_ + E_;
  const int nbx = ceilDiv(G_ * N_, 128);  // 563
  const int nbe = ceilDiv(G_ * E_, 128);  // 750

  // ---- fused prologue (wprep + enc x + enc e) and CSR ----
  k_begin<<<NB_W + NB_EX + NB_EE, 256, 0, stream>>>(
      ff(13), ff(17), ff(31), ff(35), concW, resW, ff(29), ff(47), wAll,
      x_in, enc0W, enc0b, xbuf, lastx, e_in, enc1W, enc1b, ebuf, laste);
  k_csr<<<2, 1024, 0, stream>>>(edge_ind, node_ind, offN, adjN, offE, adjE);

  auto stblock = [&](int sb, int sbi) {
    const float *gxas = ff(sb + 1), *gxad = ff(sb + 2), *gxb = ff(sb + 3);
    const float *geas = ff(sb + 5), *gead = ff(sb + 6), *geb = ff(sb + 7);
    const float *neW = ff(sb + 8), *neb = ff(sb + 9), *nw = ff(sb + 10), *np_ = ff(sb + 11);
    const float *enW = ff(sb + 12), *enb = ff(sb + 13), *ew = ff(sb + 14), *ep = ff(sb + 15);
    const float* tpb = ff(sb + 17);
    for (int l = 0; l < 2; l++) {
      const bf16* gxw_t = wAll + sbi * 24576 + l * 6144;
      const bf16* gew_t = wAll + sbi * 24576 + 12288 + l * 6144;
      // ---- node side: fused lin_neT || mat, then einsum, z, gat ----
      k_prepN<<<NBL_N + NBM_N, 256, 0, stream>>>(ebuf, neW + l * 2048, neb + l * 32, tlinT,
                                                 nw + (size_t)l * N_ * E_, np_ + (size_t)l * N_ * E_, inci, matb);
      k_mgemm64<<<dim3(24 * 24), 256, 0, stream>>>(matb, tlinT, tmat, N_, KPN, 1536, 24);
      k_mgemm96<1, 12, false, true><<<dim3(1, nbx), 256, 0, stream>>>(
          xbuf, tmat, gxw_t, zbuf, G_ * N_, N_, nullptr, 0, gxas + l * 64, gxad + l * 64, es, edv);
      k_gat_w<<<ceilDiv(G_ * N_, 256), 256, 0, stream>>>(es, edv, offN, adjN, wgt, N_, totN);
      k_gat_aggr3<<<ceilDiv(G_ * N_ * 16, 256), 256, 0, stream>>>(zbuf, wgt, offN, adjN, gxb + l * 64, xbuf, N_, totN);
      // ---- edge side: fused lin_neT || matT, then einsum, z, gat ----
      k_prepE<<<NBL_E + NBT_E, 256, 0, stream>>>(xbuf, enW + l * 2048, enb + l * 32, tlinT,
                                                 ew + (size_t)l * E_ * N_, ep + (size_t)l * E_ * N_, inci, matb);
      k_mgemm64<<<dim3(24 * 32), 256, 0, stream>>>(matb, tlinT, tmat, E_, KPE, 1536, 32);
      k_mgemm96<1, 12, false, true><<<dim3(1, nbe), 256, 0, stream>>>(
          ebuf, tmat, gew_t, zbuf, G_ * E_, E_, nullptr, 0, geas + l * 64, gead + l * 64, es, edv);
      k_gat_w<<<ceilDiv(G_ * E_, 256), 256, 0, stream>>>(es, edv, offE, adjE, wgt, E_, totE);
      k_gat_aggr3<<<ceilDiv(G_ * E_ * 16, 256), 256, 0, stream>>>(zbuf, wgt, offE, adjE, geb + l * 64, ebuf, E_, totE);
    }
    // ---- temporal convs (merged x/e) ----
    const bf16* cw0 = wAll + 59392 + sbi * 24576;
    const bf16* cw1 = cw0 + 12288;
    k_cgemm2<1><<<nbx + nbe, 256, 0, stream>>>(xbuf, cx1, G_ * N_, N_, ebuf, ce1, G_ * E_, E_, nbx, cw0, tpb);
    k_cgemm2<2><<<nbx + nbe, 256, 0, stream>>>(cx1, xbuf, G_ * N_, N_, ce1, ebuf, G_ * E_, E_, nbx, cw1, tpb + 64);
  };

  stblock(13, 0);

  // ---- conc (shared weights; in-place: gridDim.x==1 row ownership) ----
  const bf16* concT = wAll + 49152;
  k_enc2<4, 32><<<ceilDiv(G_ * N_ * 32, 256), 256, 0, stream>>>(b_in, enc2W, enc2b, bscr, N_);
  k_mgemm96<2, 12, false, false><<<dim3(1, nbx), 256, 0, stream>>>(
      xbuf, bscr, concT, xbuf, G_ * N_, 0, concb, 1, nullptr, nullptr, nullptr, nullptr);
  k_enc2<3, 32><<<ceilDiv(G_ * E_ * 32, 256), 256, 0, stream>>>(a_in, enc3W, enc3b, bscr, E_);
  k_mgemm96<2, 12, false, false><<<dim3(1, nbe), 256, 0, stream>>>(
      ebuf, bscr, concT, ebuf, G_ * E_, 0, concb, 1, nullptr, nullptr, nullptr, nullptr);

  stblock(31, 1);

  // ---- final: N side in one pass, E side per batch ----
  const bf16* resT = wAll + 55296;
  k_mgemm96<0, 8, true, false><<<dim3(1, nbx), 256, 0, stream>>>(
      xbuf, nullptr, resT, zres, G_ * N_, 0, resb, 0, nullptr, nullptr, nullptr, nullptr);
  k_out<true><<<ceilDiv(B_ * N_, 4), 256, 0, stream>>>(zres, lastx, outW, outb, dout, N_, B_);
  for (int b = 0; b < B_; b++) {
    k_mgemm96<0, 8, true, false><<<dim3(1, ceilDiv(T_ * E_, 128)), 256, 0, stream>>>(
        ebuf + (size_t)b * T_ * E_ * 64, nullptr, resT, zres, T_ * E_, 0, resb, 0,
        nullptr, nullptr, nullptr, nullptr);
    k_out<false><<<ceilDiv(E_, 4), 256, 0, stream>>>(
        zres, laste + (size_t)b * E_ * 64, outW, outb, dout + (size_t)(B_ * T_ * N_) + (size_t)b * T_ * E_, E_, 1);
  }
}